// Round 1
// 739.053 us; speedup vs baseline: 1.0444x; 1.0444x over previous
//
#include <hip/hip_runtime.h>
#include <hip/hip_bf16.h>

typedef __hip_bfloat16 bf16;
typedef unsigned short ush;

static constexpr int kN   = 4096;    // nodes
static constexpr int kND  = 256;     // hidden
static constexpr int kEL  = 131072;  // local edges
static constexpr int kED  = 32;      // edge dim
static constexpr int kELG = 262144;  // line-graph edges
static constexpr int kL   = 2;
static constexpr float kScaleN = 0.17677669529663687f; // 1/sqrt(32)

using frag_ab = __attribute__((ext_vector_type(8))) short;   // 8 bf16 (4 VGPRs)
using frag_cd = __attribute__((ext_vector_type(4))) float;   // 4 fp32

__device__ __forceinline__ float ldf(const void* p, size_t i, int isbf){
    return isbf ? __bfloat162float(((const bf16*)p)[i]) : ((const float*)p)[i];
}
__device__ __forceinline__ ush f2b(float f){ bf16 h = __float2bfloat16(f); return *(ush*)&h; }
__device__ __forceinline__ float b2f(ush u){ return __uint_as_float(((unsigned)u)<<16); }
__device__ __forceinline__ ush ldb(const void* p, size_t i, int isbf){
    return isbf ? ((const ush*)p)[i] : f2b(((const float*)p)[i]);
}

// ---------------- dtype detection ----------------
__global__ void detect_k(const ush* __restrict__ xin, int* __restrict__ flag){
    if (threadIdx.x == 0 && blockIdx.x == 0) {
        int plausible = 0;
        for (int i = 0; i < 128; ++i) {
            ush u = xin[i];
            int e = (u >> 7) & 0xFF;
            if (e == 0 || (e >= 110 && e <= 140)) ++plausible;
        }
        *flag = (plausible >= 102) ? 1 : 0;
    }
}

// ---------------- casts / init ----------------
__global__ void cast_x_k(const void* __restrict__ xin, float* __restrict__ xout,
                         const int* __restrict__ flag, int n){
    const int isbf = *flag;
    int g = blockIdx.x*256 + threadIdx.x;
    if (g < n) xout[g] = ldf(xin, g, isbf);
}
__global__ void init_lg_k(const void* __restrict__ rel, const int* __restrict__ feat,
                          float* __restrict__ lg, const int* __restrict__ flag){
    const int isbf = *flag;
    int g = blockIdx.x*256 + threadIdx.x;   // over kEL*32
    int e = g >> 5, d = g & 31;
    lg[g] = ldf(rel, (size_t)feat[e]*kED + d, isbf);
}

// ---------------- weight pre-transpose to bf16 [N][K] ----------------
__global__ void trans_qkvo_k(const void* __restrict__ W0, const void* __restrict__ W1,
                             const void* __restrict__ W2, const void* __restrict__ W3,
                             const int* __restrict__ flag,
                             ush* __restrict__ d0, ush* __restrict__ d1,
                             ush* __restrict__ d2, ush* __restrict__ d3){
    const int isbf = *flag;
    int g = blockIdx.x*256 + threadIdx.x;   // 4 weights x 2 layers x 65536
    int w = g >> 17;
    int gg = g & 131071;
    int layer = gg >> 16, idx = gg & 65535;
    int n = idx >> 8, k = idx & 255;
    const void* W = (w==0)?W0:((w==1)?W1:((w==2)?W2:W3));
    ush* D = (w==0)?d0:((w==1)?d1:((w==2)?d2:d3));
    D[gg] = ldb(W, (size_t)layer*65536 + (size_t)k*256 + n, isbf);
}
__global__ void trans_gen_k(const void* __restrict__ W, const int* __restrict__ flag,
                            ush* __restrict__ dst, int K, int N, int total){
    const int isbf = *flag;
    int g = blockIdx.x*256 + threadIdx.x;
    if (g < total) {
        int per = K*N;
        int layer = g / per;
        int rem = g - layer*per;
        int n = rem / K, k = rem - n*K;
        dst[g] = ldb(W, (size_t)layer*per + (size_t)k*N + n, isbf);
    }
}

// ---------------- CSR build: counts -> scan -> fill ----------------
__global__ void count_k(const int* __restrict__ dst, int* __restrict__ cnt, int nE){
    int g = blockIdx.x*256 + threadIdx.x;
    if (g < nE) atomicAdd(&cnt[dst[g]], 1);
}
__global__ __launch_bounds__(256) void scan_blk_k(const int* __restrict__ cnt,
                                                  int* __restrict__ out,
                                                  int* __restrict__ bsum, int n){
    __shared__ int s[256];
    const int t = threadIdx.x;
    const int b0 = blockIdx.x*1024;
    int v[4], pre[4], tsum = 0;
    #pragma unroll
    for (int j=0;j<4;++j){
        int idx = b0 + t*4 + j;
        v[j] = (idx < n) ? cnt[idx] : 0;
        pre[j] = tsum; tsum += v[j];
    }
    s[t] = tsum; __syncthreads();
    for (int off=1; off<256; off<<=1){
        int x = (t>=off) ? s[t-off] : 0;
        __syncthreads();
        s[t] += x;
        __syncthreads();
    }
    int texc = s[t] - tsum;
    #pragma unroll
    for (int j=0;j<4;++j){
        int idx = b0 + t*4 + j;
        if (idx < n) out[idx] = texc + pre[j];
    }
    if (t == 255) bsum[blockIdx.x] = s[255];
}
__global__ __launch_bounds__(256) void scan_top_k(int* __restrict__ bsum, int nb){
    __shared__ int s[256];
    const int t = threadIdx.x;
    int v = (t < nb) ? bsum[t] : 0;
    s[t] = v; __syncthreads();
    for (int off=1; off<256; off<<=1){
        int x = (t>=off) ? s[t-off] : 0;
        __syncthreads();
        s[t] += x;
        __syncthreads();
    }
    if (t < nb) bsum[t] = s[t] - v;   // exclusive
}
__global__ void scan_add_k(int* __restrict__ out, const int* __restrict__ bsum, int n){
    int g = blockIdx.x*256 + threadIdx.x;
    if (g < n) out[g] += bsum[g >> 10];
}
__global__ void seal_k(int* __restrict__ ptr, int idx, int val){
    if (threadIdx.x == 0 && blockIdx.x == 0) ptr[idx] = val;
}
__global__ void copy_i_k(const int* __restrict__ a, int* __restrict__ b, int n){
    int g = blockIdx.x*256 + threadIdx.x;
    if (g < n) b[g] = a[g];
}
__global__ void fill_k(const int* __restrict__ dst, int* __restrict__ cur,
                       int* __restrict__ eidl, int nE){
    int g = blockIdx.x*256 + threadIdx.x;
    if (g < nE){
        int pos = atomicAdd(&cur[dst[g]], 1);
        eidl[pos] = g;
    }
}

// ---------------- MFMA GEMM: C[M,N] = A(fp32)@WT^T + bias (opt relu) ----------------
// WT: bf16 [N][K] (pre-transposed). 64x64 tile, 4 waves, v_mfma_f32_16x16x32_bf16.
// flags: 2 = RELU, 4 = has-bias
__global__ __launch_bounds__(256) void mgemm_k(
    const float* __restrict__ A, const ush* __restrict__ WT,
    const void* __restrict__ bias, size_t boff,
    float* __restrict__ C, const int* __restrict__ flag,
    int M, int N, int K, int flags)
{
    __shared__ __align__(16) ush As[64*40];
    __shared__ __align__(16) ush Ws[64*40];
    const int isbf = *flag;
    const int t = threadIdx.x;
    const int m0 = blockIdx.y*64, n0 = blockIdx.x*64;
    const int wave = t>>6, lane = t&63;
    const int quad = lane>>4, l15 = lane&15;
    const int r = t>>2, kq = (t&3)*8;

    frag_cd acc[4];
    #pragma unroll
    for (int tl=0; tl<4; ++tl)
        #pragma unroll
        for (int j=0;j<4;++j) acc[tl][j] = 0.f;

    const float* aprow = A + (size_t)(m0+r)*K + kq;
    const bool wok = (n0 + r) < N;
    const ush* wprow = WT + (size_t)(n0 + (wok ? r : 0))*K + kq;

    float4 a0, a1; uint4 wv;
    auto loadT = [&](int kk){
        a0 = *(const float4*)(aprow + kk);
        a1 = *(const float4*)(aprow + kk + 4);
        wv = wok ? *(const uint4*)(wprow + kk) : make_uint4(0u,0u,0u,0u);
    };
    loadT(0);

    for (int kk = 0; kk < K; kk += 32) {
        ushort4 p0 = make_ushort4(f2b(a0.x), f2b(a0.y), f2b(a0.z), f2b(a0.w));
        ushort4 p1 = make_ushort4(f2b(a1.x), f2b(a1.y), f2b(a1.z), f2b(a1.w));
        *(ushort4*)&As[r*40 + kq]     = p0;
        *(ushort4*)&As[r*40 + kq + 4] = p1;
        *(uint4*)&Ws[r*40 + kq] = wv;
        __syncthreads();
        if (kk + 32 < K) loadT(kk + 32);
        frag_ab af = *(const frag_ab*)&As[(wave*16 + l15)*40 + quad*8];
        #pragma unroll
        for (int tl = 0; tl < 4; ++tl) {
            frag_ab bf = *(const frag_ab*)&Ws[(tl*16 + l15)*40 + quad*8];
            acc[tl] = __builtin_amdgcn_mfma_f32_16x16x32_bf16(af, bf, acc[tl], 0, 0, 0);
        }
        __syncthreads();
    }
    const bool do_relu = flags & 2;
    const bool has_b   = flags & 4;
    #pragma unroll
    for (int tl = 0; tl < 4; ++tl) {
        int col = n0 + tl*16 + l15;
        if (col < N) {
            float bv = has_b ? ldf(bias, boff + col, isbf) : 0.f;
            #pragma unroll
            for (int rg = 0; rg < 4; ++rg) {
                int row = m0 + wave*16 + quad*4 + rg;
                float v = acc[tl][rg] + bv;
                if (do_relu) v = fmaxf(v, 0.f);
                C[(size_t)row*N + col] = v;
            }
        }
    }
}

// ---------------- MFMA eq/ek/ev (+gathered mixed), 128 rows/block ----------------
__global__ __launch_bounds__(256) void eqkv_mfma_k(
    const float* __restrict__ lg, const float* __restrict__ xs, const float* __restrict__ xd,
    const int* __restrict__ gsrc, const int* __restrict__ gdst,
    const void* __restrict__ Wq, const void* __restrict__ Wk, const void* __restrict__ Wv,
    size_t woff, const void* __restrict__ bq, size_t boff,
    float* __restrict__ eq, float* __restrict__ ek, float* __restrict__ ev,
    const int* __restrict__ flag)
{
    __shared__ __align__(16) ush mixs[128*40];
    __shared__ __align__(16) ush wts[3][32*40];
    __shared__ float bqs[32];
    const int isbf = *flag;
    const int t = threadIdx.x;
    const int e0 = blockIdx.x * 128;
    for (int i = t; i < 3*1024; i += 256) {
        int m = i >> 10, r2 = i & 1023;
        int n = r2 >> 5, k2 = r2 & 31;
        const void* W = (m==0) ? Wq : ((m==1) ? Wk : Wv);
        wts[m][n*40 + k2] = ldb(W, woff + (size_t)k2*32 + n, isbf);
    }
    if (t < 32) bqs[t] = ldf(bq, boff + t, isbf);
    {
        int r = t >> 1, c0 = (t & 1) * 16;
        int e = e0 + r;
        int s = gsrc[e], d2 = gdst[e];
        const float* lp = lg + (size_t)e*32 + c0;
        const float* sp = xs + (size_t)s*32 + c0;
        const float* dp = xd + (size_t)d2*32 + c0;
        #pragma unroll
        for (int j = 0; j < 16; ++j)
            mixs[r*40 + c0 + j] = f2b(lp[j] + sp[j] + dp[j]);
    }
    __syncthreads();
    const int wave = t >> 6, l15 = t & 15, quad = (t >> 4) & 3;
    #pragma unroll
    for (int mi = 0; mi < 2; ++mi) {
        const int mt = wave*2 + mi;
        frag_ab af = *(const frag_ab*)&mixs[(mt*16 + l15)*40 + quad*8];
        #pragma unroll
        for (int w = 0; w < 3; ++w) {
            float* outp = (w==0) ? eq : ((w==1) ? ek : ev);
            #pragma unroll
            for (int nt = 0; nt < 2; ++nt) {
                frag_ab bf = *(const frag_ab*)&wts[w][(nt*16 + l15)*40 + quad*8];
                frag_cd acc = {0.f, 0.f, 0.f, 0.f};
                acc = __builtin_amdgcn_mfma_f32_16x16x32_bf16(af, bf, acc, 0, 0, 0);
                const float bv = (w==0) ? bqs[nt*16 + l15] : 0.f;
                #pragma unroll
                for (int rg = 0; rg < 4; ++rg) {
                    int row = e0 + mt*16 + quad*4 + rg;
                    outp[(size_t)row*32 + nt*16 + l15] = acc[rg] + bv;
                }
            }
        }
    }
}

// ---------------- MFMA ow@Wo + bo + res -> LN; 128 rows/block ----------------
__global__ __launch_bounds__(256) void ewo_mfma_k(
    const float* __restrict__ ow, const float* __restrict__ res,
    const void* __restrict__ Wo, size_t wooff, const void* __restrict__ bo, size_t booff,
    const void* __restrict__ g1, const void* __restrict__ be1, size_t g1off,
    float* __restrict__ out, const int* __restrict__ flag)
{
    __shared__ __align__(16) ush ows[128*40];
    __shared__ __align__(16) ush wos[32*40];
    __shared__ float bos[32];
    const int isbf = *flag;
    const int t = threadIdx.x;
    const int e0 = blockIdx.x * 128;
    for (int i = t; i < 1024; i += 256) {
        int n = i >> 5, k2 = i & 31;
        wos[n*40 + k2] = ldb(Wo, wooff + (size_t)k2*32 + n, isbf);
    }
    if (t < 32) bos[t] = ldf(bo, booff + t, isbf);
    {
        int r = t >> 1, c0 = (t & 1) * 16;
        const float* op = ow + (size_t)(e0 + r)*32 + c0;
        #pragma unroll
        for (int j = 0; j < 16; ++j) ows[r*40 + c0 + j] = f2b(op[j]);
    }
    __syncthreads();
    const int wave = t >> 6, l15 = t & 15, quad = (t >> 4) & 3;
    const float gg0 = ldf(g1, g1off + l15, isbf),      gg1 = ldf(g1, g1off + 16 + l15, isbf);
    const float bb0 = ldf(be1, g1off + l15, isbf),     bb1 = ldf(be1, g1off + 16 + l15, isbf);
    #pragma unroll
    for (int mi = 0; mi < 2; ++mi) {
        const int mt = wave*2 + mi;
        frag_ab af = *(const frag_ab*)&ows[(mt*16 + l15)*40 + quad*8];
        frag_cd acc[2] = {{0.f,0.f,0.f,0.f},{0.f,0.f,0.f,0.f}};
        #pragma unroll
        for (int nt = 0; nt < 2; ++nt) {
            frag_ab bf = *(const frag_ab*)&wos[(nt*16 + l15)*40 + quad*8];
            acc[nt] = __builtin_amdgcn_mfma_f32_16x16x32_bf16(af, bf, acc[nt], 0, 0, 0);
        }
        #pragma unroll
        for (int rg = 0; rg < 4; ++rg) {
            const int row = e0 + mt*16 + quad*4 + rg;
            float v0 = acc[0][rg] + bos[l15]      + res[(size_t)row*32 + l15];
            float v1 = acc[1][rg] + bos[16 + l15] + res[(size_t)row*32 + 16 + l15];
            float s = v0 + v1;
            s += __shfl_xor(s,1); s += __shfl_xor(s,2); s += __shfl_xor(s,4); s += __shfl_xor(s,8);
            const float mean = s * (1.f/32.f);
            float q = (v0-mean)*(v0-mean) + (v1-mean)*(v1-mean);
            q += __shfl_xor(q,1); q += __shfl_xor(q,2); q += __shfl_xor(q,4); q += __shfl_xor(q,8);
            const float inv = rsqrtf(q * (1.f/32.f) + 1e-5f);
            out[(size_t)row*32 + l15]      = (v0-mean)*inv*gg0 + bb0;
            out[(size_t)row*32 + 16 + l15] = (v1-mean)*inv*gg1 + bb1;
        }
    }
}

// ---------------- MFMA edge FFN: LN(A + relu(A@W1+b1)@W2 + b2); 64 rows/block ----------------
__global__ __launch_bounds__(256) void effn_mfma_k(
    const float* __restrict__ A,
    const void* __restrict__ W1, size_t w1off, const void* __restrict__ b1, size_t b1off,
    const void* __restrict__ W2, size_t w2off, const void* __restrict__ b2, size_t b2off,
    const void* __restrict__ g, const void* __restrict__ be, size_t goff,
    float* __restrict__ out, const int* __restrict__ flag)
{
    __shared__ __align__(16) ush w1t[128*40];    // W1^T: [n][k], k<32
    __shared__ __align__(16) ush w2t[32*136];    // W2^T: [n][k], k<128
    __shared__ __align__(16) ush hid[64*136];    // hidden bf16, [row][k]
    __shared__ float b1s[128], b2s[32];
    const int isbf = *flag;
    const int t = threadIdx.x;
    const int e0 = blockIdx.x * 64;
    const int wave = t >> 6, l15 = t & 15, quad = (t >> 4) & 3;

    for (int i = t; i < 4096; i += 256) {
        int n1 = i >> 5, k1 = i & 31;
        w1t[n1*40 + k1] = ldb(W1, w1off + (size_t)k1*128 + n1, isbf);
        int n2 = i >> 7, k2 = i & 127;
        w2t[n2*136 + k2] = ldb(W2, w2off + (size_t)k2*32 + n2, isbf);
    }
    if (t < 128) b1s[t] = ldf(b1, b1off + t, isbf);
    if (t < 32)  b2s[t] = ldf(b2, b2off + t, isbf);
    __syncthreads();

    // ---- P1: hid = relu(A@W1 + b1), one MFMA per N-tile (K=32) ----
    {
        const int m = wave*16 + l15;
        float4 a0 = *(const float4*)&A[(size_t)(e0+m)*32 + quad*8];
        float4 a1 = *(const float4*)&A[(size_t)(e0+m)*32 + quad*8 + 4];
        ush tmp[8] = {f2b(a0.x),f2b(a0.y),f2b(a0.z),f2b(a0.w),
                      f2b(a1.x),f2b(a1.y),f2b(a1.z),f2b(a1.w)};
        frag_ab af = *(frag_ab*)tmp;
        #pragma unroll
        for (int nt = 0; nt < 8; ++nt) {
            frag_ab bf = *(const frag_ab*)&w1t[(nt*16 + l15)*40 + quad*8];
            frag_cd acc = {0.f, 0.f, 0.f, 0.f};
            acc = __builtin_amdgcn_mfma_f32_16x16x32_bf16(af, bf, acc, 0, 0, 0);
            float bv = b1s[nt*16 + l15];
            #pragma unroll
            for (int rg = 0; rg < 4; ++rg) {
                int row = wave*16 + quad*4 + rg;
                hid[row*136 + nt*16 + l15] = f2b(fmaxf(acc[rg] + bv, 0.f));
            }
        }
    }
    __syncthreads();

    // ---- P2: C = hid@W2 (K=128); + b2 + residual; LN ----
    frag_cd acc2[2] = {{0.f,0.f,0.f,0.f},{0.f,0.f,0.f,0.f}};
    #pragma unroll
    for (int ks = 0; ks < 4; ++ks) {
        frag_ab af2 = *(const frag_ab*)&hid[(wave*16 + l15)*136 + ks*32 + quad*8];
        #pragma unroll
        for (int tl = 0; tl < 2; ++tl) {
            frag_ab bf2 = *(const frag_ab*)&w2t[(tl*16 + l15)*136 + ks*32 + quad*8];
            acc2[tl] = __builtin_amdgcn_mfma_f32_16x16x32_bf16(af2, bf2, acc2[tl], 0, 0, 0);
        }
    }
    const float g0  = ldf(g,  goff + l15, isbf),      g1v = ldf(g,  goff + 16 + l15, isbf);
    const float be0 = ldf(be, goff + l15, isbf),      be1 = ldf(be, goff + 16 + l15, isbf);
    const float bb0 = b2s[l15], bb1 = b2s[16 + l15];
    #pragma unroll
    for (int rg = 0; rg < 4; ++rg) {
        const int row = e0 + wave*16 + quad*4 + rg;
        float v0 = acc2[0][rg] + bb0 + A[(size_t)row*32 + l15];
        float v1 = acc2[1][rg] + bb1 + A[(size_t)row*32 + 16 + l15];
        float s = v0 + v1;
        s += __shfl_xor(s,1); s += __shfl_xor(s,2); s += __shfl_xor(s,4); s += __shfl_xor(s,8);
        const float mean = s * (1.f/32.f);
        float q = (v0-mean)*(v0-mean) + (v1-mean)*(v1-mean);
        q += __shfl_xor(q,1); q += __shfl_xor(q,2); q += __shfl_xor(q,4); q += __shfl_xor(q,8);
        const float inv = rsqrtf(q * (1.f/32.f) + 1e-5f);
        out[(size_t)row*32 + l15]      = (v0-mean)*inv*g0  + be0;
        out[(size_t)row*32 + 16 + l15] = (v1-mean)*inv*g1v + be1;
    }
}

// ---------------- LayerNorm (node rows, D=256) ----------------
__global__ __launch_bounds__(64) void ln_k(
    const float* __restrict__ a, const float* __restrict__ b,
    const void* __restrict__ g, const void* __restrict__ be, size_t goff,
    float* __restrict__ out, const int* __restrict__ flag, int D)
{
    const int isbf = *flag;
    const int row = blockIdx.x;
    const int t = threadIdx.x;
    float v[4];
    int cnt = 0;
    float s = 0.f;
    for (int i = t; i < D; i += 64) {
        float x = a[(size_t)row*D + i];
        if (b) x += b[(size_t)row*D + i];
        v[cnt++] = x; s += x;
    }
    #pragma unroll
    for (int off = 32; off > 0; off >>= 1) s += __shfl_down(s, off);
    s = __shfl(s, 0);
    const float mean = s / D;
    float qq = 0.f;
    for (int c2 = 0; c2 < cnt; ++c2) { float d = v[c2]-mean; qq += d*d; }
    #pragma unroll
    for (int off = 32; off > 0; off >>= 1) qq += __shfl_down(qq, off);
    qq = __shfl(qq, 0);
    const float inv = rsqrtf(fmaxf(qq, 0.f) / D + 1e-5f);
    cnt = 0;
    for (int i = t; i < D; i += 64)
        out[(size_t)row*D + i] = (v[cnt++] - mean)*inv*ldf(g, goff + i, isbf) + ldf(be, goff + i, isbf);
}

// ---------------- full-graph attention v4: (b,h,half) blocks, 8 waves split over src ----------------
// wave w: online softmax over src [16w, 16w+16) for all 64 dst; partials merged in LDS.
__global__ __launch_bounds__(512) void full_attn_k(
    const float* __restrict__ q, const float* __restrict__ k, const float* __restrict__ v,
    const void* __restrict__ rel, const int* __restrict__ feat, float* __restrict__ o,
    const int* __restrict__ flag)
{
    __shared__ __align__(8) ush ks[128][36];
    __shared__ __align__(8) ush vs[128][36];
    __shared__ __align__(8) ush rs[128][36];
    __shared__ float pb[8][64][34];            // per-wave partials: m, l, acc[32]
    const int isbf = *flag;
    const int bid = blockIdx.x;
    const int b = bid >> 3, h = (bid >> 1) & 3, half = bid & 1;
    const int t = threadIdx.x;
    for (int i = t; i < 4096; i += 512) {
        int r = i >> 5, d = i & 31;
        rs[r][d] = ldb(rel, i, isbf);
        size_t base = ((size_t)(b*128 + r))*kND + h*32 + d;
        ks[r][d] = f2b(k[base]);
        vs[r][d] = f2b(v[base]);
    }
    __syncthreads();
    const int wave = t >> 6, lane = t & 63;
    const int dst = half*64 + lane;
    float qr[32];
    { size_t base = ((size_t)(b*128 + dst))*kND + h*32;
      #pragma unroll
      for (int d=0; d<32; ++d) qr[d] = q[base + d]; }
    const int* fp = feat + (size_t)b*16384 + dst;
    const int s0 = wave*16;
    float m = -1e30f, l = 0.f;
    float acc[32];
    #pragma unroll
    for (int d=0; d<32; ++d) acc[d] = 0.f;
    int f = fp[s0*128];
    for (int sI = 0; sI < 16; ++sI) {
        const int s = s0 + sI;
        int fn = (sI+1 < 16) ? fp[(s+1)*128] : 0;
        float er[32];
        float sc = 0.f;
        #pragma unroll
        for (int j2 = 0; j2 < 8; ++j2) {
            ushort4 eu = *(const ushort4*)&rs[f][j2*4];
            ushort4 ku = *(const ushort4*)&ks[s][j2*4];
            float e0 = b2f(eu.x), e1 = b2f(eu.y), e2 = b2f(eu.z), e3 = b2f(eu.w);
            er[j2*4+0]=e0; er[j2*4+1]=e1; er[j2*4+2]=e2; er[j2*4+3]=e3;
            sc += (b2f(ku.x)+e0)*qr[j2*4+0] + (b2f(ku.y)+e1)*qr[j2*4+1]
                + (b2f(ku.z)+e2)*qr[j2*4+2] + (b2f(ku.w)+e3)*qr[j2*4+3];
        }
        sc *= kScaleN;
        float mn = fmaxf(m, sc);
        float c0 = __expf(m - mn);
        float pp = __expf(sc - mn);
        l = l*c0 + pp;
        #pragma unroll
        for (int j2 = 0; j2 < 8; ++j2) {
            ushort4 vu = *(const ushort4*)&vs[s][j2*4];
            acc[j2*4+0] = acc[j2*4+0]*c0 + pp*(b2f(vu.x)+er[j2*4+0]);
            acc[j2*4+1] = acc[j2*4+1]*c0 + pp*(b2f(vu.y)+er[j2*4+1]);
            acc[j2*4+2] = acc[j2*4+2]*c0 + pp*(b2f(vu.z)+er[j2*4+2]);
            acc[j2*4+3] = acc[j2*4+3]*c0 + pp*(b2f(vu.w)+er[j2*4+3]);
        }
        m = mn; f = fn;
    }
    pb[wave][lane][0] = m;
    pb[wave][lane][1] = l;
    #pragma unroll
    for (int d=0; d<32; ++d) pb[wave][lane][2+d] = acc[d];
    __syncthreads();
    // merge: thread (lane2, grp) handles dims [grp*4, grp*4+4) of dst=half*64+lane2
    {
        const int lane2 = t & 63, grp = t >> 6;   // grp in [0,8)
        float mw[8], lw[8];
        #pragma unroll
        for (int w=0; w<8; ++w){ mw[w]=pb[w][lane2][0]; lw[w]=pb[w][lane2][1]; }
        float M = mw[0];
        #pragma unroll
        for (int w=1; w<8; ++w) M = fmaxf(M, mw[w]);
        float sw[8];
        float L = 0.f;
        #pragma unroll
        for (int w=0; w<8; ++w){ sw[w] = __expf(mw[w]-M); L += lw[w]*sw[w]; }
        const float inv = 1.f / fmaxf(L, 1e-30f);
        size_t base = ((size_t)(b*128 + half*64 + lane2))*kND + h*32 + grp*4;
        #pragma unroll
        for (int d=0; d<4; ++d) {
            float a = 0.f;
            #pragma unroll
            for (int w=0; w<8; ++w) a += pb[w][lane2][2+grp*4+d]*sw[w];
            o[base + d] = a*inv;
        }
    }
}

// ---------------- local-graph GATHER attention (heads 4..7) ----------------
// v2: block per node, wave per head; the wave's four 16-lane groups process
// 4 edges concurrently (4 independent gather chains in flight), online-softmax
// partials per group, merged at the end with a 2-step shfl_xor butterfly.
__global__ __launch_bounds__(256) void loc_gather_k(
    const float* __restrict__ q, const float* __restrict__ k, const float* __restrict__ v,
    const float* __restrict__ lg, const int* __restrict__ gsrc,
    const int* __restrict__ rowp, const int* __restrict__ eidl,
    float* __restrict__ o)
{
    const int n = blockIdx.x;
    const int h = threadIdx.x >> 6;        // wave = local head (0..3 -> heads 4..7)
    const int lane = threadIdx.x & 63;
    const int g = lane >> 4;               // edge slot within wave (0..3)
    const int d0 = (lane & 15) * 2;
    const size_t hoff = (size_t)(4 + h) * 32 + d0;
    const float2 q2 = *(const float2*)&q[(size_t)n*kND + hoff];
    const int beg = rowp[n], end = rowp[n+1];
    const int deg = end - beg;
    float m = -1e30f, l = 0.f, ax = 0.f, ay = 0.f;
    if (deg > 0) {
        const int nIter = (deg + 3) >> 2;
        int idx = beg + g;
        int ce = eidl[min(idx, end-1)];
        int cs = gsrc[ce];
        for (int it = 0; it < nIter; ++it) {
            const bool valid = idx < end;
            const int e = ce, s = cs;
            idx += 4;
            if (it + 1 < nIter) { ce = eidl[min(idx, end-1)]; cs = gsrc[ce]; }
            // issue all three gathers up-front (independent chains)
            const float2 kv = *(const float2*)&k[(size_t)s*kND + hoff];
            const float2 lv = *(const float2*)&lg[(size_t)e*32 + d0];
            const float2 vv = *(const float2*)&v[(size_t)s*kND + hoff];
            float part = (kv.x+lv.x)*q2.x + (kv.y+lv.y)*q2.y;
            part += __shfl_xor(part, 1);
            part += __shfl_xor(part, 2);
            part += __shfl_xor(part, 4);
            part += __shfl_xor(part, 8);
            const float sc = part * kScaleN;
            const float mn = valid ? fmaxf(m, sc) : m;
            const float c  = __expf(m - mn);
            const float pp = valid ? __expf(sc - mn) : 0.f;
            l  = l*c  + pp;
            ax = ax*c + pp*(vv.x+lv.x);
            ay = ay*c + pp*(vv.y+lv.y);
            m  = mn;
        }
        // merge the 4 per-group online-softmax partials across lanes 16/32 apart
        #pragma unroll
        for (int off = 16; off <= 32; off <<= 1) {
            const float mo = __shfl_xor(m, off);
            const float lo = __shfl_xor(l, off);
            const float xo = __shfl_xor(ax, off);
            const float yo = __shfl_xor(ay, off);
            const float M  = fmaxf(m, mo);
            const float c1 = __expf(m - M);
            const float c2 = __expf(mo - M);
            l  = l*c1  + lo*c2;
            ax = ax*c1 + xo*c2;
            ay = ay*c1 + yo*c2;
            m  = M;
        }
    }
    if (g == 0) {
        const float inv = 1.f / fmaxf(l, 1e-30f);
        *(float2*)&o[(size_t)n*kND + hoff] = make_float2(ax*inv, ay*inv);
    }
}

// ---------------- line-graph GATHER attention (8 heads, d=4) ----------------
__global__ __launch_bounds__(256) void lgs_gather_k(
    const float* __restrict__ eq, const float* __restrict__ ek, const float* __restrict__ ev,
    const int* __restrict__ lsrc, const int* __restrict__ rowp, const int* __restrict__ eidl,
    float* __restrict__ ow)
{
    int g = blockIdx.x*256 + threadIdx.x;   // kEL*8
    int d2 = g >> 3, h = g & 7;
    float4 q4 = *(const float4*)&eq[(size_t)d2*32 + h*4];
    const int beg = rowp[d2], end = rowp[d2+1];
    float m = -1e30f, l = 0.f;
    float4 acc = make_float4(0.f,0.f,0.f,0.f);
    for (int i = beg; i < end; ++i) {
        int e = eidl[i];
        int s = lsrc[e];
        float4 k4 = *(const float4*)&ek[(size_t)s*32 + h*4];
        float sc = (k4.x*q4.x + k4.y*q4.y + k4.z*q4.z + k4.w*q4.w) * 0.5f;
        float mn = fmaxf(m, sc);
        float c = __expf(m - mn);
        float pp = __expf(sc - mn);
        l = l*c + pp;
        float4 v4 = *(const float4*)&ev[(size_t)s*32 + h*4];
        acc.x = acc.x*c + pp*v4.x;
        acc.y = acc.y*c + pp*v4.y;
        acc.z = acc.z*c + pp*v4.z;
        acc.w = acc.w*c + pp*v4.w;
        m = mn;
    }
    const float inv = 1.f / fmaxf(l, 1e-30f);
    *(float4*)&ow[(size_t)d2*32 + h*4] =
        make_float4(acc.x*inv, acc.y*inv, acc.z*inv, acc.w*inv);
}

// ---------------- output ----------------
__global__ void out_k(const float* __restrict__ xf, const float* __restrict__ lgf,
                      void* __restrict__ out, const int* __restrict__ flag){
    const int isbf = *flag;
    int g = blockIdx.x*256 + threadIdx.x;
    float v = (g < kN*kND) ? xf[g] : lgf[g - kN*kND];
    if (isbf) ((bf16*)out)[g] = __float2bfloat16(v);
    else      ((float*)out)[g] = v;
}

// ---------------- host helper ----------------
static inline void mgemm(const float* A, const ush* WT, const void* bias, size_t boff,
                         float* C, const int* flag, int M, int N, int K, int flags,
                         hipStream_t s){
    dim3 grid((N+63)/64, M/64);
    mgemm_k<<<grid, 256, 0, s>>>(A, WT, bias, boff, C, flag, M, N, K, flags);
}

extern "C" void kernel_launch(void* const* d_in, const int* in_sizes, int n_in,
                              void* d_out, int out_size, void* d_ws, size_t ws_size,
                              hipStream_t stream) {
    const void* x_in      = d_in[0];
    const void* rel       = d_in[1];
    const int* g_src      = (const int*)d_in[4];
    const int* g_dst      = (const int*)d_in[5];
    const int* lg_src     = (const int*)d_in[6];
    const int* lg_dst     = (const int*)d_in[7];
    const int* edge_feat  = (const int*)d_in[8];
    const int* full_feat  = (const int*)d_in[9];
    const void* n_Wq   = d_in[10];
    const void* n_bq   = d_in[11];
    const void* n_Wk   = d_in[12];
    const void* n_bk   = d_in[13];
    const void* n_Wv   = d_in[14];
    const void* n_bv   = d_in[15];
    const void* n_Wo   = d_in[16];
    const void* n_bo   = d_in[17];
    const void* n_lng  = d_in[18];
    const void* n_lnb  = d_in[19];
    const void* n_fW1  = d_in[20];
    const void* n_fb1  = d_in[21];
    const void* n_fW2  = d_in[22];
    const void* n_fb2  = d_in[23];
    const void* n_flng = d_in[24];
    const void* n_flnb = d_in[25];
    const void* e_Wsrc = d_in[26];
    const void* e_Wdst = d_in[27];
    const void* e_Wq   = d_in[28];
    const void* e_bq   = d_in[29];
    const void* e_Wk   = d_in[30];
    const void* e_Wv   = d_in[31];
    const void* e_Wo   = d_in[32];
    const void* e_bo   = d_in[33];
    const void* e_lng  = d_in[34];
    const void* e_lnb  = d_in[35];
    const void* e_fW1  = d_in[36];
    const void* e_fb1  = d_in[37];
    const void* e_fW2  = d_in[38];
    const void* e_fb2  = d_in[39];
    const void* e_flng = d_in[40];
    const void* e_flnb = d_in[41];

    // ---- workspace carve-up ----
    float* p = (float*)d_ws;
    size_t off = 0;
    auto AL = [&](size_t n){ float* r = p + off; off += n; return r; };
    int* flagp = (int*)AL(64);
    float* xA   = AL((size_t)kN*kND);
    float* xB   = AL((size_t)kN*kND);
    float* xM   = AL((size_t)kN*kND);
    float* qb   = AL((size_t)kN*kND);
    float* kb   = AL((size_t)kN*kND);
    float* vb   = AL((size_t)kN*kND);
    float* ob   = AL((size_t)kN*kND);
    float* tN   = AL((size_t)kN*kND);
    float* nh   = AL((size_t)kN*1024);
    float* lgA  = AL((size_t)kEL*kED);
    float* lgB  = AL((size_t)kEL*kED);
    float* lgM  = AL((size_t)kEL*kED);
    float* eqb  = AL((size_t)kEL*kED);
    float* ekb  = AL((size_t)kEL*kED);
    float* evb  = AL((size_t)kEL*kED);
    float* owb  = AL((size_t)kEL*kED);
    float* xs   = AL((size_t)kN*kED);
    float* xd   = AL((size_t)kN*kED);
    // CSR structures
    int* cntL  = (int*)AL(kN);
    int* rowL  = (int*)AL(kN + 64);
    int* curL  = (int*)AL(kN);
    int* eidL  = (int*)AL(kEL);
    int* cntG  = (int*)AL(kEL);
    int* rowG  = (int*)AL(kEL + 64);
    int* curG  = (int*)AL(kEL);
    int* eidG  = (int*)AL(kELG);
    int* bsum  = (int*)AL(256);
    // pre-transposed bf16 weights [N][K], per-layer contiguous
    ush* wtQ  = (ush*)AL(65536);
    ush* wtK  = (ush*)AL(65536);
    ush* wtV  = (ush*)AL(65536);
    ush* wtO  = (ush*)AL(65536);
    ush* wtF1 = (ush*)AL(262144);
    ush* wtF2 = (ush*)AL(262144);
    ush* wtS  = (ush*)AL(8192);
    ush* wtD  = (ush*)AL(8192);
    if (ws_size < off * sizeof(float)) return;

    detect_k<<<1, 64, 0, stream>>>((const ush*)x_in, flagp);
    cast_x_k<<<(kN*kND)/256, 256, 0, stream>>>(x_in, xA, flagp, kN*kND);
    init_lg_k<<<(kEL*kED)/256, 256, 0, stream>>>(rel, edge_feat, lgA, flagp);

    // ---- weight pre-transpose (once) ----
    trans_qkvo_k<<<2048, 256, 0, stream>>>(n_Wq, n_Wk, n_Wv, n_Wo, flagp, wtQ, wtK, wtV, wtO);
    trans_gen_k<<<2048, 256, 0, stream>>>(n_fW1, flagp, wtF1, 256, 1024, 524288);
    trans_gen_k<<<2048, 256, 0, stream>>>(n_fW2, flagp, wtF2, 1024, 256, 524288);
    trans_gen_k<<<64, 256, 0, stream>>>(e_Wsrc, flagp, wtS, 256, 32, 16384);
    trans_gen_k<<<64, 256, 0, stream>>>(e_Wdst, flagp, wtD, 256, 32, 16384);

    // ---- CSR build (both graphs) ----
    hipMemsetAsync(cntL, 0, kN*sizeof(int), stream);
    hipMemsetAsync(cntG, 0, kEL*sizeof(int), stream);
    count_k<<<kEL/256, 256, 0, stream>>>(g_dst, cntL, kEL);
    count_k<<<kELG/256, 256, 0, stream>>>(lg_dst, cntG, kELG);
    scan_blk_k<<<kN/1024, 256, 0, stream>>>(cntL, rowL, bsum, kN);
    scan_top_k<<<1, 256, 0, stream>>>(bsum, kN/1024);
    scan_add_k<<<kN/256, 256, 0, stream>>>(rowL, bsum, kN);
    seal_k<<<1, 64, 0, stream>>>(rowL, kN, kEL);
    scan_blk_k<<<kEL/1024, 256, 0, stream>>>(cntG, rowG, bsum, kEL);
    scan_top_k<<<1, 256, 0, stream>>>(bsum, kEL/1024);
    scan_add_k<<<kEL/256, 256, 0, stream>>>(rowG, bsum, kEL);
    seal_k<<<1, 64, 0, stream>>>(rowG, kEL, kELG);
    copy_i_k<<<kN/256, 256, 0, stream>>>(rowL, curL, kN);
    copy_i_k<<<kEL/256, 256, 0, stream>>>(rowG, curG, kEL);
    fill_k<<<kEL/256, 256, 0, stream>>>(g_dst, curL, eidL, kEL);
    fill_k<<<kELG/256, 256, 0, stream>>>(lg_dst, curG, eidG, kELG);

    float* xc = xA;  float* xn = xB;
    float* lgc = lgA; float* lgn = lgB;

    for (int i = 0; i < kL; ++i) {
        const size_t oeW  = (size_t)i*kED*kED;
        const size_t oefW1= (size_t)i*kED*128;
        const size_t oefW2= (size_t)i*128*kED;
        const size_t o256 = (size_t)i*kND;
        const size_t o1024= (size_t)i*1024;
        const size_t o32  = (size_t)i*kED;
        const size_t o128 = (size_t)i*128;

        // ===== node update =====
        mgemm(xc, wtQ + (size_t)i*65536, n_bq, o256, qb, flagp, kN, kND, kND, 4, stream);
        mgemm(xc, wtK + (size_t)i*65536, n_bk, o256, kb, flagp, kN, kND, kND, 4, stream);
        mgemm(xc, wtV + (size_t)i*65536, n_bv, o256, vb, flagp, kN, kND, kND, 4, stream);
        full_attn_k<<<256, 512, 0, stream>>>(qb, kb, vb, rel, full_feat, ob, flagp);
        loc_gather_k<<<kN, 256, 0, stream>>>(qb, kb, vb, lgc, g_src, rowL, eidL, ob);
        mgemm(ob, wtO + (size_t)i*65536, n_bo, o256, tN, flagp, kN, kND, kND, 4, stream);
        ln_k<<<kN, 64, 0, stream>>>(xc, tN, n_lng, n_lnb, o256, xM, flagp, kND);
        mgemm(xM, wtF1 + (size_t)i*262144, n_fb1, o1024, nh, flagp, kN, 1024, kND, 4|2, stream);
        mgemm(nh, wtF2 + (size_t)i*262144, n_fb2, o256, tN, flagp, kN, kND, 1024, 4, stream);
        ln_k<<<kN, 64, 0, stream>>>(xM, tN, n_flng, n_flnb, o256, xn, flagp, kND);

        // ===== edge update (uses PRE-update xc, lgc) =====
        mgemm(xc, wtS + (size_t)i*8192, nullptr, 0, xs, flagp, kN, kED, kND, 0, stream);
        mgemm(xc, wtD + (size_t)i*8192, nullptr, 0, xd, flagp, kN, kED, kND, 0, stream);
        eqkv_mfma_k<<<kEL/128, 256, 0, stream>>>(lgc, xs, xd, g_src, g_dst,
                                                 e_Wq, e_Wk, e_Wv, oeW, e_bq, o32,
                                                 eqb, ekb, evb, flagp);
        lgs_gather_k<<<(kEL*8)/256, 256, 0, stream>>>(eqb, ekb, evb, lg_src, rowG, eidG, owb);
        ewo_mfma_k<<<kEL/128, 256, 0, stream>>>(owb, lgc, e_Wo, oeW, e_bo, o32,
                                                e_lng, e_lnb, o32, lgM, flagp);
        effn_mfma_k<<<kEL/64, 256, 0, stream>>>(lgM, e_fW1, oefW1, e_fb1, o128,
                                                e_fW2, oefW2, e_fb2, o32,
                                                e_flng, e_flnb, o32, lgn, flagp);

        { float* t = xc; xc = xn; xn = t; }
        { float* t = lgc; lgc = lgn; lgn = t; }
    }

    out_k<<<(kN*kND + kEL*kED)/256, 256, 0, stream>>>(xc, lgc, d_out, flagp);
}

// Round 2
// 694.869 us; speedup vs baseline: 1.1108x; 1.0636x over previous
//
#include <hip/hip_runtime.h>
#include <hip/hip_bf16.h>

typedef __hip_bfloat16 bf16;
typedef unsigned short ush;

static constexpr int kN   = 4096;    // nodes
static constexpr int kND  = 256;     // hidden
static constexpr int kEL  = 131072;  // local edges
static constexpr int kED  = 32;      // edge dim
static constexpr int kELG = 262144;  // line-graph edges
static constexpr int kL   = 2;
static constexpr float kScaleN = 0.17677669529663687f; // 1/sqrt(32)

using frag_ab = __attribute__((ext_vector_type(8))) short;   // 8 bf16 (4 VGPRs)
using frag_cd = __attribute__((ext_vector_type(4))) float;   // 4 fp32

__device__ __forceinline__ float ldf(const void* p, size_t i, int isbf){
    return isbf ? __bfloat162float(((const bf16*)p)[i]) : ((const float*)p)[i];
}
__device__ __forceinline__ ush f2b(float f){ bf16 h = __float2bfloat16(f); return *(ush*)&h; }
__device__ __forceinline__ float b2f(ush u){ return __uint_as_float(((unsigned)u)<<16); }
__device__ __forceinline__ ush ldb(const void* p, size_t i, int isbf){
    return isbf ? ((const ush*)p)[i] : f2b(((const float*)p)[i]);
}

// ---------------- dtype detection ----------------
__global__ void detect_k(const ush* __restrict__ xin, int* __restrict__ flag){
    if (threadIdx.x == 0 && blockIdx.x == 0) {
        int plausible = 0;
        for (int i = 0; i < 128; ++i) {
            ush u = xin[i];
            int e = (u >> 7) & 0xFF;
            if (e == 0 || (e >= 110 && e <= 140)) ++plausible;
        }
        *flag = (plausible >= 102) ? 1 : 0;
    }
}

// ---------------- casts / init ----------------
__global__ void cast_x_k(const void* __restrict__ xin, float* __restrict__ xout,
                         const int* __restrict__ flag, int n){
    const int isbf = *flag;
    int g = blockIdx.x*256 + threadIdx.x;
    if (g < n) xout[g] = ldf(xin, g, isbf);
}
__global__ void init_lg_k(const void* __restrict__ rel, const int* __restrict__ feat,
                          float* __restrict__ lg, const int* __restrict__ flag){
    const int isbf = *flag;
    int g = blockIdx.x*256 + threadIdx.x;   // over kEL*32
    int e = g >> 5, d = g & 31;
    lg[g] = ldf(rel, (size_t)feat[e]*kED + d, isbf);
}

// ---------------- weight pre-transpose to bf16 [N][K] ----------------
// packed QKV: dst[layer][768][256], rows 0-255 = Wq^T, 256-511 = Wk^T, 512-767 = Wv^T
__global__ void trans_qkv_pack_k(const void* __restrict__ Wq, const void* __restrict__ Wk,
                                 const void* __restrict__ Wv, const int* __restrict__ flag,
                                 ush* __restrict__ dst){
    const int isbf = *flag;
    int g = blockIdx.x*256 + threadIdx.x;   // 3 x 2 x 65536
    int w = g >> 17;
    int gg = g & 131071;
    int layer = gg >> 16, idx = gg & 65535;
    int n = idx >> 8, k = idx & 255;
    const void* W = (w==0)?Wq:((w==1)?Wk:Wv);
    dst[(size_t)layer*196608 + (size_t)w*65536 + (size_t)n*256 + k] =
        ldb(W, (size_t)layer*65536 + (size_t)k*256 + n, isbf);
}
__global__ void pack_qkv_bias_k(const void* __restrict__ bq, const void* __restrict__ bk,
                                const void* __restrict__ bv, const int* __restrict__ flag,
                                float* __restrict__ dst){
    const int isbf = *flag;
    int g = blockIdx.x*256 + threadIdx.x;   // 2 x 768
    if (g < 2*768) {
        int layer = g / 768, j = g - layer*768;
        int w = j >> 8, jj = j & 255;
        const void* B = (w==0)?bq:((w==1)?bk:bv);
        dst[g] = ldf(B, (size_t)layer*256 + jj, isbf);
    }
}
// packed src/dst: dst[layer][64][256], rows 0-31 = Wsrc^T, 32-63 = Wdst^T
__global__ void trans_sd_pack_k(const void* __restrict__ Ws, const void* __restrict__ Wd,
                                const int* __restrict__ flag, ush* __restrict__ dst){
    const int isbf = *flag;
    int g = blockIdx.x*256 + threadIdx.x;   // 2 x 2 x 8192
    int w = g >> 14;
    int gg = g & 16383;
    int layer = gg >> 13, idx = gg & 8191;
    int n = idx >> 8, k = idx & 255;
    const void* W = w ? Wd : Ws;
    dst[(size_t)layer*16384 + (size_t)(w*32 + n)*256 + k] =
        ldb(W, (size_t)layer*8192 + (size_t)k*32 + n, isbf);
}
__global__ void trans_gen_k(const void* __restrict__ W, const int* __restrict__ flag,
                            ush* __restrict__ dst, int K, int N, int total){
    const int isbf = *flag;
    int g = blockIdx.x*256 + threadIdx.x;
    if (g < total) {
        int per = K*N;
        int layer = g / per;
        int rem = g - layer*per;
        int n = rem / K, k = rem - n*K;
        dst[g] = ldb(W, (size_t)layer*per + (size_t)k*N + n, isbf);
    }
}

// ---------------- CSR build: counts -> scan -> fill ----------------
__global__ void count_k(const int* __restrict__ dst, int* __restrict__ cnt, int nE){
    int g = blockIdx.x*256 + threadIdx.x;
    if (g < nE) atomicAdd(&cnt[dst[g]], 1);
}
__global__ __launch_bounds__(256) void scan_blk_k(const int* __restrict__ cnt,
                                                  int* __restrict__ out,
                                                  int* __restrict__ bsum, int n){
    __shared__ int s[256];
    const int t = threadIdx.x;
    const int b0 = blockIdx.x*1024;
    int v[4], pre[4], tsum = 0;
    #pragma unroll
    for (int j=0;j<4;++j){
        int idx = b0 + t*4 + j;
        v[j] = (idx < n) ? cnt[idx] : 0;
        pre[j] = tsum; tsum += v[j];
    }
    s[t] = tsum; __syncthreads();
    for (int off=1; off<256; off<<=1){
        int x = (t>=off) ? s[t-off] : 0;
        __syncthreads();
        s[t] += x;
        __syncthreads();
    }
    int texc = s[t] - tsum;
    #pragma unroll
    for (int j=0;j<4;++j){
        int idx = b0 + t*4 + j;
        if (idx < n) out[idx] = texc + pre[j];
    }
    if (t == 255) bsum[blockIdx.x] = s[255];
}
__global__ __launch_bounds__(256) void scan_top_k(int* __restrict__ bsum, int nb){
    __shared__ int s[256];
    const int t = threadIdx.x;
    int v = (t < nb) ? bsum[t] : 0;
    s[t] = v; __syncthreads();
    for (int off=1; off<256; off<<=1){
        int x = (t>=off) ? s[t-off] : 0;
        __syncthreads();
        s[t] += x;
        __syncthreads();
    }
    if (t < nb) bsum[t] = s[t] - v;   // exclusive
}
__global__ void scan_add_k(int* __restrict__ out, const int* __restrict__ bsum, int n){
    int g = blockIdx.x*256 + threadIdx.x;
    if (g < n) out[g] += bsum[g >> 10];
}
__global__ void seal_k(int* __restrict__ ptr, int idx, int val){
    if (threadIdx.x == 0 && blockIdx.x == 0) ptr[idx] = val;
}
__global__ void copy_i_k(const int* __restrict__ a, int* __restrict__ b, int n){
    int g = blockIdx.x*256 + threadIdx.x;
    if (g < n) b[g] = a[g];
}
__global__ void fill_k(const int* __restrict__ dst, int* __restrict__ cur,
                       int* __restrict__ eidl, int nE){
    int g = blockIdx.x*256 + threadIdx.x;
    if (g < nE){
        int pos = atomicAdd(&cur[dst[g]], 1);
        eidl[pos] = g;
    }
}

// ---------------- MFMA GEMM: C[M,N] = A(fp32)@WT^T + bias (opt relu) ----------------
// WT: bf16 [N][K] (pre-transposed). 64x64 tile, 4 waves, v_mfma_f32_16x16x32_bf16.
// flags: 2 = RELU, 4 = has-bias
__global__ __launch_bounds__(256) void mgemm_k(
    const float* __restrict__ A, const ush* __restrict__ WT,
    const void* __restrict__ bias, size_t boff,
    float* __restrict__ C, const int* __restrict__ flag,
    int M, int N, int K, int flags)
{
    __shared__ __align__(16) ush As[64*40];
    __shared__ __align__(16) ush Ws[64*40];
    const int isbf = *flag;
    const int t = threadIdx.x;
    const int m0 = blockIdx.y*64, n0 = blockIdx.x*64;
    const int wave = t>>6, lane = t&63;
    const int quad = lane>>4, l15 = lane&15;
    const int r = t>>2, kq = (t&3)*8;

    frag_cd acc[4];
    #pragma unroll
    for (int tl=0; tl<4; ++tl)
        #pragma unroll
        for (int j=0;j<4;++j) acc[tl][j] = 0.f;

    const float* aprow = A + (size_t)(m0+r)*K + kq;
    const bool wok = (n0 + r) < N;
    const ush* wprow = WT + (size_t)(n0 + (wok ? r : 0))*K + kq;

    float4 a0, a1; uint4 wv;
    auto loadT = [&](int kk){
        a0 = *(const float4*)(aprow + kk);
        a1 = *(const float4*)(aprow + kk + 4);
        wv = wok ? *(const uint4*)(wprow + kk) : make_uint4(0u,0u,0u,0u);
    };
    loadT(0);

    for (int kk = 0; kk < K; kk += 32) {
        ushort4 p0 = make_ushort4(f2b(a0.x), f2b(a0.y), f2b(a0.z), f2b(a0.w));
        ushort4 p1 = make_ushort4(f2b(a1.x), f2b(a1.y), f2b(a1.z), f2b(a1.w));
        *(ushort4*)&As[r*40 + kq]     = p0;
        *(ushort4*)&As[r*40 + kq + 4] = p1;
        *(uint4*)&Ws[r*40 + kq] = wv;
        __syncthreads();
        if (kk + 32 < K) loadT(kk + 32);
        frag_ab af = *(const frag_ab*)&As[(wave*16 + l15)*40 + quad*8];
        #pragma unroll
        for (int tl = 0; tl < 4; ++tl) {
            frag_ab bf = *(const frag_ab*)&Ws[(tl*16 + l15)*40 + quad*8];
            acc[tl] = __builtin_amdgcn_mfma_f32_16x16x32_bf16(af, bf, acc[tl], 0, 0, 0);
        }
        __syncthreads();
    }
    const bool do_relu = flags & 2;
    const bool has_b   = flags & 4;
    #pragma unroll
    for (int tl = 0; tl < 4; ++tl) {
        int col = n0 + tl*16 + l15;
        if (col < N) {
            float bv = has_b ? ldf(bias, boff + col, isbf) : 0.f;
            #pragma unroll
            for (int rg = 0; rg < 4; ++rg) {
                int row = m0 + wave*16 + quad*4 + rg;
                float v = acc[tl][rg] + bv;
                if (do_relu) v = fmaxf(v, 0.f);
                C[(size_t)row*N + col] = v;
            }
        }
    }
}

// ---------------- MFMA eq/ek/ev (+gathered mixed), 128 rows/block ----------------
// xsd: [4096][64], cols 0-31 = x@Wsrc, cols 32-63 = x@Wdst
__global__ __launch_bounds__(256) void eqkv_mfma_k(
    const float* __restrict__ lg, const float* __restrict__ xsd,
    const int* __restrict__ gsrc, const int* __restrict__ gdst,
    const void* __restrict__ Wq, const void* __restrict__ Wk, const void* __restrict__ Wv,
    size_t woff, const void* __restrict__ bq, size_t boff,
    float* __restrict__ eq, float* __restrict__ ek, float* __restrict__ ev,
    const int* __restrict__ flag)
{
    __shared__ __align__(16) ush mixs[128*40];
    __shared__ __align__(16) ush wts[3][32*40];
    __shared__ float bqs[32];
    const int isbf = *flag;
    const int t = threadIdx.x;
    const int e0 = blockIdx.x * 128;
    for (int i = t; i < 3*1024; i += 256) {
        int m = i >> 10, r2 = i & 1023;
        int n = r2 >> 5, k2 = r2 & 31;
        const void* W = (m==0) ? Wq : ((m==1) ? Wk : Wv);
        wts[m][n*40 + k2] = ldb(W, woff + (size_t)k2*32 + n, isbf);
    }
    if (t < 32) bqs[t] = ldf(bq, boff + t, isbf);
    {
        int r = t >> 1, c0 = (t & 1) * 16;
        int e = e0 + r;
        int s = gsrc[e], d2 = gdst[e];
        const float* lp = lg + (size_t)e*32 + c0;
        const float* sp = xsd + (size_t)s*64 + c0;
        const float* dp = xsd + (size_t)d2*64 + 32 + c0;
        #pragma unroll
        for (int j = 0; j < 16; ++j)
            mixs[r*40 + c0 + j] = f2b(lp[j] + sp[j] + dp[j]);
    }
    __syncthreads();
    const int wave = t >> 6, l15 = t & 15, quad = (t >> 4) & 3;
    #pragma unroll
    for (int mi = 0; mi < 2; ++mi) {
        const int mt = wave*2 + mi;
        frag_ab af = *(const frag_ab*)&mixs[(mt*16 + l15)*40 + quad*8];
        #pragma unroll
        for (int w = 0; w < 3; ++w) {
            float* outp = (w==0) ? eq : ((w==1) ? ek : ev);
            #pragma unroll
            for (int nt = 0; nt < 2; ++nt) {
                frag_ab bf = *(const frag_ab*)&wts[w][(nt*16 + l15)*40 + quad*8];
                frag_cd acc = {0.f, 0.f, 0.f, 0.f};
                acc = __builtin_amdgcn_mfma_f32_16x16x32_bf16(af, bf, acc, 0, 0, 0);
                const float bv = (w==0) ? bqs[nt*16 + l15] : 0.f;
                #pragma unroll
                for (int rg = 0; rg < 4; ++rg) {
                    int row = e0 + mt*16 + quad*4 + rg;
                    outp[(size_t)row*32 + nt*16 + l15] = acc[rg] + bv;
                }
            }
        }
    }
}

// ---------------- MFMA edge FFN: LN(A + relu(A@W1+b1)@W2 + b2); 64 rows/block ----------------
__global__ __launch_bounds__(256) void effn_mfma_k(
    const float* __restrict__ A,
    const void* __restrict__ W1, size_t w1off, const void* __restrict__ b1, size_t b1off,
    const void* __restrict__ W2, size_t w2off, const void* __restrict__ b2, size_t b2off,
    const void* __restrict__ g, const void* __restrict__ be, size_t goff,
    float* __restrict__ out, const int* __restrict__ flag)
{
    __shared__ __align__(16) ush w1t[128*40];    // W1^T: [n][k], k<32
    __shared__ __align__(16) ush w2t[32*136];    // W2^T: [n][k], k<128
    __shared__ __align__(16) ush hid[64*136];    // hidden bf16, [row][k]
    __shared__ float b1s[128], b2s[32];
    const int isbf = *flag;
    const int t = threadIdx.x;
    const int e0 = blockIdx.x * 64;
    const int wave = t >> 6, l15 = t & 15, quad = (t >> 4) & 3;

    for (int i = t; i < 4096; i += 256) {
        int n1 = i >> 5, k1 = i & 31;
        w1t[n1*40 + k1] = ldb(W1, w1off + (size_t)k1*128 + n1, isbf);
        int n2 = i >> 7, k2 = i & 127;
        w2t[n2*136 + k2] = ldb(W2, w2off + (size_t)k2*32 + n2, isbf);
    }
    if (t < 128) b1s[t] = ldf(b1, b1off + t, isbf);
    if (t < 32)  b2s[t] = ldf(b2, b2off + t, isbf);
    __syncthreads();

    // ---- P1: hid = relu(A@W1 + b1), one MFMA per N-tile (K=32) ----
    {
        const int m = wave*16 + l15;
        float4 a0 = *(const float4*)&A[(size_t)(e0+m)*32 + quad*8];
        float4 a1 = *(const float4*)&A[(size_t)(e0+m)*32 + quad*8 + 4];
        ush tmp[8] = {f2b(a0.x),f2b(a0.y),f2b(a0.z),f2b(a0.w),
                      f2b(a1.x),f2b(a1.y),f2b(a1.z),f2b(a1.w)};
        frag_ab af = *(frag_ab*)tmp;
        #pragma unroll
        for (int nt = 0; nt < 8; ++nt) {
            frag_ab bf = *(const frag_ab*)&w1t[(nt*16 + l15)*40 + quad*8];
            frag_cd acc = {0.f, 0.f, 0.f, 0.f};
            acc = __builtin_amdgcn_mfma_f32_16x16x32_bf16(af, bf, acc, 0, 0, 0);
            float bv = b1s[nt*16 + l15];
            #pragma unroll
            for (int rg = 0; rg < 4; ++rg) {
                int row = wave*16 + quad*4 + rg;
                hid[row*136 + nt*16 + l15] = f2b(fmaxf(acc[rg] + bv, 0.f));
            }
        }
    }
    __syncthreads();

    // ---- P2: C = hid@W2 (K=128); + b2 + residual; LN ----
    frag_cd acc2[2] = {{0.f,0.f,0.f,0.f},{0.f,0.f,0.f,0.f}};
    #pragma unroll
    for (int ks = 0; ks < 4; ++ks) {
        frag_ab af2 = *(const frag_ab*)&hid[(wave*16 + l15)*136 + ks*32 + quad*8];
        #pragma unroll
        for (int tl = 0; tl < 2; ++tl) {
            frag_ab bf2 = *(const frag_ab*)&w2t[(tl*16 + l15)*136 + ks*32 + quad*8];
            acc2[tl] = __builtin_amdgcn_mfma_f32_16x16x32_bf16(af2, bf2, acc2[tl], 0, 0, 0);
        }
    }
    const float g0  = ldf(g,  goff + l15, isbf),      g1v = ldf(g,  goff + 16 + l15, isbf);
    const float be0 = ldf(be, goff + l15, isbf),      be1 = ldf(be, goff + 16 + l15, isbf);
    const float bb0 = b2s[l15], bb1 = b2s[16 + l15];
    #pragma unroll
    for (int rg = 0; rg < 4; ++rg) {
        const int row = e0 + wave*16 + quad*4 + rg;
        float v0 = acc2[0][rg] + bb0 + A[(size_t)row*32 + l15];
        float v1 = acc2[1][rg] + bb1 + A[(size_t)row*32 + 16 + l15];
        float s = v0 + v1;
        s += __shfl_xor(s,1); s += __shfl_xor(s,2); s += __shfl_xor(s,4); s += __shfl_xor(s,8);
        const float mean = s * (1.f/32.f);
        float q = (v0-mean)*(v0-mean) + (v1-mean)*(v1-mean);
        q += __shfl_xor(q,1); q += __shfl_xor(q,2); q += __shfl_xor(q,4); q += __shfl_xor(q,8);
        const float inv = rsqrtf(q * (1.f/32.f) + 1e-5f);
        out[(size_t)row*32 + l15]      = (v0-mean)*inv*g0  + be0;
        out[(size_t)row*32 + 16 + l15] = (v1-mean)*inv*g1v + be1;
    }
}

// ---------------- LayerNorm (node rows, D=256) ----------------
__global__ __launch_bounds__(64) void ln_k(
    const float* __restrict__ a, const float* __restrict__ b,
    const void* __restrict__ g, const void* __restrict__ be, size_t goff,
    float* __restrict__ out, const int* __restrict__ flag, int D)
{
    const int isbf = *flag;
    const int row = blockIdx.x;
    const int t = threadIdx.x;
    float v[4];
    int cnt = 0;
    float s = 0.f;
    for (int i = t; i < D; i += 64) {
        float x = a[(size_t)row*D + i];
        if (b) x += b[(size_t)row*D + i];
        v[cnt++] = x; s += x;
    }
    #pragma unroll
    for (int off = 32; off > 0; off >>= 1) s += __shfl_down(s, off);
    s = __shfl(s, 0);
    const float mean = s / D;
    float qq = 0.f;
    for (int c2 = 0; c2 < cnt; ++c2) { float d = v[c2]-mean; qq += d*d; }
    #pragma unroll
    for (int off = 32; off > 0; off >>= 1) qq += __shfl_down(qq, off);
    qq = __shfl(qq, 0);
    const float inv = rsqrtf(fmaxf(qq, 0.f) / D + 1e-5f);
    cnt = 0;
    for (int i = t; i < D; i += 64)
        out[(size_t)row*D + i] = (v[cnt++] - mean)*inv*ldf(g, goff + i, isbf) + ldf(be, goff + i, isbf);
}

// ---------------- full-graph attention: (b,h,half) blocks, 8 waves split over src ----------------
// q/k/v read with row stride ldq (packed qkv buffer); o written at stride kND.
__global__ __launch_bounds__(512) void full_attn_k(
    const float* __restrict__ q, const float* __restrict__ k, const float* __restrict__ v,
    const void* __restrict__ rel, const int* __restrict__ feat, float* __restrict__ o,
    const int* __restrict__ flag, int ldq)
{
    __shared__ __align__(8) ush ks[128][36];
    __shared__ __align__(8) ush vs[128][36];
    __shared__ __align__(8) ush rs[128][36];
    __shared__ float pb[8][64][34];            // per-wave partials: m, l, acc[32]
    const int isbf = *flag;
    const int bid = blockIdx.x;
    const int b = bid >> 3, h = (bid >> 1) & 3, half = bid & 1;
    const int t = threadIdx.x;
    for (int i = t; i < 4096; i += 512) {
        int r = i >> 5, d = i & 31;
        rs[r][d] = ldb(rel, i, isbf);
        size_t base = ((size_t)(b*128 + r))*ldq + h*32 + d;
        ks[r][d] = f2b(k[base]);
        vs[r][d] = f2b(v[base]);
    }
    __syncthreads();
    const int wave = t >> 6, lane = t & 63;
    const int dst = half*64 + lane;
    float qr[32];
    { size_t base = ((size_t)(b*128 + dst))*ldq + h*32;
      #pragma unroll
      for (int d=0; d<32; ++d) qr[d] = q[base + d]; }
    const int* fp = feat + (size_t)b*16384 + dst;
    const int s0 = wave*16;
    float m = -1e30f, l = 0.f;
    float acc[32];
    #pragma unroll
    for (int d=0; d<32; ++d) acc[d] = 0.f;
    int f = fp[s0*128];
    for (int sI = 0; sI < 16; ++sI) {
        const int s = s0 + sI;
        int fn = (sI+1 < 16) ? fp[(s+1)*128] : 0;
        float er[32];
        float sc = 0.f;
        #pragma unroll
        for (int j2 = 0; j2 < 8; ++j2) {
            ushort4 eu = *(const ushort4*)&rs[f][j2*4];
            ushort4 ku = *(const ushort4*)&ks[s][j2*4];
            float e0 = b2f(eu.x), e1 = b2f(eu.y), e2 = b2f(eu.z), e3 = b2f(eu.w);
            er[j2*4+0]=e0; er[j2*4+1]=e1; er[j2*4+2]=e2; er[j2*4+3]=e3;
            sc += (b2f(ku.x)+e0)*qr[j2*4+0] + (b2f(ku.y)+e1)*qr[j2*4+1]
                + (b2f(ku.z)+e2)*qr[j2*4+2] + (b2f(ku.w)+e3)*qr[j2*4+3];
        }
        sc *= kScaleN;
        float mn = fmaxf(m, sc);
        float c0 = __expf(m - mn);
        float pp = __expf(sc - mn);
        l = l*c0 + pp;
        #pragma unroll
        for (int j2 = 0; j2 < 8; ++j2) {
            ushort4 vu = *(const ushort4*)&vs[s][j2*4];
            acc[j2*4+0] = acc[j2*4+0]*c0 + pp*(b2f(vu.x)+er[j2*4+0]);
            acc[j2*4+1] = acc[j2*4+1]*c0 + pp*(b2f(vu.y)+er[j2*4+1]);
            acc[j2*4+2] = acc[j2*4+2]*c0 + pp*(b2f(vu.z)+er[j2*4+2]);
            acc[j2*4+3] = acc[j2*4+3]*c0 + pp*(b2f(vu.w)+er[j2*4+3]);
        }
        m = mn; f = fn;
    }
    pb[wave][lane][0] = m;
    pb[wave][lane][1] = l;
    #pragma unroll
    for (int d=0; d<32; ++d) pb[wave][lane][2+d] = acc[d];
    __syncthreads();
    // merge: thread (lane2, grp) handles dims [grp*4, grp*4+4) of dst=half*64+lane2
    {
        const int lane2 = t & 63, grp = t >> 6;   // grp in [0,8)
        float mw[8], lw[8];
        #pragma unroll
        for (int w=0; w<8; ++w){ mw[w]=pb[w][lane2][0]; lw[w]=pb[w][lane2][1]; }
        float M = mw[0];
        #pragma unroll
        for (int w=1; w<8; ++w) M = fmaxf(M, mw[w]);
        float sw[8];
        float L = 0.f;
        #pragma unroll
        for (int w=0; w<8; ++w){ sw[w] = __expf(mw[w]-M); L += lw[w]*sw[w]; }
        const float inv = 1.f / fmaxf(L, 1e-30f);
        size_t base = ((size_t)(b*128 + half*64 + lane2))*kND + h*32 + grp*4;
        #pragma unroll
        for (int d=0; d<4; ++d) {
            float a = 0.f;
            #pragma unroll
            for (int w=0; w<8; ++w) a += pb[w][lane2][2+grp*4+d]*sw[w];
            o[base + d] = a*inv;
        }
    }
}

// ---------------- local-graph GATHER attention (heads 4..7) ----------------
// block per node, wave per head; 4 edge slots per wave (16 lanes each).
__global__ __launch_bounds__(256) void loc_gather_k(
    const float* __restrict__ q, const float* __restrict__ k, const float* __restrict__ v,
    const float* __restrict__ lg, const int* __restrict__ gsrc,
    const int* __restrict__ rowp, const int* __restrict__ eidl,
    float* __restrict__ o, int ldq)
{
    const int n = blockIdx.x;
    const int h = threadIdx.x >> 6;        // wave = local head (0..3 -> heads 4..7)
    const int lane = threadIdx.x & 63;
    const int g = lane >> 4;               // edge slot within wave (0..3)
    const int d0 = (lane & 15) * 2;
    const size_t hoff = (size_t)(4 + h) * 32 + d0;
    const float2 q2 = *(const float2*)&q[(size_t)n*ldq + hoff];
    const int beg = rowp[n], end = rowp[n+1];
    const int deg = end - beg;
    float m = -1e30f, l = 0.f, ax = 0.f, ay = 0.f;
    if (deg > 0) {
        const int nIter = (deg + 3) >> 2;
        int idx = beg + g;
        int ce = eidl[min(idx, end-1)];
        int cs = gsrc[ce];
        for (int it = 0; it < nIter; ++it) {
            const bool valid = idx < end;
            const int e = ce, s = cs;
            idx += 4;
            if (it + 1 < nIter) { ce = eidl[min(idx, end-1)]; cs = gsrc[ce]; }
            const float2 kv = *(const float2*)&k[(size_t)s*ldq + hoff];
            const float2 lv = *(const float2*)&lg[(size_t)e*32 + d0];
            const float2 vv = *(const float2*)&v[(size_t)s*ldq + hoff];
            float part = (kv.x+lv.x)*q2.x + (kv.y+lv.y)*q2.y;
            part += __shfl_xor(part, 1);
            part += __shfl_xor(part, 2);
            part += __shfl_xor(part, 4);
            part += __shfl_xor(part, 8);
            const float sc = part * kScaleN;
            const float mn = valid ? fmaxf(m, sc) : m;
            const float c  = __expf(m - mn);
            const float pp = valid ? __expf(sc - mn) : 0.f;
            l  = l*c  + pp;
            ax = ax*c + pp*(vv.x+lv.x);
            ay = ay*c + pp*(vv.y+lv.y);
            m  = mn;
        }
        #pragma unroll
        for (int off = 16; off <= 32; off <<= 1) {
            const float mo = __shfl_xor(m, off);
            const float lo = __shfl_xor(l, off);
            const float xo = __shfl_xor(ax, off);
            const float yo = __shfl_xor(ay, off);
            const float M  = fmaxf(m, mo);
            const float c1 = __expf(m - M);
            const float c2 = __expf(mo - M);
            l  = l*c1  + lo*c2;
            ax = ax*c1 + xo*c2;
            ay = ay*c1 + yo*c2;
            m  = M;
        }
    }
    if (g == 0) {
        const float inv = 1.f / fmaxf(l, 1e-30f);
        *(float2*)&o[(size_t)n*kND + hoff] = make_float2(ax*inv, ay*inv);
    }
}

// ---------------- fused line-graph attention + Wo GEMM + LN ----------------
// block = 32 dst-edges x 8 heads. Phase 1: gather attention into LDS (bf16).
// Phase 2: 32x32 @ Wo (4 MFMA) + bias + residual. Phase 3: LN -> out.
__global__ __launch_bounds__(256) void lgs_ewo_k(
    const float* __restrict__ eq, const float* __restrict__ ek, const float* __restrict__ ev,
    const int* __restrict__ lsrc, const int* __restrict__ rowp, const int* __restrict__ eidl,
    const float* __restrict__ res,
    const void* __restrict__ Wo, size_t wooff, const void* __restrict__ bo, size_t booff,
    const void* __restrict__ g1, const void* __restrict__ be1, size_t g1off,
    float* __restrict__ out, const int* __restrict__ flag)
{
    __shared__ __align__(16) ush ows[32*40];     // attention output, bf16 [row][col]
    __shared__ __align__(16) ush wos[32*40];     // Wo^T [n][k]
    __shared__ float cs[32][36];                 // GEMM out + bias + residual
    __shared__ float bos[32], gs[32], bs[32];
    const int isbf = *flag;
    const int t = threadIdx.x;
    const int base = blockIdx.x * 32;
    for (int i = t; i < 1024; i += 256) {
        int n = i >> 5, k2 = i & 31;
        wos[n*40 + k2] = ldb(Wo, wooff + (size_t)k2*32 + n, isbf);
    }
    if (t < 32) {
        bos[t] = ldf(bo, booff + t, isbf);
        gs[t]  = ldf(g1, g1off + t, isbf);
        bs[t]  = ldf(be1, g1off + t, isbf);
    }
    // ---- phase 1: gather attention, thread = (dst-edge, head) ----
    {
        const int d2 = base + (t >> 3), h = t & 7;
        const float4 q4 = *(const float4*)&eq[(size_t)d2*32 + h*4];
        const int beg = rowp[d2], end = rowp[d2+1];
        float m = -1e30f, l = 0.f;
        float4 acc = make_float4(0.f,0.f,0.f,0.f);
        int i = beg;
        int e = 0, s = 0;
        if (i < end) { e = eidl[i]; s = lsrc[e]; }
        while (i < end) {
            const int sc_s = s;
            ++i;
            if (i < end) { e = eidl[i]; s = lsrc[e]; }   // prefetch next (e,s)
            const float4 k4 = *(const float4*)&ek[(size_t)sc_s*32 + h*4];
            const float4 v4 = *(const float4*)&ev[(size_t)sc_s*32 + h*4];
            float sc = (k4.x*q4.x + k4.y*q4.y + k4.z*q4.z + k4.w*q4.w) * 0.5f;
            float mn = fmaxf(m, sc);
            float c = __expf(m - mn);
            float pp = __expf(sc - mn);
            l = l*c + pp;
            acc.x = acc.x*c + pp*v4.x;
            acc.y = acc.y*c + pp*v4.y;
            acc.z = acc.z*c + pp*v4.z;
            acc.w = acc.w*c + pp*v4.w;
            m = mn;
        }
        const float inv = 1.f / fmaxf(l, 1e-30f);
        const int r = t >> 3, c0 = h*4;
        ows[r*40 + c0 + 0] = f2b(acc.x*inv);
        ows[r*40 + c0 + 1] = f2b(acc.y*inv);
        ows[r*40 + c0 + 2] = f2b(acc.z*inv);
        ows[r*40 + c0 + 3] = f2b(acc.w*inv);
    }
    __syncthreads();
    // ---- phase 2: 32x32 GEMM, wave w: row tile mt=w&1, col tile nt=w>>1 ----
    {
        const int wave = t >> 6, l15 = t & 15, quad = (t >> 4) & 3;
        const int mt = wave & 1, nt = wave >> 1;
        frag_ab af = *(const frag_ab*)&ows[(mt*16 + l15)*40 + quad*8];
        frag_ab bf = *(const frag_ab*)&wos[(nt*16 + l15)*40 + quad*8];
        frag_cd acc = {0.f, 0.f, 0.f, 0.f};
        acc = __builtin_amdgcn_mfma_f32_16x16x32_bf16(af, bf, acc, 0, 0, 0);
        #pragma unroll
        for (int rg = 0; rg < 4; ++rg) {
            const int row = mt*16 + quad*4 + rg;
            const int col = nt*16 + l15;
            cs[row][col] = acc[rg] + bos[col] + res[(size_t)(base+row)*32 + col];
        }
    }
    __syncthreads();
    // ---- phase 3: LN per row, 8 threads/row ----
    {
        const int row = t >> 3, c0 = (t & 7) * 4;
        const float v0 = cs[row][c0], v1 = cs[row][c0+1];
        const float v2 = cs[row][c0+2], v3 = cs[row][c0+3];
        float s = v0+v1+v2+v3;
        s += __shfl_xor(s,1); s += __shfl_xor(s,2); s += __shfl_xor(s,4);
        const float mean = s * (1.f/32.f);
        float qq = (v0-mean)*(v0-mean)+(v1-mean)*(v1-mean)
                 + (v2-mean)*(v2-mean)+(v3-mean)*(v3-mean);
        qq += __shfl_xor(qq,1); qq += __shfl_xor(qq,2); qq += __shfl_xor(qq,4);
        const float inv = rsqrtf(qq * (1.f/32.f) + 1e-5f);
        float o0 = (v0-mean)*inv*gs[c0+0] + bs[c0+0];
        float o1 = (v1-mean)*inv*gs[c0+1] + bs[c0+1];
        float o2 = (v2-mean)*inv*gs[c0+2] + bs[c0+2];
        float o3 = (v3-mean)*inv*gs[c0+3] + bs[c0+3];
        *(float4*)&out[(size_t)(base+row)*32 + c0] = make_float4(o0,o1,o2,o3);
    }
}

// ---------------- output ----------------
__global__ void out_k(const float* __restrict__ xf, const float* __restrict__ lgf,
                      void* __restrict__ out, const int* __restrict__ flag){
    const int isbf = *flag;
    int g = blockIdx.x*256 + threadIdx.x;
    float v = (g < kN*kND) ? xf[g] : lgf[g - kN*kND];
    if (isbf) ((bf16*)out)[g] = __float2bfloat16(v);
    else      ((float*)out)[g] = v;
}

// ---------------- host helper ----------------
static inline void mgemm(const float* A, const ush* WT, const void* bias, size_t boff,
                         float* C, const int* flag, int M, int N, int K, int flags,
                         hipStream_t s){
    dim3 grid((N+63)/64, M/64);
    mgemm_k<<<grid, 256, 0, s>>>(A, WT, bias, boff, C, flag, M, N, K, flags);
}

extern "C" void kernel_launch(void* const* d_in, const int* in_sizes, int n_in,
                              void* d_out, int out_size, void* d_ws, size_t ws_size,
                              hipStream_t stream) {
    const void* x_in      = d_in[0];
    const void* rel       = d_in[1];
    const int* g_src      = (const int*)d_in[4];
    const int* g_dst      = (const int*)d_in[5];
    const int* lg_src     = (const int*)d_in[6];
    const int* lg_dst     = (const int*)d_in[7];
    const int* edge_feat  = (const int*)d_in[8];
    const int* full_feat  = (const int*)d_in[9];
    const void* n_Wq   = d_in[10];
    const void* n_bq   = d_in[11];
    const void* n_Wk   = d_in[12];
    const void* n_bk   = d_in[13];
    const void* n_Wv   = d_in[14];
    const void* n_bv   = d_in[15];
    const void* n_Wo   = d_in[16];
    const void* n_bo   = d_in[17];
    const void* n_lng  = d_in[18];
    const void* n_lnb  = d_in[19];
    const void* n_fW1  = d_in[20];
    const void* n_fb1  = d_in[21];
    const void* n_fW2  = d_in[22];
    const void* n_fb2  = d_in[23];
    const void* n_flng = d_in[24];
    const void* n_flnb = d_in[25];
    const void* e_Wsrc = d_in[26];
    const void* e_Wdst = d_in[27];
    const void* e_Wq   = d_in[28];
    const void* e_bq   = d_in[29];
    const void* e_Wk   = d_in[30];
    const void* e_Wv   = d_in[31];
    const void* e_Wo   = d_in[32];
    const void* e_bo   = d_in[33];
    const void* e_lng  = d_in[34];
    const void* e_lnb  = d_in[35];
    const void* e_fW1  = d_in[36];
    const void* e_fb1  = d_in[37];
    const void* e_fW2  = d_in[38];
    const void* e_fb2  = d_in[39];
    const void* e_flng = d_in[40];
    const void* e_flnb = d_in[41];

    // ---- workspace carve-up ----
    float* p = (float*)d_ws;
    size_t off = 0;
    auto AL = [&](size_t n){ float* r = p + off; off += n; return r; };
    int* flagp = (int*)AL(64);
    float* xA   = AL((size_t)kN*kND);
    float* xB   = AL((size_t)kN*kND);
    float* xM   = AL((size_t)kN*kND);
    float* qkvb = AL((size_t)kN*768);
    float* ob   = AL((size_t)kN*kND);
    float* tN   = AL((size_t)kN*kND);
    float* nh   = AL((size_t)kN*1024);
    float* lgA  = AL((size_t)kEL*kED);
    float* lgB  = AL((size_t)kEL*kED);
    float* lgM  = AL((size_t)kEL*kED);
    float* eqb  = AL((size_t)kEL*kED);
    float* ekb  = AL((size_t)kEL*kED);
    float* evb  = AL((size_t)kEL*kED);
    float* xsd  = AL((size_t)kN*64);
    // CSR structures
    int* cntL  = (int*)AL(kN);
    int* rowL  = (int*)AL(kN + 64);
    int* curL  = (int*)AL(kN);
    int* eidL  = (int*)AL(kEL);
    int* cntG  = (int*)AL(kEL);
    int* rowG  = (int*)AL(kEL + 64);
    int* curG  = (int*)AL(kEL);
    int* eidG  = (int*)AL(kELG);
    int* bsum  = (int*)AL(256);
    // pre-transposed bf16 weights [N][K], per-layer contiguous
    ush* wtQKV = (ush*)AL(196608);   // [L][768][256] bf16
    float* bQKV = AL(2*768);
    ush* wtO  = (ush*)AL(65536);
    ush* wtF1 = (ush*)AL(262144);
    ush* wtF2 = (ush*)AL(262144);
    ush* wtSD = (ush*)AL(16384);     // [L][64][256] bf16
    if (ws_size < off * sizeof(float)) return;

    detect_k<<<1, 64, 0, stream>>>((const ush*)x_in, flagp);
    cast_x_k<<<(kN*kND)/256, 256, 0, stream>>>(x_in, xA, flagp, kN*kND);
    init_lg_k<<<(kEL*kED)/256, 256, 0, stream>>>(rel, edge_feat, lgA, flagp);

    // ---- weight pre-transpose (once) ----
    trans_qkv_pack_k<<<1536, 256, 0, stream>>>(n_Wq, n_Wk, n_Wv, flagp, wtQKV);
    pack_qkv_bias_k<<<6, 256, 0, stream>>>(n_bq, n_bk, n_bv, flagp, bQKV);
    trans_gen_k<<<512, 256, 0, stream>>>(n_Wo, flagp, wtO, 256, 256, 131072);
    trans_gen_k<<<2048, 256, 0, stream>>>(n_fW1, flagp, wtF1, 256, 1024, 524288);
    trans_gen_k<<<2048, 256, 0, stream>>>(n_fW2, flagp, wtF2, 1024, 256, 524288);
    trans_sd_pack_k<<<128, 256, 0, stream>>>(e_Wsrc, e_Wdst, flagp, wtSD);

    // ---- CSR build (both graphs) ----
    hipMemsetAsync(cntL, 0, kN*sizeof(int), stream);
    hipMemsetAsync(cntG, 0, kEL*sizeof(int), stream);
    count_k<<<kEL/256, 256, 0, stream>>>(g_dst, cntL, kEL);
    count_k<<<kELG/256, 256, 0, stream>>>(lg_dst, cntG, kELG);
    scan_blk_k<<<kN/1024, 256, 0, stream>>>(cntL, rowL, bsum, kN);
    scan_top_k<<<1, 256, 0, stream>>>(bsum, kN/1024);
    scan_add_k<<<kN/256, 256, 0, stream>>>(rowL, bsum, kN);
    seal_k<<<1, 64, 0, stream>>>(rowL, kN, kEL);
    scan_blk_k<<<kEL/1024, 256, 0, stream>>>(cntG, rowG, bsum, kEL);
    scan_top_k<<<1, 256, 0, stream>>>(bsum, kEL/1024);
    scan_add_k<<<kEL/256, 256, 0, stream>>>(rowG, bsum, kEL);
    seal_k<<<1, 64, 0, stream>>>(rowG, kEL, kELG);
    copy_i_k<<<kN/256, 256, 0, stream>>>(rowL, curL, kN);
    copy_i_k<<<kEL/256, 256, 0, stream>>>(rowG, curG, kEL);
    fill_k<<<kEL/256, 256, 0, stream>>>(g_dst, curL, eidL, kEL);
    fill_k<<<kELG/256, 256, 0, stream>>>(lg_dst, curG, eidG, kELG);

    float* xc = xA;  float* xn = xB;
    float* lgc = lgA; float* lgn = lgB;

    for (int i = 0; i < kL; ++i) {
        const size_t oeW  = (size_t)i*kED*kED;
        const size_t oefW1= (size_t)i*kED*128;
        const size_t oefW2= (size_t)i*128*kED;
        const size_t o256 = (size_t)i*kND;
        const size_t o1024= (size_t)i*1024;
        const size_t o32  = (size_t)i*kED;
        const size_t o128 = (size_t)i*128;

        // ===== node update =====
        mgemm(xc, wtQKV + (size_t)i*196608, bQKV, (size_t)i*768, qkvb, flagp,
              kN, 768, kND, 4, stream);
        full_attn_k<<<256, 512, 0, stream>>>(qkvb, qkvb+256, qkvb+512, rel, full_feat,
                                             ob, flagp, 768);
        loc_gather_k<<<kN, 256, 0, stream>>>(qkvb, qkvb+256, qkvb+512, lgc, g_src,
                                             rowL, eidL, ob, 768);
        mgemm(ob, wtO + (size_t)i*65536, n_bo, o256, tN, flagp, kN, kND, kND, 4, stream);
        ln_k<<<kN, 64, 0, stream>>>(xc, tN, n_lng, n_lnb, o256, xM, flagp, kND);
        mgemm(xM, wtF1 + (size_t)i*262144, n_fb1, o1024, nh, flagp, kN, 1024, kND, 4|2, stream);
        mgemm(nh, wtF2 + (size_t)i*262144, n_fb2, o256, tN, flagp, kN, kND, 1024, 4, stream);
        ln_k<<<kN, 64, 0, stream>>>(xM, tN, n_flng, n_flnb, o256, xn, flagp, kND);

        // ===== edge update (uses PRE-update xc, lgc) =====
        mgemm(xc, wtSD + (size_t)i*16384, nullptr, 0, xsd, flagp, kN, 64, kND, 0, stream);
        eqkv_mfma_k<<<kEL/128, 256, 0, stream>>>(lgc, xsd, g_src, g_dst,
                                                 e_Wq, e_Wk, e_Wv, oeW, e_bq, o32,
                                                 eqb, ekb, evb, flagp);
        lgs_ewo_k<<<kEL/32, 256, 0, stream>>>(eqb, ekb, evb, lg_src, rowG, eidG,
                                              lgc, e_Wo, oeW, e_bo, o32,
                                              e_lng, e_lnb, o32, lgM, flagp);
        effn_mfma_k<<<kEL/64, 256, 0, stream>>>(lgM, e_fW1, oefW1, e_fb1, o128,
                                                e_fW2, oefW2, e_fb2, o32,
                                                e_flng, e_flnb, o32, lgn, flagp);

        { float* t = xc; xc = xn; xn = t; }
        { float* t = lgc; lgc = lgn; lgn = t; }
    }

    out_k<<<(kN*kND + kEL*kED)/256, 256, 0, stream>>>(xc, lgc, d_out, flagp);
}

// Round 3
// 635.783 us; speedup vs baseline: 1.2140x; 1.0929x over previous
//
#include <hip/hip_runtime.h>
#include <hip/hip_bf16.h>

typedef __hip_bfloat16 bf16;
typedef unsigned short ush;

static constexpr int kN   = 4096;    // nodes
static constexpr int kND  = 256;     // hidden
static constexpr int kEL  = 131072;  // local edges
static constexpr int kED  = 32;      // edge dim
static constexpr int kELG = 262144;  // line-graph edges
static constexpr int kL   = 2;
static constexpr float kScaleN = 0.17677669529663687f; // 1/sqrt(32)

using frag_ab = __attribute__((ext_vector_type(8))) short;   // 8 bf16 (4 VGPRs)
using frag_cd = __attribute__((ext_vector_type(4))) float;   // 4 fp32

__device__ __forceinline__ float ldf(const void* p, size_t i, int isbf){
    return isbf ? __bfloat162float(((const bf16*)p)[i]) : ((const float*)p)[i];
}
__device__ __forceinline__ ush f2b(float f){ bf16 h = __float2bfloat16(f); return *(ush*)&h; }
__device__ __forceinline__ float b2f(ush u){ return __uint_as_float(((unsigned)u)<<16); }
__device__ __forceinline__ ush ldb(const void* p, size_t i, int isbf){
    return isbf ? ((const ush*)p)[i] : f2b(((const float*)p)[i]);
}

// ---------------- dtype detection ----------------
__global__ void detect_k(const ush* __restrict__ xin, int* __restrict__ flag){
    if (threadIdx.x == 0 && blockIdx.x == 0) {
        int plausible = 0;
        for (int i = 0; i < 128; ++i) {
            ush u = xin[i];
            int e = (u >> 7) & 0xFF;
            if (e == 0 || (e >= 110 && e <= 140)) ++plausible;
        }
        *flag = (plausible >= 102) ? 1 : 0;
    }
}

// ---------------- casts / init ----------------
__global__ void cast_x_k(const void* __restrict__ xin, float* __restrict__ xout,
                         const int* __restrict__ flag, int n){
    const int isbf = *flag;
    int g = blockIdx.x*256 + threadIdx.x;
    if (g < n) xout[g] = ldf(xin, g, isbf);
}
__global__ void init_lg_k(const void* __restrict__ rel, const int* __restrict__ feat,
                          float* __restrict__ lg, const int* __restrict__ flag){
    const int isbf = *flag;
    int g = blockIdx.x*256 + threadIdx.x;   // over kEL*32
    int e = g >> 5, d = g & 31;
    lg[g] = ldf(rel, (size_t)feat[e]*kED + d, isbf);
}

// ---------------- weight pre-transpose to bf16 [N][K] ----------------
// packed QKV: dst[layer][768][256], rows 0-255 = Wq^T, 256-511 = Wk^T, 512-767 = Wv^T
__global__ void trans_qkv_pack_k(const void* __restrict__ Wq, const void* __restrict__ Wk,
                                 const void* __restrict__ Wv, const int* __restrict__ flag,
                                 ush* __restrict__ dst){
    const int isbf = *flag;
    int g = blockIdx.x*256 + threadIdx.x;   // 3 x 2 x 65536
    int w = g >> 17;
    int gg = g & 131071;
    int layer = gg >> 16, idx = gg & 65535;
    int n = idx >> 8, k = idx & 255;
    const void* W = (w==0)?Wq:((w==1)?Wk:Wv);
    dst[(size_t)layer*196608 + (size_t)w*65536 + (size_t)n*256 + k] =
        ldb(W, (size_t)layer*65536 + (size_t)k*256 + n, isbf);
}
__global__ void pack_qkv_bias_k(const void* __restrict__ bq, const void* __restrict__ bk,
                                const void* __restrict__ bv, const int* __restrict__ flag,
                                float* __restrict__ dst){
    const int isbf = *flag;
    int g = blockIdx.x*256 + threadIdx.x;   // 2 x 768
    if (g < 2*768) {
        int layer = g / 768, j = g - layer*768;
        int w = j >> 8, jj = j & 255;
        const void* B = (w==0)?bq:((w==1)?bk:bv);
        dst[g] = ldf(B, (size_t)layer*256 + jj, isbf);
    }
}
// packed src/dst: dst[layer][64][256], rows 0-31 = Wsrc^T, 32-63 = Wdst^T
__global__ void trans_sd_pack_k(const void* __restrict__ Ws, const void* __restrict__ Wd,
                                const int* __restrict__ flag, ush* __restrict__ dst){
    const int isbf = *flag;
    int g = blockIdx.x*256 + threadIdx.x;   // 2 x 2 x 8192
    int w = g >> 14;
    int gg = g & 16383;
    int layer = gg >> 13, idx = gg & 8191;
    int n = idx >> 8, k = idx & 255;
    const void* W = w ? Wd : Ws;
    dst[(size_t)layer*16384 + (size_t)(w*32 + n)*256 + k] =
        ldb(W, (size_t)layer*8192 + (size_t)k*32 + n, isbf);
}
__global__ void trans_gen_k(const void* __restrict__ W, const int* __restrict__ flag,
                            ush* __restrict__ dst, int K, int N, int total){
    const int isbf = *flag;
    int g = blockIdx.x*256 + threadIdx.x;
    if (g < total) {
        int per = K*N;
        int layer = g / per;
        int rem = g - layer*per;
        int n = rem / K, k = rem - n*K;
        dst[g] = ldb(W, (size_t)layer*per + (size_t)k*N + n, isbf);
    }
}

// ---------------- CSR build: counts -> scan -> fill ----------------
__global__ void count_k(const int* __restrict__ dst, int* __restrict__ cnt, int nE){
    int g = blockIdx.x*256 + threadIdx.x;
    if (g < nE) atomicAdd(&cnt[dst[g]], 1);
}
__global__ __launch_bounds__(256) void scan_blk_k(const int* __restrict__ cnt,
                                                  int* __restrict__ out,
                                                  int* __restrict__ bsum, int n){
    __shared__ int s[256];
    const int t = threadIdx.x;
    const int b0 = blockIdx.x*1024;
    int v[4], pre[4], tsum = 0;
    #pragma unroll
    for (int j=0;j<4;++j){
        int idx = b0 + t*4 + j;
        v[j] = (idx < n) ? cnt[idx] : 0;
        pre[j] = tsum; tsum += v[j];
    }
    s[t] = tsum; __syncthreads();
    for (int off=1; off<256; off<<=1){
        int x = (t>=off) ? s[t-off] : 0;
        __syncthreads();
        s[t] += x;
        __syncthreads();
    }
    int texc = s[t] - tsum;
    #pragma unroll
    for (int j=0;j<4;++j){
        int idx = b0 + t*4 + j;
        if (idx < n) out[idx] = texc + pre[j];
    }
    if (t == 255) bsum[blockIdx.x] = s[255];
}
__global__ __launch_bounds__(256) void scan_top_k(int* __restrict__ bsum, int nb){
    __shared__ int s[256];
    const int t = threadIdx.x;
    int v = (t < nb) ? bsum[t] : 0;
    s[t] = v; __syncthreads();
    for (int off=1; off<256; off<<=1){
        int x = (t>=off) ? s[t-off] : 0;
        __syncthreads();
        s[t] += x;
        __syncthreads();
    }
    if (t < nb) bsum[t] = s[t] - v;   // exclusive
}
__global__ void scan_add_k(int* __restrict__ out, const int* __restrict__ bsum, int n){
    int g = blockIdx.x*256 + threadIdx.x;
    if (g < n) out[g] += bsum[g >> 10];
}
__global__ void seal_k(int* __restrict__ ptr, int idx, int val){
    if (threadIdx.x == 0 && blockIdx.x == 0) ptr[idx] = val;
}
__global__ void copy_i_k(const int* __restrict__ a, int* __restrict__ b, int n){
    int g = blockIdx.x*256 + threadIdx.x;
    if (g < n) b[g] = a[g];
}
__global__ void fill_k(const int* __restrict__ dst, int* __restrict__ cur,
                       int* __restrict__ eidl, int nE){
    int g = blockIdx.x*256 + threadIdx.x;
    if (g < nE){
        int pos = atomicAdd(&cur[dst[g]], 1);
        eidl[pos] = g;
    }
}

// ---------------- MFMA GEMM: C[M,N] = A(fp32)@WT^T + bias (opt relu) ----------------
// WT: bf16 [N][K] (pre-transposed). 64x64 tile, 4 waves, v_mfma_f32_16x16x32_bf16.
// flags: 2 = RELU, 4 = has-bias
__global__ __launch_bounds__(256) void mgemm_k(
    const float* __restrict__ A, const ush* __restrict__ WT,
    const void* __restrict__ bias, size_t boff,
    float* __restrict__ C, const int* __restrict__ flag,
    int M, int N, int K, int flags)
{
    __shared__ __align__(16) ush As[64*40];
    __shared__ __align__(16) ush Ws[64*40];
    const int isbf = *flag;
    const int t = threadIdx.x;
    const int m0 = blockIdx.y*64, n0 = blockIdx.x*64;
    const int wave = t>>6, lane = t&63;
    const int quad = lane>>4, l15 = lane&15;
    const int r = t>>2, kq = (t&3)*8;

    frag_cd acc[4];
    #pragma unroll
    for (int tl=0; tl<4; ++tl)
        #pragma unroll
        for (int j=0;j<4;++j) acc[tl][j] = 0.f;

    const float* aprow = A + (size_t)(m0+r)*K + kq;
    const bool wok = (n0 + r) < N;
    const ush* wprow = WT + (size_t)(n0 + (wok ? r : 0))*K + kq;

    float4 a0, a1; uint4 wv;
    auto loadT = [&](int kk){
        a0 = *(const float4*)(aprow + kk);
        a1 = *(const float4*)(aprow + kk + 4);
        wv = wok ? *(const uint4*)(wprow + kk) : make_uint4(0u,0u,0u,0u);
    };
    loadT(0);

    for (int kk = 0; kk < K; kk += 32) {
        ushort4 p0 = make_ushort4(f2b(a0.x), f2b(a0.y), f2b(a0.z), f2b(a0.w));
        ushort4 p1 = make_ushort4(f2b(a1.x), f2b(a1.y), f2b(a1.z), f2b(a1.w));
        *(ushort4*)&As[r*40 + kq]     = p0;
        *(ushort4*)&As[r*40 + kq + 4] = p1;
        *(uint4*)&Ws[r*40 + kq] = wv;
        __syncthreads();
        if (kk + 32 < K) loadT(kk + 32);
        frag_ab af = *(const frag_ab*)&As[(wave*16 + l15)*40 + quad*8];
        #pragma unroll
        for (int tl = 0; tl < 4; ++tl) {
            frag_ab bf = *(const frag_ab*)&Ws[(tl*16 + l15)*40 + quad*8];
            acc[tl] = __builtin_amdgcn_mfma_f32_16x16x32_bf16(af, bf, acc[tl], 0, 0, 0);
        }
        __syncthreads();
    }
    const bool do_relu = flags & 2;
    const bool has_b   = flags & 4;
    #pragma unroll
    for (int tl = 0; tl < 4; ++tl) {
        int col = n0 + tl*16 + l15;
        if (col < N) {
            float bv = has_b ? ldf(bias, boff + col, isbf) : 0.f;
            #pragma unroll
            for (int rg = 0; rg < 4; ++rg) {
                int row = m0 + wave*16 + quad*4 + rg;
                float v = acc[tl][rg] + bv;
                if (do_relu) v = fmaxf(v, 0.f);
                C[(size_t)row*N + col] = v;
            }
        }
    }
}

// ---------------- MFMA eq/ek/ev (+gathered mixed), 128 rows/block ----------------
// xsd: [4096][64], cols 0-31 = x@Wsrc, cols 32-63 = x@Wdst
// WQKV: bf16, [3][L][32][32] (each [N][K] pre-transposed); woff = layer*1024
__global__ __launch_bounds__(256) void eqkv_mfma_k(
    const float* __restrict__ lg, const float* __restrict__ xsd,
    const int* __restrict__ gsrc, const int* __restrict__ gdst,
    const ush* __restrict__ WQKV, size_t woff,
    const void* __restrict__ bq, size_t boff,
    float* __restrict__ eq, float* __restrict__ ek, float* __restrict__ ev,
    const int* __restrict__ flag)
{
    __shared__ __align__(16) ush mixs[128*40];
    __shared__ __align__(16) ush wts[3][32*40];
    __shared__ float bqs[32];
    const int isbf = *flag;
    const int t = threadIdx.x;
    const int e0 = blockIdx.x * 128;
    #pragma unroll
    for (int i = t; i < 768; i += 256) {     // 3 matrices x 256 quads, coalesced
        int m = i >> 8, r2 = i & 255;
        int n = r2 >> 3, k4 = (r2 & 7) * 4;
        *(ushort4*)&wts[m][n*40 + k4] =
            *(const ushort4*)&WQKV[(size_t)m*2048 + woff + (size_t)n*32 + k4];
    }
    if (t < 32) bqs[t] = ldf(bq, boff + t, isbf);
    {
        int r = t >> 1, c0 = (t & 1) * 16;
        int e = e0 + r;
        int s = gsrc[e], d2 = gdst[e];
        const float* lp = lg + (size_t)e*32 + c0;
        const float* sp = xsd + (size_t)s*64 + c0;
        const float* dp = xsd + (size_t)d2*64 + 32 + c0;
        #pragma unroll
        for (int j = 0; j < 16; ++j)
            mixs[r*40 + c0 + j] = f2b(lp[j] + sp[j] + dp[j]);
    }
    __syncthreads();
    const int wave = t >> 6, l15 = t & 15, quad = (t >> 4) & 3;
    #pragma unroll
    for (int mi = 0; mi < 2; ++mi) {
        const int mt = wave*2 + mi;
        frag_ab af = *(const frag_ab*)&mixs[(mt*16 + l15)*40 + quad*8];
        #pragma unroll
        for (int w = 0; w < 3; ++w) {
            float* outp = (w==0) ? eq : ((w==1) ? ek : ev);
            #pragma unroll
            for (int nt = 0; nt < 2; ++nt) {
                frag_ab bf = *(const frag_ab*)&wts[w][(nt*16 + l15)*40 + quad*8];
                frag_cd acc = {0.f, 0.f, 0.f, 0.f};
                acc = __builtin_amdgcn_mfma_f32_16x16x32_bf16(af, bf, acc, 0, 0, 0);
                const float bv = (w==0) ? bqs[nt*16 + l15] : 0.f;
                #pragma unroll
                for (int rg = 0; rg < 4; ++rg) {
                    int row = e0 + mt*16 + quad*4 + rg;
                    outp[(size_t)row*32 + nt*16 + l15] = acc[rg] + bv;
                }
            }
        }
    }
}

// ---------------- MFMA edge FFN: LN(A + relu(A@W1+b1)@W2 + b2) ----------------
// 2 x 64-row tiles per block (weight staging amortized); hid is wave-private.
// W1T: bf16 [L][128][32]; W2T: bf16 [L][32][128]; offsets in elements.
__global__ __launch_bounds__(256) void effn_mfma_k(
    const float* __restrict__ A,
    const ush* __restrict__ W1T, size_t w1off, const void* __restrict__ b1, size_t b1off,
    const ush* __restrict__ W2T, size_t w2off, const void* __restrict__ b2, size_t b2off,
    const void* __restrict__ g, const void* __restrict__ be, size_t goff,
    float* __restrict__ out, const int* __restrict__ flag)
{
    __shared__ __align__(16) ush w1t[128*40];    // W1^T: [n][k], k<32
    __shared__ __align__(16) ush w2t[32*136];    // W2^T: [n][k], k<128
    __shared__ __align__(16) ush hid[64*136];    // hidden bf16, [row][k] (wave-private rows)
    __shared__ float b1s[128], b2s[32];
    const int isbf = *flag;
    const int t = threadIdx.x;
    const int wave = t >> 6, l15 = t & 15, quad = (t >> 4) & 3;

    #pragma unroll
    for (int i = t; i < 1024; i += 256) {        // coalesced ushort4 staging
        int n1 = i >> 3, k4 = (i & 7) * 4;
        *(ushort4*)&w1t[n1*40 + k4] = *(const ushort4*)&W1T[w1off + (size_t)n1*32 + k4];
        int n2 = i >> 5, kq2 = (i & 31) * 4;
        *(ushort4*)&w2t[n2*136 + kq2] = *(const ushort4*)&W2T[w2off + (size_t)n2*128 + kq2];
    }
    if (t < 128) b1s[t] = ldf(b1, b1off + t, isbf);
    if (t < 32)  b2s[t] = ldf(b2, b2off + t, isbf);
    __syncthreads();

    const float g0  = ldf(g,  goff + l15, isbf),      g1v = ldf(g,  goff + 16 + l15, isbf);
    const float be0 = ldf(be, goff + l15, isbf),      be1 = ldf(be, goff + 16 + l15, isbf);
    const float bb0 = b2s[l15], bb1 = b2s[16 + l15];

    for (int tt = 0; tt < 2; ++tt) {
        const int e0 = (blockIdx.x*2 + tt) * 64;
        // ---- P1: hid = relu(A@W1 + b1), one MFMA per N-tile (K=32) ----
        {
            const int m = wave*16 + l15;
            float4 a0 = *(const float4*)&A[(size_t)(e0+m)*32 + quad*8];
            float4 a1 = *(const float4*)&A[(size_t)(e0+m)*32 + quad*8 + 4];
            ush tmp[8] = {f2b(a0.x),f2b(a0.y),f2b(a0.z),f2b(a0.w),
                          f2b(a1.x),f2b(a1.y),f2b(a1.z),f2b(a1.w)};
            frag_ab af = *(frag_ab*)tmp;
            #pragma unroll
            for (int nt = 0; nt < 8; ++nt) {
                frag_ab bf = *(const frag_ab*)&w1t[(nt*16 + l15)*40 + quad*8];
                frag_cd acc = {0.f, 0.f, 0.f, 0.f};
                acc = __builtin_amdgcn_mfma_f32_16x16x32_bf16(af, bf, acc, 0, 0, 0);
                float bv = b1s[nt*16 + l15];
                #pragma unroll
                for (int rg = 0; rg < 4; ++rg) {
                    int row = wave*16 + quad*4 + rg;
                    hid[row*136 + nt*16 + l15] = f2b(fmaxf(acc[rg] + bv, 0.f));
                }
            }
        }
        // hid rows [16w,16w+16) are written and read only by wave w -> no barrier.
        // ---- P2: C = hid@W2 (K=128); + b2 + residual; LN ----
        frag_cd acc2[2] = {{0.f,0.f,0.f,0.f},{0.f,0.f,0.f,0.f}};
        #pragma unroll
        for (int ks = 0; ks < 4; ++ks) {
            frag_ab af2 = *(const frag_ab*)&hid[(wave*16 + l15)*136 + ks*32 + quad*8];
            #pragma unroll
            for (int tl = 0; tl < 2; ++tl) {
                frag_ab bf2 = *(const frag_ab*)&w2t[(tl*16 + l15)*136 + ks*32 + quad*8];
                acc2[tl] = __builtin_amdgcn_mfma_f32_16x16x32_bf16(af2, bf2, acc2[tl], 0, 0, 0);
            }
        }
        #pragma unroll
        for (int rg = 0; rg < 4; ++rg) {
            const int row = e0 + wave*16 + quad*4 + rg;
            float v0 = acc2[0][rg] + bb0 + A[(size_t)row*32 + l15];
            float v1 = acc2[1][rg] + bb1 + A[(size_t)row*32 + 16 + l15];
            float s = v0 + v1;
            s += __shfl_xor(s,1); s += __shfl_xor(s,2); s += __shfl_xor(s,4); s += __shfl_xor(s,8);
            const float mean = s * (1.f/32.f);
            float q = (v0-mean)*(v0-mean) + (v1-mean)*(v1-mean);
            q += __shfl_xor(q,1); q += __shfl_xor(q,2); q += __shfl_xor(q,4); q += __shfl_xor(q,8);
            const float inv = rsqrtf(q * (1.f/32.f) + 1e-5f);
            out[(size_t)row*32 + l15]      = (v0-mean)*inv*g0  + be0;
            out[(size_t)row*32 + 16 + l15] = (v1-mean)*inv*g1v + be1;
        }
    }
}

// ---------------- LayerNorm (node rows, D=256) ----------------
__global__ __launch_bounds__(64) void ln_k(
    const float* __restrict__ a, const float* __restrict__ b,
    const void* __restrict__ g, const void* __restrict__ be, size_t goff,
    float* __restrict__ out, const int* __restrict__ flag, int D)
{
    const int isbf = *flag;
    const int row = blockIdx.x;
    const int t = threadIdx.x;
    float v[4];
    int cnt = 0;
    float s = 0.f;
    for (int i = t; i < D; i += 64) {
        float x = a[(size_t)row*D + i];
        if (b) x += b[(size_t)row*D + i];
        v[cnt++] = x; s += x;
    }
    #pragma unroll
    for (int off = 32; off > 0; off >>= 1) s += __shfl_down(s, off);
    s = __shfl(s, 0);
    const float mean = s / D;
    float qq = 0.f;
    for (int c2 = 0; c2 < cnt; ++c2) { float d = v[c2]-mean; qq += d*d; }
    #pragma unroll
    for (int off = 32; off > 0; off >>= 1) qq += __shfl_down(qq, off);
    qq = __shfl(qq, 0);
    const float inv = rsqrtf(fmaxf(qq, 0.f) / D + 1e-5f);
    cnt = 0;
    for (int i = t; i < D; i += 64)
        out[(size_t)row*D + i] = (v[cnt++] - mean)*inv*ldf(g, goff + i, isbf) + ldf(be, goff + i, isbf);
}

// ---------------- full-graph attention: (b,h,half) blocks, 8 waves split over src ----------------
// q/k/v read with row stride ldq (packed qkv buffer); o written at stride kND.
__global__ __launch_bounds__(512) void full_attn_k(
    const float* __restrict__ q, const float* __restrict__ k, const float* __restrict__ v,
    const void* __restrict__ rel, const int* __restrict__ feat, float* __restrict__ o,
    const int* __restrict__ flag, int ldq)
{
    __shared__ __align__(8) ush ks[128][36];
    __shared__ __align__(8) ush vs[128][36];
    __shared__ __align__(8) ush rs[128][36];
    __shared__ float pb[8][64][34];            // per-wave partials: m, l, acc[32]
    const int isbf = *flag;
    const int bid = blockIdx.x;
    const int b = bid >> 3, h = (bid >> 1) & 3, half = bid & 1;
    const int t = threadIdx.x;
    for (int i = t; i < 4096; i += 512) {
        int r = i >> 5, d = i & 31;
        rs[r][d] = ldb(rel, i, isbf);
        size_t base = ((size_t)(b*128 + r))*ldq + h*32 + d;
        ks[r][d] = f2b(k[base]);
        vs[r][d] = f2b(v[base]);
    }
    __syncthreads();
    const int wave = t >> 6, lane = t & 63;
    const int dst = half*64 + lane;
    float qr[32];
    { size_t base = ((size_t)(b*128 + dst))*ldq + h*32;
      #pragma unroll
      for (int d=0; d<32; ++d) qr[d] = q[base + d]; }
    const int* fp = feat + (size_t)b*16384 + dst;
    const int s0 = wave*16;
    float m = -1e30f, l = 0.f;
    float acc[32];
    #pragma unroll
    for (int d=0; d<32; ++d) acc[d] = 0.f;
    int f = fp[s0*128];
    for (int sI = 0; sI < 16; ++sI) {
        const int s = s0 + sI;
        int fn = (sI+1 < 16) ? fp[(s+1)*128] : 0;
        float er[32];
        float sc = 0.f;
        #pragma unroll
        for (int j2 = 0; j2 < 8; ++j2) {
            ushort4 eu = *(const ushort4*)&rs[f][j2*4];
            ushort4 ku = *(const ushort4*)&ks[s][j2*4];
            float e0 = b2f(eu.x), e1 = b2f(eu.y), e2 = b2f(eu.z), e3 = b2f(eu.w);
            er[j2*4+0]=e0; er[j2*4+1]=e1; er[j2*4+2]=e2; er[j2*4+3]=e3;
            sc += (b2f(ku.x)+e0)*qr[j2*4+0] + (b2f(ku.y)+e1)*qr[j2*4+1]
                + (b2f(ku.z)+e2)*qr[j2*4+2] + (b2f(ku.w)+e3)*qr[j2*4+3];
        }
        sc *= kScaleN;
        float mn = fmaxf(m, sc);
        float c0 = __expf(m - mn);
        float pp = __expf(sc - mn);
        l = l*c0 + pp;
        #pragma unroll
        for (int j2 = 0; j2 < 8; ++j2) {
            ushort4 vu = *(const ushort4*)&vs[s][j2*4];
            acc[j2*4+0] = acc[j2*4+0]*c0 + pp*(b2f(vu.x)+er[j2*4+0]);
            acc[j2*4+1] = acc[j2*4+1]*c0 + pp*(b2f(vu.y)+er[j2*4+1]);
            acc[j2*4+2] = acc[j2*4+2]*c0 + pp*(b2f(vu.z)+er[j2*4+2]);
            acc[j2*4+3] = acc[j2*4+3]*c0 + pp*(b2f(vu.w)+er[j2*4+3]);
        }
        m = mn; f = fn;
    }
    pb[wave][lane][0] = m;
    pb[wave][lane][1] = l;
    #pragma unroll
    for (int d=0; d<32; ++d) pb[wave][lane][2+d] = acc[d];
    __syncthreads();
    // merge: thread (lane2, grp) handles dims [grp*4, grp*4+4) of dst=half*64+lane2
    {
        const int lane2 = t & 63, grp = t >> 6;   // grp in [0,8)
        float mw[8], lw[8];
        #pragma unroll
        for (int w=0; w<8; ++w){ mw[w]=pb[w][lane2][0]; lw[w]=pb[w][lane2][1]; }
        float M = mw[0];
        #pragma unroll
        for (int w=1; w<8; ++w) M = fmaxf(M, mw[w]);
        float sw[8];
        float L = 0.f;
        #pragma unroll
        for (int w=0; w<8; ++w){ sw[w] = __expf(mw[w]-M); L += lw[w]*sw[w]; }
        const float inv = 1.f / fmaxf(L, 1e-30f);
        size_t base = ((size_t)(b*128 + half*64 + lane2))*kND + h*32 + grp*4;
        #pragma unroll
        for (int d=0; d<4; ++d) {
            float a = 0.f;
            #pragma unroll
            for (int w=0; w<8; ++w) a += pb[w][lane2][2+grp*4+d]*sw[w];
            o[base + d] = a*inv;
        }
    }
}

// ---------------- local-graph GATHER attention (heads 4..7) ----------------
// block per node, wave per head; 4 edge slots per wave (16 lanes each).
__global__ __launch_bounds__(256) void loc_gather_k(
    const float* __restrict__ q, const float* __restrict__ k, const float* __restrict__ v,
    const float* __restrict__ lg, const int* __restrict__ gsrc,
    const int* __restrict__ rowp, const int* __restrict__ eidl,
    float* __restrict__ o, int ldq)
{
    const int n = blockIdx.x;
    const int h = threadIdx.x >> 6;        // wave = local head (0..3 -> heads 4..7)
    const int lane = threadIdx.x & 63;
    const int g = lane >> 4;               // edge slot within wave (0..3)
    const int d0 = (lane & 15) * 2;
    const size_t hoff = (size_t)(4 + h) * 32 + d0;
    const float2 q2 = *(const float2*)&q[(size_t)n*ldq + hoff];
    const int beg = rowp[n], end = rowp[n+1];
    const int deg = end - beg;
    float m = -1e30f, l = 0.f, ax = 0.f, ay = 0.f;
    if (deg > 0) {
        const int nIter = (deg + 3) >> 2;
        int idx = beg + g;
        int ce = eidl[min(idx, end-1)];
        int cs = gsrc[ce];
        for (int it = 0; it < nIter; ++it) {
            const bool valid = idx < end;
            const int e = ce, s = cs;
            idx += 4;
            if (it + 1 < nIter) { ce = eidl[min(idx, end-1)]; cs = gsrc[ce]; }
            const float2 kv = *(const float2*)&k[(size_t)s*ldq + hoff];
            const float2 lv = *(const float2*)&lg[(size_t)e*32 + d0];
            const float2 vv = *(const float2*)&v[(size_t)s*ldq + hoff];
            float part = (kv.x+lv.x)*q2.x + (kv.y+lv.y)*q2.y;
            part += __shfl_xor(part, 1);
            part += __shfl_xor(part, 2);
            part += __shfl_xor(part, 4);
            part += __shfl_xor(part, 8);
            const float sc = part * kScaleN;
            const float mn = valid ? fmaxf(m, sc) : m;
            const float c  = __expf(m - mn);
            const float pp = valid ? __expf(sc - mn) : 0.f;
            l  = l*c  + pp;
            ax = ax*c + pp*(vv.x+lv.x);
            ay = ay*c + pp*(vv.y+lv.y);
            m  = mn;
        }
        #pragma unroll
        for (int off = 16; off <= 32; off <<= 1) {
            const float mo = __shfl_xor(m, off);
            const float lo = __shfl_xor(l, off);
            const float xo = __shfl_xor(ax, off);
            const float yo = __shfl_xor(ay, off);
            const float M  = fmaxf(m, mo);
            const float c1 = __expf(m - M);
            const float c2 = __expf(mo - M);
            l  = l*c1  + lo*c2;
            ax = ax*c1 + xo*c2;
            ay = ay*c1 + yo*c2;
            m  = M;
        }
    }
    if (g == 0) {
        const float inv = 1.f / fmaxf(l, 1e-30f);
        *(float2*)&o[(size_t)n*kND + hoff] = make_float2(ax*inv, ay*inv);
    }
}

// ---------------- fused line-graph attention + Wo GEMM + LN ----------------
// block = 32 dst-edges x 8 heads. Phase 1: gather attention into LDS (bf16).
// Phase 2: 32x32 @ Wo (4 MFMA) + bias + residual. Phase 3: LN -> out.
// WO: bf16 [L][32][32] pre-transposed; wooff in elements.
__global__ __launch_bounds__(256) void lgs_ewo_k(
    const float* __restrict__ eq, const float* __restrict__ ek, const float* __restrict__ ev,
    const int* __restrict__ lsrc, const int* __restrict__ rowp, const int* __restrict__ eidl,
    const float* __restrict__ res,
    const ush* __restrict__ WO, size_t wooff, const void* __restrict__ bo, size_t booff,
    const void* __restrict__ g1, const void* __restrict__ be1, size_t g1off,
    float* __restrict__ out, const int* __restrict__ flag)
{
    __shared__ __align__(16) ush ows[32*40];     // attention output, bf16 [row][col]
    __shared__ __align__(16) ush wos[32*40];     // Wo^T [n][k]
    __shared__ float cs[32][36];                 // GEMM out + bias + residual
    __shared__ float bos[32], gs[32], bs[32];
    const int isbf = *flag;
    const int t = threadIdx.x;
    const int base = blockIdx.x * 32;
    {
        int n = t >> 3, k4 = (t & 7) * 4;        // one coalesced ushort4 per thread
        *(ushort4*)&wos[n*40 + k4] = *(const ushort4*)&WO[wooff + (size_t)n*32 + k4];
    }
    if (t < 32) {
        bos[t] = ldf(bo, booff + t, isbf);
        gs[t]  = ldf(g1, g1off + t, isbf);
        bs[t]  = ldf(be1, g1off + t, isbf);
    }
    // ---- phase 1: gather attention, thread = (dst-edge, head) ----
    {
        const int d2 = base + (t >> 3), h = t & 7;
        const float4 q4 = *(const float4*)&eq[(size_t)d2*32 + h*4];
        const int beg = rowp[d2], end = rowp[d2+1];
        float m = -1e30f, l = 0.f;
        float4 acc = make_float4(0.f,0.f,0.f,0.f);
        int i = beg;
        int e = 0, s = 0;
        if (i < end) { e = eidl[i]; s = lsrc[e]; }
        while (i < end) {
            const int sc_s = s;
            ++i;
            if (i < end) { e = eidl[i]; s = lsrc[e]; }   // prefetch next (e,s)
            const float4 k4 = *(const float4*)&ek[(size_t)sc_s*32 + h*4];
            const float4 v4 = *(const float4*)&ev[(size_t)sc_s*32 + h*4];
            float sc = (k4.x*q4.x + k4.y*q4.y + k4.z*q4.z + k4.w*q4.w) * 0.5f;
            float mn = fmaxf(m, sc);
            float c = __expf(m - mn);
            float pp = __expf(sc - mn);
            l = l*c + pp;
            acc.x = acc.x*c + pp*v4.x;
            acc.y = acc.y*c + pp*v4.y;
            acc.z = acc.z*c + pp*v4.z;
            acc.w = acc.w*c + pp*v4.w;
            m = mn;
        }
        const float inv = 1.f / fmaxf(l, 1e-30f);
        const int r = t >> 3, c0 = h*4;
        ows[r*40 + c0 + 0] = f2b(acc.x*inv);
        ows[r*40 + c0 + 1] = f2b(acc.y*inv);
        ows[r*40 + c0 + 2] = f2b(acc.z*inv);
        ows[r*40 + c0 + 3] = f2b(acc.w*inv);
    }
    __syncthreads();
    // ---- phase 2: 32x32 GEMM, wave w: row tile mt=w&1, col tile nt=w>>1 ----
    {
        const int wave = t >> 6, l15 = t & 15, quad = (t >> 4) & 3;
        const int mt = wave & 1, nt = wave >> 1;
        frag_ab af = *(const frag_ab*)&ows[(mt*16 + l15)*40 + quad*8];
        frag_ab bf = *(const frag_ab*)&wos[(nt*16 + l15)*40 + quad*8];
        frag_cd acc = {0.f, 0.f, 0.f, 0.f};
        acc = __builtin_amdgcn_mfma_f32_16x16x32_bf16(af, bf, acc, 0, 0, 0);
        #pragma unroll
        for (int rg = 0; rg < 4; ++rg) {
            const int row = mt*16 + quad*4 + rg;
            const int col = nt*16 + l15;
            cs[row][col] = acc[rg] + bos[col] + res[(size_t)(base+row)*32 + col];
        }
    }
    __syncthreads();
    // ---- phase 3: LN per row, 8 threads/row ----
    {
        const int row = t >> 3, c0 = (t & 7) * 4;
        const float v0 = cs[row][c0], v1 = cs[row][c0+1];
        const float v2 = cs[row][c0+2], v3 = cs[row][c0+3];
        float s = v0+v1+v2+v3;
        s += __shfl_xor(s,1); s += __shfl_xor(s,2); s += __shfl_xor(s,4);
        const float mean = s * (1.f/32.f);
        float qq = (v0-mean)*(v0-mean)+(v1-mean)*(v1-mean)
                 + (v2-mean)*(v2-mean)+(v3-mean)*(v3-mean);
        qq += __shfl_xor(qq,1); qq += __shfl_xor(qq,2); qq += __shfl_xor(qq,4);
        const float inv = rsqrtf(qq * (1.f/32.f) + 1e-5f);
        float o0 = (v0-mean)*inv*gs[c0+0] + bs[c0+0];
        float o1 = (v1-mean)*inv*gs[c0+1] + bs[c0+1];
        float o2 = (v2-mean)*inv*gs[c0+2] + bs[c0+2];
        float o3 = (v3-mean)*inv*gs[c0+3] + bs[c0+3];
        *(float4*)&out[(size_t)(base+row)*32 + c0] = make_float4(o0,o1,o2,o3);
    }
}

// ---------------- output ----------------
__global__ void out_k(const float* __restrict__ xf, const float* __restrict__ lgf,
                      void* __restrict__ out, const int* __restrict__ flag){
    const int isbf = *flag;
    int g = blockIdx.x*256 + threadIdx.x;
    float v = (g < kN*kND) ? xf[g] : lgf[g - kN*kND];
    if (isbf) ((bf16*)out)[g] = __float2bfloat16(v);
    else      ((float*)out)[g] = v;
}

// ---------------- host helper ----------------
static inline void mgemm(const float* A, const ush* WT, const void* bias, size_t boff,
                         float* C, const int* flag, int M, int N, int K, int flags,
                         hipStream_t s){
    dim3 grid((N+63)/64, M/64);
    mgemm_k<<<grid, 256, 0, s>>>(A, WT, bias, boff, C, flag, M, N, K, flags);
}

extern "C" void kernel_launch(void* const* d_in, const int* in_sizes, int n_in,
                              void* d_out, int out_size, void* d_ws, size_t ws_size,
                              hipStream_t stream) {
    const void* x_in      = d_in[0];
    const void* rel       = d_in[1];
    const int* g_src      = (const int*)d_in[4];
    const int* g_dst      = (const int*)d_in[5];
    const int* lg_src     = (const int*)d_in[6];
    const int* lg_dst     = (const int*)d_in[7];
    const int* edge_feat  = (const int*)d_in[8];
    const int* full_feat  = (const int*)d_in[9];
    const void* n_Wq   = d_in[10];
    const void* n_bq   = d_in[11];
    const void* n_Wk   = d_in[12];
    const void* n_bk   = d_in[13];
    const void* n_Wv   = d_in[14];
    const void* n_bv   = d_in[15];
    const void* n_Wo   = d_in[16];
    const void* n_bo   = d_in[17];
    const void* n_lng  = d_in[18];
    const void* n_lnb  = d_in[19];
    const void* n_fW1  = d_in[20];
    const void* n_fb1  = d_in[21];
    const void* n_fW2  = d_in[22];
    const void* n_fb2  = d_in[23];
    const void* n_flng = d_in[24];
    const void* n_flnb = d_in[25];
    const void* e_Wsrc = d_in[26];
    const void* e_Wdst = d_in[27];
    const void* e_Wq   = d_in[28];
    const void* e_bq   = d_in[29];
    const void* e_Wk   = d_in[30];
    const void* e_Wv   = d_in[31];
    const void* e_Wo   = d_in[32];
    const void* e_bo   = d_in[33];
    const void* e_lng  = d_in[34];
    const void* e_lnb  = d_in[35];
    const void* e_fW1  = d_in[36];
    const void* e_fb1  = d_in[37];
    const void* e_fW2  = d_in[38];
    const void* e_fb2  = d_in[39];
    const void* e_flng = d_in[40];
    const void* e_flnb = d_in[41];

    // ---- workspace carve-up ----
    float* p = (float*)d_ws;
    size_t off = 0;
    auto AL = [&](size_t n){ float* r = p + off; off += n; return r; };
    int* flagp = (int*)AL(64);
    float* xA   = AL((size_t)kN*kND);
    float* xB   = AL((size_t)kN*kND);
    float* xM   = AL((size_t)kN*kND);
    float* qkvb = AL((size_t)kN*768);
    float* ob   = AL((size_t)kN*kND);
    float* tN   = AL((size_t)kN*kND);
    float* nh   = AL((size_t)kN*1024);
    float* lgA  = AL((size_t)kEL*kED);
    float* lgB  = AL((size_t)kEL*kED);
    float* lgM  = AL((size_t)kEL*kED);
    float* eqb  = AL((size_t)kEL*kED);
    float* ekb  = AL((size_t)kEL*kED);
    float* evb  = AL((size_t)kEL*kED);
    float* xsd  = AL((size_t)kN*64);
    // CSR structures
    int* cntL  = (int*)AL(kN);
    int* rowL  = (int*)AL(kN + 64);
    int* curL  = (int*)AL(kN);
    int* eidL  = (int*)AL(kEL);
    int* cntG  = (int*)AL(kEL);
    int* rowG  = (int*)AL(kEL + 64);
    int* curG  = (int*)AL(kEL);
    int* eidG  = (int*)AL(kELG);
    int* bsum  = (int*)AL(256);
    // pre-transposed bf16 weights [N][K], per-layer contiguous
    ush* wtQKV = (ush*)AL(196608);   // [L][768][256] bf16
    float* bQKV = AL(2*768);
    ush* wtO  = (ush*)AL(65536);
    ush* wtF1 = (ush*)AL(262144);
    ush* wtF2 = (ush*)AL(262144);
    ush* wtSD = (ush*)AL(16384);     // [L][64][256] bf16
    ush* wtEQKV = (ush*)AL(3072);    // [3][L][32][32] bf16 (6144 ush)
    ush* wtEO   = (ush*)AL(1024);    // [L][32][32] bf16
    ush* wtEF1  = (ush*)AL(4096);    // [L][128][32] bf16
    ush* wtEF2  = (ush*)AL(4096);    // [L][32][128] bf16
    if (ws_size < off * sizeof(float)) return;

    detect_k<<<1, 64, 0, stream>>>((const ush*)x_in, flagp);
    cast_x_k<<<(kN*kND)/256, 256, 0, stream>>>(x_in, xA, flagp, kN*kND);
    init_lg_k<<<(kEL*kED)/256, 256, 0, stream>>>(rel, edge_feat, lgA, flagp);

    // ---- weight pre-transpose (once) ----
    trans_qkv_pack_k<<<1536, 256, 0, stream>>>(n_Wq, n_Wk, n_Wv, flagp, wtQKV);
    pack_qkv_bias_k<<<6, 256, 0, stream>>>(n_bq, n_bk, n_bv, flagp, bQKV);
    trans_gen_k<<<512, 256, 0, stream>>>(n_Wo, flagp, wtO, 256, 256, 131072);
    trans_gen_k<<<2048, 256, 0, stream>>>(n_fW1, flagp, wtF1, 256, 1024, 524288);
    trans_gen_k<<<2048, 256, 0, stream>>>(n_fW2, flagp, wtF2, 1024, 256, 524288);
    trans_sd_pack_k<<<128, 256, 0, stream>>>(e_Wsrc, e_Wdst, flagp, wtSD);
    trans_gen_k<<<8, 256, 0, stream>>>(e_Wq, flagp, wtEQKV,        32, 32, 2048);
    trans_gen_k<<<8, 256, 0, stream>>>(e_Wk, flagp, wtEQKV + 2048, 32, 32, 2048);
    trans_gen_k<<<8, 256, 0, stream>>>(e_Wv, flagp, wtEQKV + 4096, 32, 32, 2048);
    trans_gen_k<<<8, 256, 0, stream>>>(e_Wo, flagp, wtEO,          32, 32, 2048);
    trans_gen_k<<<32, 256, 0, stream>>>(e_fW1, flagp, wtEF1, 32, 128, 8192);
    trans_gen_k<<<32, 256, 0, stream>>>(e_fW2, flagp, wtEF2, 128, 32, 8192);

    // ---- CSR build (both graphs) ----
    hipMemsetAsync(cntL, 0, kN*sizeof(int), stream);
    hipMemsetAsync(cntG, 0, kEL*sizeof(int), stream);
    count_k<<<kEL/256, 256, 0, stream>>>(g_dst, cntL, kEL);
    count_k<<<kELG/256, 256, 0, stream>>>(lg_dst, cntG, kELG);
    scan_blk_k<<<kN/1024, 256, 0, stream>>>(cntL, rowL, bsum, kN);
    scan_top_k<<<1, 256, 0, stream>>>(bsum, kN/1024);
    scan_add_k<<<kN/256, 256, 0, stream>>>(rowL, bsum, kN);
    seal_k<<<1, 64, 0, stream>>>(rowL, kN, kEL);
    scan_blk_k<<<kEL/1024, 256, 0, stream>>>(cntG, rowG, bsum, kEL);
    scan_top_k<<<1, 256, 0, stream>>>(bsum, kEL/1024);
    scan_add_k<<<kEL/256, 256, 0, stream>>>(rowG, bsum, kEL);
    seal_k<<<1, 64, 0, stream>>>(rowG, kEL, kELG);
    copy_i_k<<<kN/256, 256, 0, stream>>>(rowL, curL, kN);
    copy_i_k<<<kEL/256, 256, 0, stream>>>(rowG, curG, kEL);
    fill_k<<<kEL/256, 256, 0, stream>>>(g_dst, curL, eidL, kEL);
    fill_k<<<kELG/256, 256, 0, stream>>>(lg_dst, curG, eidG, kELG);

    float* xc = xA;  float* xn = xB;
    float* lgc = lgA; float* lgn = lgB;

    for (int i = 0; i < kL; ++i) {
        const size_t o256 = (size_t)i*kND;
        const size_t o1024= (size_t)i*1024;
        const size_t o32  = (size_t)i*kED;
        const size_t o128 = (size_t)i*128;

        // ===== node update =====
        mgemm(xc, wtQKV + (size_t)i*196608, bQKV, (size_t)i*768, qkvb, flagp,
              kN, 768, kND, 4, stream);
        full_attn_k<<<256, 512, 0, stream>>>(qkvb, qkvb+256, qkvb+512, rel, full_feat,
                                             ob, flagp, 768);
        loc_gather_k<<<kN, 256, 0, stream>>>(qkvb, qkvb+256, qkvb+512, lgc, g_src,
                                             rowL, eidL, ob, 768);
        mgemm(ob, wtO + (size_t)i*65536, n_bo, o256, tN, flagp, kN, kND, kND, 4, stream);
        ln_k<<<kN, 64, 0, stream>>>(xc, tN, n_lng, n_lnb, o256, xM, flagp, kND);
        mgemm(xM, wtF1 + (size_t)i*262144, n_fb1, o1024, nh, flagp, kN, 1024, kND, 4|2, stream);
        mgemm(nh, wtF2 + (size_t)i*262144, n_fb2, o256, tN, flagp, kN, kND, 1024, 4, stream);
        ln_k<<<kN, 64, 0, stream>>>(xM, tN, n_flng, n_flnb, o256, xn, flagp, kND);

        // ===== edge update (uses PRE-update xc, lgc) =====
        mgemm(xc, wtSD + (size_t)i*16384, nullptr, 0, xsd, flagp, kN, 64, kND, 0, stream);
        eqkv_mfma_k<<<kEL/128, 256, 0, stream>>>(lgc, xsd, g_src, g_dst,
                                                 wtEQKV, (size_t)i*1024, e_bq, o32,
                                                 eqb, ekb, evb, flagp);
        lgs_ewo_k<<<kEL/32, 256, 0, stream>>>(eqb, ekb, evb, lg_src, rowG, eidG,
                                              lgc, wtEO, (size_t)i*1024, e_bo, o32,
                                              e_lng, e_lnb, o32, lgM, flagp);
        effn_mfma_k<<<kEL/128, 256, 0, stream>>>(lgM, wtEF1, (size_t)i*4096, e_fb1, o128,
                                                 wtEF2, (size_t)i*4096, e_fb2, o32,
                                                 e_flng, e_flnb, o32, lgn, flagp);

        { float* t = xc; xc = xn; xn = t; }
        { float* t = lgc; lgc = lgn; lgn = t; }
    }

    out_k<<<(kN*kND + kEL*kED)/256, 256, 0, stream>>>(xc, lgc, d_out, flagp);
}

// Round 4
// 634.840 us; speedup vs baseline: 1.2158x; 1.0015x over previous
//
#include <hip/hip_runtime.h>
#include <hip/hip_bf16.h>

typedef __hip_bfloat16 bf16;
typedef unsigned short ush;

static constexpr int kN   = 4096;    // nodes
static constexpr int kND  = 256;     // hidden
static constexpr int kEL  = 131072;  // local edges
static constexpr int kED  = 32;      // edge dim
static constexpr int kELG = 262144;  // line-graph edges
static constexpr int kL   = 2;
static constexpr int kQW  = 832;     // packed qkv+sd width
static constexpr float kScaleN = 0.17677669529663687f; // 1/sqrt(32)

using frag_ab = __attribute__((ext_vector_type(8))) short;   // 8 bf16 (4 VGPRs)
using frag_cd = __attribute__((ext_vector_type(4))) float;   // 4 fp32

__device__ __forceinline__ float ldf(const void* p, size_t i, int isbf){
    return isbf ? __bfloat162float(((const bf16*)p)[i]) : ((const float*)p)[i];
}
__device__ __forceinline__ ush f2b(float f){ bf16 h = __float2bfloat16(f); return *(ush*)&h; }
__device__ __forceinline__ float b2f(ush u){ return __uint_as_float(((unsigned)u)<<16); }
__device__ __forceinline__ ush ldb(const void* p, size_t i, int isbf){
    return isbf ? ((const ush*)p)[i] : f2b(((const float*)p)[i]);
}

// ---------------- dtype detection ----------------
__global__ void detect_k(const ush* __restrict__ xin, int* __restrict__ flag){
    if (threadIdx.x == 0 && blockIdx.x == 0) {
        int plausible = 0;
        for (int i = 0; i < 128; ++i) {
            ush u = xin[i];
            int e = (u >> 7) & 0xFF;
            if (e == 0 || (e >= 110 && e <= 140)) ++plausible;
        }
        *flag = (plausible >= 102) ? 1 : 0;
    }
}

// ---------------- fused setup: cast x, init lg, pack qkv+sd bias, zero counters ----------------
__global__ void setup_misc_k(const void* __restrict__ xin, const void* __restrict__ rel,
                             const int* __restrict__ feat,
                             const void* __restrict__ bq, const void* __restrict__ bk,
                             const void* __restrict__ bv,
                             float* __restrict__ xA, float* __restrict__ lgA,
                             float* __restrict__ bQKV,
                             int* __restrict__ cntL, int* __restrict__ cntG,
                             const int* __restrict__ flag){
    const int isbf = *flag;
    long g = (long)blockIdx.x*256 + threadIdx.x;
    if (g < (long)kN*kND) { xA[g] = ldf(xin, g, isbf); return; }
    g -= (long)kN*kND;
    if (g < (long)kEL*kED) { int e = (int)(g >> 5), d = (int)(g & 31);
        lgA[g] = ldf(rel, (size_t)feat[e]*kED + d, isbf); return; }
    g -= (long)kEL*kED;
    if (g < 2*kQW) {
        int layer = (int)(g / kQW), j = (int)(g - (long)layer*kQW);
        float v = 0.f;
        if (j < 768) { int w = j >> 8, jj = j & 255;
            const void* B = (w==0)?bq:((w==1)?bk:bv);
            v = ldf(B, (size_t)layer*256 + jj, isbf); }
        bQKV[g] = v; return;
    }
    g -= 2*kQW;
    if (g < kN) { cntL[g] = 0; return; }
    g -= kN;
    if (g < kEL) { cntG[g] = 0; return; }
}

// ---------------- ALL weight pre-transposes in one kernel ----------------
__global__ void trans_all_k(
    const void* __restrict__ nWq, const void* __restrict__ nWk, const void* __restrict__ nWv,
    const void* __restrict__ nWo, const void* __restrict__ nF1, const void* __restrict__ nF2,
    const void* __restrict__ eWs, const void* __restrict__ eWd,
    const void* __restrict__ eWq, const void* __restrict__ eWk, const void* __restrict__ eWv,
    const void* __restrict__ eWo, const void* __restrict__ eF1, const void* __restrict__ eF2,
    const int* __restrict__ flag,
    ush* __restrict__ wtQKVSD, ush* __restrict__ wtO, ush* __restrict__ wtF1,
    ush* __restrict__ wtF2, ush* __restrict__ wtEQKV, ush* __restrict__ wtEO,
    ush* __restrict__ wtEF1, ush* __restrict__ wtEF2)
{
    const int isbf = *flag;
    int g = blockIdx.x*256 + threadIdx.x;
    if (g < 393216){                                   // QKV -> wtQKVSD rows 0-767
        int w = g >> 17, gg = g & 131071;
        int layer = gg >> 16, idx = gg & 65535;
        int n = idx >> 8, k = idx & 255;
        const void* W = (w==0)?nWq:((w==1)?nWk:nWv);
        wtQKVSD[(size_t)layer*212992 + (size_t)(w*256+n)*256 + k] =
            ldb(W, (size_t)layer*65536 + (size_t)k*256 + n, isbf);
        return;
    }
    g -= 393216;
    if (g < 32768){                                    // src/dst -> wtQKVSD rows 768-831
        int w = g >> 14, gg = g & 16383;
        int layer = gg >> 13, idx = gg & 8191;
        int n = idx >> 8, k = idx & 255;
        const void* W = w ? eWd : eWs;
        wtQKVSD[(size_t)layer*212992 + (size_t)(768 + w*32 + n)*256 + k] =
            ldb(W, (size_t)layer*8192 + (size_t)k*32 + n, isbf);
        return;
    }
    g -= 32768;
    if (g < 131072){                                   // Wo [L][256][256]
        int layer = g >> 16, rem = g & 65535;
        int n = rem >> 8, k = rem & 255;
        wtO[g] = ldb(nWo, (size_t)layer*65536 + (size_t)k*256 + n, isbf);
        return;
    }
    g -= 131072;
    if (g < 524288){                                   // F1 [L][1024][256]
        int layer = g >> 18, rem = g & 262143;
        int n = rem >> 8, k = rem & 255;
        wtF1[g] = ldb(nF1, (size_t)layer*262144 + (size_t)k*1024 + n, isbf);
        return;
    }
    g -= 524288;
    if (g < 524288){                                   // F2 [L][256][1024]
        int layer = g >> 18, rem = g & 262143;
        int n = rem >> 10, k = rem & 1023;
        wtF2[g] = ldb(nF2, (size_t)layer*262144 + (size_t)k*256 + n, isbf);
        return;
    }
    g -= 524288;
    if (g < 6144){                                     // eQKV [3][L][32][32]
        int w = g >> 11, gg = g & 2047;
        int layer = gg >> 10, rem = gg & 1023;
        int n = rem >> 5, k = rem & 31;
        const void* W = (w==0)?eWq:((w==1)?eWk:eWv);
        wtEQKV[g] = ldb(W, (size_t)layer*1024 + (size_t)k*32 + n, isbf);
        return;
    }
    g -= 6144;
    if (g < 2048){                                     // eWo [L][32][32]
        int layer = g >> 10, rem = g & 1023;
        int n = rem >> 5, k = rem & 31;
        wtEO[g] = ldb(eWo, (size_t)layer*1024 + (size_t)k*32 + n, isbf);
        return;
    }
    g -= 2048;
    if (g < 8192){                                     // eF1 [L][128][32]
        int layer = g >> 12, rem = g & 4095;
        int n = rem >> 5, k = rem & 31;
        wtEF1[g] = ldb(eF1, (size_t)layer*4096 + (size_t)k*128 + n, isbf);
        return;
    }
    g -= 8192;
    if (g < 8192){                                     // eF2 [L][32][128]
        int layer = g >> 12, rem = g & 4095;
        int n = rem >> 7, k = rem & 127;
        wtEF2[g] = ldb(eF2, (size_t)layer*4096 + (size_t)k*32 + n, isbf);
        return;
    }
}

// ---------------- CSR build (both graphs fused) ----------------
__global__ void count2_k(const int* __restrict__ gd, const int* __restrict__ lgd,
                         int* __restrict__ cntL, int* __restrict__ cntG){
    int g = blockIdx.x*256 + threadIdx.x;
    if (g < kEL) atomicAdd(&cntL[gd[g]], 1);
    else if (g < kEL + kELG) atomicAdd(&cntG[lgd[g - kEL]], 1);
}
__global__ __launch_bounds__(256) void scan_blk2_k(
    const int* __restrict__ cntL, const int* __restrict__ cntG,
    int* __restrict__ rowL, int* __restrict__ rowG, int* __restrict__ bsum)
{
    __shared__ int s[256];
    const int t = threadIdx.x;
    const bool isL = blockIdx.x < 4;
    const int* cnt = isL ? cntL : cntG;
    int* out = isL ? rowL : rowG;
    const int blk = isL ? blockIdx.x : blockIdx.x - 4;
    const int n = isL ? kN : kEL;
    const int b0 = blk*1024;
    int v[4], pre[4], tsum = 0;
    #pragma unroll
    for (int j=0;j<4;++j){
        int idx = b0 + t*4 + j;
        v[j] = (idx < n) ? cnt[idx] : 0;
        pre[j] = tsum; tsum += v[j];
    }
    s[t] = tsum; __syncthreads();
    for (int off=1; off<256; off<<=1){
        int x = (t>=off) ? s[t-off] : 0;
        __syncthreads();
        s[t] += x;
        __syncthreads();
    }
    int texc = s[t] - tsum;
    #pragma unroll
    for (int j=0;j<4;++j){
        int idx = b0 + t*4 + j;
        if (idx < n) out[idx] = texc + pre[j];
    }
    if (t == 255) bsum[(isL ? 0 : 8) + blk] = s[255];
}
__global__ __launch_bounds__(256) void scan_top2_k(int* __restrict__ bsum){
    __shared__ int sL[256], sG[256];
    const int t = threadIdx.x;
    int vL = (t < 4)   ? bsum[t]     : 0;
    int vG = (t < 128) ? bsum[8 + t] : 0;
    sL[t] = vL; sG[t] = vG; __syncthreads();
    for (int off=1; off<256; off<<=1){
        int xL = (t>=off) ? sL[t-off] : 0;
        int xG = (t>=off) ? sG[t-off] : 0;
        __syncthreads();
        sL[t] += xL; sG[t] += xG;
        __syncthreads();
    }
    if (t < 4)   bsum[t]     = sL[t] - vL;
    if (t < 128) bsum[8 + t] = sG[t] - vG;
}
__global__ void scan_add2_k(int* __restrict__ rowL, int* __restrict__ rowG,
                            const int* __restrict__ bsum,
                            int* __restrict__ curL, int* __restrict__ curG){
    int g = blockIdx.x*256 + threadIdx.x;
    if (g < kN){ int v = rowL[g] + bsum[g >> 10]; rowL[g] = v; curL[g] = v; }
    else if (g < kN + kEL){ int gg = g - kN;
        int v = rowG[gg] + bsum[8 + (gg >> 10)]; rowG[gg] = v; curG[gg] = v; }
    if (g == 0){ rowL[kN] = kEL; rowG[kEL] = kELG; }
}
__global__ void fill2_k(const int* __restrict__ gd, const int* __restrict__ lgd,
                        int* __restrict__ curL, int* __restrict__ curG,
                        int* __restrict__ eidL, int* __restrict__ eidG){
    int g = blockIdx.x*256 + threadIdx.x;
    if (g < kEL){ int pos = atomicAdd(&curL[gd[g]], 1); eidL[pos] = g; }
    else if (g < kEL + kELG){ int gg = g - kEL;
        int pos = atomicAdd(&curG[lgd[gg]], 1); eidG[pos] = gg; }
}

// ---------------- MFMA GEMM: C[M,N] = A(fp32)@WT^T + bias (opt relu) ----------------
// flags: 2 = RELU, 4 = has-bias, 8 = bf16 output, 16 = bias is packed fp32
__global__ __launch_bounds__(256) void mgemm_k(
    const float* __restrict__ A, const ush* __restrict__ WT,
    const void* __restrict__ bias, size_t boff,
    float* __restrict__ C, const int* __restrict__ flag,
    int M, int N, int K, int flags)
{
    __shared__ __align__(16) ush As[64*40];
    __shared__ __align__(16) ush Ws[64*40];
    const int isbf = *flag;
    const int t = threadIdx.x;
    const int m0 = blockIdx.y*64, n0 = blockIdx.x*64;
    const int wave = t>>6, lane = t&63;
    const int quad = lane>>4, l15 = lane&15;
    const int r = t>>2, kq = (t&3)*8;

    frag_cd acc[4];
    #pragma unroll
    for (int tl=0; tl<4; ++tl)
        #pragma unroll
        for (int j=0;j<4;++j) acc[tl][j] = 0.f;

    const float* aprow = A + (size_t)(m0+r)*K + kq;
    const bool wok = (n0 + r) < N;
    const ush* wprow = WT + (size_t)(n0 + (wok ? r : 0))*K + kq;

    float4 a0, a1; uint4 wv;
    auto loadT = [&](int kk){
        a0 = *(const float4*)(aprow + kk);
        a1 = *(const float4*)(aprow + kk + 4);
        wv = wok ? *(const uint4*)(wprow + kk) : make_uint4(0u,0u,0u,0u);
    };
    loadT(0);

    for (int kk = 0; kk < K; kk += 32) {
        ushort4 p0 = make_ushort4(f2b(a0.x), f2b(a0.y), f2b(a0.z), f2b(a0.w));
        ushort4 p1 = make_ushort4(f2b(a1.x), f2b(a1.y), f2b(a1.z), f2b(a1.w));
        *(ushort4*)&As[r*40 + kq]     = p0;
        *(ushort4*)&As[r*40 + kq + 4] = p1;
        *(uint4*)&Ws[r*40 + kq] = wv;
        __syncthreads();
        if (kk + 32 < K) loadT(kk + 32);
        frag_ab af = *(const frag_ab*)&As[(wave*16 + l15)*40 + quad*8];
        #pragma unroll
        for (int tl = 0; tl < 4; ++tl) {
            frag_ab bf = *(const frag_ab*)&Ws[(tl*16 + l15)*40 + quad*8];
            acc[tl] = __builtin_amdgcn_mfma_f32_16x16x32_bf16(af, bf, acc[tl], 0, 0, 0);
        }
        __syncthreads();
    }
    const bool do_relu = flags & 2;
    const bool has_b   = flags & 4;
    const bool obf     = flags & 8;
    #pragma unroll
    for (int tl = 0; tl < 4; ++tl) {
        int col = n0 + tl*16 + l15;
        if (col < N) {
            float bv = 0.f;
            if (has_b) bv = (flags & 16) ? ((const float*)bias)[boff + col]
                                         : ldf(bias, boff + col, isbf);
            #pragma unroll
            for (int rg = 0; rg < 4; ++rg) {
                int row = m0 + wave*16 + quad*4 + rg;
                float v = acc[tl][rg] + bv;
                if (do_relu) v = fmaxf(v, 0.f);
                if (obf) ((ush*)C)[(size_t)row*N + col] = f2b(v);
                else     C[(size_t)row*N + col] = v;
            }
        }
    }
}

// ---------------- fused GEMM + bias + residual + LayerNorm (N=256) ----------------
// out = LN(res + A@WT^T + bias); 16 rows/block, 4 waves (wave = 64-col quarter).
__global__ __launch_bounds__(256) void gemm_ln_k(
    const void* __restrict__ Ain, int abf,
    const ush* __restrict__ WT,
    const float* __restrict__ res,
    const void* __restrict__ bias, size_t boff,
    const void* __restrict__ g, const void* __restrict__ be, size_t goff,
    float* __restrict__ out, const int* __restrict__ flag, int K)
{
    __shared__ __align__(16) ush As[16*40];
    __shared__ __align__(16) ush Ws[256*40];
    __shared__ float redS[4][16], redQ[4][16];
    const int isbf = *flag;
    const int t = threadIdx.x;
    const int wave = t>>6, lane = t&63, quad = lane>>4, l15 = lane&15;
    const int m0 = blockIdx.x*16;

    frag_cd acc[4];
    #pragma unroll
    for (int tl=0; tl<4; ++tl)
        #pragma unroll
        for (int j=0;j<4;++j) acc[tl][j] = 0.f;

    const int ar = t>>2, ak = (t&3)*8;   // A staging assignment (t<64)
    const float* af32 = (const float*)Ain + (size_t)(m0+ar)*K + ak;
    const ush*  ab16 = (const ush*)Ain + (size_t)(m0+ar)*K + ak;

    uint4 wv[4]; float4 a0, a1; uint4 av;
    auto loadT = [&](int kk){
        #pragma unroll
        for (int j=0;j<4;++j){
            int idx = t + j*256;
            int n = idx>>2, k8 = (idx&3)*8;
            wv[j] = *(const uint4*)&WT[(size_t)n*K + kk + k8];
        }
        if (t < 64) {
            if (abf) av = *(const uint4*)&ab16[kk];
            else { a0 = *(const float4*)&af32[kk]; a1 = *(const float4*)&af32[kk+4]; }
        }
    };
    loadT(0);
    for (int kk = 0; kk < K; kk += 32){
        #pragma unroll
        for (int j=0;j<4;++j){
            int idx = t + j*256;
            int n = idx>>2, k8 = (idx&3)*8;
            *(uint4*)&Ws[n*40 + k8] = wv[j];
        }
        if (t < 64) {
            if (abf) *(uint4*)&As[ar*40 + ak] = av;
            else {
                ushort4 p0 = make_ushort4(f2b(a0.x),f2b(a0.y),f2b(a0.z),f2b(a0.w));
                ushort4 p1 = make_ushort4(f2b(a1.x),f2b(a1.y),f2b(a1.z),f2b(a1.w));
                *(ushort4*)&As[ar*40 + ak] = p0;
                *(ushort4*)&As[ar*40 + ak + 4] = p1;
            }
        }
        __syncthreads();
        if (kk + 32 < K) loadT(kk + 32);
        frag_ab af = *(const frag_ab*)&As[l15*40 + quad*8];
        #pragma unroll
        for (int tl=0; tl<4; ++tl){
            frag_ab bf = *(const frag_ab*)&Ws[(wave*64 + tl*16 + l15)*40 + quad*8];
            acc[tl] = __builtin_amdgcn_mfma_f32_16x16x32_bf16(af, bf, acc[tl], 0, 0, 0);
        }
        __syncthreads();
    }
    // epilogue: v = acc + bias + res; LN over 256 cols per row
    float v[4][4], bcol[4], gcol[4], becol[4];
    #pragma unroll
    for (int tl=0; tl<4; ++tl){
        const int col = wave*64 + tl*16 + l15;
        bcol[tl]  = ldf(bias, boff + col, isbf);
        gcol[tl]  = ldf(g,  goff + col, isbf);
        becol[tl] = ldf(be, goff + col, isbf);
        #pragma unroll
        for (int rg=0; rg<4; ++rg){
            const int row = m0 + quad*4 + rg;
            v[tl][rg] = acc[tl][rg] + bcol[tl] + res[(size_t)row*kND + col];
        }
    }
    #pragma unroll
    for (int rg=0; rg<4; ++rg){
        float s = v[0][rg]+v[1][rg]+v[2][rg]+v[3][rg];
        float q = v[0][rg]*v[0][rg]+v[1][rg]*v[1][rg]+v[2][rg]*v[2][rg]+v[3][rg]*v[3][rg];
        s += __shfl_xor(s,1); s += __shfl_xor(s,2); s += __shfl_xor(s,4); s += __shfl_xor(s,8);
        q += __shfl_xor(q,1); q += __shfl_xor(q,2); q += __shfl_xor(q,4); q += __shfl_xor(q,8);
        if (l15 == 0){ redS[wave][quad*4+rg] = s; redQ[wave][quad*4+rg] = q; }
    }
    __syncthreads();
    #pragma unroll
    for (int rg=0; rg<4; ++rg){
        const int r16 = quad*4 + rg;
        const float S = redS[0][r16]+redS[1][r16]+redS[2][r16]+redS[3][r16];
        const float Q = redQ[0][r16]+redQ[1][r16]+redQ[2][r16]+redQ[3][r16];
        const float mean = S * (1.f/256.f);
        const float var = fmaxf(Q * (1.f/256.f) - mean*mean, 0.f);
        const float inv = rsqrtf(var + 1e-5f);
        const int row = m0 + r16;
        #pragma unroll
        for (int tl=0; tl<4; ++tl){
            const int col = wave*64 + tl*16 + l15;
            out[(size_t)row*kND + col] = (v[tl][rg]-mean)*inv*gcol[tl] + becol[tl];
        }
    }
}

// ---------------- MFMA eq/ek/ev (+gathered mixed), 128 rows/block, bf16 out ----------------
// xsd: packed qkv buffer cols 768.. (row stride kQW): cols 0-31 src, 32-63 dst
__global__ __launch_bounds__(256) void eqkv_mfma_k(
    const float* __restrict__ lg, const float* __restrict__ xsd,
    const int* __restrict__ gsrc, const int* __restrict__ gdst,
    const ush* __restrict__ WQKV, size_t woff,
    const void* __restrict__ bq, size_t boff,
    ush* __restrict__ eq, ush* __restrict__ ek, ush* __restrict__ ev,
    const int* __restrict__ flag)
{
    __shared__ __align__(16) ush mixs[128*40];
    __shared__ __align__(16) ush wts[3][32*40];
    __shared__ float bqs[32];
    const int isbf = *flag;
    const int t = threadIdx.x;
    const int e0 = blockIdx.x * 128;
    #pragma unroll
    for (int i = t; i < 768; i += 256) {
        int m = i >> 8, r2 = i & 255;
        int n = r2 >> 3, k4 = (r2 & 7) * 4;
        *(ushort4*)&wts[m][n*40 + k4] =
            *(const ushort4*)&WQKV[(size_t)m*2048 + woff + (size_t)n*32 + k4];
    }
    if (t < 32) bqs[t] = ldf(bq, boff + t, isbf);
    {
        int r = t >> 1, c0 = (t & 1) * 16;
        int e = e0 + r;
        int s = gsrc[e], d2 = gdst[e];
        const float* lp = lg + (size_t)e*32 + c0;
        const float* sp = xsd + (size_t)s*kQW + c0;
        const float* dp = xsd + (size_t)d2*kQW + 32 + c0;
        #pragma unroll
        for (int j = 0; j < 16; ++j)
            mixs[r*40 + c0 + j] = f2b(lp[j] + sp[j] + dp[j]);
    }
    __syncthreads();
    const int wave = t >> 6, l15 = t & 15, quad = (t >> 4) & 3;
    #pragma unroll
    for (int mi = 0; mi < 2; ++mi) {
        const int mt = wave*2 + mi;
        frag_ab af = *(const frag_ab*)&mixs[(mt*16 + l15)*40 + quad*8];
        #pragma unroll
        for (int w = 0; w < 3; ++w) {
            ush* outp = (w==0) ? eq : ((w==1) ? ek : ev);
            #pragma unroll
            for (int nt = 0; nt < 2; ++nt) {
                frag_ab bf = *(const frag_ab*)&wts[w][(nt*16 + l15)*40 + quad*8];
                frag_cd acc = {0.f, 0.f, 0.f, 0.f};
                acc = __builtin_amdgcn_mfma_f32_16x16x32_bf16(af, bf, acc, 0, 0, 0);
                const float bv = (w==0) ? bqs[nt*16 + l15] : 0.f;
                #pragma unroll
                for (int rg = 0; rg < 4; ++rg) {
                    int row = e0 + mt*16 + quad*4 + rg;
                    outp[(size_t)row*32 + nt*16 + l15] = f2b(acc[rg] + bv);
                }
            }
        }
    }
}

// ---------------- MFMA edge FFN: LN(A + relu(A@W1+b1)@W2 + b2) ----------------
__global__ __launch_bounds__(256) void effn_mfma_k(
    const float* __restrict__ A,
    const ush* __restrict__ W1T, size_t w1off, const void* __restrict__ b1, size_t b1off,
    const ush* __restrict__ W2T, size_t w2off, const void* __restrict__ b2, size_t b2off,
    const void* __restrict__ g, const void* __restrict__ be, size_t goff,
    float* __restrict__ out, const int* __restrict__ flag)
{
    __shared__ __align__(16) ush w1t[128*40];
    __shared__ __align__(16) ush w2t[32*136];
    __shared__ __align__(16) ush hid[64*136];
    __shared__ float b1s[128], b2s[32];
    const int isbf = *flag;
    const int t = threadIdx.x;
    const int wave = t >> 6, l15 = t & 15, quad = (t >> 4) & 3;

    #pragma unroll
    for (int i = t; i < 1024; i += 256) {
        int n1 = i >> 3, k4 = (i & 7) * 4;
        *(ushort4*)&w1t[n1*40 + k4] = *(const ushort4*)&W1T[w1off + (size_t)n1*32 + k4];
        int n2 = i >> 5, kq2 = (i & 31) * 4;
        *(ushort4*)&w2t[n2*136 + kq2] = *(const ushort4*)&W2T[w2off + (size_t)n2*128 + kq2];
    }
    if (t < 128) b1s[t] = ldf(b1, b1off + t, isbf);
    if (t < 32)  b2s[t] = ldf(b2, b2off + t, isbf);
    __syncthreads();

    const float g0  = ldf(g,  goff + l15, isbf),      g1v = ldf(g,  goff + 16 + l15, isbf);
    const float be0 = ldf(be, goff + l15, isbf),      be1 = ldf(be, goff + 16 + l15, isbf);
    const float bb0 = b2s[l15], bb1 = b2s[16 + l15];

    for (int tt = 0; tt < 2; ++tt) {
        const int e0 = (blockIdx.x*2 + tt) * 64;
        {
            const int m = wave*16 + l15;
            float4 a0 = *(const float4*)&A[(size_t)(e0+m)*32 + quad*8];
            float4 a1 = *(const float4*)&A[(size_t)(e0+m)*32 + quad*8 + 4];
            ush tmp[8] = {f2b(a0.x),f2b(a0.y),f2b(a0.z),f2b(a0.w),
                          f2b(a1.x),f2b(a1.y),f2b(a1.z),f2b(a1.w)};
            frag_ab af = *(frag_ab*)tmp;
            #pragma unroll
            for (int nt = 0; nt < 8; ++nt) {
                frag_ab bf = *(const frag_ab*)&w1t[(nt*16 + l15)*40 + quad*8];
                frag_cd acc = {0.f, 0.f, 0.f, 0.f};
                acc = __builtin_amdgcn_mfma_f32_16x16x32_bf16(af, bf, acc, 0, 0, 0);
                float bv = b1s[nt*16 + l15];
                #pragma unroll
                for (int rg = 0; rg < 4; ++rg) {
                    int row = wave*16 + quad*4 + rg;
                    hid[row*136 + nt*16 + l15] = f2b(fmaxf(acc[rg] + bv, 0.f));
                }
            }
        }
        // hid rows are wave-private -> no barrier needed
        frag_cd acc2[2] = {{0.f,0.f,0.f,0.f},{0.f,0.f,0.f,0.f}};
        #pragma unroll
        for (int ks = 0; ks < 4; ++ks) {
            frag_ab af2 = *(const frag_ab*)&hid[(wave*16 + l15)*136 + ks*32 + quad*8];
            #pragma unroll
            for (int tl = 0; tl < 2; ++tl) {
                frag_ab bf2 = *(const frag_ab*)&w2t[(tl*16 + l15)*136 + ks*32 + quad*8];
                acc2[tl] = __builtin_amdgcn_mfma_f32_16x16x32_bf16(af2, bf2, acc2[tl], 0, 0, 0);
            }
        }
        #pragma unroll
        for (int rg = 0; rg < 4; ++rg) {
            const int row = e0 + wave*16 + quad*4 + rg;
            float v0 = acc2[0][rg] + bb0 + A[(size_t)row*32 + l15];
            float v1 = acc2[1][rg] + bb1 + A[(size_t)row*32 + 16 + l15];
            float s = v0 + v1;
            s += __shfl_xor(s,1); s += __shfl_xor(s,2); s += __shfl_xor(s,4); s += __shfl_xor(s,8);
            const float mean = s * (1.f/32.f);
            float q = (v0-mean)*(v0-mean) + (v1-mean)*(v1-mean);
            q += __shfl_xor(q,1); q += __shfl_xor(q,2); q += __shfl_xor(q,4); q += __shfl_xor(q,8);
            const float inv = rsqrtf(q * (1.f/32.f) + 1e-5f);
            out[(size_t)row*32 + l15]      = (v0-mean)*inv*g0  + be0;
            out[(size_t)row*32 + 16 + l15] = (v1-mean)*inv*g1v + be1;
        }
    }
}

// ---------------- full-graph attention: (b,h,half) blocks, 8 waves split over src ----------------
__global__ __launch_bounds__(512) void full_attn_k(
    const float* __restrict__ q, const float* __restrict__ k, const float* __restrict__ v,
    const void* __restrict__ rel, const int* __restrict__ feat, float* __restrict__ o,
    const int* __restrict__ flag, int ldq)
{
    __shared__ __align__(8) ush ks[128][36];
    __shared__ __align__(8) ush vs[128][36];
    __shared__ __align__(8) ush rs[128][36];
    __shared__ float pb[8][64][34];
    const int isbf = *flag;
    const int bid = blockIdx.x;
    const int b = bid >> 3, h = (bid >> 1) & 3, half = bid & 1;
    const int t = threadIdx.x;
    for (int i = t; i < 4096; i += 512) {
        int r = i >> 5, d = i & 31;
        rs[r][d] = ldb(rel, i, isbf);
        size_t base = ((size_t)(b*128 + r))*ldq + h*32 + d;
        ks[r][d] = f2b(k[base]);
        vs[r][d] = f2b(v[base]);
    }
    __syncthreads();
    const int wave = t >> 6, lane = t & 63;
    const int dst = half*64 + lane;
    float qr[32];
    { size_t base = ((size_t)(b*128 + dst))*ldq + h*32;
      #pragma unroll
      for (int d=0; d<32; ++d) qr[d] = q[base + d]; }
    const int* fp = feat + (size_t)b*16384 + dst;
    const int s0 = wave*16;
    float m = -1e30f, l = 0.f;
    float acc[32];
    #pragma unroll
    for (int d=0; d<32; ++d) acc[d] = 0.f;
    int f = fp[s0*128];
    for (int sI = 0; sI < 16; ++sI) {
        const int s = s0 + sI;
        int fn = (sI+1 < 16) ? fp[(s+1)*128] : 0;
        float er[32];
        float sc = 0.f;
        #pragma unroll
        for (int j2 = 0; j2 < 8; ++j2) {
            ushort4 eu = *(const ushort4*)&rs[f][j2*4];
            ushort4 ku = *(const ushort4*)&ks[s][j2*4];
            float e0 = b2f(eu.x), e1 = b2f(eu.y), e2 = b2f(eu.z), e3 = b2f(eu.w);
            er[j2*4+0]=e0; er[j2*4+1]=e1; er[j2*4+2]=e2; er[j2*4+3]=e3;
            sc += (b2f(ku.x)+e0)*qr[j2*4+0] + (b2f(ku.y)+e1)*qr[j2*4+1]
                + (b2f(ku.z)+e2)*qr[j2*4+2] + (b2f(ku.w)+e3)*qr[j2*4+3];
        }
        sc *= kScaleN;
        float mn = fmaxf(m, sc);
        float c0 = __expf(m - mn);
        float pp = __expf(sc - mn);
        l = l*c0 + pp;
        #pragma unroll
        for (int j2 = 0; j2 < 8; ++j2) {
            ushort4 vu = *(const ushort4*)&vs[s][j2*4];
            acc[j2*4+0] = acc[j2*4+0]*c0 + pp*(b2f(vu.x)+er[j2*4+0]);
            acc[j2*4+1] = acc[j2*4+1]*c0 + pp*(b2f(vu.y)+er[j2*4+1]);
            acc[j2*4+2] = acc[j2*4+2]*c0 + pp*(b2f(vu.z)+er[j2*4+2]);
            acc[j2*4+3] = acc[j2*4+3]*c0 + pp*(b2f(vu.w)+er[j2*4+3]);
        }
        m = mn; f = fn;
    }
    pb[wave][lane][0] = m;
    pb[wave][lane][1] = l;
    #pragma unroll
    for (int d=0; d<32; ++d) pb[wave][lane][2+d] = acc[d];
    __syncthreads();
    {
        const int lane2 = t & 63, grp = t >> 6;
        float mw[8], lw[8];
        #pragma unroll
        for (int w=0; w<8; ++w){ mw[w]=pb[w][lane2][0]; lw[w]=pb[w][lane2][1]; }
        float M = mw[0];
        #pragma unroll
        for (int w=1; w<8; ++w) M = fmaxf(M, mw[w]);
        float sw[8];
        float L = 0.f;
        #pragma unroll
        for (int w=0; w<8; ++w){ sw[w] = __expf(mw[w]-M); L += lw[w]*sw[w]; }
        const float inv = 1.f / fmaxf(L, 1e-30f);
        size_t base = ((size_t)(b*128 + half*64 + lane2))*kND + h*32 + grp*4;
        #pragma unroll
        for (int d=0; d<4; ++d) {
            float a = 0.f;
            #pragma unroll
            for (int w=0; w<8; ++w) a += pb[w][lane2][2+grp*4+d]*sw[w];
            o[base + d] = a*inv;
        }
    }
}

// ---------------- local-graph GATHER attention (heads 4..7) ----------------
__global__ __launch_bounds__(256) void loc_gather_k(
    const float* __restrict__ q, const float* __restrict__ k, const float* __restrict__ v,
    const float* __restrict__ lg, const int* __restrict__ gsrc,
    const int* __restrict__ rowp, const int* __restrict__ eidl,
    float* __restrict__ o, int ldq)
{
    const int n = blockIdx.x;
    const int h = threadIdx.x >> 6;
    const int lane = threadIdx.x & 63;
    const int g = lane >> 4;
    const int d0 = (lane & 15) * 2;
    const size_t hoff = (size_t)(4 + h) * 32 + d0;
    const float2 q2 = *(const float2*)&q[(size_t)n*ldq + hoff];
    const int beg = rowp[n], end = rowp[n+1];
    const int deg = end - beg;
    float m = -1e30f, l = 0.f, ax = 0.f, ay = 0.f;
    if (deg > 0) {
        const int nIter = (deg + 3) >> 2;
        int idx = beg + g;
        int ce = eidl[min(idx, end-1)];
        int cs = gsrc[ce];
        for (int it = 0; it < nIter; ++it) {
            const bool valid = idx < end;
            const int e = ce, s = cs;
            idx += 4;
            if (it + 1 < nIter) { ce = eidl[min(idx, end-1)]; cs = gsrc[ce]; }
            const float2 kv = *(const float2*)&k[(size_t)s*ldq + hoff];
            const float2 lv = *(const float2*)&lg[(size_t)e*32 + d0];
            const float2 vv = *(const float2*)&v[(size_t)s*ldq + hoff];
            float part = (kv.x+lv.x)*q2.x + (kv.y+lv.y)*q2.y;
            part += __shfl_xor(part, 1);
            part += __shfl_xor(part, 2);
            part += __shfl_xor(part, 4);
            part += __shfl_xor(part, 8);
            const float sc = part * kScaleN;
            const float mn = valid ? fmaxf(m, sc) : m;
            const float c  = __expf(m - mn);
            const float pp = valid ? __expf(sc - mn) : 0.f;
            l  = l*c  + pp;
            ax = ax*c + pp*(vv.x+lv.x);
            ay = ay*c + pp*(vv.y+lv.y);
            m  = mn;
        }
        #pragma unroll
        for (int off = 16; off <= 32; off <<= 1) {
            const float mo = __shfl_xor(m, off);
            const float lo = __shfl_xor(l, off);
            const float xo = __shfl_xor(ax, off);
            const float yo = __shfl_xor(ay, off);
            const float M  = fmaxf(m, mo);
            const float c1 = __expf(m - M);
            const float c2 = __expf(mo - M);
            l  = l*c1  + lo*c2;
            ax = ax*c1 + xo*c2;
            ay = ay*c1 + yo*c2;
            m  = M;
        }
    }
    if (g == 0) {
        const float inv = 1.f / fmaxf(l, 1e-30f);
        *(float2*)&o[(size_t)n*kND + hoff] = make_float2(ax*inv, ay*inv);
    }
}

// ---------------- fused line-graph attention + Wo GEMM + LN (bf16 eq/ek/ev) ----------------
__global__ __launch_bounds__(256) void lgs_ewo_k(
    const ush* __restrict__ eq, const ush* __restrict__ ek, const ush* __restrict__ ev,
    const int* __restrict__ lsrc, const int* __restrict__ rowp, const int* __restrict__ eidl,
    const float* __restrict__ res,
    const ush* __restrict__ WO, size_t wooff, const void* __restrict__ bo, size_t booff,
    const void* __restrict__ g1, const void* __restrict__ be1, size_t g1off,
    float* __restrict__ out, const int* __restrict__ flag)
{
    __shared__ __align__(16) ush ows[32*40];
    __shared__ __align__(16) ush wos[32*40];
    __shared__ float cs[32][36];
    __shared__ float bos[32], gs[32], bs[32];
    const int isbf = *flag;
    const int t = threadIdx.x;
    const int base = blockIdx.x * 32;
    {
        int n = t >> 3, k4 = (t & 7) * 4;
        *(ushort4*)&wos[n*40 + k4] = *(const ushort4*)&WO[wooff + (size_t)n*32 + k4];
    }
    if (t < 32) {
        bos[t] = ldf(bo, booff + t, isbf);
        gs[t]  = ldf(g1, g1off + t, isbf);
        bs[t]  = ldf(be1, g1off + t, isbf);
    }
    // ---- phase 1: gather attention, thread = (dst-edge, head) ----
    {
        const int d2 = base + (t >> 3), h = t & 7;
        const ushort4 qu = *(const ushort4*)&eq[(size_t)d2*32 + h*4];
        const float q0 = b2f(qu.x), q1 = b2f(qu.y), q2 = b2f(qu.z), q3 = b2f(qu.w);
        const int beg = rowp[d2], end = rowp[d2+1];
        float m = -1e30f, l = 0.f;
        float4 acc = make_float4(0.f,0.f,0.f,0.f);
        int i = beg;
        int s = 0;
        if (i < end) { s = lsrc[eidl[i]]; }
        while (i < end) {
            const int sc_s = s;
            ++i;
            if (i < end) { s = lsrc[eidl[i]]; }      // prefetch next src
            const ushort4 ku = *(const ushort4*)&ek[(size_t)sc_s*32 + h*4];
            const ushort4 vu = *(const ushort4*)&ev[(size_t)sc_s*32 + h*4];
            float sc = (b2f(ku.x)*q0 + b2f(ku.y)*q1 + b2f(ku.z)*q2 + b2f(ku.w)*q3) * 0.5f;
            float mn = fmaxf(m, sc);
            float c = __expf(m - mn);
            float pp = __expf(sc - mn);
            l = l*c + pp;
            acc.x = acc.x*c + pp*b2f(vu.x);
            acc.y = acc.y*c + pp*b2f(vu.y);
            acc.z = acc.z*c + pp*b2f(vu.z);
            acc.w = acc.w*c + pp*b2f(vu.w);
            m = mn;
        }
        const float inv = 1.f / fmaxf(l, 1e-30f);
        const int r = t >> 3, c0 = h*4;
        ows[r*40 + c0 + 0] = f2b(acc.x*inv);
        ows[r*40 + c0 + 1] = f2b(acc.y*inv);
        ows[r*40 + c0 + 2] = f2b(acc.z*inv);
        ows[r*40 + c0 + 3] = f2b(acc.w*inv);
    }
    __syncthreads();
    // ---- phase 2: 32x32 GEMM ----
    {
        const int wave = t >> 6, l15 = t & 15, quad = (t >> 4) & 3;
        const int mt = wave & 1, nt = wave >> 1;
        frag_ab af = *(const frag_ab*)&ows[(mt*16 + l15)*40 + quad*8];
        frag_ab bf = *(const frag_ab*)&wos[(nt*16 + l15)*40 + quad*8];
        frag_cd acc = {0.f, 0.f, 0.f, 0.f};
        acc = __builtin_amdgcn_mfma_f32_16x16x32_bf16(af, bf, acc, 0, 0, 0);
        #pragma unroll
        for (int rg = 0; rg < 4; ++rg) {
            const int row = mt*16 + quad*4 + rg;
            const int col = nt*16 + l15;
            cs[row][col] = acc[rg] + bos[col] + res[(size_t)(base+row)*32 + col];
        }
    }
    __syncthreads();
    // ---- phase 3: LN per row ----
    {
        const int row = t >> 3, c0 = (t & 7) * 4;
        const float v0 = cs[row][c0], v1 = cs[row][c0+1];
        const float v2 = cs[row][c0+2], v3 = cs[row][c0+3];
        float s = v0+v1+v2+v3;
        s += __shfl_xor(s,1); s += __shfl_xor(s,2); s += __shfl_xor(s,4);
        const float mean = s * (1.f/32.f);
        float qq = (v0-mean)*(v0-mean)+(v1-mean)*(v1-mean)
                 + (v2-mean)*(v2-mean)+(v3-mean)*(v3-mean);
        qq += __shfl_xor(qq,1); qq += __shfl_xor(qq,2); qq += __shfl_xor(qq,4);
        const float inv = rsqrtf(qq * (1.f/32.f) + 1e-5f);
        float o0 = (v0-mean)*inv*gs[c0+0] + bs[c0+0];
        float o1 = (v1-mean)*inv*gs[c0+1] + bs[c0+1];
        float o2 = (v2-mean)*inv*gs[c0+2] + bs[c0+2];
        float o3 = (v3-mean)*inv*gs[c0+3] + bs[c0+3];
        *(float4*)&out[(size_t)(base+row)*32 + c0] = make_float4(o0,o1,o2,o3);
    }
}

// ---------------- output ----------------
__global__ void out_k(const float* __restrict__ xf, const float* __restrict__ lgf,
                      void* __restrict__ out, const int* __restrict__ flag){
    const int isbf = *flag;
    int g = blockIdx.x*256 + threadIdx.x;
    float v = (g < kN*kND) ? xf[g] : lgf[g - kN*kND];
    if (isbf) ((bf16*)out)[g] = __float2bfloat16(v);
    else      ((float*)out)[g] = v;
}

// ---------------- host helper ----------------
static inline void mgemm(const float* A, const ush* WT, const void* bias, size_t boff,
                         float* C, const int* flag, int M, int N, int K, int flags,
                         hipStream_t s){
    dim3 grid((N+63)/64, M/64);
    mgemm_k<<<grid, 256, 0, s>>>(A, WT, bias, boff, C, flag, M, N, K, flags);
}

extern "C" void kernel_launch(void* const* d_in, const int* in_sizes, int n_in,
                              void* d_out, int out_size, void* d_ws, size_t ws_size,
                              hipStream_t stream) {
    const void* x_in      = d_in[0];
    const void* rel       = d_in[1];
    const int* g_src      = (const int*)d_in[4];
    const int* g_dst      = (const int*)d_in[5];
    const int* lg_src     = (const int*)d_in[6];
    const int* lg_dst     = (const int*)d_in[7];
    const int* edge_feat  = (const int*)d_in[8];
    const int* full_feat  = (const int*)d_in[9];
    const void* n_Wq   = d_in[10];
    const void* n_bq   = d_in[11];
    const void* n_Wk   = d_in[12];
    const void* n_bk   = d_in[13];
    const void* n_Wv   = d_in[14];
    const void* n_bv   = d_in[15];
    const void* n_Wo   = d_in[16];
    const void* n_bo   = d_in[17];
    const void* n_lng  = d_in[18];
    const void* n_lnb  = d_in[19];
    const void* n_fW1  = d_in[20];
    const void* n_fb1  = d_in[21];
    const void* n_fW2  = d_in[22];
    const void* n_fb2  = d_in[23];
    const void* n_flng = d_in[24];
    const void* n_flnb = d_in[25];
    const void* e_Wsrc = d_in[26];
    const void* e_Wdst = d_in[27];
    const void* e_Wq   = d_in[28];
    const void* e_bq   = d_in[29];
    const void* e_Wk   = d_in[30];
    const void* e_Wv   = d_in[31];
    const void* e_Wo   = d_in[32];
    const void* e_bo   = d_in[33];
    const void* e_lng  = d_in[34];
    const void* e_lnb  = d_in[35];
    const void* e_fW1  = d_in[36];
    const void* e_fb1  = d_in[37];
    const void* e_fW2  = d_in[38];
    const void* e_fb2  = d_in[39];
    const void* e_flng = d_in[40];
    const void* e_flnb = d_in[41];

    // ---- workspace carve-up (units: floats) ----
    float* p = (float*)d_ws;
    size_t off = 0;
    auto AL = [&](size_t n){ float* r = p + off; off += n; return r; };
    int* flagp = (int*)AL(64);
    float* xA   = AL((size_t)kN*kND);
    float* xB   = AL((size_t)kN*kND);
    float* xM   = AL((size_t)kN*kND);
    float* qkvb = AL((size_t)kN*kQW);
    float* ob   = AL((size_t)kN*kND);
    ush*   nh   = (ush*)AL((size_t)kN*512);      // kN*1024 bf16
    float* lgA  = AL((size_t)kEL*kED);
    float* lgB  = AL((size_t)kEL*kED);
    float* lgM  = AL((size_t)kEL*kED);
    ush*   eqb  = (ush*)AL((size_t)kEL*16);      // kEL*32 bf16
    ush*   ekb  = (ush*)AL((size_t)kEL*16);
    ush*   evb  = (ush*)AL((size_t)kEL*16);
    // CSR structures
    int* cntL  = (int*)AL(kN);
    int* rowL  = (int*)AL(kN + 64);
    int* curL  = (int*)AL(kN);
    int* eidL  = (int*)AL(kEL);
    int* cntG  = (int*)AL(kEL);
    int* rowG  = (int*)AL(kEL + 64);
    int* curG  = (int*)AL(kEL);
    int* eidG  = (int*)AL(kELG);
    int* bsum  = (int*)AL(256);
    // pre-transposed bf16 weights
    ush* wtQKVSD = (ush*)AL(212992);   // [L][832][256] bf16 (425984 ush)
    float* bQKV  = AL(2*kQW);
    ush* wtO  = (ush*)AL(65536);
    ush* wtF1 = (ush*)AL(262144);
    ush* wtF2 = (ush*)AL(262144);
    ush* wtEQKV = (ush*)AL(3072);
    ush* wtEO   = (ush*)AL(1024);
    ush* wtEF1  = (ush*)AL(4096);
    ush* wtEF2  = (ush*)AL(4096);
    if (ws_size < off * sizeof(float)) return;

    detect_k<<<1, 64, 0, stream>>>((const ush*)x_in, flagp);
    {
        long total = (long)kN*kND + (long)kEL*kED + 2*kQW + kN + kEL;
        int blocks = (int)((total + 255) / 256);
        setup_misc_k<<<blocks, 256, 0, stream>>>(x_in, rel, edge_feat, n_bq, n_bk, n_bv,
                                                 xA, lgA, bQKV, cntL, cntG, flagp);
    }
    trans_all_k<<<6368, 256, 0, stream>>>(n_Wq, n_Wk, n_Wv, n_Wo, n_fW1, n_fW2,
                                          e_Wsrc, e_Wdst, e_Wq, e_Wk, e_Wv, e_Wo,
                                          e_fW1, e_fW2, flagp,
                                          wtQKVSD, wtO, wtF1, wtF2,
                                          wtEQKV, wtEO, wtEF1, wtEF2);

    count2_k<<<(kEL+kELG)/256, 256, 0, stream>>>(g_dst, lg_dst, cntL, cntG);
    scan_blk2_k<<<132, 256, 0, stream>>>(cntL, cntG, rowL, rowG, bsum);
    scan_top2_k<<<1, 256, 0, stream>>>(bsum);
    scan_add2_k<<<(kN+kEL)/256, 256, 0, stream>>>(rowL, rowG, bsum, curL, curG);
    fill2_k<<<(kEL+kELG)/256, 256, 0, stream>>>(g_dst, lg_dst, curL, curG, eidL, eidG);

    float* xc = xA;  float* xn = xB;
    float* lgc = lgA; float* lgn = lgB;

    for (int i = 0; i < kL; ++i) {
        const size_t o256 = (size_t)i*kND;
        const size_t o1024= (size_t)i*1024;
        const size_t o32  = (size_t)i*kED;
        const size_t o128 = (size_t)i*128;

        // ===== node update (+ packed xs/xd in cols 768-831) =====
        mgemm(xc, wtQKVSD + (size_t)i*212992, bQKV, (size_t)i*kQW, qkvb, flagp,
              kN, kQW, kND, 4|16, stream);
        full_attn_k<<<256, 512, 0, stream>>>(qkvb, qkvb+256, qkvb+512, rel, full_feat,
                                             ob, flagp, kQW);
        loc_gather_k<<<kN, 256, 0, stream>>>(qkvb, qkvb+256, qkvb+512, lgc, g_src,
                                             rowL, eidL, ob, kQW);
        gemm_ln_k<<<kN/16, 256, 0, stream>>>(ob, 0, wtO + (size_t)i*65536, xc,
                                             n_bo, o256, n_lng, n_lnb, o256,
                                             xM, flagp, kND);
        mgemm(xM, wtF1 + (size_t)i*262144, n_fb1, o1024, (float*)nh, flagp,
              kN, 1024, kND, 4|2|8, stream);
        gemm_ln_k<<<kN/16, 256, 0, stream>>>(nh, 1, wtF2 + (size_t)i*262144, xM,
                                             n_fb2, o256, n_flng, n_flnb, o256,
                                             xn, flagp, 1024);

        // ===== edge update (uses PRE-update xc, lgc) =====
        eqkv_mfma_k<<<kEL/128, 256, 0, stream>>>(lgc, qkvb + 768, g_src, g_dst,
                                                 wtEQKV, (size_t)i*1024, e_bq, o32,
                                                 eqb, ekb, evb, flagp);
        lgs_ewo_k<<<kEL/32, 256, 0, stream>>>(eqb, ekb, evb, lg_src, rowG, eidG,
                                              lgc, wtEO, (size_t)i*1024, e_bo, o32,
                                              e_lng, e_lnb, o32, lgM, flagp);
        effn_mfma_k<<<kEL/128, 256, 0, stream>>>(lgM, wtEF1, (size_t)i*4096, e_fb1, o128,
                                                 wtEF2, (size_t)i*4096, e_fb2, o32,
                                                 e_flng, e_flnb, o32, lgn, flagp);

        { float* t = xc; xc = xn; xn = t; }
        { float* t = lgc; lgc = lgn; lgn = t; }
    }

    out_k<<<(kN*kND + kEL*kED)/256, 256, 0, stream>>>(xc, lgc, d_out, flagp);
}

// Round 5
// 613.526 us; speedup vs baseline: 1.2581x; 1.0347x over previous
//
#include <hip/hip_runtime.h>
#include <hip/hip_bf16.h>

typedef __hip_bfloat16 bf16;
typedef unsigned short ush;

static constexpr int kN   = 4096;    // nodes
static constexpr int kND  = 256;     // hidden
static constexpr int kEL  = 131072;  // local edges
static constexpr int kED  = 32;      // edge dim
static constexpr int kELG = 262144;  // line-graph edges
static constexpr int kL   = 2;
static constexpr int kQW  = 832;     // packed qkv+sd width
static constexpr float kScaleN = 0.17677669529663687f; // 1/sqrt(32)

using frag_ab = __attribute__((ext_vector_type(8))) short;   // 8 bf16 (4 VGPRs)
using frag_cd = __attribute__((ext_vector_type(4))) float;   // 4 fp32

__device__ __forceinline__ float ldf(const void* p, size_t i, int isbf){
    return isbf ? __bfloat162float(((const bf16*)p)[i]) : ((const float*)p)[i];
}
__device__ __forceinline__ ush f2b(float f){ bf16 h = __float2bfloat16(f); return *(ush*)&h; }
__device__ __forceinline__ float b2f(ush u){ return __uint_as_float(((unsigned)u)<<16); }
__device__ __forceinline__ ush ldb(const void* p, size_t i, int isbf){
    return isbf ? ((const ush*)p)[i] : f2b(((const float*)p)[i]);
}

// ---------------- dtype detection ----------------
__global__ void detect_k(const ush* __restrict__ xin, int* __restrict__ flag){
    if (threadIdx.x == 0 && blockIdx.x == 0) {
        int plausible = 0;
        for (int i = 0; i < 128; ++i) {
            ush u = xin[i];
            int e = (u >> 7) & 0xFF;
            if (e == 0 || (e >= 110 && e <= 140)) ++plausible;
        }
        *flag = (plausible >= 102) ? 1 : 0;
    }
}

// ---------------- fused setup: cast x, init lg, pack qkv+sd bias, zero counters ----------------
__global__ void setup_misc_k(const void* __restrict__ xin, const void* __restrict__ rel,
                             const int* __restrict__ feat,
                             const void* __restrict__ bq, const void* __restrict__ bk,
                             const void* __restrict__ bv,
                             float* __restrict__ xA, float* __restrict__ lgA,
                             float* __restrict__ bQKV,
                             int* __restrict__ cntL, int* __restrict__ cntG,
                             const int* __restrict__ flag){
    const int isbf = *flag;
    long g = (long)blockIdx.x*256 + threadIdx.x;
    if (g < (long)kN*kND) { xA[g] = ldf(xin, g, isbf); return; }
    g -= (long)kN*kND;
    if (g < (long)kEL*kED) { int e = (int)(g >> 5), d = (int)(g & 31);
        lgA[g] = ldf(rel, (size_t)feat[e]*kED + d, isbf); return; }
    g -= (long)kEL*kED;
    if (g < 2*kQW) {
        int layer = (int)(g / kQW), j = (int)(g - (long)layer*kQW);
        float v = 0.f;
        if (j < 768) { int w = j >> 8, jj = j & 255;
            const void* B = (w==0)?bq:((w==1)?bk:bv);
            v = ldf(B, (size_t)layer*256 + jj, isbf); }
        bQKV[g] = v; return;
    }
    g -= 2*kQW;
    if (g < kN) { cntL[g] = 0; return; }
    g -= kN;
    if (g < kEL) { cntG[g] = 0; return; }
}

// ---------------- ALL weight pre-transposes in one kernel ----------------
__global__ void trans_all_k(
    const void* __restrict__ nWq, const void* __restrict__ nWk, const void* __restrict__ nWv,
    const void* __restrict__ nWo, const void* __restrict__ nF1, const void* __restrict__ nF2,
    const void* __restrict__ eWs, const void* __restrict__ eWd,
    const void* __restrict__ eWq, const void* __restrict__ eWk, const void* __restrict__ eWv,
    const void* __restrict__ eWo, const void* __restrict__ eF1, const void* __restrict__ eF2,
    const int* __restrict__ flag,
    ush* __restrict__ wtQKVSD, ush* __restrict__ wtO, ush* __restrict__ wtF1,
    ush* __restrict__ wtF2, ush* __restrict__ wtEQKV, ush* __restrict__ wtEO,
    ush* __restrict__ wtEF1, ush* __restrict__ wtEF2)
{
    const int isbf = *flag;
    int g = blockIdx.x*256 + threadIdx.x;
    if (g < 393216){                                   // QKV -> wtQKVSD rows 0-767
        int w = g >> 17, gg = g & 131071;
        int layer = gg >> 16, idx = gg & 65535;
        int n = idx >> 8, k = idx & 255;
        const void* W = (w==0)?nWq:((w==1)?nWk:nWv);
        wtQKVSD[(size_t)layer*212992 + (size_t)(w*256+n)*256 + k] =
            ldb(W, (size_t)layer*65536 + (size_t)k*256 + n, isbf);
        return;
    }
    g -= 393216;
    if (g < 32768){                                    // src/dst -> wtQKVSD rows 768-831
        int w = g >> 14, gg = g & 16383;
        int layer = gg >> 13, idx = gg & 8191;
        int n = idx >> 8, k = idx & 255;
        const void* W = w ? eWd : eWs;
        wtQKVSD[(size_t)layer*212992 + (size_t)(768 + w*32 + n)*256 + k] =
            ldb(W, (size_t)layer*8192 + (size_t)k*32 + n, isbf);
        return;
    }
    g -= 32768;
    if (g < 131072){                                   // Wo [L][256][256]
        int layer = g >> 16, rem = g & 65535;
        int n = rem >> 8, k = rem & 255;
        wtO[g] = ldb(nWo, (size_t)layer*65536 + (size_t)k*256 + n, isbf);
        return;
    }
    g -= 131072;
    if (g < 524288){                                   // F1 [L][1024][256]
        int layer = g >> 18, rem = g & 262143;
        int n = rem >> 8, k = rem & 255;
        wtF1[g] = ldb(nF1, (size_t)layer*262144 + (size_t)k*1024 + n, isbf);
        return;
    }
    g -= 524288;
    if (g < 524288){                                   // F2 [L][256][1024]
        int layer = g >> 18, rem = g & 262143;
        int n = rem >> 10, k = rem & 1023;
        wtF2[g] = ldb(nF2, (size_t)layer*262144 + (size_t)k*256 + n, isbf);
        return;
    }
    g -= 524288;
    if (g < 6144){                                     // eQKV [3][L][32][32]
        int w = g >> 11, gg = g & 2047;
        int layer = gg >> 10, rem = gg & 1023;
        int n = rem >> 5, k = rem & 31;
        const void* W = (w==0)?eWq:((w==1)?eWk:eWv);
        wtEQKV[g] = ldb(W, (size_t)layer*1024 + (size_t)k*32 + n, isbf);
        return;
    }
    g -= 6144;
    if (g < 2048){                                     // eWo [L][32][32]
        int layer = g >> 10, rem = g & 1023;
        int n = rem >> 5, k = rem & 31;
        wtEO[g] = ldb(eWo, (size_t)layer*1024 + (size_t)k*32 + n, isbf);
        return;
    }
    g -= 2048;
    if (g < 8192){                                     // eF1 [L][128][32]
        int layer = g >> 12, rem = g & 4095;
        int n = rem >> 5, k = rem & 31;
        wtEF1[g] = ldb(eF1, (size_t)layer*4096 + (size_t)k*128 + n, isbf);
        return;
    }
    g -= 8192;
    if (g < 8192){                                     // eF2 [L][32][128]
        int layer = g >> 12, rem = g & 4095;
        int n = rem >> 7, k = rem & 127;
        wtEF2[g] = ldb(eF2, (size_t)layer*4096 + (size_t)k*32 + n, isbf);
        return;
    }
}

// ---------------- CSR build (both graphs fused) ----------------
__global__ void count2_k(const int* __restrict__ gd, const int* __restrict__ lgd,
                         int* __restrict__ cntL, int* __restrict__ cntG){
    int g = blockIdx.x*256 + threadIdx.x;
    if (g < kEL) atomicAdd(&cntL[gd[g]], 1);
    else if (g < kEL + kELG) atomicAdd(&cntG[lgd[g - kEL]], 1);
}
__global__ __launch_bounds__(256) void scan_blk2_k(
    const int* __restrict__ cntL, const int* __restrict__ cntG,
    int* __restrict__ rowL, int* __restrict__ rowG, int* __restrict__ bsum)
{
    __shared__ int s[256];
    const int t = threadIdx.x;
    const bool isL = blockIdx.x < 4;
    const int* cnt = isL ? cntL : cntG;
    int* out = isL ? rowL : rowG;
    const int blk = isL ? blockIdx.x : blockIdx.x - 4;
    const int n = isL ? kN : kEL;
    const int b0 = blk*1024;
    int v[4], pre[4], tsum = 0;
    #pragma unroll
    for (int j=0;j<4;++j){
        int idx = b0 + t*4 + j;
        v[j] = (idx < n) ? cnt[idx] : 0;
        pre[j] = tsum; tsum += v[j];
    }
    s[t] = tsum; __syncthreads();
    for (int off=1; off<256; off<<=1){
        int x = (t>=off) ? s[t-off] : 0;
        __syncthreads();
        s[t] += x;
        __syncthreads();
    }
    int texc = s[t] - tsum;
    #pragma unroll
    for (int j=0;j<4;++j){
        int idx = b0 + t*4 + j;
        if (idx < n) out[idx] = texc + pre[j];
    }
    if (t == 255) bsum[(isL ? 0 : 8) + blk] = s[255];
}
__global__ __launch_bounds__(256) void scan_top2_k(int* __restrict__ bsum){
    __shared__ int sL[256], sG[256];
    const int t = threadIdx.x;
    int vL = (t < 4)   ? bsum[t]     : 0;
    int vG = (t < 128) ? bsum[8 + t] : 0;
    sL[t] = vL; sG[t] = vG; __syncthreads();
    for (int off=1; off<256; off<<=1){
        int xL = (t>=off) ? sL[t-off] : 0;
        int xG = (t>=off) ? sG[t-off] : 0;
        __syncthreads();
        sL[t] += xL; sG[t] += xG;
        __syncthreads();
    }
    if (t < 4)   bsum[t]     = sL[t] - vL;
    if (t < 128) bsum[8 + t] = sG[t] - vG;
}
__global__ void scan_add2_k(int* __restrict__ rowL, int* __restrict__ rowG,
                            const int* __restrict__ bsum,
                            int* __restrict__ curL, int* __restrict__ curG){
    int g = blockIdx.x*256 + threadIdx.x;
    if (g < kN){ int v = rowL[g] + bsum[g >> 10]; rowL[g] = v; curL[g] = v; }
    else if (g < kN + kEL){ int gg = g - kN;
        int v = rowG[gg] + bsum[8 + (gg >> 10)]; rowG[gg] = v; curG[gg] = v; }
    if (g == 0){ rowL[kN] = kEL; rowG[kEL] = kELG; }
}
__global__ void fill2_k(const int* __restrict__ gd, const int* __restrict__ lgd,
                        int* __restrict__ curL, int* __restrict__ curG,
                        int* __restrict__ eidL, int* __restrict__ eidG){
    int g = blockIdx.x*256 + threadIdx.x;
    if (g < kEL){ int pos = atomicAdd(&curL[gd[g]], 1); eidL[pos] = g; }
    else if (g < kEL + kELG){ int gg = g - kEL;
        int pos = atomicAdd(&curG[lgd[gg]], 1); eidG[pos] = gg; }
}

// ---------------- MFMA GEMM: C[M,N] = A@WT^T + bias (opt relu) ----------------
// WT: bf16 [N][K]. 64x64 tile, 4 waves.
// flags: 2=RELU, 4=has-bias, 8=bf16 out, 16=bias packed fp32, 32=A is bf16
__global__ __launch_bounds__(256) void mgemm_k(
    const float* __restrict__ A, const ush* __restrict__ WT,
    const void* __restrict__ bias, size_t boff,
    float* __restrict__ C, const int* __restrict__ flag,
    int M, int N, int K, int flags)
{
    __shared__ __align__(16) ush As[64*40];
    __shared__ __align__(16) ush Ws[64*40];
    const int isbf = *flag;
    const int t = threadIdx.x;
    const int m0 = blockIdx.y*64, n0 = blockIdx.x*64;
    const int wave = t>>6, lane = t&63;
    const int quad = lane>>4, l15 = lane&15;
    const int r = t>>2, kq = (t&3)*8;
    const bool abf = flags & 32;

    frag_cd acc[4];
    #pragma unroll
    for (int tl=0; tl<4; ++tl)
        #pragma unroll
        for (int j=0;j<4;++j) acc[tl][j] = 0.f;

    const float* aprow = A + (size_t)(m0+r)*K + kq;
    const ush*   abrow = (const ush*)A + (size_t)(m0+r)*K + kq;
    const bool wok = (n0 + r) < N;
    const ush* wprow = WT + (size_t)(n0 + (wok ? r : 0))*K + kq;

    float4 a0, a1; uint4 av; uint4 wv;
    auto loadT = [&](int kk){
        if (abf) av = *(const uint4*)(abrow + kk);
        else { a0 = *(const float4*)(aprow + kk); a1 = *(const float4*)(aprow + kk + 4); }
        wv = wok ? *(const uint4*)(wprow + kk) : make_uint4(0u,0u,0u,0u);
    };
    loadT(0);

    for (int kk = 0; kk < K; kk += 32) {
        if (abf) {
            *(uint4*)&As[r*40 + kq] = av;
        } else {
            ushort4 p0 = make_ushort4(f2b(a0.x), f2b(a0.y), f2b(a0.z), f2b(a0.w));
            ushort4 p1 = make_ushort4(f2b(a1.x), f2b(a1.y), f2b(a1.z), f2b(a1.w));
            *(ushort4*)&As[r*40 + kq]     = p0;
            *(ushort4*)&As[r*40 + kq + 4] = p1;
        }
        *(uint4*)&Ws[r*40 + kq] = wv;
        __syncthreads();
        if (kk + 32 < K) loadT(kk + 32);
        frag_ab af = *(const frag_ab*)&As[(wave*16 + l15)*40 + quad*8];
        #pragma unroll
        for (int tl = 0; tl < 4; ++tl) {
            frag_ab bf = *(const frag_ab*)&Ws[(tl*16 + l15)*40 + quad*8];
            acc[tl] = __builtin_amdgcn_mfma_f32_16x16x32_bf16(af, bf, acc[tl], 0, 0, 0);
        }
        __syncthreads();
    }
    const bool do_relu = flags & 2;
    const bool has_b   = flags & 4;
    const bool obf     = flags & 8;
    #pragma unroll
    for (int tl = 0; tl < 4; ++tl) {
        int col = n0 + tl*16 + l15;
        if (col < N) {
            float bv = 0.f;
            if (has_b) bv = (flags & 16) ? ((const float*)bias)[boff + col]
                                         : ldf(bias, boff + col, isbf);
            #pragma unroll
            for (int rg = 0; rg < 4; ++rg) {
                int row = m0 + wave*16 + quad*4 + rg;
                float v = acc[tl][rg] + bv;
                if (do_relu) v = fmaxf(v, 0.f);
                if (obf) ((ush*)C)[(size_t)row*N + col] = f2b(v);
                else     C[(size_t)row*N + col] = v;
            }
        }
    }
}

// ---------------- LayerNorm (node rows, D=256): out = LN(a + b) ----------------
__global__ __launch_bounds__(64) void ln_k(
    const float* __restrict__ a, const float* __restrict__ b,
    const void* __restrict__ g, const void* __restrict__ be, size_t goff,
    float* __restrict__ out, const int* __restrict__ flag, int D)
{
    const int isbf = *flag;
    const int row = blockIdx.x;
    const int t = threadIdx.x;
    float v[4];
    int cnt = 0;
    float s = 0.f;
    for (int i = t; i < D; i += 64) {
        float x = a[(size_t)row*D + i];
        if (b) x += b[(size_t)row*D + i];
        v[cnt++] = x; s += x;
    }
    #pragma unroll
    for (int off = 32; off > 0; off >>= 1) s += __shfl_down(s, off);
    s = __shfl(s, 0);
    const float mean = s / D;
    float qq = 0.f;
    for (int c2 = 0; c2 < cnt; ++c2) { float d = v[c2]-mean; qq += d*d; }
    #pragma unroll
    for (int off = 32; off > 0; off >>= 1) qq += __shfl_down(qq, off);
    qq = __shfl(qq, 0);
    const float inv = rsqrtf(fmaxf(qq, 0.f) / D + 1e-5f);
    cnt = 0;
    for (int i = t; i < D; i += 64)
        out[(size_t)row*D + i] = (v[cnt++] - mean)*inv*ldf(g, goff + i, isbf) + ldf(be, goff + i, isbf);
}

// ---------------- MFMA eq/ek/ev (+gathered mixed), 128 rows/block, bf16 out ----------------
__global__ __launch_bounds__(256) void eqkv_mfma_k(
    const float* __restrict__ lg, const float* __restrict__ xsd,
    const int* __restrict__ gsrc, const int* __restrict__ gdst,
    const ush* __restrict__ WQKV, size_t woff,
    const void* __restrict__ bq, size_t boff,
    ush* __restrict__ eq, ush* __restrict__ ek, ush* __restrict__ ev,
    const int* __restrict__ flag)
{
    __shared__ __align__(16) ush mixs[128*40];
    __shared__ __align__(16) ush wts[3][32*40];
    __shared__ float bqs[32];
    const int isbf = *flag;
    const int t = threadIdx.x;
    const int e0 = blockIdx.x * 128;
    #pragma unroll
    for (int i = t; i < 768; i += 256) {
        int m = i >> 8, r2 = i & 255;
        int n = r2 >> 3, k4 = (r2 & 7) * 4;
        *(ushort4*)&wts[m][n*40 + k4] =
            *(const ushort4*)&WQKV[(size_t)m*2048 + woff + (size_t)n*32 + k4];
    }
    if (t < 32) bqs[t] = ldf(bq, boff + t, isbf);
    {
        int r = t >> 1, c0 = (t & 1) * 16;
        int e = e0 + r;
        int s = gsrc[e], d2 = gdst[e];
        const float* lp = lg + (size_t)e*32 + c0;
        const float* sp = xsd + (size_t)s*kQW + c0;
        const float* dp = xsd + (size_t)d2*kQW + 32 + c0;
        #pragma unroll
        for (int j = 0; j < 16; ++j)
            mixs[r*40 + c0 + j] = f2b(lp[j] + sp[j] + dp[j]);
    }
    __syncthreads();
    const int wave = t >> 6, l15 = t & 15, quad = (t >> 4) & 3;
    #pragma unroll
    for (int mi = 0; mi < 2; ++mi) {
        const int mt = wave*2 + mi;
        frag_ab af = *(const frag_ab*)&mixs[(mt*16 + l15)*40 + quad*8];
        #pragma unroll
        for (int w = 0; w < 3; ++w) {
            ush* outp = (w==0) ? eq : ((w==1) ? ek : ev);
            #pragma unroll
            for (int nt = 0; nt < 2; ++nt) {
                frag_ab bf = *(const frag_ab*)&wts[w][(nt*16 + l15)*40 + quad*8];
                frag_cd acc = {0.f, 0.f, 0.f, 0.f};
                acc = __builtin_amdgcn_mfma_f32_16x16x32_bf16(af, bf, acc, 0, 0, 0);
                const float bv = (w==0) ? bqs[nt*16 + l15] : 0.f;
                #pragma unroll
                for (int rg = 0; rg < 4; ++rg) {
                    int row = e0 + mt*16 + quad*4 + rg;
                    outp[(size_t)row*32 + nt*16 + l15] = f2b(acc[rg] + bv);
                }
            }
        }
    }
}

// ---------------- MFMA edge FFN: LN(A + relu(A@W1+b1)@W2 + b2) ----------------
__global__ __launch_bounds__(256) void effn_mfma_k(
    const float* __restrict__ A,
    const ush* __restrict__ W1T, size_t w1off, const void* __restrict__ b1, size_t b1off,
    const ush* __restrict__ W2T, size_t w2off, const void* __restrict__ b2, size_t b2off,
    const void* __restrict__ g, const void* __restrict__ be, size_t goff,
    float* __restrict__ out, const int* __restrict__ flag)
{
    __shared__ __align__(16) ush w1t[128*40];
    __shared__ __align__(16) ush w2t[32*136];
    __shared__ __align__(16) ush hid[64*136];
    __shared__ float b1s[128], b2s[32];
    const int isbf = *flag;
    const int t = threadIdx.x;
    const int wave = t >> 6, l15 = t & 15, quad = (t >> 4) & 3;

    #pragma unroll
    for (int i = t; i < 1024; i += 256) {
        int n1 = i >> 3, k4 = (i & 7) * 4;
        *(ushort4*)&w1t[n1*40 + k4] = *(const ushort4*)&W1T[w1off + (size_t)n1*32 + k4];
        int n2 = i >> 5, kq2 = (i & 31) * 4;
        *(ushort4*)&w2t[n2*136 + kq2] = *(const ushort4*)&W2T[w2off + (size_t)n2*128 + kq2];
    }
    if (t < 128) b1s[t] = ldf(b1, b1off + t, isbf);
    if (t < 32)  b2s[t] = ldf(b2, b2off + t, isbf);
    __syncthreads();

    const float g0  = ldf(g,  goff + l15, isbf),      g1v = ldf(g,  goff + 16 + l15, isbf);
    const float be0 = ldf(be, goff + l15, isbf),      be1 = ldf(be, goff + 16 + l15, isbf);
    const float bb0 = b2s[l15], bb1 = b2s[16 + l15];

    for (int tt = 0; tt < 2; ++tt) {
        const int e0 = (blockIdx.x*2 + tt) * 64;
        {
            const int m = wave*16 + l15;
            float4 a0 = *(const float4*)&A[(size_t)(e0+m)*32 + quad*8];
            float4 a1 = *(const float4*)&A[(size_t)(e0+m)*32 + quad*8 + 4];
            ush tmp[8] = {f2b(a0.x),f2b(a0.y),f2b(a0.z),f2b(a0.w),
                          f2b(a1.x),f2b(a1.y),f2b(a1.z),f2b(a1.w)};
            frag_ab af = *(frag_ab*)tmp;
            #pragma unroll
            for (int nt = 0; nt < 8; ++nt) {
                frag_ab bf = *(const frag_ab*)&w1t[(nt*16 + l15)*40 + quad*8];
                frag_cd acc = {0.f, 0.f, 0.f, 0.f};
                acc = __builtin_amdgcn_mfma_f32_16x16x32_bf16(af, bf, acc, 0, 0, 0);
                float bv = b1s[nt*16 + l15];
                #pragma unroll
                for (int rg = 0; rg < 4; ++rg) {
                    int row = wave*16 + quad*4 + rg;
                    hid[row*136 + nt*16 + l15] = f2b(fmaxf(acc[rg] + bv, 0.f));
                }
            }
        }
        // hid rows are wave-private -> no barrier needed
        frag_cd acc2[2] = {{0.f,0.f,0.f,0.f},{0.f,0.f,0.f,0.f}};
        #pragma unroll
        for (int ks = 0; ks < 4; ++ks) {
            frag_ab af2 = *(const frag_ab*)&hid[(wave*16 + l15)*136 + ks*32 + quad*8];
            #pragma unroll
            for (int tl = 0; tl < 2; ++tl) {
                frag_ab bf2 = *(const frag_ab*)&w2t[(tl*16 + l15)*136 + ks*32 + quad*8];
                acc2[tl] = __builtin_amdgcn_mfma_f32_16x16x32_bf16(af2, bf2, acc2[tl], 0, 0, 0);
            }
        }
        #pragma unroll
        for (int rg = 0; rg < 4; ++rg) {
            const int row = e0 + wave*16 + quad*4 + rg;
            float v0 = acc2[0][rg] + bb0 + A[(size_t)row*32 + l15];
            float v1 = acc2[1][rg] + bb1 + A[(size_t)row*32 + 16 + l15];
            float s = v0 + v1;
            s += __shfl_xor(s,1); s += __shfl_xor(s,2); s += __shfl_xor(s,4); s += __shfl_xor(s,8);
            const float mean = s * (1.f/32.f);
            float q = (v0-mean)*(v0-mean) + (v1-mean)*(v1-mean);
            q += __shfl_xor(q,1); q += __shfl_xor(q,2); q += __shfl_xor(q,4); q += __shfl_xor(q,8);
            const float inv = rsqrtf(q * (1.f/32.f) + 1e-5f);
            out[(size_t)row*32 + l15]      = (v0-mean)*inv*g0  + be0;
            out[(size_t)row*32 + 16 + l15] = (v1-mean)*inv*g1v + be1;
        }
    }
}

// ---------------- full-graph attention: (b,h,half) blocks, 8 waves split over src ----------------
__global__ __launch_bounds__(512) void full_attn_k(
    const float* __restrict__ q, const float* __restrict__ k, const float* __restrict__ v,
    const void* __restrict__ rel, const int* __restrict__ feat, float* __restrict__ o,
    const int* __restrict__ flag, int ldq)
{
    __shared__ __align__(8) ush ks[128][36];
    __shared__ __align__(8) ush vs[128][36];
    __shared__ __align__(8) ush rs[128][36];
    __shared__ float pb[8][64][34];
    const int isbf = *flag;
    const int bid = blockIdx.x;
    const int b = bid >> 3, h = (bid >> 1) & 3, half = bid & 1;
    const int t = threadIdx.x;
    for (int i = t; i < 4096; i += 512) {
        int r = i >> 5, d = i & 31;
        rs[r][d] = ldb(rel, i, isbf);
        size_t base = ((size_t)(b*128 + r))*ldq + h*32 + d;
        ks[r][d] = f2b(k[base]);
        vs[r][d] = f2b(v[base]);
    }
    __syncthreads();
    const int wave = t >> 6, lane = t & 63;
    const int dst = half*64 + lane;
    float qr[32];
    { size_t base = ((size_t)(b*128 + dst))*ldq + h*32;
      #pragma unroll
      for (int d=0; d<32; ++d) qr[d] = q[base + d]; }
    const int* fp = feat + (size_t)b*16384 + dst;
    const int s0 = wave*16;
    float m = -1e30f, l = 0.f;
    float acc[32];
    #pragma unroll
    for (int d=0; d<32; ++d) acc[d] = 0.f;
    int f = fp[s0*128];
    for (int sI = 0; sI < 16; ++sI) {
        const int s = s0 + sI;
        int fn = (sI+1 < 16) ? fp[(s+1)*128] : 0;
        float er[32];
        float sc = 0.f;
        #pragma unroll
        for (int j2 = 0; j2 < 8; ++j2) {
            ushort4 eu = *(const ushort4*)&rs[f][j2*4];
            ushort4 ku = *(const ushort4*)&ks[s][j2*4];
            float e0 = b2f(eu.x), e1 = b2f(eu.y), e2 = b2f(eu.z), e3 = b2f(eu.w);
            er[j2*4+0]=e0; er[j2*4+1]=e1; er[j2*4+2]=e2; er[j2*4+3]=e3;
            sc += (b2f(ku.x)+e0)*qr[j2*4+0] + (b2f(ku.y)+e1)*qr[j2*4+1]
                + (b2f(ku.z)+e2)*qr[j2*4+2] + (b2f(ku.w)+e3)*qr[j2*4+3];
        }
        sc *= kScaleN;
        float mn = fmaxf(m, sc);
        float c0 = __expf(m - mn);
        float pp = __expf(sc - mn);
        l = l*c0 + pp;
        #pragma unroll
        for (int j2 = 0; j2 < 8; ++j2) {
            ushort4 vu = *(const ushort4*)&vs[s][j2*4];
            acc[j2*4+0] = acc[j2*4+0]*c0 + pp*(b2f(vu.x)+er[j2*4+0]);
            acc[j2*4+1] = acc[j2*4+1]*c0 + pp*(b2f(vu.y)+er[j2*4+1]);
            acc[j2*4+2] = acc[j2*4+2]*c0 + pp*(b2f(vu.z)+er[j2*4+2]);
            acc[j2*4+3] = acc[j2*4+3]*c0 + pp*(b2f(vu.w)+er[j2*4+3]);
        }
        m = mn; f = fn;
    }
    pb[wave][lane][0] = m;
    pb[wave][lane][1] = l;
    #pragma unroll
    for (int d=0; d<32; ++d) pb[wave][lane][2+d] = acc[d];
    __syncthreads();
    {
        const int lane2 = t & 63, grp = t >> 6;
        float mw[8], lw[8];
        #pragma unroll
        for (int w=0; w<8; ++w){ mw[w]=pb[w][lane2][0]; lw[w]=pb[w][lane2][1]; }
        float M = mw[0];
        #pragma unroll
        for (int w=1; w<8; ++w) M = fmaxf(M, mw[w]);
        float sw[8];
        float L = 0.f;
        #pragma unroll
        for (int w=0; w<8; ++w){ sw[w] = __expf(mw[w]-M); L += lw[w]*sw[w]; }
        const float inv = 1.f / fmaxf(L, 1e-30f);
        size_t base = ((size_t)(b*128 + half*64 + lane2))*kND + h*32 + grp*4;
        #pragma unroll
        for (int d=0; d<4; ++d) {
            float a = 0.f;
            #pragma unroll
            for (int w=0; w<8; ++w) a += pb[w][lane2][2+grp*4+d]*sw[w];
            o[base + d] = a*inv;
        }
    }
}

// ---------------- local-graph GATHER attention (heads 4..7) ----------------
__global__ __launch_bounds__(256) void loc_gather_k(
    const float* __restrict__ q, const float* __restrict__ k, const float* __restrict__ v,
    const float* __restrict__ lg, const int* __restrict__ gsrc,
    const int* __restrict__ rowp, const int* __restrict__ eidl,
    float* __restrict__ o, int ldq)
{
    const int n = blockIdx.x;
    const int h = threadIdx.x >> 6;
    const int lane = threadIdx.x & 63;
    const int g = lane >> 4;
    const int d0 = (lane & 15) * 2;
    const size_t hoff = (size_t)(4 + h) * 32 + d0;
    const float2 q2 = *(const float2*)&q[(size_t)n*ldq + hoff];
    const int beg = rowp[n], end = rowp[n+1];
    const int deg = end - beg;
    float m = -1e30f, l = 0.f, ax = 0.f, ay = 0.f;
    if (deg > 0) {
        const int nIter = (deg + 3) >> 2;
        int idx = beg + g;
        int ce = eidl[min(idx, end-1)];
        int cs = gsrc[ce];
        for (int it = 0; it < nIter; ++it) {
            const bool valid = idx < end;
            const int e = ce, s = cs;
            idx += 4;
            if (it + 1 < nIter) { ce = eidl[min(idx, end-1)]; cs = gsrc[ce]; }
            const float2 kv = *(const float2*)&k[(size_t)s*ldq + hoff];
            const float2 lv = *(const float2*)&lg[(size_t)e*32 + d0];
            const float2 vv = *(const float2*)&v[(size_t)s*ldq + hoff];
            float part = (kv.x+lv.x)*q2.x + (kv.y+lv.y)*q2.y;
            part += __shfl_xor(part, 1);
            part += __shfl_xor(part, 2);
            part += __shfl_xor(part, 4);
            part += __shfl_xor(part, 8);
            const float sc = part * kScaleN;
            const float mn = valid ? fmaxf(m, sc) : m;
            const float c  = __expf(m - mn);
            const float pp = valid ? __expf(sc - mn) : 0.f;
            l  = l*c  + pp;
            ax = ax*c + pp*(vv.x+lv.x);
            ay = ay*c + pp*(vv.y+lv.y);
            m  = mn;
        }
        #pragma unroll
        for (int off = 16; off <= 32; off <<= 1) {
            const float mo = __shfl_xor(m, off);
            const float lo = __shfl_xor(l, off);
            const float xo = __shfl_xor(ax, off);
            const float yo = __shfl_xor(ay, off);
            const float M  = fmaxf(m, mo);
            const float c1 = __expf(m - M);
            const float c2 = __expf(mo - M);
            l  = l*c1  + lo*c2;
            ax = ax*c1 + xo*c2;
            ay = ay*c1 + yo*c2;
            m  = M;
        }
    }
    if (g == 0) {
        const float inv = 1.f / fmaxf(l, 1e-30f);
        *(float2*)&o[(size_t)n*kND + hoff] = make_float2(ax*inv, ay*inv);
    }
}

// ---------------- fused line-graph attention + Wo GEMM + LN (bf16 eq/ek/ev) ----------------
__global__ __launch_bounds__(256) void lgs_ewo_k(
    const ush* __restrict__ eq, const ush* __restrict__ ek, const ush* __restrict__ ev,
    const int* __restrict__ lsrc, const int* __restrict__ rowp, const int* __restrict__ eidl,
    const float* __restrict__ res,
    const ush* __restrict__ WO, size_t wooff, const void* __restrict__ bo, size_t booff,
    const void* __restrict__ g1, const void* __restrict__ be1, size_t g1off,
    float* __restrict__ out, const int* __restrict__ flag)
{
    __shared__ __align__(16) ush ows[32*40];
    __shared__ __align__(16) ush wos[32*40];
    __shared__ float cs[32][36];
    __shared__ float bos[32], gs[32], bs[32];
    const int isbf = *flag;
    const int t = threadIdx.x;
    const int base = blockIdx.x * 32;
    {
        int n = t >> 3, k4 = (t & 7) * 4;
        *(ushort4*)&wos[n*40 + k4] = *(const ushort4*)&WO[wooff + (size_t)n*32 + k4];
    }
    if (t < 32) {
        bos[t] = ldf(bo, booff + t, isbf);
        gs[t]  = ldf(g1, g1off + t, isbf);
        bs[t]  = ldf(be1, g1off + t, isbf);
    }
    // ---- phase 1: gather attention, thread = (dst-edge, head) ----
    {
        const int d2 = base + (t >> 3), h = t & 7;
        const ushort4 qu = *(const ushort4*)&eq[(size_t)d2*32 + h*4];
        const float q0 = b2f(qu.x), q1 = b2f(qu.y), q2 = b2f(qu.z), q3 = b2f(qu.w);
        const int beg = rowp[d2], end = rowp[d2+1];
        float m = -1e30f, l = 0.f;
        float4 acc = make_float4(0.f,0.f,0.f,0.f);
        int i = beg;
        int s = 0;
        if (i < end) { s = lsrc[eidl[i]]; }
        while (i < end) {
            const int sc_s = s;
            ++i;
            if (i < end) { s = lsrc[eidl[i]]; }      // prefetch next src
            const ushort4 ku = *(const ushort4*)&ek[(size_t)sc_s*32 + h*4];
            const ushort4 vu = *(const ushort4*)&ev[(size_t)sc_s*32 + h*4];
            float sc = (b2f(ku.x)*q0 + b2f(ku.y)*q1 + b2f(ku.z)*q2 + b2f(ku.w)*q3) * 0.5f;
            float mn = fmaxf(m, sc);
            float c = __expf(m - mn);
            float pp = __expf(sc - mn);
            l = l*c + pp;
            acc.x = acc.x*c + pp*b2f(vu.x);
            acc.y = acc.y*c + pp*b2f(vu.y);
            acc.z = acc.z*c + pp*b2f(vu.z);
            acc.w = acc.w*c + pp*b2f(vu.w);
            m = mn;
        }
        const float inv = 1.f / fmaxf(l, 1e-30f);
        const int r = t >> 3, c0 = h*4;
        ows[r*40 + c0 + 0] = f2b(acc.x*inv);
        ows[r*40 + c0 + 1] = f2b(acc.y*inv);
        ows[r*40 + c0 + 2] = f2b(acc.z*inv);
        ows[r*40 + c0 + 3] = f2b(acc.w*inv);
    }
    __syncthreads();
    // ---- phase 2: 32x32 GEMM ----
    {
        const int wave = t >> 6, l15 = t & 15, quad = (t >> 4) & 3;
        const int mt = wave & 1, nt = wave >> 1;
        frag_ab af = *(const frag_ab*)&ows[(mt*16 + l15)*40 + quad*8];
        frag_ab bf = *(const frag_ab*)&wos[(nt*16 + l15)*40 + quad*8];
        frag_cd acc = {0.f, 0.f, 0.f, 0.f};
        acc = __builtin_amdgcn_mfma_f32_16x16x32_bf16(af, bf, acc, 0, 0, 0);
        #pragma unroll
        for (int rg = 0; rg < 4; ++rg) {
            const int row = mt*16 + quad*4 + rg;
            const int col = nt*16 + l15;
            cs[row][col] = acc[rg] + bos[col] + res[(size_t)(base+row)*32 + col];
        }
    }
    __syncthreads();
    // ---- phase 3: LN per row ----
    {
        const int row = t >> 3, c0 = (t & 7) * 4;
        const float v0 = cs[row][c0], v1 = cs[row][c0+1];
        const float v2 = cs[row][c0+2], v3 = cs[row][c0+3];
        float s = v0+v1+v2+v3;
        s += __shfl_xor(s,1); s += __shfl_xor(s,2); s += __shfl_xor(s,4);
        const float mean = s * (1.f/32.f);
        float qq = (v0-mean)*(v0-mean)+(v1-mean)*(v1-mean)
                 + (v2-mean)*(v2-mean)+(v3-mean)*(v3-mean);
        qq += __shfl_xor(qq,1); qq += __shfl_xor(qq,2); qq += __shfl_xor(qq,4);
        const float inv = rsqrtf(qq * (1.f/32.f) + 1e-5f);
        float o0 = (v0-mean)*inv*gs[c0+0] + bs[c0+0];
        float o1 = (v1-mean)*inv*gs[c0+1] + bs[c0+1];
        float o2 = (v2-mean)*inv*gs[c0+2] + bs[c0+2];
        float o3 = (v3-mean)*inv*gs[c0+3] + bs[c0+3];
        *(float4*)&out[(size_t)(base+row)*32 + c0] = make_float4(o0,o1,o2,o3);
    }
}

// ---------------- output ----------------
__global__ void out_k(const float* __restrict__ xf, const float* __restrict__ lgf,
                      void* __restrict__ out, const int* __restrict__ flag){
    const int isbf = *flag;
    int g = blockIdx.x*256 + threadIdx.x;
    float v = (g < kN*kND) ? xf[g] : lgf[g - kN*kND];
    if (isbf) ((bf16*)out)[g] = __float2bfloat16(v);
    else      ((float*)out)[g] = v;
}

// ---------------- host helper ----------------
static inline void mgemm(const float* A, const ush* WT, const void* bias, size_t boff,
                         float* C, const int* flag, int M, int N, int K, int flags,
                         hipStream_t s){
    dim3 grid((N+63)/64, M/64);
    mgemm_k<<<grid, 256, 0, s>>>(A, WT, bias, boff, C, flag, M, N, K, flags);
}

extern "C" void kernel_launch(void* const* d_in, const int* in_sizes, int n_in,
                              void* d_out, int out_size, void* d_ws, size_t ws_size,
                              hipStream_t stream) {
    const void* x_in      = d_in[0];
    const void* rel       = d_in[1];
    const int* g_src      = (const int*)d_in[4];
    const int* g_dst      = (const int*)d_in[5];
    const int* lg_src     = (const int*)d_in[6];
    const int* lg_dst     = (const int*)d_in[7];
    const int* edge_feat  = (const int*)d_in[8];
    const int* full_feat  = (const int*)d_in[9];
    const void* n_Wq   = d_in[10];
    const void* n_bq   = d_in[11];
    const void* n_Wk   = d_in[12];
    const void* n_bk   = d_in[13];
    const void* n_Wv   = d_in[14];
    const void* n_bv   = d_in[15];
    const void* n_Wo   = d_in[16];
    const void* n_bo   = d_in[17];
    const void* n_lng  = d_in[18];
    const void* n_lnb  = d_in[19];
    const void* n_fW1  = d_in[20];
    const void* n_fb1  = d_in[21];
    const void* n_fW2  = d_in[22];
    const void* n_fb2  = d_in[23];
    const void* n_flng = d_in[24];
    const void* n_flnb = d_in[25];
    const void* e_Wsrc = d_in[26];
    const void* e_Wdst = d_in[27];
    const void* e_Wq   = d_in[28];
    const void* e_bq   = d_in[29];
    const void* e_Wk   = d_in[30];
    const void* e_Wv   = d_in[31];
    const void* e_Wo   = d_in[32];
    const void* e_bo   = d_in[33];
    const void* e_lng  = d_in[34];
    const void* e_lnb  = d_in[35];
    const void* e_fW1  = d_in[36];
    const void* e_fb1  = d_in[37];
    const void* e_fW2  = d_in[38];
    const void* e_fb2  = d_in[39];
    const void* e_flng = d_in[40];
    const void* e_flnb = d_in[41];

    // ---- workspace carve-up (units: floats) ----
    float* p = (float*)d_ws;
    size_t off = 0;
    auto AL = [&](size_t n){ float* r = p + off; off += n; return r; };
    int* flagp = (int*)AL(64);
    float* xA   = AL((size_t)kN*kND);
    float* xB   = AL((size_t)kN*kND);
    float* xM   = AL((size_t)kN*kND);
    float* qkvb = AL((size_t)kN*kQW);
    float* ob   = AL((size_t)kN*kND);
    float* tN   = AL((size_t)kN*kND);
    ush*   nh   = (ush*)AL((size_t)kN*512);      // kN*1024 bf16
    float* lgA  = AL((size_t)kEL*kED);
    float* lgB  = AL((size_t)kEL*kED);
    float* lgM  = AL((size_t)kEL*kED);
    ush*   eqb  = (ush*)AL((size_t)kEL*16);      // kEL*32 bf16
    ush*   ekb  = (ush*)AL((size_t)kEL*16);
    ush*   evb  = (ush*)AL((size_t)kEL*16);
    // CSR structures
    int* cntL  = (int*)AL(kN);
    int* rowL  = (int*)AL(kN + 64);
    int* curL  = (int*)AL(kN);
    int* eidL  = (int*)AL(kEL);
    int* cntG  = (int*)AL(kEL);
    int* rowG  = (int*)AL(kEL + 64);
    int* curG  = (int*)AL(kEL);
    int* eidG  = (int*)AL(kELG);
    int* bsum  = (int*)AL(256);
    // pre-transposed bf16 weights
    ush* wtQKVSD = (ush*)AL(212992);   // [L][832][256] bf16 (425984 ush)
    float* bQKV  = AL(2*kQW);
    ush* wtO  = (ush*)AL(65536);
    ush* wtF1 = (ush*)AL(262144);
    ush* wtF2 = (ush*)AL(262144);
    ush* wtEQKV = (ush*)AL(3072);
    ush* wtEO   = (ush*)AL(1024);
    ush* wtEF1  = (ush*)AL(4096);
    ush* wtEF2  = (ush*)AL(4096);
    if (ws_size < off * sizeof(float)) return;

    detect_k<<<1, 64, 0, stream>>>((const ush*)x_in, flagp);
    {
        long total = (long)kN*kND + (long)kEL*kED + 2*kQW + kN + kEL;
        int blocks = (int)((total + 255) / 256);
        setup_misc_k<<<blocks, 256, 0, stream>>>(x_in, rel, edge_feat, n_bq, n_bk, n_bv,
                                                 xA, lgA, bQKV, cntL, cntG, flagp);
    }
    trans_all_k<<<6368, 256, 0, stream>>>(n_Wq, n_Wk, n_Wv, n_Wo, n_fW1, n_fW2,
                                          e_Wsrc, e_Wdst, e_Wq, e_Wk, e_Wv, e_Wo,
                                          e_fW1, e_fW2, flagp,
                                          wtQKVSD, wtO, wtF1, wtF2,
                                          wtEQKV, wtEO, wtEF1, wtEF2);

    count2_k<<<(kEL+kELG)/256, 256, 0, stream>>>(g_dst, lg_dst, cntL, cntG);
    scan_blk2_k<<<132, 256, 0, stream>>>(cntL, cntG, rowL, rowG, bsum);
    scan_top2_k<<<1, 256, 0, stream>>>(bsum);
    scan_add2_k<<<(kN+kEL)/256, 256, 0, stream>>>(rowL, rowG, bsum, curL, curG);
    fill2_k<<<(kEL+kELG)/256, 256, 0, stream>>>(g_dst, lg_dst, curL, curG, eidL, eidG);

    float* xc = xA;  float* xn = xB;
    float* lgc = lgA; float* lgn = lgB;

    for (int i = 0; i < kL; ++i) {
        const size_t o256 = (size_t)i*kND;
        const size_t o1024= (size_t)i*1024;
        const size_t o32  = (size_t)i*kED;
        const size_t o128 = (size_t)i*128;

        // ===== node update (+ packed xs/xd in cols 768-831) =====
        mgemm(xc, wtQKVSD + (size_t)i*212992, bQKV, (size_t)i*kQW, qkvb, flagp,
              kN, kQW, kND, 4|16, stream);
        full_attn_k<<<256, 512, 0, stream>>>(qkvb, qkvb+256, qkvb+512, rel, full_feat,
                                             ob, flagp, kQW);
        loc_gather_k<<<kN, 256, 0, stream>>>(qkvb, qkvb+256, qkvb+512, lgc, g_src,
                                             rowL, eidL, ob, kQW);
        mgemm(ob, wtO + (size_t)i*65536, n_bo, o256, tN, flagp, kN, kND, kND, 4, stream);
        ln_k<<<kN, 64, 0, stream>>>(xc, tN, n_lng, n_lnb, o256, xM, flagp, kND);
        mgemm(xM, wtF1 + (size_t)i*262144, n_fb1, o1024, (float*)nh, flagp,
              kN, 1024, kND, 4|2|8, stream);
        mgemm((const float*)nh, wtF2 + (size_t)i*262144, n_fb2, o256, tN, flagp,
              kN, kND, 1024, 4|32, stream);
        ln_k<<<kN, 64, 0, stream>>>(xM, tN, n_flng, n_flnb, o256, xn, flagp, kND);

        // ===== edge update (uses PRE-update xc, lgc) =====
        eqkv_mfma_k<<<kEL/128, 256, 0, stream>>>(lgc, qkvb + 768, g_src, g_dst,
                                                 wtEQKV, (size_t)i*1024, e_bq, o32,
                                                 eqb, ekb, evb, flagp);
        lgs_ewo_k<<<kEL/32, 256, 0, stream>>>(eqb, ekb, evb, lg_src, rowG, eidG,
                                              lgc, wtEO, (size_t)i*1024, e_bo, o32,
                                              e_lng, e_lnb, o32, lgM, flagp);
        effn_mfma_k<<<kEL/128, 256, 0, stream>>>(lgM, wtEF1, (size_t)i*4096, e_fb1, o128,
                                                 wtEF2, (size_t)i*4096, e_fb2, o32,
                                                 e_flng, e_flnb, o32, lgn, flagp);

        { float* t = xc; xc = xn; xn = t; }
        { float* t = lgc; lgc = lgn; lgn = t; }
    }

    out_k<<<(kN*kND + kEL*kED)/256, 256, 0, stream>>>(xc, lgc, d_out, flagp);
}

// Round 6
// 579.611 us; speedup vs baseline: 1.3317x; 1.0585x over previous
//
#include <hip/hip_runtime.h>
#include <hip/hip_bf16.h>

typedef __hip_bfloat16 bf16;
typedef unsigned short ush;

static constexpr int kN   = 4096;    // nodes
static constexpr int kND  = 256;     // hidden
static constexpr int kEL  = 131072;  // local edges
static constexpr int kED  = 32;      // edge dim
static constexpr int kELG = 262144;  // line-graph edges
static constexpr int kL   = 2;
static constexpr int kQW  = 832;     // packed qkv+sd width
static constexpr float kScaleN = 0.17677669529663687f; // 1/sqrt(32)

using frag_ab = __attribute__((ext_vector_type(8))) short;   // 8 bf16 (4 VGPRs)
using frag_cd = __attribute__((ext_vector_type(4))) float;   // 4 fp32

__device__ __forceinline__ float ldf(const void* p, size_t i, int isbf){
    return isbf ? __bfloat162float(((const bf16*)p)[i]) : ((const float*)p)[i];
}
__device__ __forceinline__ ush f2b(float f){ bf16 h = __float2bfloat16(f); return *(ush*)&h; }
__device__ __forceinline__ float b2f(ush u){ return __uint_as_float(((unsigned)u)<<16); }
__device__ __forceinline__ ush ldb(const void* p, size_t i, int isbf){
    return isbf ? ((const ush*)p)[i] : f2b(((const float*)p)[i]);
}

// ---------------- dtype detection ----------------
__global__ void detect_k(const ush* __restrict__ xin, int* __restrict__ flag){
    if (threadIdx.x == 0 && blockIdx.x == 0) {
        int plausible = 0;
        for (int i = 0; i < 128; ++i) {
            ush u = xin[i];
            int e = (u >> 7) & 0xFF;
            if (e == 0 || (e >= 110 && e <= 140)) ++plausible;
        }
        *flag = (plausible >= 102) ? 1 : 0;
    }
}

// ---------------- fused setup: cast x, init lg, pack qkv+sd bias, zero counters ----------------
__global__ void setup_misc_k(const void* __restrict__ xin, const void* __restrict__ rel,
                             const int* __restrict__ feat,
                             const void* __restrict__ bq, const void* __restrict__ bk,
                             const void* __restrict__ bv,
                             float* __restrict__ xA, float* __restrict__ lgA,
                             float* __restrict__ bQKV,
                             int* __restrict__ cntL, int* __restrict__ cntG,
                             const int* __restrict__ flag){
    const int isbf = *flag;
    long g = (long)blockIdx.x*256 + threadIdx.x;
    if (g < (long)kN*kND) { xA[g] = ldf(xin, g, isbf); return; }
    g -= (long)kN*kND;
    if (g < (long)kEL*kED) { int e = (int)(g >> 5), d = (int)(g & 31);
        lgA[g] = ldf(rel, (size_t)feat[e]*kED + d, isbf); return; }
    g -= (long)kEL*kED;
    if (g < 2*kQW) {
        int layer = (int)(g / kQW), j = (int)(g - (long)layer*kQW);
        float v = 0.f;
        if (j < 768) { int w = j >> 8, jj = j & 255;
            const void* B = (w==0)?bq:((w==1)?bk:bv);
            v = ldf(B, (size_t)layer*256 + jj, isbf); }
        bQKV[g] = v; return;
    }
    g -= 2*kQW;
    if (g < kN) { cntL[g] = 0; return; }
    g -= kN;
    if (g < kEL) { cntG[g] = 0; return; }
}

// ---------------- ALL weight pre-transposes in one kernel ----------------
__global__ void trans_all_k(
    const void* __restrict__ nWq, const void* __restrict__ nWk, const void* __restrict__ nWv,
    const void* __restrict__ nWo, const void* __restrict__ nF1, const void* __restrict__ nF2,
    const void* __restrict__ eWs, const void* __restrict__ eWd,
    const void* __restrict__ eWq, const void* __restrict__ eWk, const void* __restrict__ eWv,
    const void* __restrict__ eWo, const void* __restrict__ eF1, const void* __restrict__ eF2,
    const int* __restrict__ flag,
    ush* __restrict__ wtQKVSD, ush* __restrict__ wtO, ush* __restrict__ wtF1,
    ush* __restrict__ wtF2, ush* __restrict__ wtEQKV, ush* __restrict__ wtEO,
    ush* __restrict__ wtEF1, ush* __restrict__ wtEF2)
{
    const int isbf = *flag;
    int g = blockIdx.x*256 + threadIdx.x;
    if (g < 393216){                                   // QKV -> wtQKVSD rows 0-767
        int w = g >> 17, gg = g & 131071;
        int layer = gg >> 16, idx = gg & 65535;
        int n = idx >> 8, k = idx & 255;
        const void* W = (w==0)?nWq:((w==1)?nWk:nWv);
        wtQKVSD[(size_t)layer*212992 + (size_t)(w*256+n)*256 + k] =
            ldb(W, (size_t)layer*65536 + (size_t)k*256 + n, isbf);
        return;
    }
    g -= 393216;
    if (g < 32768){                                    // src/dst -> wtQKVSD rows 768-831
        int w = g >> 14, gg = g & 16383;
        int layer = gg >> 13, idx = gg & 8191;
        int n = idx >> 8, k = idx & 255;
        const void* W = w ? eWd : eWs;
        wtQKVSD[(size_t)layer*212992 + (size_t)(768 + w*32 + n)*256 + k] =
            ldb(W, (size_t)layer*8192 + (size_t)k*32 + n, isbf);
        return;
    }
    g -= 32768;
    if (g < 131072){                                   // Wo [L][256][256]
        int layer = g >> 16, rem = g & 65535;
        int n = rem >> 8, k = rem & 255;
        wtO[g] = ldb(nWo, (size_t)layer*65536 + (size_t)k*256 + n, isbf);
        return;
    }
    g -= 131072;
    if (g < 524288){                                   // F1 [L][1024][256]
        int layer = g >> 18, rem = g & 262143;
        int n = rem >> 8, k = rem & 255;
        wtF1[g] = ldb(nF1, (size_t)layer*262144 + (size_t)k*1024 + n, isbf);
        return;
    }
    g -= 524288;
    if (g < 524288){                                   // F2 [L][256][1024]
        int layer = g >> 18, rem = g & 262143;
        int n = rem >> 10, k = rem & 1023;
        wtF2[g] = ldb(nF2, (size_t)layer*262144 + (size_t)k*256 + n, isbf);
        return;
    }
    g -= 524288;
    if (g < 6144){                                     // eQKV [3][L][32][32]
        int w = g >> 11, gg = g & 2047;
        int layer = gg >> 10, rem = gg & 1023;
        int n = rem >> 5, k = rem & 31;
        const void* W = (w==0)?eWq:((w==1)?eWk:eWv);
        wtEQKV[g] = ldb(W, (size_t)layer*1024 + (size_t)k*32 + n, isbf);
        return;
    }
    g -= 6144;
    if (g < 2048){                                     // eWo [L][32][32]
        int layer = g >> 10, rem = g & 1023;
        int n = rem >> 5, k = rem & 31;
        wtEO[g] = ldb(eWo, (size_t)layer*1024 + (size_t)k*32 + n, isbf);
        return;
    }
    g -= 2048;
    if (g < 8192){                                     // eF1 [L][128][32]
        int layer = g >> 12, rem = g & 4095;
        int n = rem >> 5, k = rem & 31;
        wtEF1[g] = ldb(eF1, (size_t)layer*4096 + (size_t)k*128 + n, isbf);
        return;
    }
    g -= 8192;
    if (g < 8192){                                     // eF2 [L][32][128]
        int layer = g >> 12, rem = g & 4095;
        int n = rem >> 7, k = rem & 127;
        wtEF2[g] = ldb(eF2, (size_t)layer*4096 + (size_t)k*32 + n, isbf);
        return;
    }
}

// ---------------- CSR build (both graphs fused) ----------------
__global__ void count2_k(const int* __restrict__ gd, const int* __restrict__ lgd,
                         int* __restrict__ cntL, int* __restrict__ cntG){
    int g = blockIdx.x*256 + threadIdx.x;
    if (g < kEL) atomicAdd(&cntL[gd[g]], 1);
    else if (g < kEL + kELG) atomicAdd(&cntG[lgd[g - kEL]], 1);
}
__global__ __launch_bounds__(256) void scan_blk2_k(
    const int* __restrict__ cntL, const int* __restrict__ cntG,
    int* __restrict__ rowL, int* __restrict__ rowG, int* __restrict__ bsum)
{
    __shared__ int s[256];
    const int t = threadIdx.x;
    const bool isL = blockIdx.x < 4;
    const int* cnt = isL ? cntL : cntG;
    int* out = isL ? rowL : rowG;
    const int blk = isL ? blockIdx.x : blockIdx.x - 4;
    const int n = isL ? kN : kEL;
    const int b0 = blk*1024;
    int v[4], pre[4], tsum = 0;
    #pragma unroll
    for (int j=0;j<4;++j){
        int idx = b0 + t*4 + j;
        v[j] = (idx < n) ? cnt[idx] : 0;
        pre[j] = tsum; tsum += v[j];
    }
    s[t] = tsum; __syncthreads();
    for (int off=1; off<256; off<<=1){
        int x = (t>=off) ? s[t-off] : 0;
        __syncthreads();
        s[t] += x;
        __syncthreads();
    }
    int texc = s[t] - tsum;
    #pragma unroll
    for (int j=0;j<4;++j){
        int idx = b0 + t*4 + j;
        if (idx < n) out[idx] = texc + pre[j];
    }
    if (t == 255) bsum[(isL ? 0 : 8) + blk] = s[255];
}
__global__ __launch_bounds__(256) void scan_top2_k(int* __restrict__ bsum){
    __shared__ int sL[256], sG[256];
    const int t = threadIdx.x;
    int vL = (t < 4)   ? bsum[t]     : 0;
    int vG = (t < 128) ? bsum[8 + t] : 0;
    sL[t] = vL; sG[t] = vG; __syncthreads();
    for (int off=1; off<256; off<<=1){
        int xL = (t>=off) ? sL[t-off] : 0;
        int xG = (t>=off) ? sG[t-off] : 0;
        __syncthreads();
        sL[t] += xL; sG[t] += xG;
        __syncthreads();
    }
    if (t < 4)   bsum[t]     = sL[t] - vL;
    if (t < 128) bsum[8 + t] = sG[t] - vG;
}
__global__ void scan_add2_k(int* __restrict__ rowL, int* __restrict__ rowG,
                            const int* __restrict__ bsum,
                            int* __restrict__ curL, int* __restrict__ curG){
    int g = blockIdx.x*256 + threadIdx.x;
    if (g < kN){ int v = rowL[g] + bsum[g >> 10]; rowL[g] = v; curL[g] = v; }
    else if (g < kN + kEL){ int gg = g - kN;
        int v = rowG[gg] + bsum[8 + (gg >> 10)]; rowG[gg] = v; curG[gg] = v; }
    if (g == 0){ rowL[kN] = kEL; rowG[kEL] = kELG; }
}
__global__ void fill2_k(const int* __restrict__ gd, const int* __restrict__ lgd,
                        int* __restrict__ curL, int* __restrict__ curG,
                        int* __restrict__ eidL, int* __restrict__ eidG){
    int g = blockIdx.x*256 + threadIdx.x;
    if (g < kEL){ int pos = atomicAdd(&curL[gd[g]], 1); eidL[pos] = g; }
    else if (g < kEL + kELG){ int gg = g - kEL;
        int pos = atomicAdd(&curG[lgd[gg]], 1); eidG[pos] = gg; }
}

// ---------------- MFMA GEMM: C[M,N] = A@WT^T + bias (opt relu) ----------------
// WT: bf16 [N][K]. 64x64 tile, 4 waves.
// flags: 2=RELU, 4=has-bias, 8=bf16 out, 16=bias packed fp32, 32=A is bf16
__global__ __launch_bounds__(256) void mgemm_k(
    const float* __restrict__ A, const ush* __restrict__ WT,
    const void* __restrict__ bias, size_t boff,
    float* __restrict__ C, const int* __restrict__ flag,
    int M, int N, int K, int flags)
{
    __shared__ __align__(16) ush As[64*40];
    __shared__ __align__(16) ush Ws[64*40];
    const int isbf = *flag;
    const int t = threadIdx.x;
    const int m0 = blockIdx.y*64, n0 = blockIdx.x*64;
    const int wave = t>>6, lane = t&63;
    const int quad = lane>>4, l15 = lane&15;
    const int r = t>>2, kq = (t&3)*8;
    const bool abf = flags & 32;

    frag_cd acc[4];
    #pragma unroll
    for (int tl=0; tl<4; ++tl)
        #pragma unroll
        for (int j=0;j<4;++j) acc[tl][j] = 0.f;

    const float* aprow = A + (size_t)(m0+r)*K + kq;
    const ush*   abrow = (const ush*)A + (size_t)(m0+r)*K + kq;
    const bool wok = (n0 + r) < N;
    const ush* wprow = WT + (size_t)(n0 + (wok ? r : 0))*K + kq;

    float4 a0, a1; uint4 av; uint4 wv;
    auto loadT = [&](int kk){
        if (abf) av = *(const uint4*)(abrow + kk);
        else { a0 = *(const float4*)(aprow + kk); a1 = *(const float4*)(aprow + kk + 4); }
        wv = wok ? *(const uint4*)(wprow + kk) : make_uint4(0u,0u,0u,0u);
    };
    loadT(0);

    for (int kk = 0; kk < K; kk += 32) {
        if (abf) {
            *(uint4*)&As[r*40 + kq] = av;
        } else {
            ushort4 p0 = make_ushort4(f2b(a0.x), f2b(a0.y), f2b(a0.z), f2b(a0.w));
            ushort4 p1 = make_ushort4(f2b(a1.x), f2b(a1.y), f2b(a1.z), f2b(a1.w));
            *(ushort4*)&As[r*40 + kq]     = p0;
            *(ushort4*)&As[r*40 + kq + 4] = p1;
        }
        *(uint4*)&Ws[r*40 + kq] = wv;
        __syncthreads();
        if (kk + 32 < K) loadT(kk + 32);
        frag_ab af = *(const frag_ab*)&As[(wave*16 + l15)*40 + quad*8];
        #pragma unroll
        for (int tl = 0; tl < 4; ++tl) {
            frag_ab bf = *(const frag_ab*)&Ws[(tl*16 + l15)*40 + quad*8];
            acc[tl] = __builtin_amdgcn_mfma_f32_16x16x32_bf16(af, bf, acc[tl], 0, 0, 0);
        }
        __syncthreads();
    }
    const bool do_relu = flags & 2;
    const bool has_b   = flags & 4;
    const bool obf     = flags & 8;
    #pragma unroll
    for (int tl = 0; tl < 4; ++tl) {
        int col = n0 + tl*16 + l15;
        if (col < N) {
            float bv = 0.f;
            if (has_b) bv = (flags & 16) ? ((const float*)bias)[boff + col]
                                         : ldf(bias, boff + col, isbf);
            #pragma unroll
            for (int rg = 0; rg < 4; ++rg) {
                int row = m0 + wave*16 + quad*4 + rg;
                float v = acc[tl][rg] + bv;
                if (do_relu) v = fmaxf(v, 0.f);
                if (obf) ((ush*)C)[(size_t)row*N + col] = f2b(v);
                else     C[(size_t)row*N + col] = v;
            }
        }
    }
}

// ---------------- LayerNorm (node rows, D=256): out = LN(a + b) ----------------
__global__ __launch_bounds__(64) void ln_k(
    const float* __restrict__ a, const float* __restrict__ b,
    const void* __restrict__ g, const void* __restrict__ be, size_t goff,
    float* __restrict__ out, const int* __restrict__ flag, int D)
{
    const int isbf = *flag;
    const int row = blockIdx.x;
    const int t = threadIdx.x;
    float v[4];
    int cnt = 0;
    float s = 0.f;
    for (int i = t; i < D; i += 64) {
        float x = a[(size_t)row*D + i];
        if (b) x += b[(size_t)row*D + i];
        v[cnt++] = x; s += x;
    }
    #pragma unroll
    for (int off = 32; off > 0; off >>= 1) s += __shfl_down(s, off);
    s = __shfl(s, 0);
    const float mean = s / D;
    float qq = 0.f;
    for (int c2 = 0; c2 < cnt; ++c2) { float d = v[c2]-mean; qq += d*d; }
    #pragma unroll
    for (int off = 32; off > 0; off >>= 1) qq += __shfl_down(qq, off);
    qq = __shfl(qq, 0);
    const float inv = rsqrtf(fmaxf(qq, 0.f) / D + 1e-5f);
    cnt = 0;
    for (int i = t; i < D; i += 64)
        out[(size_t)row*D + i] = (v[cnt++] - mean)*inv*ldf(g, goff + i, isbf) + ldf(be, goff + i, isbf);
}

// ---------------- MFMA eq/ek/ev (+gathered mixed), 128 rows/block, bf16 out ----------------
__global__ __launch_bounds__(256) void eqkv_mfma_k(
    const float* __restrict__ lg, const float* __restrict__ xsd,
    const int* __restrict__ gsrc, const int* __restrict__ gdst,
    const ush* __restrict__ WQKV, size_t woff,
    const void* __restrict__ bq, size_t boff,
    ush* __restrict__ eq, ush* __restrict__ ek, ush* __restrict__ ev,
    const int* __restrict__ flag)
{
    __shared__ __align__(16) ush mixs[128*40];
    __shared__ __align__(16) ush wts[3][32*40];
    __shared__ float bqs[32];
    const int isbf = *flag;
    const int t = threadIdx.x;
    const int e0 = blockIdx.x * 128;
    #pragma unroll
    for (int i = t; i < 768; i += 256) {
        int m = i >> 8, r2 = i & 255;
        int n = r2 >> 3, k4 = (r2 & 7) * 4;
        *(ushort4*)&wts[m][n*40 + k4] =
            *(const ushort4*)&WQKV[(size_t)m*2048 + woff + (size_t)n*32 + k4];
    }
    if (t < 32) bqs[t] = ldf(bq, boff + t, isbf);
    {
        int r = t >> 1, c0 = (t & 1) * 16;
        int e = e0 + r;
        int s = gsrc[e], d2 = gdst[e];
        const float* lp = lg + (size_t)e*32 + c0;
        const float* sp = xsd + (size_t)s*kQW + c0;
        const float* dp = xsd + (size_t)d2*kQW + 32 + c0;
        #pragma unroll
        for (int j = 0; j < 16; ++j)
            mixs[r*40 + c0 + j] = f2b(lp[j] + sp[j] + dp[j]);
    }
    __syncthreads();
    const int wave = t >> 6, l15 = t & 15, quad = (t >> 4) & 3;
    #pragma unroll
    for (int mi = 0; mi < 2; ++mi) {
        const int mt = wave*2 + mi;
        frag_ab af = *(const frag_ab*)&mixs[(mt*16 + l15)*40 + quad*8];
        #pragma unroll
        for (int w = 0; w < 3; ++w) {
            ush* outp = (w==0) ? eq : ((w==1) ? ek : ev);
            #pragma unroll
            for (int nt = 0; nt < 2; ++nt) {
                frag_ab bf = *(const frag_ab*)&wts[w][(nt*16 + l15)*40 + quad*8];
                frag_cd acc = {0.f, 0.f, 0.f, 0.f};
                acc = __builtin_amdgcn_mfma_f32_16x16x32_bf16(af, bf, acc, 0, 0, 0);
                const float bv = (w==0) ? bqs[nt*16 + l15] : 0.f;
                #pragma unroll
                for (int rg = 0; rg < 4; ++rg) {
                    int row = e0 + mt*16 + quad*4 + rg;
                    outp[(size_t)row*32 + nt*16 + l15] = f2b(acc[rg] + bv);
                }
            }
        }
    }
}

// ---------------- MFMA edge FFN: LN(A + relu(A@W1+b1)@W2 + b2) ----------------
__global__ __launch_bounds__(256) void effn_mfma_k(
    const float* __restrict__ A,
    const ush* __restrict__ W1T, size_t w1off, const void* __restrict__ b1, size_t b1off,
    const ush* __restrict__ W2T, size_t w2off, const void* __restrict__ b2, size_t b2off,
    const void* __restrict__ g, const void* __restrict__ be, size_t goff,
    float* __restrict__ out, const int* __restrict__ flag)
{
    __shared__ __align__(16) ush w1t[128*40];
    __shared__ __align__(16) ush w2t[32*136];
    __shared__ __align__(16) ush hid[64*136];
    __shared__ float b1s[128], b2s[32];
    const int isbf = *flag;
    const int t = threadIdx.x;
    const int wave = t >> 6, l15 = t & 15, quad = (t >> 4) & 3;

    #pragma unroll
    for (int i = t; i < 1024; i += 256) {
        int n1 = i >> 3, k4 = (i & 7) * 4;
        *(ushort4*)&w1t[n1*40 + k4] = *(const ushort4*)&W1T[w1off + (size_t)n1*32 + k4];
        int n2 = i >> 5, kq2 = (i & 31) * 4;
        *(ushort4*)&w2t[n2*136 + kq2] = *(const ushort4*)&W2T[w2off + (size_t)n2*128 + kq2];
    }
    if (t < 128) b1s[t] = ldf(b1, b1off + t, isbf);
    if (t < 32)  b2s[t] = ldf(b2, b2off + t, isbf);
    __syncthreads();

    const float g0  = ldf(g,  goff + l15, isbf),      g1v = ldf(g,  goff + 16 + l15, isbf);
    const float be0 = ldf(be, goff + l15, isbf),      be1 = ldf(be, goff + 16 + l15, isbf);
    const float bb0 = b2s[l15], bb1 = b2s[16 + l15];

    for (int tt = 0; tt < 2; ++tt) {
        const int e0 = (blockIdx.x*2 + tt) * 64;
        {
            const int m = wave*16 + l15;
            float4 a0 = *(const float4*)&A[(size_t)(e0+m)*32 + quad*8];
            float4 a1 = *(const float4*)&A[(size_t)(e0+m)*32 + quad*8 + 4];
            ush tmp[8] = {f2b(a0.x),f2b(a0.y),f2b(a0.z),f2b(a0.w),
                          f2b(a1.x),f2b(a1.y),f2b(a1.z),f2b(a1.w)};
            frag_ab af = *(frag_ab*)tmp;
            #pragma unroll
            for (int nt = 0; nt < 8; ++nt) {
                frag_ab bf = *(const frag_ab*)&w1t[(nt*16 + l15)*40 + quad*8];
                frag_cd acc = {0.f, 0.f, 0.f, 0.f};
                acc = __builtin_amdgcn_mfma_f32_16x16x32_bf16(af, bf, acc, 0, 0, 0);
                float bv = b1s[nt*16 + l15];
                #pragma unroll
                for (int rg = 0; rg < 4; ++rg) {
                    int row = wave*16 + quad*4 + rg;
                    hid[row*136 + nt*16 + l15] = f2b(fmaxf(acc[rg] + bv, 0.f));
                }
            }
        }
        // hid rows are wave-private -> no barrier needed
        frag_cd acc2[2] = {{0.f,0.f,0.f,0.f},{0.f,0.f,0.f,0.f}};
        #pragma unroll
        for (int ks = 0; ks < 4; ++ks) {
            frag_ab af2 = *(const frag_ab*)&hid[(wave*16 + l15)*136 + ks*32 + quad*8];
            #pragma unroll
            for (int tl = 0; tl < 2; ++tl) {
                frag_ab bf2 = *(const frag_ab*)&w2t[(tl*16 + l15)*136 + ks*32 + quad*8];
                acc2[tl] = __builtin_amdgcn_mfma_f32_16x16x32_bf16(af2, bf2, acc2[tl], 0, 0, 0);
            }
        }
        #pragma unroll
        for (int rg = 0; rg < 4; ++rg) {
            const int row = e0 + wave*16 + quad*4 + rg;
            float v0 = acc2[0][rg] + bb0 + A[(size_t)row*32 + l15];
            float v1 = acc2[1][rg] + bb1 + A[(size_t)row*32 + 16 + l15];
            float s = v0 + v1;
            s += __shfl_xor(s,1); s += __shfl_xor(s,2); s += __shfl_xor(s,4); s += __shfl_xor(s,8);
            const float mean = s * (1.f/32.f);
            float q = (v0-mean)*(v0-mean) + (v1-mean)*(v1-mean);
            q += __shfl_xor(q,1); q += __shfl_xor(q,2); q += __shfl_xor(q,4); q += __shfl_xor(q,8);
            const float inv = rsqrtf(q * (1.f/32.f) + 1e-5f);
            out[(size_t)row*32 + l15]      = (v0-mean)*inv*g0  + be0;
            out[(size_t)row*32 + 16 + l15] = (v1-mean)*inv*g1v + be1;
        }
    }
}

// ---------------- full-graph attention v5: (b,h,quarter) blocks, 512 grid ----------------
// Block = 32 dst x 128 src for one head. 8 waves each cover 16 src; a lane PAIR
// shares one dst (16 dims each). Merge over 8 wave-partials in pb[8][32][34].
__global__ __launch_bounds__(512) void full_attn_k(
    const float* __restrict__ q, const float* __restrict__ k, const float* __restrict__ v,
    const void* __restrict__ rel, const int* __restrict__ feat, float* __restrict__ o,
    const int* __restrict__ flag, int ldq)
{
    __shared__ __align__(8) ush ks[128][36];
    __shared__ __align__(8) ush vs[128][36];
    __shared__ __align__(8) ush rs[128][36];
    __shared__ float pb[8][32][34];            // per-wave partials: m, l, acc[32]
    const int isbf = *flag;
    const int bid = blockIdx.x;
    const int b = bid >> 4, h = (bid >> 2) & 3, qtr = bid & 3;
    const int t = threadIdx.x;
    for (int i = t; i < 4096; i += 512) {
        int r = i >> 5, d = i & 31;
        rs[r][d] = ldb(rel, i, isbf);
        size_t base = ((size_t)(b*128 + r))*ldq + h*32 + d;
        ks[r][d] = f2b(k[base]);
        vs[r][d] = f2b(v[base]);
    }
    __syncthreads();
    const int wave = t >> 6, lane = t & 63;
    const int dstL = lane >> 1, part = lane & 1;   // 2 lanes per dst
    const int dst = qtr*32 + dstL;
    const int dbase = part*16;                     // this lane's 16 dims
    float qr[16];
    { size_t base = ((size_t)(b*128 + dst))*ldq + h*32 + dbase;
      #pragma unroll
      for (int d=0; d<16; ++d) qr[d] = q[base + d]; }
    const int* fp = feat + (size_t)b*16384 + dst;
    const int s0 = wave*16;
    float m = -1e30f, l = 0.f;
    float acc[16];
    #pragma unroll
    for (int d=0; d<16; ++d) acc[d] = 0.f;
    int f = fp[s0*128];
    for (int sI = 0; sI < 16; ++sI) {
        const int s = s0 + sI;
        int fn = (sI+1 < 16) ? fp[(s+1)*128] : 0;
        float er[16];
        float scp = 0.f;
        #pragma unroll
        for (int j2 = 0; j2 < 4; ++j2) {
            ushort4 eu = *(const ushort4*)&rs[f][dbase + j2*4];
            ushort4 ku = *(const ushort4*)&ks[s][dbase + j2*4];
            float e0 = b2f(eu.x), e1 = b2f(eu.y), e2 = b2f(eu.z), e3 = b2f(eu.w);
            er[j2*4+0]=e0; er[j2*4+1]=e1; er[j2*4+2]=e2; er[j2*4+3]=e3;
            scp += (b2f(ku.x)+e0)*qr[j2*4+0] + (b2f(ku.y)+e1)*qr[j2*4+1]
                 + (b2f(ku.z)+e2)*qr[j2*4+2] + (b2f(ku.w)+e3)*qr[j2*4+3];
        }
        const float sc = (scp + __shfl_xor(scp, 1)) * kScaleN;
        float mn = fmaxf(m, sc);
        float c0 = __expf(m - mn);
        float pp = __expf(sc - mn);
        l = l*c0 + pp;
        #pragma unroll
        for (int j2 = 0; j2 < 4; ++j2) {
            ushort4 vu = *(const ushort4*)&vs[s][dbase + j2*4];
            acc[j2*4+0] = acc[j2*4+0]*c0 + pp*(b2f(vu.x)+er[j2*4+0]);
            acc[j2*4+1] = acc[j2*4+1]*c0 + pp*(b2f(vu.y)+er[j2*4+1]);
            acc[j2*4+2] = acc[j2*4+2]*c0 + pp*(b2f(vu.z)+er[j2*4+2]);
            acc[j2*4+3] = acc[j2*4+3]*c0 + pp*(b2f(vu.w)+er[j2*4+3]);
        }
        m = mn; f = fn;
    }
    if (part == 0) { pb[wave][dstL][0] = m; pb[wave][dstL][1] = l; }
    #pragma unroll
    for (int d=0; d<16; ++d) pb[wave][dstL][2 + dbase + d] = acc[d];
    __syncthreads();
    // merge: thread (dstL2, grp) handles dims [grp*2, grp*2+2) of dst=qtr*32+dstL2
    {
        const int dstL2 = t & 31, grp = t >> 5;   // grp in [0,16)
        float mw[8], lw[8];
        #pragma unroll
        for (int w=0; w<8; ++w){ mw[w]=pb[w][dstL2][0]; lw[w]=pb[w][dstL2][1]; }
        float M = mw[0];
        #pragma unroll
        for (int w=1; w<8; ++w) M = fmaxf(M, mw[w]);
        float sw[8];
        float L = 0.f;
        #pragma unroll
        for (int w=0; w<8; ++w){ sw[w] = __expf(mw[w]-M); L += lw[w]*sw[w]; }
        const float inv = 1.f / fmaxf(L, 1e-30f);
        size_t base = ((size_t)(b*128 + qtr*32 + dstL2))*kND + h*32 + grp*2;
        #pragma unroll
        for (int d=0; d<2; ++d) {
            float a = 0.f;
            #pragma unroll
            for (int w=0; w<8; ++w) a += pb[w][dstL2][2+grp*2+d]*sw[w];
            o[base + d] = a*inv;
        }
    }
}

// ---------------- local-graph GATHER attention (heads 4..7) ----------------
__global__ __launch_bounds__(256) void loc_gather_k(
    const float* __restrict__ q, const float* __restrict__ k, const float* __restrict__ v,
    const float* __restrict__ lg, const int* __restrict__ gsrc,
    const int* __restrict__ rowp, const int* __restrict__ eidl,
    float* __restrict__ o, int ldq)
{
    const int n = blockIdx.x;
    const int h = threadIdx.x >> 6;
    const int lane = threadIdx.x & 63;
    const int g = lane >> 4;
    const int d0 = (lane & 15) * 2;
    const size_t hoff = (size_t)(4 + h) * 32 + d0;
    const float2 q2 = *(const float2*)&q[(size_t)n*ldq + hoff];
    const int beg = rowp[n], end = rowp[n+1];
    const int deg = end - beg;
    float m = -1e30f, l = 0.f, ax = 0.f, ay = 0.f;
    if (deg > 0) {
        const int nIter = (deg + 3) >> 2;
        int idx = beg + g;
        int ce = eidl[min(idx, end-1)];
        int cs = gsrc[ce];
        for (int it = 0; it < nIter; ++it) {
            const bool valid = idx < end;
            const int e = ce, s = cs;
            idx += 4;
            if (it + 1 < nIter) { ce = eidl[min(idx, end-1)]; cs = gsrc[ce]; }
            const float2 kv = *(const float2*)&k[(size_t)s*ldq + hoff];
            const float2 lv = *(const float2*)&lg[(size_t)e*32 + d0];
            const float2 vv = *(const float2*)&v[(size_t)s*ldq + hoff];
            float part = (kv.x+lv.x)*q2.x + (kv.y+lv.y)*q2.y;
            part += __shfl_xor(part, 1);
            part += __shfl_xor(part, 2);
            part += __shfl_xor(part, 4);
            part += __shfl_xor(part, 8);
            const float sc = part * kScaleN;
            const float mn = valid ? fmaxf(m, sc) : m;
            const float c  = __expf(m - mn);
            const float pp = valid ? __expf(sc - mn) : 0.f;
            l  = l*c  + pp;
            ax = ax*c + pp*(vv.x+lv.x);
            ay = ay*c + pp*(vv.y+lv.y);
            m  = mn;
        }
        #pragma unroll
        for (int off = 16; off <= 32; off <<= 1) {
            const float mo = __shfl_xor(m, off);
            const float lo = __shfl_xor(l, off);
            const float xo = __shfl_xor(ax, off);
            const float yo = __shfl_xor(ay, off);
            const float M  = fmaxf(m, mo);
            const float c1 = __expf(m - M);
            const float c2 = __expf(mo - M);
            l  = l*c1  + lo*c2;
            ax = ax*c1 + xo*c2;
            ay = ay*c1 + yo*c2;
            m  = M;
        }
    }
    if (g == 0) {
        const float inv = 1.f / fmaxf(l, 1e-30f);
        *(float2*)&o[(size_t)n*kND + hoff] = make_float2(ax*inv, ay*inv);
    }
}

// ---------------- fused line-graph attention + Wo GEMM + LN (bf16 eq/ek/ev) ----------------
__global__ __launch_bounds__(256) void lgs_ewo_k(
    const ush* __restrict__ eq, const ush* __restrict__ ek, const ush* __restrict__ ev,
    const int* __restrict__ lsrc, const int* __restrict__ rowp, const int* __restrict__ eidl,
    const float* __restrict__ res,
    const ush* __restrict__ WO, size_t wooff, const void* __restrict__ bo, size_t booff,
    const void* __restrict__ g1, const void* __restrict__ be1, size_t g1off,
    float* __restrict__ out, const int* __restrict__ flag)
{
    __shared__ __align__(16) ush ows[32*40];
    __shared__ __align__(16) ush wos[32*40];
    __shared__ float cs[32][36];
    __shared__ float bos[32], gs[32], bs[32];
    const int isbf = *flag;
    const int t = threadIdx.x;
    const int base = blockIdx.x * 32;
    {
        int n = t >> 3, k4 = (t & 7) * 4;
        *(ushort4*)&wos[n*40 + k4] = *(const ushort4*)&WO[wooff + (size_t)n*32 + k4];
    }
    if (t < 32) {
        bos[t] = ldf(bo, booff + t, isbf);
        gs[t]  = ldf(g1, g1off + t, isbf);
        bs[t]  = ldf(be1, g1off + t, isbf);
    }
    // ---- phase 1: gather attention, thread = (dst-edge, head) ----
    {
        const int d2 = base + (t >> 3), h = t & 7;
        const ushort4 qu = *(const ushort4*)&eq[(size_t)d2*32 + h*4];
        const float q0 = b2f(qu.x), q1 = b2f(qu.y), q2 = b2f(qu.z), q3 = b2f(qu.w);
        const int beg = rowp[d2], end = rowp[d2+1];
        float m = -1e30f, l = 0.f;
        float4 acc = make_float4(0.f,0.f,0.f,0.f);
        int i = beg;
        int s = 0;
        if (i < end) { s = lsrc[eidl[i]]; }
        while (i < end) {
            const int sc_s = s;
            ++i;
            if (i < end) { s = lsrc[eidl[i]]; }      // prefetch next src
            const ushort4 ku = *(const ushort4*)&ek[(size_t)sc_s*32 + h*4];
            const ushort4 vu = *(const ushort4*)&ev[(size_t)sc_s*32 + h*4];
            float sc = (b2f(ku.x)*q0 + b2f(ku.y)*q1 + b2f(ku.z)*q2 + b2f(ku.w)*q3) * 0.5f;
            float mn = fmaxf(m, sc);
            float c = __expf(m - mn);
            float pp = __expf(sc - mn);
            l = l*c + pp;
            acc.x = acc.x*c + pp*b2f(vu.x);
            acc.y = acc.y*c + pp*b2f(vu.y);
            acc.z = acc.z*c + pp*b2f(vu.z);
            acc.w = acc.w*c + pp*b2f(vu.w);
            m = mn;
        }
        const float inv = 1.f / fmaxf(l, 1e-30f);
        const int r = t >> 3, c0 = h*4;
        ows[r*40 + c0 + 0] = f2b(acc.x*inv);
        ows[r*40 + c0 + 1] = f2b(acc.y*inv);
        ows[r*40 + c0 + 2] = f2b(acc.z*inv);
        ows[r*40 + c0 + 3] = f2b(acc.w*inv);
    }
    __syncthreads();
    // ---- phase 2: 32x32 GEMM ----
    {
        const int wave = t >> 6, l15 = t & 15, quad = (t >> 4) & 3;
        const int mt = wave & 1, nt = wave >> 1;
        frag_ab af = *(const frag_ab*)&ows[(mt*16 + l15)*40 + quad*8];
        frag_ab bf = *(const frag_ab*)&wos[(nt*16 + l15)*40 + quad*8];
        frag_cd acc = {0.f, 0.f, 0.f, 0.f};
        acc = __builtin_amdgcn_mfma_f32_16x16x32_bf16(af, bf, acc, 0, 0, 0);
        #pragma unroll
        for (int rg = 0; rg < 4; ++rg) {
            const int row = mt*16 + quad*4 + rg;
            const int col = nt*16 + l15;
            cs[row][col] = acc[rg] + bos[col] + res[(size_t)(base+row)*32 + col];
        }
    }
    __syncthreads();
    // ---- phase 3: LN per row ----
    {
        const int row = t >> 3, c0 = (t & 7) * 4;
        const float v0 = cs[row][c0], v1 = cs[row][c0+1];
        const float v2 = cs[row][c0+2], v3 = cs[row][c0+3];
        float s = v0+v1+v2+v3;
        s += __shfl_xor(s,1); s += __shfl_xor(s,2); s += __shfl_xor(s,4);
        const float mean = s * (1.f/32.f);
        float qq = (v0-mean)*(v0-mean)+(v1-mean)*(v1-mean)
                 + (v2-mean)*(v2-mean)+(v3-mean)*(v3-mean);
        qq += __shfl_xor(qq,1); qq += __shfl_xor(qq,2); qq += __shfl_xor(qq,4);
        const float inv = rsqrtf(qq * (1.f/32.f) + 1e-5f);
        float o0 = (v0-mean)*inv*gs[c0+0] + bs[c0+0];
        float o1 = (v1-mean)*inv*gs[c0+1] + bs[c0+1];
        float o2 = (v2-mean)*inv*gs[c0+2] + bs[c0+2];
        float o3 = (v3-mean)*inv*gs[c0+3] + bs[c0+3];
        *(float4*)&out[(size_t)(base+row)*32 + c0] = make_float4(o0,o1,o2,o3);
    }
}

// ---------------- output ----------------
__global__ void out_k(const float* __restrict__ xf, const float* __restrict__ lgf,
                      void* __restrict__ out, const int* __restrict__ flag){
    const int isbf = *flag;
    int g = blockIdx.x*256 + threadIdx.x;
    float v = (g < kN*kND) ? xf[g] : lgf[g - kN*kND];
    if (isbf) ((bf16*)out)[g] = __float2bfloat16(v);
    else      ((float*)out)[g] = v;
}

// ---------------- host helper ----------------
static inline void mgemm(const float* A, const ush* WT, const void* bias, size_t boff,
                         float* C, const int* flag, int M, int N, int K, int flags,
                         hipStream_t s){
    dim3 grid((N+63)/64, M/64);
    mgemm_k<<<grid, 256, 0, s>>>(A, WT, bias, boff, C, flag, M, N, K, flags);
}

extern "C" void kernel_launch(void* const* d_in, const int* in_sizes, int n_in,
                              void* d_out, int out_size, void* d_ws, size_t ws_size,
                              hipStream_t stream) {
    const void* x_in      = d_in[0];
    const void* rel       = d_in[1];
    const int* g_src      = (const int*)d_in[4];
    const int* g_dst      = (const int*)d_in[5];
    const int* lg_src     = (const int*)d_in[6];
    const int* lg_dst     = (const int*)d_in[7];
    const int* edge_feat  = (const int*)d_in[8];
    const int* full_feat  = (const int*)d_in[9];
    const void* n_Wq   = d_in[10];
    const void* n_bq   = d_in[11];
    const void* n_Wk   = d_in[12];
    const void* n_bk   = d_in[13];
    const void* n_Wv   = d_in[14];
    const void* n_bv   = d_in[15];
    const void* n_Wo   = d_in[16];
    const void* n_bo   = d_in[17];
    const void* n_lng  = d_in[18];
    const void* n_lnb  = d_in[19];
    const void* n_fW1  = d_in[20];
    const void* n_fb1  = d_in[21];
    const void* n_fW2  = d_in[22];
    const void* n_fb2  = d_in[23];
    const void* n_flng = d_in[24];
    const void* n_flnb = d_in[25];
    const void* e_Wsrc = d_in[26];
    const void* e_Wdst = d_in[27];
    const void* e_Wq   = d_in[28];
    const void* e_bq   = d_in[29];
    const void* e_Wk   = d_in[30];
    const void* e_Wv   = d_in[31];
    const void* e_Wo   = d_in[32];
    const void* e_bo   = d_in[33];
    const void* e_lng  = d_in[34];
    const void* e_lnb  = d_in[35];
    const void* e_fW1  = d_in[36];
    const void* e_fb1  = d_in[37];
    const void* e_fW2  = d_in[38];
    const void* e_fb2  = d_in[39];
    const void* e_flng = d_in[40];
    const void* e_flnb = d_in[41];

    // ---- workspace carve-up (units: floats) ----
    float* p = (float*)d_ws;
    size_t off = 0;
    auto AL = [&](size_t n){ float* r = p + off; off += n; return r; };
    int* flagp = (int*)AL(64);
    float* xA   = AL((size_t)kN*kND);
    float* xB   = AL((size_t)kN*kND);
    float* xM   = AL((size_t)kN*kND);
    float* qkvb = AL((size_t)kN*kQW);
    float* ob   = AL((size_t)kN*kND);
    float* tN   = AL((size_t)kN*kND);
    ush*   nh   = (ush*)AL((size_t)kN*512);      // kN*1024 bf16
    float* lgA  = AL((size_t)kEL*kED);
    float* lgB  = AL((size_t)kEL*kED);
    float* lgM  = AL((size_t)kEL*kED);
    ush*   eqb  = (ush*)AL((size_t)kEL*16);      // kEL*32 bf16
    ush*   ekb  = (ush*)AL((size_t)kEL*16);
    ush*   evb  = (ush*)AL((size_t)kEL*16);
    // CSR structures
    int* cntL  = (int*)AL(kN);
    int* rowL  = (int*)AL(kN + 64);
    int* curL  = (int*)AL(kN);
    int* eidL  = (int*)AL(kEL);
    int* cntG  = (int*)AL(kEL);
    int* rowG  = (int*)AL(kEL + 64);
    int* curG  = (int*)AL(kEL);
    int* eidG  = (int*)AL(kELG);
    int* bsum  = (int*)AL(256);
    // pre-transposed bf16 weights
    ush* wtQKVSD = (ush*)AL(212992);   // [L][832][256] bf16 (425984 ush)
    float* bQKV  = AL(2*kQW);
    ush* wtO  = (ush*)AL(65536);
    ush* wtF1 = (ush*)AL(262144);
    ush* wtF2 = (ush*)AL(262144);
    ush* wtEQKV = (ush*)AL(3072);
    ush* wtEO   = (ush*)AL(1024);
    ush* wtEF1  = (ush*)AL(4096);
    ush* wtEF2  = (ush*)AL(4096);
    if (ws_size < off * sizeof(float)) return;

    detect_k<<<1, 64, 0, stream>>>((const ush*)x_in, flagp);
    {
        long total = (long)kN*kND + (long)kEL*kED + 2*kQW + kN + kEL;
        int blocks = (int)((total + 255) / 256);
        setup_misc_k<<<blocks, 256, 0, stream>>>(x_in, rel, edge_feat, n_bq, n_bk, n_bv,
                                                 xA, lgA, bQKV, cntL, cntG, flagp);
    }
    trans_all_k<<<6368, 256, 0, stream>>>(n_Wq, n_Wk, n_Wv, n_Wo, n_fW1, n_fW2,
                                          e_Wsrc, e_Wdst, e_Wq, e_Wk, e_Wv, e_Wo,
                                          e_fW1, e_fW2, flagp,
                                          wtQKVSD, wtO, wtF1, wtF2,
                                          wtEQKV, wtEO, wtEF1, wtEF2);

    count2_k<<<(kEL+kELG)/256, 256, 0, stream>>>(g_dst, lg_dst, cntL, cntG);
    scan_blk2_k<<<132, 256, 0, stream>>>(cntL, cntG, rowL, rowG, bsum);
    scan_top2_k<<<1, 256, 0, stream>>>(bsum);
    scan_add2_k<<<(kN+kEL)/256, 256, 0, stream>>>(rowL, rowG, bsum, curL, curG);
    fill2_k<<<(kEL+kELG)/256, 256, 0, stream>>>(g_dst, lg_dst, curL, curG, eidL, eidG);

    float* xc = xA;  float* xn = xB;
    float* lgc = lgA; float* lgn = lgB;

    for (int i = 0; i < kL; ++i) {
        const size_t o256 = (size_t)i*kND;
        const size_t o1024= (size_t)i*1024;
        const size_t o32  = (size_t)i*kED;
        const size_t o128 = (size_t)i*128;

        // ===== node update (+ packed xs/xd in cols 768-831) =====
        mgemm(xc, wtQKVSD + (size_t)i*212992, bQKV, (size_t)i*kQW, qkvb, flagp,
              kN, kQW, kND, 4|16, stream);
        full_attn_k<<<512, 512, 0, stream>>>(qkvb, qkvb+256, qkvb+512, rel, full_feat,
                                             ob, flagp, kQW);
        loc_gather_k<<<kN, 256, 0, stream>>>(qkvb, qkvb+256, qkvb+512, lgc, g_src,
                                             rowL, eidL, ob, kQW);
        mgemm(ob, wtO + (size_t)i*65536, n_bo, o256, tN, flagp, kN, kND, kND, 4, stream);
        ln_k<<<kN, 64, 0, stream>>>(xc, tN, n_lng, n_lnb, o256, xM, flagp, kND);
        mgemm(xM, wtF1 + (size_t)i*262144, n_fb1, o1024, (float*)nh, flagp,
              kN, 1024, kND, 4|2|8, stream);
        mgemm((const float*)nh, wtF2 + (size_t)i*262144, n_fb2, o256, tN, flagp,
              kN, kND, 1024, 4|32, stream);
        ln_k<<<kN, 64, 0, stream>>>(xM, tN, n_flng, n_flnb, o256, xn, flagp, kND);

        // ===== edge update (uses PRE-update xc, lgc) =====
        eqkv_mfma_k<<<kEL/128, 256, 0, stream>>>(lgc, qkvb + 768, g_src, g_dst,
                                                 wtEQKV, (size_t)i*1024, e_bq, o32,
                                                 eqb, ekb, evb, flagp);
        lgs_ewo_k<<<kEL/32, 256, 0, stream>>>(eqb, ekb, evb, lg_src, rowG, eidG,
                                              lgc, wtEO, (size_t)i*1024, e_bo, o32,
                                              e_lng, e_lnb, o32, lgM, flagp);
        effn_mfma_k<<<kEL/128, 256, 0, stream>>>(lgM, wtEF1, (size_t)i*4096, e_fb1, o128,
                                                 wtEF2, (size_t)i*4096, e_fb2, o32,
                                                 e_flng, e_flnb, o32, lgn, flagp);

        { float* t = xc; xc = xn; xn = t; }
        { float* t = lgc; lgc = lgn; lgn = t; }
    }

    out_k<<<(kN*kND + kEL*kED)/256, 256, 0, stream>>>(xc, lgc, d_out, flagp);
}

// Round 7
// 564.136 us; speedup vs baseline: 1.3682x; 1.0274x over previous
//
#include <hip/hip_runtime.h>
#include <hip/hip_bf16.h>

typedef __hip_bfloat16 bf16;
typedef unsigned short ush;

static constexpr int kN   = 4096;    // nodes
static constexpr int kND  = 256;     // hidden
static constexpr int kEL  = 131072;  // local edges
static constexpr int kED  = 32;      // edge dim
static constexpr int kELG = 262144;  // line-graph edges
static constexpr int kL   = 2;
static constexpr int kQW  = 832;     // packed qkv+sd width
static constexpr float kScaleN = 0.17677669529663687f; // 1/sqrt(32)

using frag_ab = __attribute__((ext_vector_type(8))) short;   // 8 bf16 (4 VGPRs)
using frag_cd = __attribute__((ext_vector_type(4))) float;   // 4 fp32

__device__ __forceinline__ float ldf(const void* p, size_t i, int isbf){
    return isbf ? __bfloat162float(((const bf16*)p)[i]) : ((const float*)p)[i];
}
__device__ __forceinline__ ush f2b(float f){ bf16 h = __float2bfloat16(f); return *(ush*)&h; }
__device__ __forceinline__ float b2f(ush u){ return __uint_as_float(((unsigned)u)<<16); }
__device__ __forceinline__ ush ldb(const void* p, size_t i, int isbf){
    return isbf ? ((const ush*)p)[i] : f2b(((const float*)p)[i]);
}

// ---------------- dtype detection ----------------
__global__ void detect_k(const ush* __restrict__ xin, int* __restrict__ flag){
    if (threadIdx.x == 0 && blockIdx.x == 0) {
        int plausible = 0;
        for (int i = 0; i < 128; ++i) {
            ush u = xin[i];
            int e = (u >> 7) & 0xFF;
            if (e == 0 || (e >= 110 && e <= 140)) ++plausible;
        }
        *flag = (plausible >= 102) ? 1 : 0;
    }
}

// ---------------- fused setup: cast x (f32+bf16), init lg (bf16), pack bias, zero counters ----------------
__global__ void setup_misc_k(const void* __restrict__ xin, const void* __restrict__ rel,
                             const int* __restrict__ feat,
                             const void* __restrict__ bq, const void* __restrict__ bk,
                             const void* __restrict__ bv,
                             float* __restrict__ xA, ush* __restrict__ xAb,
                             ush* __restrict__ lgA,
                             float* __restrict__ bQKV,
                             int* __restrict__ cntL, int* __restrict__ cntG,
                             const int* __restrict__ flag){
    const int isbf = *flag;
    long g = (long)blockIdx.x*256 + threadIdx.x;
    if (g < (long)kN*kND) {
        float v = ldf(xin, g, isbf);
        xA[g] = v; xAb[g] = f2b(v);
        return;
    }
    g -= (long)kN*kND;
    if (g < (long)kEL*kED) { int e = (int)(g >> 5), d = (int)(g & 31);
        lgA[g] = ldb(rel, (size_t)feat[e]*kED + d, isbf); return; }
    g -= (long)kEL*kED;
    if (g < 2*kQW) {
        int layer = (int)(g / kQW), j = (int)(g - (long)layer*kQW);
        float v = 0.f;
        if (j < 768) { int w = j >> 8, jj = j & 255;
            const void* B = (w==0)?bq:((w==1)?bk:bv);
            v = ldf(B, (size_t)layer*256 + jj, isbf); }
        bQKV[g] = v; return;
    }
    g -= 2*kQW;
    if (g < kN) { cntL[g] = 0; return; }
    g -= kN;
    if (g < kEL) { cntG[g] = 0; return; }
}

// ---------------- ALL weight pre-transposes in one kernel ----------------
__global__ void trans_all_k(
    const void* __restrict__ nWq, const void* __restrict__ nWk, const void* __restrict__ nWv,
    const void* __restrict__ nWo, const void* __restrict__ nF1, const void* __restrict__ nF2,
    const void* __restrict__ eWs, const void* __restrict__ eWd,
    const void* __restrict__ eWq, const void* __restrict__ eWk, const void* __restrict__ eWv,
    const void* __restrict__ eWo, const void* __restrict__ eF1, const void* __restrict__ eF2,
    const int* __restrict__ flag,
    ush* __restrict__ wtQKVSD, ush* __restrict__ wtO, ush* __restrict__ wtF1,
    ush* __restrict__ wtF2, ush* __restrict__ wtEQKV, ush* __restrict__ wtEO,
    ush* __restrict__ wtEF1, ush* __restrict__ wtEF2)
{
    const int isbf = *flag;
    int g = blockIdx.x*256 + threadIdx.x;
    if (g < 393216){                                   // QKV -> wtQKVSD rows 0-767
        int w = g >> 17, gg = g & 131071;
        int layer = gg >> 16, idx = gg & 65535;
        int n = idx >> 8, k = idx & 255;
        const void* W = (w==0)?nWq:((w==1)?nWk:nWv);
        wtQKVSD[(size_t)layer*212992 + (size_t)(w*256+n)*256 + k] =
            ldb(W, (size_t)layer*65536 + (size_t)k*256 + n, isbf);
        return;
    }
    g -= 393216;
    if (g < 32768){                                    // src/dst -> wtQKVSD rows 768-831
        int w = g >> 14, gg = g & 16383;
        int layer = gg >> 13, idx = gg & 8191;
        int n = idx >> 8, k = idx & 255;
        const void* W = w ? eWd : eWs;
        wtQKVSD[(size_t)layer*212992 + (size_t)(768 + w*32 + n)*256 + k] =
            ldb(W, (size_t)layer*8192 + (size_t)k*32 + n, isbf);
        return;
    }
    g -= 32768;
    if (g < 131072){                                   // Wo [L][256][256]
        int layer = g >> 16, rem = g & 65535;
        int n = rem >> 8, k = rem & 255;
        wtO[g] = ldb(nWo, (size_t)layer*65536 + (size_t)k*256 + n, isbf);
        return;
    }
    g -= 131072;
    if (g < 524288){                                   // F1 [L][1024][256]
        int layer = g >> 18, rem = g & 262143;
        int n = rem >> 8, k = rem & 255;
        wtF1[g] = ldb(nF1, (size_t)layer*262144 + (size_t)k*1024 + n, isbf);
        return;
    }
    g -= 524288;
    if (g < 524288){                                   // F2 [L][256][1024]
        int layer = g >> 18, rem = g & 262143;
        int n = rem >> 10, k = rem & 1023;
        wtF2[g] = ldb(nF2, (size_t)layer*262144 + (size_t)k*256 + n, isbf);
        return;
    }
    g -= 524288;
    if (g < 6144){                                     // eQKV [3][L][32][32]
        int w = g >> 11, gg = g & 2047;
        int layer = gg >> 10, rem = gg & 1023;
        int n = rem >> 5, k = rem & 31;
        const void* W = (w==0)?eWq:((w==1)?eWk:eWv);
        wtEQKV[g] = ldb(W, (size_t)layer*1024 + (size_t)k*32 + n, isbf);
        return;
    }
    g -= 6144;
    if (g < 2048){                                     // eWo [L][32][32]
        int layer = g >> 10, rem = g & 1023;
        int n = rem >> 5, k = rem & 31;
        wtEO[g] = ldb(eWo, (size_t)layer*1024 + (size_t)k*32 + n, isbf);
        return;
    }
    g -= 2048;
    if (g < 8192){                                     // eF1 [L][128][32]
        int layer = g >> 12, rem = g & 4095;
        int n = rem >> 5, k = rem & 31;
        wtEF1[g] = ldb(eF1, (size_t)layer*4096 + (size_t)k*128 + n, isbf);
        return;
    }
    g -= 8192;
    if (g < 8192){                                     // eF2 [L][32][128]
        int layer = g >> 12, rem = g & 4095;
        int n = rem >> 7, k = rem & 127;
        wtEF2[g] = ldb(eF2, (size_t)layer*4096 + (size_t)k*32 + n, isbf);
        return;
    }
}

// ---------------- CSR build (both graphs fused) ----------------
__global__ void count2_k(const int* __restrict__ gd, const int* __restrict__ lgd,
                         int* __restrict__ cntL, int* __restrict__ cntG){
    int g = blockIdx.x*256 + threadIdx.x;
    if (g < kEL) atomicAdd(&cntL[gd[g]], 1);
    else if (g < kEL + kELG) atomicAdd(&cntG[lgd[g - kEL]], 1);
}
__global__ __launch_bounds__(256) void scan_blk2_k(
    const int* __restrict__ cntL, const int* __restrict__ cntG,
    int* __restrict__ rowL, int* __restrict__ rowG, int* __restrict__ bsum)
{
    __shared__ int s[256];
    const int t = threadIdx.x;
    const bool isL = blockIdx.x < 4;
    const int* cnt = isL ? cntL : cntG;
    int* out = isL ? rowL : rowG;
    const int blk = isL ? blockIdx.x : blockIdx.x - 4;
    const int n = isL ? kN : kEL;
    const int b0 = blk*1024;
    int v[4], pre[4], tsum = 0;
    #pragma unroll
    for (int j=0;j<4;++j){
        int idx = b0 + t*4 + j;
        v[j] = (idx < n) ? cnt[idx] : 0;
        pre[j] = tsum; tsum += v[j];
    }
    s[t] = tsum; __syncthreads();
    for (int off=1; off<256; off<<=1){
        int x = (t>=off) ? s[t-off] : 0;
        __syncthreads();
        s[t] += x;
        __syncthreads();
    }
    int texc = s[t] - tsum;
    #pragma unroll
    for (int j=0;j<4;++j){
        int idx = b0 + t*4 + j;
        if (idx < n) out[idx] = texc + pre[j];
    }
    if (t == 255) bsum[(isL ? 0 : 8) + blk] = s[255];
}
__global__ __launch_bounds__(256) void scan_top2_k(int* __restrict__ bsum){
    __shared__ int sL[256], sG[256];
    const int t = threadIdx.x;
    int vL = (t < 4)   ? bsum[t]     : 0;
    int vG = (t < 128) ? bsum[8 + t] : 0;
    sL[t] = vL; sG[t] = vG; __syncthreads();
    for (int off=1; off<256; off<<=1){
        int xL = (t>=off) ? sL[t-off] : 0;
        int xG = (t>=off) ? sG[t-off] : 0;
        __syncthreads();
        sL[t] += xL; sG[t] += xG;
        __syncthreads();
    }
    if (t < 4)   bsum[t]     = sL[t] - vL;
    if (t < 128) bsum[8 + t] = sG[t] - vG;
}
__global__ void scan_add2_k(int* __restrict__ rowL, int* __restrict__ rowG,
                            const int* __restrict__ bsum,
                            int* __restrict__ curL, int* __restrict__ curG){
    int g = blockIdx.x*256 + threadIdx.x;
    if (g < kN){ int v = rowL[g] + bsum[g >> 10]; rowL[g] = v; curL[g] = v; }
    else if (g < kN + kEL){ int gg = g - kN;
        int v = rowG[gg] + bsum[8 + (gg >> 10)]; rowG[gg] = v; curG[gg] = v; }
    if (g == 0){ rowL[kN] = kEL; rowG[kEL] = kELG; }
}
__global__ void fill2_k(const int* __restrict__ gd, const int* __restrict__ lgd,
                        int* __restrict__ curL, int* __restrict__ curG,
                        int* __restrict__ eidL, int* __restrict__ eidG){
    int g = blockIdx.x*256 + threadIdx.x;
    if (g < kEL){ int pos = atomicAdd(&curL[gd[g]], 1); eidL[pos] = g; }
    else if (g < kEL + kELG){ int gg = g - kEL;
        int pos = atomicAdd(&curG[lgd[gg]], 1); eidG[pos] = gg; }
}

// ---------------- MFMA GEMM: C[M,N] = A@WT^T + bias (opt relu) ----------------
// WT: bf16 [N][K]. 64x64 tile, 4 waves.
// flags: 2=RELU, 4=has-bias, 8=bf16 out, 16=bias packed fp32, 32=A is bf16
__global__ __launch_bounds__(256) void mgemm_k(
    const float* __restrict__ A, const ush* __restrict__ WT,
    const void* __restrict__ bias, size_t boff,
    float* __restrict__ C, const int* __restrict__ flag,
    int M, int N, int K, int flags)
{
    __shared__ __align__(16) ush As[64*40];
    __shared__ __align__(16) ush Ws[64*40];
    const int isbf = *flag;
    const int t = threadIdx.x;
    const int m0 = blockIdx.y*64, n0 = blockIdx.x*64;
    const int wave = t>>6, lane = t&63;
    const int quad = lane>>4, l15 = lane&15;
    const int r = t>>2, kq = (t&3)*8;
    const bool abf = flags & 32;

    frag_cd acc[4];
    #pragma unroll
    for (int tl=0; tl<4; ++tl)
        #pragma unroll
        for (int j=0;j<4;++j) acc[tl][j] = 0.f;

    const float* aprow = A + (size_t)(m0+r)*K + kq;
    const ush*   abrow = (const ush*)A + (size_t)(m0+r)*K + kq;
    const bool wok = (n0 + r) < N;
    const ush* wprow = WT + (size_t)(n0 + (wok ? r : 0))*K + kq;

    float4 a0, a1; uint4 av; uint4 wv;
    auto loadT = [&](int kk){
        if (abf) av = *(const uint4*)(abrow + kk);
        else { a0 = *(const float4*)(aprow + kk); a1 = *(const float4*)(aprow + kk + 4); }
        wv = wok ? *(const uint4*)(wprow + kk) : make_uint4(0u,0u,0u,0u);
    };
    loadT(0);

    for (int kk = 0; kk < K; kk += 32) {
        if (abf) {
            *(uint4*)&As[r*40 + kq] = av;
        } else {
            ushort4 p0 = make_ushort4(f2b(a0.x), f2b(a0.y), f2b(a0.z), f2b(a0.w));
            ushort4 p1 = make_ushort4(f2b(a1.x), f2b(a1.y), f2b(a1.z), f2b(a1.w));
            *(ushort4*)&As[r*40 + kq]     = p0;
            *(ushort4*)&As[r*40 + kq + 4] = p1;
        }
        *(uint4*)&Ws[r*40 + kq] = wv;
        __syncthreads();
        if (kk + 32 < K) loadT(kk + 32);
        frag_ab af = *(const frag_ab*)&As[(wave*16 + l15)*40 + quad*8];
        #pragma unroll
        for (int tl = 0; tl < 4; ++tl) {
            frag_ab bf = *(const frag_ab*)&Ws[(tl*16 + l15)*40 + quad*8];
            acc[tl] = __builtin_amdgcn_mfma_f32_16x16x32_bf16(af, bf, acc[tl], 0, 0, 0);
        }
        __syncthreads();
    }
    const bool do_relu = flags & 2;
    const bool has_b   = flags & 4;
    const bool obf     = flags & 8;
    #pragma unroll
    for (int tl = 0; tl < 4; ++tl) {
        int col = n0 + tl*16 + l15;
        if (col < N) {
            float bv = 0.f;
            if (has_b) bv = (flags & 16) ? ((const float*)bias)[boff + col]
                                         : ldf(bias, boff + col, isbf);
            #pragma unroll
            for (int rg = 0; rg < 4; ++rg) {
                int row = m0 + wave*16 + quad*4 + rg;
                float v = acc[tl][rg] + bv;
                if (do_relu) v = fmaxf(v, 0.f);
                if (obf) ((ush*)C)[(size_t)row*N + col] = f2b(v);
                else     C[(size_t)row*N + col] = v;
            }
        }
    }
}

// ---------------- LayerNorm (node rows, D=256): out = LN(a + b), dual f32+bf16 ----------------
__global__ __launch_bounds__(64) void ln_k(
    const float* __restrict__ a, const float* __restrict__ b,
    const void* __restrict__ g, const void* __restrict__ be, size_t goff,
    float* __restrict__ out, ush* __restrict__ outb,
    const int* __restrict__ flag, int D)
{
    const int isbf = *flag;
    const int row = blockIdx.x;
    const int t = threadIdx.x;
    float v[4];
    int cnt = 0;
    float s = 0.f;
    for (int i = t; i < D; i += 64) {
        float x = a[(size_t)row*D + i];
        if (b) x += b[(size_t)row*D + i];
        v[cnt++] = x; s += x;
    }
    #pragma unroll
    for (int off = 32; off > 0; off >>= 1) s += __shfl_down(s, off);
    s = __shfl(s, 0);
    const float mean = s / D;
    float qq = 0.f;
    for (int c2 = 0; c2 < cnt; ++c2) { float d = v[c2]-mean; qq += d*d; }
    #pragma unroll
    for (int off = 32; off > 0; off >>= 1) qq += __shfl_down(qq, off);
    qq = __shfl(qq, 0);
    const float inv = rsqrtf(fmaxf(qq, 0.f) / D + 1e-5f);
    cnt = 0;
    for (int i = t; i < D; i += 64) {
        float r = (v[cnt++] - mean)*inv*ldf(g, goff + i, isbf) + ldf(be, goff + i, isbf);
        out[(size_t)row*D + i] = r;
        outb[(size_t)row*D + i] = f2b(r);
    }
}

// ---------------- MFMA eq/ek/ev (+gathered mixed), 128 rows/block, bf16 in/out ----------------
__global__ __launch_bounds__(256) void eqkv_mfma_k(
    const ush* __restrict__ lg, const float* __restrict__ xsd,
    const int* __restrict__ gsrc, const int* __restrict__ gdst,
    const ush* __restrict__ WQKV, size_t woff,
    const void* __restrict__ bq, size_t boff,
    ush* __restrict__ eq, ush* __restrict__ ek, ush* __restrict__ ev,
    const int* __restrict__ flag)
{
    __shared__ __align__(16) ush mixs[128*40];
    __shared__ __align__(16) ush wts[3][32*40];
    __shared__ float bqs[32];
    const int isbf = *flag;
    const int t = threadIdx.x;
    const int e0 = blockIdx.x * 128;
    #pragma unroll
    for (int i = t; i < 768; i += 256) {
        int m = i >> 8, r2 = i & 255;
        int n = r2 >> 3, k4 = (r2 & 7) * 4;
        *(ushort4*)&wts[m][n*40 + k4] =
            *(const ushort4*)&WQKV[(size_t)m*2048 + woff + (size_t)n*32 + k4];
    }
    if (t < 32) bqs[t] = ldf(bq, boff + t, isbf);
    {
        int r = t >> 1, c0 = (t & 1) * 16;
        int e = e0 + r;
        int s = gsrc[e], d2 = gdst[e];
        const ush* lp = lg + (size_t)e*32 + c0;
        const float* sp = xsd + (size_t)s*kQW + c0;
        const float* dp = xsd + (size_t)d2*kQW + 32 + c0;
        #pragma unroll
        for (int j = 0; j < 16; ++j)
            mixs[r*40 + c0 + j] = f2b(b2f(lp[j]) + sp[j] + dp[j]);
    }
    __syncthreads();
    const int wave = t >> 6, l15 = t & 15, quad = (t >> 4) & 3;
    #pragma unroll
    for (int mi = 0; mi < 2; ++mi) {
        const int mt = wave*2 + mi;
        frag_ab af = *(const frag_ab*)&mixs[(mt*16 + l15)*40 + quad*8];
        #pragma unroll
        for (int w = 0; w < 3; ++w) {
            ush* outp = (w==0) ? eq : ((w==1) ? ek : ev);
            #pragma unroll
            for (int nt = 0; nt < 2; ++nt) {
                frag_ab bf = *(const frag_ab*)&wts[w][(nt*16 + l15)*40 + quad*8];
                frag_cd acc = {0.f, 0.f, 0.f, 0.f};
                acc = __builtin_amdgcn_mfma_f32_16x16x32_bf16(af, bf, acc, 0, 0, 0);
                const float bv = (w==0) ? bqs[nt*16 + l15] : 0.f;
                #pragma unroll
                for (int rg = 0; rg < 4; ++rg) {
                    int row = e0 + mt*16 + quad*4 + rg;
                    outp[(size_t)row*32 + nt*16 + l15] = f2b(acc[rg] + bv);
                }
            }
        }
    }
}

// ---------------- MFMA edge FFN: LN(A + relu(A@W1+b1)@W2 + b2); bf16 A / bf16 out ----------------
__global__ __launch_bounds__(256) void effn_mfma_k(
    const ush* __restrict__ A,
    const ush* __restrict__ W1T, size_t w1off, const void* __restrict__ b1, size_t b1off,
    const ush* __restrict__ W2T, size_t w2off, const void* __restrict__ b2, size_t b2off,
    const void* __restrict__ g, const void* __restrict__ be, size_t goff,
    ush* __restrict__ out, const int* __restrict__ flag)
{
    __shared__ __align__(16) ush w1t[128*40];
    __shared__ __align__(16) ush w2t[32*136];
    __shared__ __align__(16) ush hid[64*136];
    __shared__ float b1s[128], b2s[32];
    const int isbf = *flag;
    const int t = threadIdx.x;
    const int wave = t >> 6, l15 = t & 15, quad = (t >> 4) & 3;

    #pragma unroll
    for (int i = t; i < 1024; i += 256) {
        int n1 = i >> 3, k4 = (i & 7) * 4;
        *(ushort4*)&w1t[n1*40 + k4] = *(const ushort4*)&W1T[w1off + (size_t)n1*32 + k4];
        int n2 = i >> 5, kq2 = (i & 31) * 4;
        *(ushort4*)&w2t[n2*136 + kq2] = *(const ushort4*)&W2T[w2off + (size_t)n2*128 + kq2];
    }
    if (t < 128) b1s[t] = ldf(b1, b1off + t, isbf);
    if (t < 32)  b2s[t] = ldf(b2, b2off + t, isbf);
    __syncthreads();

    const float g0  = ldf(g,  goff + l15, isbf),      g1v = ldf(g,  goff + 16 + l15, isbf);
    const float be0 = ldf(be, goff + l15, isbf),      be1 = ldf(be, goff + 16 + l15, isbf);
    const float bb0 = b2s[l15], bb1 = b2s[16 + l15];

    for (int tt = 0; tt < 2; ++tt) {
        const int e0 = (blockIdx.x*2 + tt) * 64;
        {
            const int m = wave*16 + l15;
            frag_ab af = *(const frag_ab*)&A[(size_t)(e0+m)*32 + quad*8];
            #pragma unroll
            for (int nt = 0; nt < 8; ++nt) {
                frag_ab bf = *(const frag_ab*)&w1t[(nt*16 + l15)*40 + quad*8];
                frag_cd acc = {0.f, 0.f, 0.f, 0.f};
                acc = __builtin_amdgcn_mfma_f32_16x16x32_bf16(af, bf, acc, 0, 0, 0);
                float bv = b1s[nt*16 + l15];
                #pragma unroll
                for (int rg = 0; rg < 4; ++rg) {
                    int row = wave*16 + quad*4 + rg;
                    hid[row*136 + nt*16 + l15] = f2b(fmaxf(acc[rg] + bv, 0.f));
                }
            }
        }
        // hid rows are wave-private -> no barrier needed
        frag_cd acc2[2] = {{0.f,0.f,0.f,0.f},{0.f,0.f,0.f,0.f}};
        #pragma unroll
        for (int ks = 0; ks < 4; ++ks) {
            frag_ab af2 = *(const frag_ab*)&hid[(wave*16 + l15)*136 + ks*32 + quad*8];
            #pragma unroll
            for (int tl = 0; tl < 2; ++tl) {
                frag_ab bf2 = *(const frag_ab*)&w2t[(tl*16 + l15)*136 + ks*32 + quad*8];
                acc2[tl] = __builtin_amdgcn_mfma_f32_16x16x32_bf16(af2, bf2, acc2[tl], 0, 0, 0);
            }
        }
        #pragma unroll
        for (int rg = 0; rg < 4; ++rg) {
            const int row = e0 + wave*16 + quad*4 + rg;
            float v0 = acc2[0][rg] + bb0 + b2f(A[(size_t)row*32 + l15]);
            float v1 = acc2[1][rg] + bb1 + b2f(A[(size_t)row*32 + 16 + l15]);
            float s = v0 + v1;
            s += __shfl_xor(s,1); s += __shfl_xor(s,2); s += __shfl_xor(s,4); s += __shfl_xor(s,8);
            const float mean = s * (1.f/32.f);
            float q = (v0-mean)*(v0-mean) + (v1-mean)*(v1-mean);
            q += __shfl_xor(q,1); q += __shfl_xor(q,2); q += __shfl_xor(q,4); q += __shfl_xor(q,8);
            const float inv = rsqrtf(q * (1.f/32.f) + 1e-5f);
            out[(size_t)row*32 + l15]      = f2b((v0-mean)*inv*g0  + be0);
            out[(size_t)row*32 + 16 + l15] = f2b((v1-mean)*inv*g1v + be1);
        }
    }
}

// ---------------- full-graph attention v5: (b,h,quarter) blocks, 512 grid, bf16 out ----------------
__global__ __launch_bounds__(512) void full_attn_k(
    const float* __restrict__ q, const float* __restrict__ k, const float* __restrict__ v,
    const void* __restrict__ rel, const int* __restrict__ feat, ush* __restrict__ o,
    const int* __restrict__ flag, int ldq)
{
    __shared__ __align__(8) ush ks[128][36];
    __shared__ __align__(8) ush vs[128][36];
    __shared__ __align__(8) ush rs[128][36];
    __shared__ float pb[8][32][34];            // per-wave partials: m, l, acc[32]
    const int isbf = *flag;
    const int bid = blockIdx.x;
    const int b = bid >> 4, h = (bid >> 2) & 3, qtr = bid & 3;
    const int t = threadIdx.x;
    for (int i = t; i < 4096; i += 512) {
        int r = i >> 5, d = i & 31;
        rs[r][d] = ldb(rel, i, isbf);
        size_t base = ((size_t)(b*128 + r))*ldq + h*32 + d;
        ks[r][d] = f2b(k[base]);
        vs[r][d] = f2b(v[base]);
    }
    __syncthreads();
    const int wave = t >> 6, lane = t & 63;
    const int dstL = lane >> 1, part = lane & 1;   // 2 lanes per dst
    const int dst = qtr*32 + dstL;
    const int dbase = part*16;                     // this lane's 16 dims
    float qr[16];
    { size_t base = ((size_t)(b*128 + dst))*ldq + h*32 + dbase;
      #pragma unroll
      for (int d=0; d<16; ++d) qr[d] = q[base + d]; }
    const int* fp = feat + (size_t)b*16384 + dst;
    const int s0 = wave*16;
    float m = -1e30f, l = 0.f;
    float acc[16];
    #pragma unroll
    for (int d=0; d<16; ++d) acc[d] = 0.f;
    int f = fp[s0*128];
    for (int sI = 0; sI < 16; ++sI) {
        const int s = s0 + sI;
        int fn = (sI+1 < 16) ? fp[(s+1)*128] : 0;
        float er[16];
        float scp = 0.f;
        #pragma unroll
        for (int j2 = 0; j2 < 4; ++j2) {
            ushort4 eu = *(const ushort4*)&rs[f][dbase + j2*4];
            ushort4 ku = *(const ushort4*)&ks[s][dbase + j2*4];
            float e0 = b2f(eu.x), e1 = b2f(eu.y), e2 = b2f(eu.z), e3 = b2f(eu.w);
            er[j2*4+0]=e0; er[j2*4+1]=e1; er[j2*4+2]=e2; er[j2*4+3]=e3;
            scp += (b2f(ku.x)+e0)*qr[j2*4+0] + (b2f(ku.y)+e1)*qr[j2*4+1]
                 + (b2f(ku.z)+e2)*qr[j2*4+2] + (b2f(ku.w)+e3)*qr[j2*4+3];
        }
        const float sc = (scp + __shfl_xor(scp, 1)) * kScaleN;
        float mn = fmaxf(m, sc);
        float c0 = __expf(m - mn);
        float pp = __expf(sc - mn);
        l = l*c0 + pp;
        #pragma unroll
        for (int j2 = 0; j2 < 4; ++j2) {
            ushort4 vu = *(const ushort4*)&vs[s][dbase + j2*4];
            acc[j2*4+0] = acc[j2*4+0]*c0 + pp*(b2f(vu.x)+er[j2*4+0]);
            acc[j2*4+1] = acc[j2*4+1]*c0 + pp*(b2f(vu.y)+er[j2*4+1]);
            acc[j2*4+2] = acc[j2*4+2]*c0 + pp*(b2f(vu.z)+er[j2*4+2]);
            acc[j2*4+3] = acc[j2*4+3]*c0 + pp*(b2f(vu.w)+er[j2*4+3]);
        }
        m = mn; f = fn;
    }
    if (part == 0) { pb[wave][dstL][0] = m; pb[wave][dstL][1] = l; }
    #pragma unroll
    for (int d=0; d<16; ++d) pb[wave][dstL][2 + dbase + d] = acc[d];
    __syncthreads();
    // merge: thread (dstL2, grp) handles dims [grp*2, grp*2+2) of dst=qtr*32+dstL2
    {
        const int dstL2 = t & 31, grp = t >> 5;   // grp in [0,16)
        float mw[8], lw[8];
        #pragma unroll
        for (int w=0; w<8; ++w){ mw[w]=pb[w][dstL2][0]; lw[w]=pb[w][dstL2][1]; }
        float M = mw[0];
        #pragma unroll
        for (int w=1; w<8; ++w) M = fmaxf(M, mw[w]);
        float sw[8];
        float L = 0.f;
        #pragma unroll
        for (int w=0; w<8; ++w){ sw[w] = __expf(mw[w]-M); L += lw[w]*sw[w]; }
        const float inv = 1.f / fmaxf(L, 1e-30f);
        size_t base = ((size_t)(b*128 + qtr*32 + dstL2))*kND + h*32 + grp*2;
        #pragma unroll
        for (int d=0; d<2; ++d) {
            float a = 0.f;
            #pragma unroll
            for (int w=0; w<8; ++w) a += pb[w][dstL2][2+grp*2+d]*sw[w];
            o[base + d] = f2b(a*inv);
        }
    }
}

// ---------------- local-graph GATHER attention (heads 4..7), bf16 lg/out ----------------
__global__ __launch_bounds__(256) void loc_gather_k(
    const float* __restrict__ q, const float* __restrict__ k, const float* __restrict__ v,
    const ush* __restrict__ lg, const int* __restrict__ gsrc,
    const int* __restrict__ rowp, const int* __restrict__ eidl,
    ush* __restrict__ o, int ldq)
{
    const int n = blockIdx.x;
    const int h = threadIdx.x >> 6;
    const int lane = threadIdx.x & 63;
    const int g = lane >> 4;
    const int d0 = (lane & 15) * 2;
    const size_t hoff = (size_t)(4 + h) * 32 + d0;
    const float2 q2 = *(const float2*)&q[(size_t)n*ldq + hoff];
    const int beg = rowp[n], end = rowp[n+1];
    const int deg = end - beg;
    float m = -1e30f, l = 0.f, ax = 0.f, ay = 0.f;
    if (deg > 0) {
        const int nIter = (deg + 3) >> 2;
        int idx = beg + g;
        int ce = eidl[min(idx, end-1)];
        int cs = gsrc[ce];
        for (int it = 0; it < nIter; ++it) {
            const bool valid = idx < end;
            const int e = ce, s = cs;
            idx += 4;
            if (it + 1 < nIter) { ce = eidl[min(idx, end-1)]; cs = gsrc[ce]; }
            const float2 kv = *(const float2*)&k[(size_t)s*ldq + hoff];
            const ushort2 lvu = *(const ushort2*)&lg[(size_t)e*32 + d0];
            const float2 vv = *(const float2*)&v[(size_t)s*ldq + hoff];
            const float lvx = b2f(lvu.x), lvy = b2f(lvu.y);
            float part = (kv.x+lvx)*q2.x + (kv.y+lvy)*q2.y;
            part += __shfl_xor(part, 1);
            part += __shfl_xor(part, 2);
            part += __shfl_xor(part, 4);
            part += __shfl_xor(part, 8);
            const float sc = part * kScaleN;
            const float mn = valid ? fmaxf(m, sc) : m;
            const float c  = __expf(m - mn);
            const float pp = valid ? __expf(sc - mn) : 0.f;
            l  = l*c  + pp;
            ax = ax*c + pp*(vv.x+lvx);
            ay = ay*c + pp*(vv.y+lvy);
            m  = mn;
        }
        #pragma unroll
        for (int off = 16; off <= 32; off <<= 1) {
            const float mo = __shfl_xor(m, off);
            const float lo = __shfl_xor(l, off);
            const float xo = __shfl_xor(ax, off);
            const float yo = __shfl_xor(ay, off);
            const float M  = fmaxf(m, mo);
            const float c1 = __expf(m - M);
            const float c2 = __expf(mo - M);
            l  = l*c1  + lo*c2;
            ax = ax*c1 + xo*c2;
            ay = ay*c1 + yo*c2;
            m  = M;
        }
    }
    if (g == 0) {
        const float inv = 1.f / fmaxf(l, 1e-30f);
        *(ushort2*)&o[(size_t)n*kND + hoff] = make_ushort2(f2b(ax*inv), f2b(ay*inv));
    }
}

// ---------------- fused line-graph attention + Wo GEMM + LN (bf16 in/out) ----------------
__global__ __launch_bounds__(256) void lgs_ewo_k(
    const ush* __restrict__ eq, const ush* __restrict__ ek, const ush* __restrict__ ev,
    const int* __restrict__ lsrc, const int* __restrict__ rowp, const int* __restrict__ eidl,
    const ush* __restrict__ res,
    const ush* __restrict__ WO, size_t wooff, const void* __restrict__ bo, size_t booff,
    const void* __restrict__ g1, const void* __restrict__ be1, size_t g1off,
    ush* __restrict__ out, const int* __restrict__ flag)
{
    __shared__ __align__(16) ush ows[32*40];
    __shared__ __align__(16) ush wos[32*40];
    __shared__ float cs[32][36];
    __shared__ float bos[32], gs[32], bs[32];
    const int isbf = *flag;
    const int t = threadIdx.x;
    const int base = blockIdx.x * 32;
    {
        int n = t >> 3, k4 = (t & 7) * 4;
        *(ushort4*)&wos[n*40 + k4] = *(const ushort4*)&WO[wooff + (size_t)n*32 + k4];
    }
    if (t < 32) {
        bos[t] = ldf(bo, booff + t, isbf);
        gs[t]  = ldf(g1, g1off + t, isbf);
        bs[t]  = ldf(be1, g1off + t, isbf);
    }
    // ---- phase 1: gather attention, thread = (dst-edge, head) ----
    {
        const int d2 = base + (t >> 3), h = t & 7;
        const ushort4 qu = *(const ushort4*)&eq[(size_t)d2*32 + h*4];
        const float q0 = b2f(qu.x), q1 = b2f(qu.y), q2 = b2f(qu.z), q3 = b2f(qu.w);
        const int beg = rowp[d2], end = rowp[d2+1];
        float m = -1e30f, l = 0.f;
        float4 acc = make_float4(0.f,0.f,0.f,0.f);
        int i = beg;
        int s = 0;
        if (i < end) { s = lsrc[eidl[i]]; }
        while (i < end) {
            const int sc_s = s;
            ++i;
            if (i < end) { s = lsrc[eidl[i]]; }      // prefetch next src
            const ushort4 ku = *(const ushort4*)&ek[(size_t)sc_s*32 + h*4];
            const ushort4 vu = *(const ushort4*)&ev[(size_t)sc_s*32 + h*4];
            float sc = (b2f(ku.x)*q0 + b2f(ku.y)*q1 + b2f(ku.z)*q2 + b2f(ku.w)*q3) * 0.5f;
            float mn = fmaxf(m, sc);
            float c = __expf(m - mn);
            float pp = __expf(sc - mn);
            l = l*c + pp;
            acc.x = acc.x*c + pp*b2f(vu.x);
            acc.y = acc.y*c + pp*b2f(vu.y);
            acc.z = acc.z*c + pp*b2f(vu.z);
            acc.w = acc.w*c + pp*b2f(vu.w);
            m = mn;
        }
        const float inv = 1.f / fmaxf(l, 1e-30f);
        const int r = t >> 3, c0 = h*4;
        ows[r*40 + c0 + 0] = f2b(acc.x*inv);
        ows[r*40 + c0 + 1] = f2b(acc.y*inv);
        ows[r*40 + c0 + 2] = f2b(acc.z*inv);
        ows[r*40 + c0 + 3] = f2b(acc.w*inv);
    }
    __syncthreads();
    // ---- phase 2: 32x32 GEMM ----
    {
        const int wave = t >> 6, l15 = t & 15, quad = (t >> 4) & 3;
        const int mt = wave & 1, nt = wave >> 1;
        frag_ab af = *(const frag_ab*)&ows[(mt*16 + l15)*40 + quad*8];
        frag_ab bf = *(const frag_ab*)&wos[(nt*16 + l15)*40 + quad*8];
        frag_cd acc = {0.f, 0.f, 0.f, 0.f};
        acc = __builtin_amdgcn_mfma_f32_16x16x32_bf16(af, bf, acc, 0, 0, 0);
        #pragma unroll
        for (int rg = 0; rg < 4; ++rg) {
            const int row = mt*16 + quad*4 + rg;
            const int col = nt*16 + l15;
            cs[row][col] = acc[rg] + bos[col] + b2f(res[(size_t)(base+row)*32 + col]);
        }
    }
    __syncthreads();
    // ---- phase 3: LN per row ----
    {
        const int row = t >> 3, c0 = (t & 7) * 4;
        const float v0 = cs[row][c0], v1 = cs[row][c0+1];
        const float v2 = cs[row][c0+2], v3 = cs[row][c0+3];
        float s = v0+v1+v2+v3;
        s += __shfl_xor(s,1); s += __shfl_xor(s,2); s += __shfl_xor(s,4);
        const float mean = s * (1.f/32.f);
        float qq = (v0-mean)*(v0-mean)+(v1-mean)*(v1-mean)
                 + (v2-mean)*(v2-mean)+(v3-mean)*(v3-mean);
        qq += __shfl_xor(qq,1); qq += __shfl_xor(qq,2); qq += __shfl_xor(qq,4);
        const float inv = rsqrtf(qq * (1.f/32.f) + 1e-5f);
        out[(size_t)(base+row)*32 + c0 + 0] = f2b((v0-mean)*inv*gs[c0+0] + bs[c0+0]);
        out[(size_t)(base+row)*32 + c0 + 1] = f2b((v1-mean)*inv*gs[c0+1] + bs[c0+1]);
        out[(size_t)(base+row)*32 + c0 + 2] = f2b((v2-mean)*inv*gs[c0+2] + bs[c0+2]);
        out[(size_t)(base+row)*32 + c0 + 3] = f2b((v3-mean)*inv*gs[c0+3] + bs[c0+3]);
    }
}

// ---------------- output ----------------
__global__ void out_k(const float* __restrict__ xf, const ush* __restrict__ lgf,
                      void* __restrict__ out, const int* __restrict__ flag){
    const int isbf = *flag;
    int g = blockIdx.x*256 + threadIdx.x;
    if (g < kN*kND) {
        float v = xf[g];
        if (isbf) ((ush*)out)[g] = f2b(v);
        else      ((float*)out)[g] = v;
    } else {
        ush u = lgf[g - kN*kND];
        if (isbf) ((ush*)out)[g] = u;
        else      ((float*)out)[g] = b2f(u);
    }
}

// ---------------- host helper ----------------
static inline void mgemm(const float* A, const ush* WT, const void* bias, size_t boff,
                         float* C, const int* flag, int M, int N, int K, int flags,
                         hipStream_t s){
    dim3 grid((N+63)/64, M/64);
    mgemm_k<<<grid, 256, 0, s>>>(A, WT, bias, boff, C, flag, M, N, K, flags);
}

extern "C" void kernel_launch(void* const* d_in, const int* in_sizes, int n_in,
                              void* d_out, int out_size, void* d_ws, size_t ws_size,
                              hipStream_t stream) {
    const void* x_in      = d_in[0];
    const void* rel       = d_in[1];
    const int* g_src      = (const int*)d_in[4];
    const int* g_dst      = (const int*)d_in[5];
    const int* lg_src     = (const int*)d_in[6];
    const int* lg_dst     = (const int*)d_in[7];
    const int* edge_feat  = (const int*)d_in[8];
    const int* full_feat  = (const int*)d_in[9];
    const void* n_Wq   = d_in[10];
    const void* n_bq   = d_in[11];
    const void* n_Wk   = d_in[12];
    const void* n_bk   = d_in[13];
    const void* n_Wv   = d_in[14];
    const void* n_bv   = d_in[15];
    const void* n_Wo   = d_in[16];
    const void* n_bo   = d_in[17];
    const void* n_lng  = d_in[18];
    const void* n_lnb  = d_in[19];
    const void* n_fW1  = d_in[20];
    const void* n_fb1  = d_in[21];
    const void* n_fW2  = d_in[22];
    const void* n_fb2  = d_in[23];
    const void* n_flng = d_in[24];
    const void* n_flnb = d_in[25];
    const void* e_Wsrc = d_in[26];
    const void* e_Wdst = d_in[27];
    const void* e_Wq   = d_in[28];
    const void* e_bq   = d_in[29];
    const void* e_Wk   = d_in[30];
    const void* e_Wv   = d_in[31];
    const void* e_Wo   = d_in[32];
    const void* e_bo   = d_in[33];
    const void* e_lng  = d_in[34];
    const void* e_lnb  = d_in[35];
    const void* e_fW1  = d_in[36];
    const void* e_fb1  = d_in[37];
    const void* e_fW2  = d_in[38];
    const void* e_fb2  = d_in[39];
    const void* e_flng = d_in[40];
    const void* e_flnb = d_in[41];

    // ---- workspace carve-up (units: floats) ----
    float* p = (float*)d_ws;
    size_t off = 0;
    auto AL = [&](size_t n){ float* r = p + off; off += n; return r; };
    int* flagp = (int*)AL(64);
    float* xA   = AL((size_t)kN*kND);
    float* xB   = AL((size_t)kN*kND);
    float* xM   = AL((size_t)kN*kND);
    ush*   xAb  = (ush*)AL((size_t)kN*kND/2);
    ush*   xBb  = (ush*)AL((size_t)kN*kND/2);
    ush*   xMb  = (ush*)AL((size_t)kN*kND/2);
    float* qkvb = AL((size_t)kN*kQW);
    ush*   ob   = (ush*)AL((size_t)kN*kND/2);
    float* tN   = AL((size_t)kN*kND);
    ush*   nh   = (ush*)AL((size_t)kN*512);      // kN*1024 bf16
    ush*   lgA  = (ush*)AL((size_t)kEL*kED/2);   // bf16 edge residual chain
    ush*   lgB  = (ush*)AL((size_t)kEL*kED/2);
    ush*   lgM  = (ush*)AL((size_t)kEL*kED/2);
    ush*   eqb  = (ush*)AL((size_t)kEL*16);      // kEL*32 bf16
    ush*   ekb  = (ush*)AL((size_t)kEL*16);
    ush*   evb  = (ush*)AL((size_t)kEL*16);
    // CSR structures
    int* cntL  = (int*)AL(kN);
    int* rowL  = (int*)AL(kN + 64);
    int* curL  = (int*)AL(kN);
    int* eidL  = (int*)AL(kEL);
    int* cntG  = (int*)AL(kEL);
    int* rowG  = (int*)AL(kEL + 64);
    int* curG  = (int*)AL(kEL);
    int* eidG  = (int*)AL(kELG);
    int* bsum  = (int*)AL(256);
    // pre-transposed bf16 weights
    ush* wtQKVSD = (ush*)AL(212992);   // [L][832][256] bf16 (425984 ush)
    float* bQKV  = AL(2*kQW);
    ush* wtO  = (ush*)AL(65536);
    ush* wtF1 = (ush*)AL(262144);
    ush* wtF2 = (ush*)AL(262144);
    ush* wtEQKV = (ush*)AL(3072);
    ush* wtEO   = (ush*)AL(1024);
    ush* wtEF1  = (ush*)AL(4096);
    ush* wtEF2  = (ush*)AL(4096);
    if (ws_size < off * sizeof(float)) return;

    detect_k<<<1, 64, 0, stream>>>((const ush*)x_in, flagp);
    {
        long total = (long)kN*kND + (long)kEL*kED + 2*kQW + kN + kEL;
        int blocks = (int)((total + 255) / 256);
        setup_misc_k<<<blocks, 256, 0, stream>>>(x_in, rel, edge_feat, n_bq, n_bk, n_bv,
                                                 xA, xAb, lgA, bQKV, cntL, cntG, flagp);
    }
    trans_all_k<<<6368, 256, 0, stream>>>(n_Wq, n_Wk, n_Wv, n_Wo, n_fW1, n_fW2,
                                          e_Wsrc, e_Wdst, e_Wq, e_Wk, e_Wv, e_Wo,
                                          e_fW1, e_fW2, flagp,
                                          wtQKVSD, wtO, wtF1, wtF2,
                                          wtEQKV, wtEO, wtEF1, wtEF2);

    count2_k<<<(kEL+kELG)/256, 256, 0, stream>>>(g_dst, lg_dst, cntL, cntG);
    scan_blk2_k<<<132, 256, 0, stream>>>(cntL, cntG, rowL, rowG, bsum);
    scan_top2_k<<<1, 256, 0, stream>>>(bsum);
    scan_add2_k<<<(kN+kEL)/256, 256, 0, stream>>>(rowL, rowG, bsum, curL, curG);
    fill2_k<<<(kEL+kELG)/256, 256, 0, stream>>>(g_dst, lg_dst, curL, curG, eidL, eidG);

    float* xc = xA;  float* xn = xB;
    ush* xcb = xAb;  ush* xnb = xBb;
    ush* lgc = lgA;  ush* lgn = lgB;

    for (int i = 0; i < kL; ++i) {
        const size_t o256 = (size_t)i*kND;
        const size_t o1024= (size_t)i*1024;
        const size_t o32  = (size_t)i*kED;
        const size_t o128 = (size_t)i*128;

        // ===== node update (+ packed xs/xd in cols 768-831) =====
        mgemm((const float*)xcb, wtQKVSD + (size_t)i*212992, bQKV, (size_t)i*kQW, qkvb,
              flagp, kN, kQW, kND, 4|16|32, stream);
        full_attn_k<<<512, 512, 0, stream>>>(qkvb, qkvb+256, qkvb+512, rel, full_feat,
                                             ob, flagp, kQW);
        loc_gather_k<<<kN, 256, 0, stream>>>(qkvb, qkvb+256, qkvb+512, lgc, g_src,
                                             rowL, eidL, ob, kQW);
        mgemm((const float*)ob, wtO + (size_t)i*65536, n_bo, o256, tN, flagp,
              kN, kND, kND, 4|32, stream);
        ln_k<<<kN, 64, 0, stream>>>(xc, tN, n_lng, n_lnb, o256, xM, xMb, flagp, kND);
        mgemm((const float*)xMb, wtF1 + (size_t)i*262144, n_fb1, o1024, (float*)nh, flagp,
              kN, 1024, kND, 4|2|8|32, stream);
        mgemm((const float*)nh, wtF2 + (size_t)i*262144, n_fb2, o256, tN, flagp,
              kN, kND, 1024, 4|32, stream);
        ln_k<<<kN, 64, 0, stream>>>(xM, tN, n_flng, n_flnb, o256, xn, xnb, flagp, kND);

        // ===== edge update (uses PRE-update xc, lgc) =====
        eqkv_mfma_k<<<kEL/128, 256, 0, stream>>>(lgc, qkvb + 768, g_src, g_dst,
                                                 wtEQKV, (size_t)i*1024, e_bq, o32,
                                                 eqb, ekb, evb, flagp);
        lgs_ewo_k<<<kEL/32, 256, 0, stream>>>(eqb, ekb, evb, lg_src, rowG, eidG,
                                              lgc, wtEO, (size_t)i*1024, e_bo, o32,
                                              e_lng, e_lnb, o32, lgM, flagp);
        effn_mfma_k<<<kEL/128, 256, 0, stream>>>(lgM, wtEF1, (size_t)i*4096, e_fb1, o128,
                                                 wtEF2, (size_t)i*4096, e_fb2, o32,
                                                 e_flng, e_flnb, o32, lgn, flagp);

        { float* t = xc; xc = xn; xn = t; }
        { ush* t = xcb; xcb = xnb; xnb = t; }
        { ush* t = lgc; lgc = lgn; lgn = t; }
    }

    out_k<<<(kN*kND + kEL*kED)/256, 256, 0, stream>>>(xc, lgc, d_out, flagp);
}

// Round 8
// 525.177 us; speedup vs baseline: 1.4697x; 1.0742x over previous
//
#include <hip/hip_runtime.h>
#include <hip/hip_bf16.h>

typedef __hip_bfloat16 bf16;
typedef unsigned short ush;

static constexpr int kN   = 4096;    // nodes
static constexpr int kND  = 256;     // hidden
static constexpr int kEL  = 131072;  // local edges
static constexpr int kED  = 32;      // edge dim
static constexpr int kELG = 262144;  // line-graph edges
static constexpr int kL   = 2;
static constexpr int kQW  = 832;     // packed qkv+sd width
static constexpr float kScaleN = 0.17677669529663687f; // 1/sqrt(32)

using frag_ab = __attribute__((ext_vector_type(8))) short;   // 8 bf16 (4 VGPRs)
using frag_cd = __attribute__((ext_vector_type(4))) float;   // 4 fp32

__device__ __forceinline__ float ldf(const void* p, size_t i, int isbf){
    return isbf ? __bfloat162float(((const bf16*)p)[i]) : ((const float*)p)[i];
}
__device__ __forceinline__ ush f2b(float f){ bf16 h = __float2bfloat16(f); return *(ush*)&h; }
__device__ __forceinline__ float b2f(ush u){ return __uint_as_float(((unsigned)u)<<16); }
__device__ __forceinline__ ush ldb(const void* p, size_t i, int isbf){
    return isbf ? ((const ush*)p)[i] : f2b(((const float*)p)[i]);
}

// ---------------- dtype detection ----------------
__global__ void detect_k(const ush* __restrict__ xin, int* __restrict__ flag){
    if (threadIdx.x == 0 && blockIdx.x == 0) {
        int plausible = 0;
        for (int i = 0; i < 128; ++i) {
            ush u = xin[i];
            int e = (u >> 7) & 0xFF;
            if (e == 0 || (e >= 110 && e <= 140)) ++plausible;
        }
        *flag = (plausible >= 102) ? 1 : 0;
    }
}

// ---------------- fused setup: cast x (f32+bf16), init lg (bf16), pack bias, zero counters ----------------
__global__ void setup_misc_k(const void* __restrict__ xin, const void* __restrict__ rel,
                             const int* __restrict__ feat,
                             const void* __restrict__ bq, const void* __restrict__ bk,
                             const void* __restrict__ bv,
                             float* __restrict__ xA, ush* __restrict__ xAb,
                             ush* __restrict__ lgA,
                             float* __restrict__ bQKV,
                             int* __restrict__ cntL, int* __restrict__ cntG,
                             const int* __restrict__ flag){
    const int isbf = *flag;
    long g = (long)blockIdx.x*256 + threadIdx.x;
    if (g < (long)kN*kND) {
        float v = ldf(xin, g, isbf);
        xA[g] = v; xAb[g] = f2b(v);
        return;
    }
    g -= (long)kN*kND;
    if (g < (long)kEL*kED) { int e = (int)(g >> 5), d = (int)(g & 31);
        lgA[g] = ldb(rel, (size_t)feat[e]*kED + d, isbf); return; }
    g -= (long)kEL*kED;
    if (g < 2*kQW) {
        int layer = (int)(g / kQW), j = (int)(g - (long)layer*kQW);
        float v = 0.f;
        if (j < 768) { int w = j >> 8, jj = j & 255;
            const void* B = (w==0)?bq:((w==1)?bk:bv);
            v = ldf(B, (size_t)layer*256 + jj, isbf); }
        bQKV[g] = v; return;
    }
    g -= 2*kQW;
    if (g < kN) { cntL[g] = 0; return; }
    g -= kN;
    if (g < kEL) { cntG[g] = 0; return; }
}

// ---------------- ALL weight pre-transposes in one kernel ----------------
__global__ void trans_all_k(
    const void* __restrict__ nWq, const void* __restrict__ nWk, const void* __restrict__ nWv,
    const void* __restrict__ nWo, const void* __restrict__ nF1, const void* __restrict__ nF2,
    const void* __restrict__ eWs, const void* __restrict__ eWd,
    const void* __restrict__ eWq, const void* __restrict__ eWk, const void* __restrict__ eWv,
    const void* __restrict__ eWo, const void* __restrict__ eF1, const void* __restrict__ eF2,
    const int* __restrict__ flag,
    ush* __restrict__ wtQKVSD, ush* __restrict__ wtO, ush* __restrict__ wtF1,
    ush* __restrict__ wtF2, ush* __restrict__ wtEQKV, ush* __restrict__ wtEO,
    ush* __restrict__ wtEF1, ush* __restrict__ wtEF2)
{
    const int isbf = *flag;
    int g = blockIdx.x*256 + threadIdx.x;
    if (g < 393216){                                   // QKV -> wtQKVSD rows 0-767
        int w = g >> 17, gg = g & 131071;
        int layer = gg >> 16, idx = gg & 65535;
        int n = idx >> 8, k = idx & 255;
        const void* W = (w==0)?nWq:((w==1)?nWk:nWv);
        wtQKVSD[(size_t)layer*212992 + (size_t)(w*256+n)*256 + k] =
            ldb(W, (size_t)layer*65536 + (size_t)k*256 + n, isbf);
        return;
    }
    g -= 393216;
    if (g < 32768){                                    // src/dst -> wtQKVSD rows 768-831
        int w = g >> 14, gg = g & 16383;
        int layer = gg >> 13, idx = gg & 8191;
        int n = idx >> 8, k = idx & 255;
        const void* W = w ? eWd : eWs;
        wtQKVSD[(size_t)layer*212992 + (size_t)(768 + w*32 + n)*256 + k] =
            ldb(W, (size_t)layer*8192 + (size_t)k*32 + n, isbf);
        return;
    }
    g -= 32768;
    if (g < 131072){                                   // Wo [L][256][256]
        int layer = g >> 16, rem = g & 65535;
        int n = rem >> 8, k = rem & 255;
        wtO[g] = ldb(nWo, (size_t)layer*65536 + (size_t)k*256 + n, isbf);
        return;
    }
    g -= 131072;
    if (g < 524288){                                   // F1 [L][1024][256]
        int layer = g >> 18, rem = g & 262143;
        int n = rem >> 8, k = rem & 255;
        wtF1[g] = ldb(nF1, (size_t)layer*262144 + (size_t)k*1024 + n, isbf);
        return;
    }
    g -= 524288;
    if (g < 524288){                                   // F2 [L][256][1024]
        int layer = g >> 18, rem = g & 262143;
        int n = rem >> 10, k = rem & 1023;
        wtF2[g] = ldb(nF2, (size_t)layer*262144 + (size_t)k*256 + n, isbf);
        return;
    }
    g -= 524288;
    if (g < 6144){                                     // eQKV [3][L][32][32]
        int w = g >> 11, gg = g & 2047;
        int layer = gg >> 10, rem = gg & 1023;
        int n = rem >> 5, k = rem & 31;
        const void* W = (w==0)?eWq:((w==1)?eWk:eWv);
        wtEQKV[g] = ldb(W, (size_t)layer*1024 + (size_t)k*32 + n, isbf);
        return;
    }
    g -= 6144;
    if (g < 2048){                                     // eWo [L][32][32]
        int layer = g >> 10, rem = g & 1023;
        int n = rem >> 5, k = rem & 31;
        wtEO[g] = ldb(eWo, (size_t)layer*1024 + (size_t)k*32 + n, isbf);
        return;
    }
    g -= 2048;
    if (g < 8192){                                     // eF1 [L][128][32]
        int layer = g >> 12, rem = g & 4095;
        int n = rem >> 5, k = rem & 31;
        wtEF1[g] = ldb(eF1, (size_t)layer*4096 + (size_t)k*128 + n, isbf);
        return;
    }
    g -= 8192;
    if (g < 8192){                                     // eF2 [L][32][128]
        int layer = g >> 12, rem = g & 4095;
        int n = rem >> 7, k = rem & 127;
        wtEF2[g] = ldb(eF2, (size_t)layer*4096 + (size_t)k*32 + n, isbf);
        return;
    }
}

// ---------------- CSR build (both graphs fused) ----------------
__global__ void count2_k(const int* __restrict__ gd, const int* __restrict__ lgd,
                         int* __restrict__ cntL, int* __restrict__ cntG){
    int g = blockIdx.x*256 + threadIdx.x;
    if (g < kEL) atomicAdd(&cntL[gd[g]], 1);
    else if (g < kEL + kELG) atomicAdd(&cntG[lgd[g - kEL]], 1);
}
__global__ __launch_bounds__(256) void scan_blk2_k(
    const int* __restrict__ cntL, const int* __restrict__ cntG,
    int* __restrict__ rowL, int* __restrict__ rowG, int* __restrict__ bsum)
{
    __shared__ int s[256];
    const int t = threadIdx.x;
    const bool isL = blockIdx.x < 4;
    const int* cnt = isL ? cntL : cntG;
    int* out = isL ? rowL : rowG;
    const int blk = isL ? blockIdx.x : blockIdx.x - 4;
    const int n = isL ? kN : kEL;
    const int b0 = blk*1024;
    int v[4], pre[4], tsum = 0;
    #pragma unroll
    for (int j=0;j<4;++j){
        int idx = b0 + t*4 + j;
        v[j] = (idx < n) ? cnt[idx] : 0;
        pre[j] = tsum; tsum += v[j];
    }
    s[t] = tsum; __syncthreads();
    for (int off=1; off<256; off<<=1){
        int x = (t>=off) ? s[t-off] : 0;
        __syncthreads();
        s[t] += x;
        __syncthreads();
    }
    int texc = s[t] - tsum;
    #pragma unroll
    for (int j=0;j<4;++j){
        int idx = b0 + t*4 + j;
        if (idx < n) out[idx] = texc + pre[j];
    }
    if (t == 255) bsum[(isL ? 0 : 8) + blk] = s[255];
}
__global__ __launch_bounds__(256) void scan_top2_k(int* __restrict__ bsum){
    __shared__ int sL[256], sG[256];
    const int t = threadIdx.x;
    int vL = (t < 4)   ? bsum[t]     : 0;
    int vG = (t < 128) ? bsum[8 + t] : 0;
    sL[t] = vL; sG[t] = vG; __syncthreads();
    for (int off=1; off<256; off<<=1){
        int xL = (t>=off) ? sL[t-off] : 0;
        int xG = (t>=off) ? sG[t-off] : 0;
        __syncthreads();
        sL[t] += xL; sG[t] += xG;
        __syncthreads();
    }
    if (t < 4)   bsum[t]     = sL[t] - vL;
    if (t < 128) bsum[8 + t] = sG[t] - vG;
}
__global__ void scan_add2_k(int* __restrict__ rowL, int* __restrict__ rowG,
                            const int* __restrict__ bsum,
                            int* __restrict__ curL, int* __restrict__ curG){
    int g = blockIdx.x*256 + threadIdx.x;
    if (g < kN){ int v = rowL[g] + bsum[g >> 10]; rowL[g] = v; curL[g] = v; }
    else if (g < kN + kEL){ int gg = g - kN;
        int v = rowG[gg] + bsum[8 + (gg >> 10)]; rowG[gg] = v; curG[gg] = v; }
    if (g == 0){ rowL[kN] = kEL; rowG[kEL] = kELG; }
}
__global__ void fill2_k(const int* __restrict__ gd, const int* __restrict__ lgd,
                        int* __restrict__ curL, int* __restrict__ curG,
                        int* __restrict__ eidL, int* __restrict__ eidG){
    int g = blockIdx.x*256 + threadIdx.x;
    if (g < kEL){ int pos = atomicAdd(&curL[gd[g]], 1); eidL[pos] = g; }
    else if (g < kEL + kELG){ int gg = g - kEL;
        int pos = atomicAdd(&curG[lgd[gg]], 1); eidG[pos] = gg; }
}

// ---------------- MFMA GEMM: C[M,N] = A@WT^T + bias (opt relu); BK=64 ----------------
// WT: bf16 [N][K]. 64x64 tile, 4 waves. Requires K%64==0, N%64==0.
// flags: 2=RELU, 4=has-bias, 8=bf16 out, 16=bias packed fp32, 32=A is bf16,
//        64=also emit bf16 kvloc (cols 384-511 -> aux[.. -384], 640-767 -> aux[.. -512])
__global__ __launch_bounds__(256) void mgemm_k(
    const float* __restrict__ A, const ush* __restrict__ WT,
    const void* __restrict__ bias, size_t boff,
    float* __restrict__ C, const int* __restrict__ flag,
    int M, int N, int K, int flags, ush* __restrict__ aux)
{
    __shared__ __align__(16) ush As[64*72];
    __shared__ __align__(16) ush Ws[64*72];
    const int isbf = *flag;
    const int t = threadIdx.x;
    const int m0 = blockIdx.y*64, n0 = blockIdx.x*64;
    const int wave = t>>6, lane = t&63;
    const int quad = lane>>4, l15 = lane&15;
    const int r = t>>3, kq = (t&7)*8;      // rows r and r+32, 8 K-elems at kq
    const bool abf = flags & 32;

    frag_cd acc[4];
    #pragma unroll
    for (int tl=0; tl<4; ++tl)
        #pragma unroll
        for (int j=0;j<4;++j) acc[tl][j] = 0.f;

    const float* ap0 = A + (size_t)(m0+r)*K + kq;
    const float* ap1 = A + (size_t)(m0+r+32)*K + kq;
    const ush*   ab0 = (const ush*)A + (size_t)(m0+r)*K + kq;
    const ush*   ab1 = (const ush*)A + (size_t)(m0+r+32)*K + kq;
    const ush*   wp0 = WT + (size_t)(n0+r)*K + kq;
    const ush*   wp1 = WT + (size_t)(n0+r+32)*K + kq;

    float4 a00,a01,a10,a11; uint4 av0,av1, wv0,wv1;
    auto loadT = [&](int kk){
        if (abf) { av0 = *(const uint4*)(ab0+kk); av1 = *(const uint4*)(ab1+kk); }
        else { a00 = *(const float4*)(ap0+kk); a01 = *(const float4*)(ap0+kk+4);
               a10 = *(const float4*)(ap1+kk); a11 = *(const float4*)(ap1+kk+4); }
        wv0 = *(const uint4*)(wp0+kk); wv1 = *(const uint4*)(wp1+kk);
    };
    loadT(0);

    for (int kk = 0; kk < K; kk += 64) {
        if (abf) {
            *(uint4*)&As[r*72 + kq]        = av0;
            *(uint4*)&As[(r+32)*72 + kq]   = av1;
        } else {
            *(ushort4*)&As[r*72 + kq]       = make_ushort4(f2b(a00.x),f2b(a00.y),f2b(a00.z),f2b(a00.w));
            *(ushort4*)&As[r*72 + kq + 4]   = make_ushort4(f2b(a01.x),f2b(a01.y),f2b(a01.z),f2b(a01.w));
            *(ushort4*)&As[(r+32)*72 + kq]     = make_ushort4(f2b(a10.x),f2b(a10.y),f2b(a10.z),f2b(a10.w));
            *(ushort4*)&As[(r+32)*72 + kq + 4] = make_ushort4(f2b(a11.x),f2b(a11.y),f2b(a11.z),f2b(a11.w));
        }
        *(uint4*)&Ws[r*72 + kq]      = wv0;
        *(uint4*)&Ws[(r+32)*72 + kq] = wv1;
        __syncthreads();
        if (kk + 64 < K) loadT(kk + 64);
        frag_ab af0 = *(const frag_ab*)&As[(wave*16 + l15)*72 + quad*8];
        frag_ab af1 = *(const frag_ab*)&As[(wave*16 + l15)*72 + 32 + quad*8];
        #pragma unroll
        for (int tl = 0; tl < 4; ++tl) {
            frag_ab bf0 = *(const frag_ab*)&Ws[(tl*16 + l15)*72 + quad*8];
            acc[tl] = __builtin_amdgcn_mfma_f32_16x16x32_bf16(af0, bf0, acc[tl], 0, 0, 0);
            frag_ab bf1 = *(const frag_ab*)&Ws[(tl*16 + l15)*72 + 32 + quad*8];
            acc[tl] = __builtin_amdgcn_mfma_f32_16x16x32_bf16(af1, bf1, acc[tl], 0, 0, 0);
        }
        __syncthreads();
    }
    const bool do_relu = flags & 2;
    const bool has_b   = flags & 4;
    const bool obf     = flags & 8;
    #pragma unroll
    for (int tl = 0; tl < 4; ++tl) {
        int col = n0 + tl*16 + l15;
        float bv = 0.f;
        if (has_b) bv = (flags & 16) ? ((const float*)bias)[boff + col]
                                     : ldf(bias, boff + col, isbf);
        int c2 = -1;
        if (flags & 64) {
            if (col >= 384 && col < 512) c2 = col - 384;        // K local heads
            else if (col >= 640 && col < 768) c2 = col - 512;   // V local heads
        }
        #pragma unroll
        for (int rg = 0; rg < 4; ++rg) {
            int row = m0 + wave*16 + quad*4 + rg;
            float v = acc[tl][rg] + bv;
            if (do_relu) v = fmaxf(v, 0.f);
            if (obf) ((ush*)C)[(size_t)row*N + col] = f2b(v);
            else     C[(size_t)row*N + col] = v;
            if (c2 >= 0) aux[(size_t)row*256 + c2] = f2b(v);
        }
    }
}

// ---------------- LayerNorm (node rows, D=256): out = LN(a + b), dual f32+bf16 ----------------
__global__ __launch_bounds__(64) void ln_k(
    const float* __restrict__ a, const float* __restrict__ b,
    const void* __restrict__ g, const void* __restrict__ be, size_t goff,
    float* __restrict__ out, ush* __restrict__ outb,
    const int* __restrict__ flag, int D)
{
    const int isbf = *flag;
    const int row = blockIdx.x;
    const int t = threadIdx.x;
    float v[4];
    int cnt = 0;
    float s = 0.f;
    for (int i = t; i < D; i += 64) {
        float x = a[(size_t)row*D + i];
        if (b) x += b[(size_t)row*D + i];
        v[cnt++] = x; s += x;
    }
    #pragma unroll
    for (int off = 32; off > 0; off >>= 1) s += __shfl_down(s, off);
    s = __shfl(s, 0);
    const float mean = s / D;
    float qq = 0.f;
    for (int c2 = 0; c2 < cnt; ++c2) { float d = v[c2]-mean; qq += d*d; }
    #pragma unroll
    for (int off = 32; off > 0; off >>= 1) qq += __shfl_down(qq, off);
    qq = __shfl(qq, 0);
    const float inv = rsqrtf(fmaxf(qq, 0.f) / D + 1e-5f);
    cnt = 0;
    for (int i = t; i < D; i += 64) {
        float r = (v[cnt++] - mean)*inv*ldf(g, goff + i, isbf) + ldf(be, goff + i, isbf);
        out[(size_t)row*D + i] = r;
        outb[(size_t)row*D + i] = f2b(r);
    }
}

// ---------------- MFMA eq/ek/ev (+gathered mixed), 128 rows/block, bf16 in/out ----------------
__global__ __launch_bounds__(256) void eqkv_mfma_k(
    const ush* __restrict__ lg, const float* __restrict__ xsd,
    const int* __restrict__ gsrc, const int* __restrict__ gdst,
    const ush* __restrict__ WQKV, size_t woff,
    const void* __restrict__ bq, size_t boff,
    ush* __restrict__ eq, ush* __restrict__ ek, ush* __restrict__ ev,
    const int* __restrict__ flag)
{
    __shared__ __align__(16) ush mixs[128*40];
    __shared__ __align__(16) ush wts[3][32*40];
    __shared__ float bqs[32];
    const int isbf = *flag;
    const int t = threadIdx.x;
    const int e0 = blockIdx.x * 128;
    #pragma unroll
    for (int i = t; i < 768; i += 256) {
        int m = i >> 8, r2 = i & 255;
        int n = r2 >> 3, k4 = (r2 & 7) * 4;
        *(ushort4*)&wts[m][n*40 + k4] =
            *(const ushort4*)&WQKV[(size_t)m*2048 + woff + (size_t)n*32 + k4];
    }
    if (t < 32) bqs[t] = ldf(bq, boff + t, isbf);
    {
        int r = t >> 1, c0 = (t & 1) * 16;
        int e = e0 + r;
        int s = gsrc[e], d2 = gdst[e];
        const ush* lp = lg + (size_t)e*32 + c0;
        const float* sp = xsd + (size_t)s*kQW + c0;
        const float* dp = xsd + (size_t)d2*kQW + 32 + c0;
        #pragma unroll
        for (int j = 0; j < 16; ++j)
            mixs[r*40 + c0 + j] = f2b(b2f(lp[j]) + sp[j] + dp[j]);
    }
    __syncthreads();
    const int wave = t >> 6, l15 = t & 15, quad = (t >> 4) & 3;
    #pragma unroll
    for (int mi = 0; mi < 2; ++mi) {
        const int mt = wave*2 + mi;
        frag_ab af = *(const frag_ab*)&mixs[(mt*16 + l15)*40 + quad*8];
        #pragma unroll
        for (int w = 0; w < 3; ++w) {
            ush* outp = (w==0) ? eq : ((w==1) ? ek : ev);
            #pragma unroll
            for (int nt = 0; nt < 2; ++nt) {
                frag_ab bf = *(const frag_ab*)&wts[w][(nt*16 + l15)*40 + quad*8];
                frag_cd acc = {0.f, 0.f, 0.f, 0.f};
                acc = __builtin_amdgcn_mfma_f32_16x16x32_bf16(af, bf, acc, 0, 0, 0);
                const float bv = (w==0) ? bqs[nt*16 + l15] : 0.f;
                #pragma unroll
                for (int rg = 0; rg < 4; ++rg) {
                    int row = e0 + mt*16 + quad*4 + rg;
                    outp[(size_t)row*32 + nt*16 + l15] = f2b(acc[rg] + bv);
                }
            }
        }
    }
}

// ---------------- MFMA edge FFN: LN(A + relu(A@W1+b1)@W2 + b2); bf16 A / bf16 out ----------------
__global__ __launch_bounds__(256) void effn_mfma_k(
    const ush* __restrict__ A,
    const ush* __restrict__ W1T, size_t w1off, const void* __restrict__ b1, size_t b1off,
    const ush* __restrict__ W2T, size_t w2off, const void* __restrict__ b2, size_t b2off,
    const void* __restrict__ g, const void* __restrict__ be, size_t goff,
    ush* __restrict__ out, const int* __restrict__ flag)
{
    __shared__ __align__(16) ush w1t[128*40];
    __shared__ __align__(16) ush w2t[32*136];
    __shared__ __align__(16) ush hid[64*136];
    __shared__ float b1s[128], b2s[32];
    const int isbf = *flag;
    const int t = threadIdx.x;
    const int wave = t >> 6, l15 = t & 15, quad = (t >> 4) & 3;

    #pragma unroll
    for (int i = t; i < 1024; i += 256) {
        int n1 = i >> 3, k4 = (i & 7) * 4;
        *(ushort4*)&w1t[n1*40 + k4] = *(const ushort4*)&W1T[w1off + (size_t)n1*32 + k4];
        int n2 = i >> 5, kq2 = (i & 31) * 4;
        *(ushort4*)&w2t[n2*136 + kq2] = *(const ushort4*)&W2T[w2off + (size_t)n2*128 + kq2];
    }
    if (t < 128) b1s[t] = ldf(b1, b1off + t, isbf);
    if (t < 32)  b2s[t] = ldf(b2, b2off + t, isbf);
    __syncthreads();

    const float g0  = ldf(g,  goff + l15, isbf),      g1v = ldf(g,  goff + 16 + l15, isbf);
    const float be0 = ldf(be, goff + l15, isbf),      be1 = ldf(be, goff + 16 + l15, isbf);
    const float bb0 = b2s[l15], bb1 = b2s[16 + l15];

    for (int tt = 0; tt < 2; ++tt) {
        const int e0 = (blockIdx.x*2 + tt) * 64;
        {
            const int m = wave*16 + l15;
            frag_ab af = *(const frag_ab*)&A[(size_t)(e0+m)*32 + quad*8];
            #pragma unroll
            for (int nt = 0; nt < 8; ++nt) {
                frag_ab bf = *(const frag_ab*)&w1t[(nt*16 + l15)*40 + quad*8];
                frag_cd acc = {0.f, 0.f, 0.f, 0.f};
                acc = __builtin_amdgcn_mfma_f32_16x16x32_bf16(af, bf, acc, 0, 0, 0);
                float bv = b1s[nt*16 + l15];
                #pragma unroll
                for (int rg = 0; rg < 4; ++rg) {
                    int row = wave*16 + quad*4 + rg;
                    hid[row*136 + nt*16 + l15] = f2b(fmaxf(acc[rg] + bv, 0.f));
                }
            }
        }
        // hid rows are wave-private -> no barrier needed
        frag_cd acc2[2] = {{0.f,0.f,0.f,0.f},{0.f,0.f,0.f,0.f}};
        #pragma unroll
        for (int ks = 0; ks < 4; ++ks) {
            frag_ab af2 = *(const frag_ab*)&hid[(wave*16 + l15)*136 + ks*32 + quad*8];
            #pragma unroll
            for (int tl = 0; tl < 2; ++tl) {
                frag_ab bf2 = *(const frag_ab*)&w2t[(tl*16 + l15)*136 + ks*32 + quad*8];
                acc2[tl] = __builtin_amdgcn_mfma_f32_16x16x32_bf16(af2, bf2, acc2[tl], 0, 0, 0);
            }
        }
        #pragma unroll
        for (int rg = 0; rg < 4; ++rg) {
            const int row = e0 + wave*16 + quad*4 + rg;
            float v0 = acc2[0][rg] + bb0 + b2f(A[(size_t)row*32 + l15]);
            float v1 = acc2[1][rg] + bb1 + b2f(A[(size_t)row*32 + 16 + l15]);
            float s = v0 + v1;
            s += __shfl_xor(s,1); s += __shfl_xor(s,2); s += __shfl_xor(s,4); s += __shfl_xor(s,8);
            const float mean = s * (1.f/32.f);
            float q = (v0-mean)*(v0-mean) + (v1-mean)*(v1-mean);
            q += __shfl_xor(q,1); q += __shfl_xor(q,2); q += __shfl_xor(q,4); q += __shfl_xor(q,8);
            const float inv = rsqrtf(q * (1.f/32.f) + 1e-5f);
            out[(size_t)row*32 + l15]      = f2b((v0-mean)*inv*g0  + be0);
            out[(size_t)row*32 + 16 + l15] = f2b((v1-mean)*inv*g1v + be1);
        }
    }
}

// ---------------- full-graph attention v5: (b,h,quarter) blocks, 512 grid, bf16 out ----------------
__global__ __launch_bounds__(512) void full_attn_k(
    const float* __restrict__ q, const float* __restrict__ k, const float* __restrict__ v,
    const void* __restrict__ rel, const int* __restrict__ feat, ush* __restrict__ o,
    const int* __restrict__ flag, int ldq)
{
    __shared__ __align__(8) ush ks[128][36];
    __shared__ __align__(8) ush vs[128][36];
    __shared__ __align__(8) ush rs[128][36];
    __shared__ float pb[8][32][34];            // per-wave partials: m, l, acc[32]
    const int isbf = *flag;
    const int bid = blockIdx.x;
    const int b = bid >> 4, h = (bid >> 2) & 3, qtr = bid & 3;
    const int t = threadIdx.x;
    for (int i = t; i < 4096; i += 512) {
        int r = i >> 5, d = i & 31;
        rs[r][d] = ldb(rel, i, isbf);
        size_t base = ((size_t)(b*128 + r))*ldq + h*32 + d;
        ks[r][d] = f2b(k[base]);
        vs[r][d] = f2b(v[base]);
    }
    __syncthreads();
    const int wave = t >> 6, lane = t & 63;
    const int dstL = lane >> 1, part = lane & 1;   // 2 lanes per dst
    const int dst = qtr*32 + dstL;
    const int dbase = part*16;                     // this lane's 16 dims
    float qr[16];
    { size_t base = ((size_t)(b*128 + dst))*ldq + h*32 + dbase;
      #pragma unroll
      for (int d=0; d<16; ++d) qr[d] = q[base + d]; }
    const int* fp = feat + (size_t)b*16384 + dst;
    const int s0 = wave*16;
    float m = -1e30f, l = 0.f;
    float acc[16];
    #pragma unroll
    for (int d=0; d<16; ++d) acc[d] = 0.f;
    int f = fp[s0*128];
    for (int sI = 0; sI < 16; ++sI) {
        const int s = s0 + sI;
        int fn = (sI+1 < 16) ? fp[(s+1)*128] : 0;
        float er[16];
        float scp = 0.f;
        #pragma unroll
        for (int j2 = 0; j2 < 4; ++j2) {
            ushort4 eu = *(const ushort4*)&rs[f][dbase + j2*4];
            ushort4 ku = *(const ushort4*)&ks[s][dbase + j2*4];
            float e0 = b2f(eu.x), e1 = b2f(eu.y), e2 = b2f(eu.z), e3 = b2f(eu.w);
            er[j2*4+0]=e0; er[j2*4+1]=e1; er[j2*4+2]=e2; er[j2*4+3]=e3;
            scp += (b2f(ku.x)+e0)*qr[j2*4+0] + (b2f(ku.y)+e1)*qr[j2*4+1]
                 + (b2f(ku.z)+e2)*qr[j2*4+2] + (b2f(ku.w)+e3)*qr[j2*4+3];
        }
        const float sc = (scp + __shfl_xor(scp, 1)) * kScaleN;
        float mn = fmaxf(m, sc);
        float c0 = __expf(m - mn);
        float pp = __expf(sc - mn);
        l = l*c0 + pp;
        #pragma unroll
        for (int j2 = 0; j2 < 4; ++j2) {
            ushort4 vu = *(const ushort4*)&vs[s][dbase + j2*4];
            acc[j2*4+0] = acc[j2*4+0]*c0 + pp*(b2f(vu.x)+er[j2*4+0]);
            acc[j2*4+1] = acc[j2*4+1]*c0 + pp*(b2f(vu.y)+er[j2*4+1]);
            acc[j2*4+2] = acc[j2*4+2]*c0 + pp*(b2f(vu.z)+er[j2*4+2]);
            acc[j2*4+3] = acc[j2*4+3]*c0 + pp*(b2f(vu.w)+er[j2*4+3]);
        }
        m = mn; f = fn;
    }
    if (part == 0) { pb[wave][dstL][0] = m; pb[wave][dstL][1] = l; }
    #pragma unroll
    for (int d=0; d<16; ++d) pb[wave][dstL][2 + dbase + d] = acc[d];
    __syncthreads();
    // merge: thread (dstL2, grp) handles dims [grp*2, grp*2+2) of dst=qtr*32+dstL2
    {
        const int dstL2 = t & 31, grp = t >> 5;   // grp in [0,16)
        float mw[8], lw[8];
        #pragma unroll
        for (int w=0; w<8; ++w){ mw[w]=pb[w][dstL2][0]; lw[w]=pb[w][dstL2][1]; }
        float M = mw[0];
        #pragma unroll
        for (int w=1; w<8; ++w) M = fmaxf(M, mw[w]);
        float sw[8];
        float L = 0.f;
        #pragma unroll
        for (int w=0; w<8; ++w){ sw[w] = __expf(mw[w]-M); L += lw[w]*sw[w]; }
        const float inv = 1.f / fmaxf(L, 1e-30f);
        size_t base = ((size_t)(b*128 + qtr*32 + dstL2))*kND + h*32 + grp*2;
        #pragma unroll
        for (int d=0; d<2; ++d) {
            float a = 0.f;
            #pragma unroll
            for (int w=0; w<8; ++w) a += pb[w][dstL2][2+grp*2+d]*sw[w];
            o[base + d] = f2b(a*inv);
        }
    }
}

// ---------------- local-graph GATHER attention (heads 4..7), compact bf16 kvloc ----------------
// kvloc[4096][256]: cols 0-127 = K local heads, 128-255 = V local heads (bias included)
__global__ __launch_bounds__(256) void loc_gather_k(
    const float* __restrict__ q, const ush* __restrict__ kv,
    const ush* __restrict__ lg, const int* __restrict__ gsrc,
    const int* __restrict__ rowp, const int* __restrict__ eidl,
    ush* __restrict__ o, int ldq)
{
    const int n = blockIdx.x;
    const int h = threadIdx.x >> 6;
    const int lane = threadIdx.x & 63;
    const int g = lane >> 4;
    const int d0 = (lane & 15) * 2;
    const size_t hoff = (size_t)(4 + h) * 32 + d0;
    const float2 q2 = *(const float2*)&q[(size_t)n*ldq + hoff];
    const int beg = rowp[n], end = rowp[n+1];
    const int deg = end - beg;
    float m = -1e30f, l = 0.f, ax = 0.f, ay = 0.f;
    if (deg > 0) {
        const int nIter = (deg + 3) >> 2;
        int idx = beg + g;
        int ce = eidl[min(idx, end-1)];
        int cs = gsrc[ce];
        for (int it = 0; it < nIter; ++it) {
            const bool valid = idx < end;
            const int e = ce, s = cs;
            idx += 4;
            if (it + 1 < nIter) { ce = eidl[min(idx, end-1)]; cs = gsrc[ce]; }
            const ushort2 ku = *(const ushort2*)&kv[(size_t)s*256 + h*32 + d0];
            const ushort2 lvu = *(const ushort2*)&lg[(size_t)e*32 + d0];
            const ushort2 vu = *(const ushort2*)&kv[(size_t)s*256 + 128 + h*32 + d0];
            const float lvx = b2f(lvu.x), lvy = b2f(lvu.y);
            float part = (b2f(ku.x)+lvx)*q2.x + (b2f(ku.y)+lvy)*q2.y;
            part += __shfl_xor(part, 1);
            part += __shfl_xor(part, 2);
            part += __shfl_xor(part, 4);
            part += __shfl_xor(part, 8);
            const float sc = part * kScaleN;
            const float mn = valid ? fmaxf(m, sc) : m;
            const float c  = __expf(m - mn);
            const float pp = valid ? __expf(sc - mn) : 0.f;
            l  = l*c  + pp;
            ax = ax*c + pp*(b2f(vu.x)+lvx);
            ay = ay*c + pp*(b2f(vu.y)+lvy);
            m  = mn;
        }
        #pragma unroll
        for (int off = 16; off <= 32; off <<= 1) {
            const float mo = __shfl_xor(m, off);
            const float lo = __shfl_xor(l, off);
            const float xo = __shfl_xor(ax, off);
            const float yo = __shfl_xor(ay, off);
            const float M  = fmaxf(m, mo);
            const float c1 = __expf(m - M);
            const float c2 = __expf(mo - M);
            l  = l*c1  + lo*c2;
            ax = ax*c1 + xo*c2;
            ay = ay*c1 + yo*c2;
            m  = M;
        }
    }
    if (g == 0) {
        const float inv = 1.f / fmaxf(l, 1e-30f);
        *(ushort2*)&o[(size_t)n*kND + hoff] = make_ushort2(f2b(ax*inv), f2b(ay*inv));
    }
}

// ---------------- fused line-graph attention + Wo GEMM + LN (bf16 in/out) ----------------
__global__ __launch_bounds__(256) void lgs_ewo_k(
    const ush* __restrict__ eq, const ush* __restrict__ ek, const ush* __restrict__ ev,
    const int* __restrict__ lsrc, const int* __restrict__ rowp, const int* __restrict__ eidl,
    const ush* __restrict__ res,
    const ush* __restrict__ WO, size_t wooff, const void* __restrict__ bo, size_t booff,
    const void* __restrict__ g1, const void* __restrict__ be1, size_t g1off,
    ush* __restrict__ out, const int* __restrict__ flag)
{
    __shared__ __align__(16) ush ows[32*40];
    __shared__ __align__(16) ush wos[32*40];
    __shared__ float cs[32][36];
    __shared__ float bos[32], gs[32], bs[32];
    const int isbf = *flag;
    const int t = threadIdx.x;
    const int base = blockIdx.x * 32;
    {
        int n = t >> 3, k4 = (t & 7) * 4;
        *(ushort4*)&wos[n*40 + k4] = *(const ushort4*)&WO[wooff + (size_t)n*32 + k4];
    }
    if (t < 32) {
        bos[t] = ldf(bo, booff + t, isbf);
        gs[t]  = ldf(g1, g1off + t, isbf);
        bs[t]  = ldf(be1, g1off + t, isbf);
    }
    // ---- phase 1: gather attention, thread = (dst-edge, head) ----
    {
        const int d2 = base + (t >> 3), h = t & 7;
        const ushort4 qu = *(const ushort4*)&eq[(size_t)d2*32 + h*4];
        const float q0 = b2f(qu.x), q1 = b2f(qu.y), q2 = b2f(qu.z), q3 = b2f(qu.w);
        const int beg = rowp[d2], end = rowp[d2+1];
        float m = -1e30f, l = 0.f;
        float4 acc = make_float4(0.f,0.f,0.f,0.f);
        int i = beg;
        int s = 0;
        if (i < end) { s = lsrc[eidl[i]]; }
        while (i < end) {
            const int sc_s = s;
            ++i;
            if (i < end) { s = lsrc[eidl[i]]; }      // prefetch next src
            const ushort4 ku = *(const ushort4*)&ek[(size_t)sc_s*32 + h*4];
            const ushort4 vu = *(const ushort4*)&ev[(size_t)sc_s*32 + h*4];
            float sc = (b2f(ku.x)*q0 + b2f(ku.y)*q1 + b2f(ku.z)*q2 + b2f(ku.w)*q3) * 0.5f;
            float mn = fmaxf(m, sc);
            float c = __expf(m - mn);
            float pp = __expf(sc - mn);
            l = l*c + pp;
            acc.x = acc.x*c + pp*b2f(vu.x);
            acc.y = acc.y*c + pp*b2f(vu.y);
            acc.z = acc.z*c + pp*b2f(vu.z);
            acc.w = acc.w*c + pp*b2f(vu.w);
            m = mn;
        }
        const float inv = 1.f / fmaxf(l, 1e-30f);
        const int r = t >> 3, c0 = h*4;
        ows[r*40 + c0 + 0] = f2b(acc.x*inv);
        ows[r*40 + c0 + 1] = f2b(acc.y*inv);
        ows[r*40 + c0 + 2] = f2b(acc.z*inv);
        ows[r*40 + c0 + 3] = f2b(acc.w*inv);
    }
    __syncthreads();
    // ---- phase 2: 32x32 GEMM ----
    {
        const int wave = t >> 6, l15 = t & 15, quad = (t >> 4) & 3;
        const int mt = wave & 1, nt = wave >> 1;
        frag_ab af = *(const frag_ab*)&ows[(mt*16 + l15)*40 + quad*8];
        frag_ab bf = *(const frag_ab*)&wos[(nt*16 + l15)*40 + quad*8];
        frag_cd acc = {0.f, 0.f, 0.f, 0.f};
        acc = __builtin_amdgcn_mfma_f32_16x16x32_bf16(af, bf, acc, 0, 0, 0);
        #pragma unroll
        for (int rg = 0; rg < 4; ++rg) {
            const int row = mt*16 + quad*4 + rg;
            const int col = nt*16 + l15;
            cs[row][col] = acc[rg] + bos[col] + b2f(res[(size_t)(base+row)*32 + col]);
        }
    }
    __syncthreads();
    // ---- phase 3: LN per row ----
    {
        const int row = t >> 3, c0 = (t & 7) * 4;
        const float v0 = cs[row][c0], v1 = cs[row][c0+1];
        const float v2 = cs[row][c0+2], v3 = cs[row][c0+3];
        float s = v0+v1+v2+v3;
        s += __shfl_xor(s,1); s += __shfl_xor(s,2); s += __shfl_xor(s,4);
        const float mean = s * (1.f/32.f);
        float qq = (v0-mean)*(v0-mean)+(v1-mean)*(v1-mean)
                 + (v2-mean)*(v2-mean)+(v3-mean)*(v3-mean);
        qq += __shfl_xor(qq,1); qq += __shfl_xor(qq,2); qq += __shfl_xor(qq,4);
        const float inv = rsqrtf(qq * (1.f/32.f) + 1e-5f);
        out[(size_t)(base+row)*32 + c0 + 0] = f2b((v0-mean)*inv*gs[c0+0] + bs[c0+0]);
        out[(size_t)(base+row)*32 + c0 + 1] = f2b((v1-mean)*inv*gs[c0+1] + bs[c0+1]);
        out[(size_t)(base+row)*32 + c0 + 2] = f2b((v2-mean)*inv*gs[c0+2] + bs[c0+2]);
        out[(size_t)(base+row)*32 + c0 + 3] = f2b((v3-mean)*inv*gs[c0+3] + bs[c0+3]);
    }
}

// ---------------- output ----------------
__global__ void out_k(const float* __restrict__ xf, const ush* __restrict__ lgf,
                      void* __restrict__ out, const int* __restrict__ flag){
    const int isbf = *flag;
    int g = blockIdx.x*256 + threadIdx.x;
    if (g < kN*kND) {
        float v = xf[g];
        if (isbf) ((ush*)out)[g] = f2b(v);
        else      ((float*)out)[g] = v;
    } else {
        ush u = lgf[g - kN*kND];
        if (isbf) ((ush*)out)[g] = u;
        else      ((float*)out)[g] = b2f(u);
    }
}

// ---------------- host helper ----------------
static inline void mgemm(const float* A, const ush* WT, const void* bias, size_t boff,
                         float* C, const int* flag, int M, int N, int K, int flags,
                         hipStream_t s, ush* aux){
    dim3 grid((N+63)/64, M/64);
    mgemm_k<<<grid, 256, 0, s>>>(A, WT, bias, boff, C, flag, M, N, K, flags, aux);
}

extern "C" void kernel_launch(void* const* d_in, const int* in_sizes, int n_in,
                              void* d_out, int out_size, void* d_ws, size_t ws_size,
                              hipStream_t stream) {
    const void* x_in      = d_in[0];
    const void* rel       = d_in[1];
    const int* g_src      = (const int*)d_in[4];
    const int* g_dst      = (const int*)d_in[5];
    const int* lg_src     = (const int*)d_in[6];
    const int* lg_dst     = (const int*)d_in[7];
    const int* edge_feat  = (const int*)d_in[8];
    const int* full_feat  = (const int*)d_in[9];
    const void* n_Wq   = d_in[10];
    const void* n_bq   = d_in[11];
    const void* n_Wk   = d_in[12];
    const void* n_bk   = d_in[13];
    const void* n_Wv   = d_in[14];
    const void* n_bv   = d_in[15];
    const void* n_Wo   = d_in[16];
    const void* n_bo   = d_in[17];
    const void* n_lng  = d_in[18];
    const void* n_lnb  = d_in[19];
    const void* n_fW1  = d_in[20];
    const void* n_fb1  = d_in[21];
    const void* n_fW2  = d_in[22];
    const void* n_fb2  = d_in[23];
    const void* n_flng = d_in[24];
    const void* n_flnb = d_in[25];
    const void* e_Wsrc = d_in[26];
    const void* e_Wdst = d_in[27];
    const void* e_Wq   = d_in[28];
    const void* e_bq   = d_in[29];
    const void* e_Wk   = d_in[30];
    const void* e_Wv   = d_in[31];
    const void* e_Wo   = d_in[32];
    const void* e_bo   = d_in[33];
    const void* e_lng  = d_in[34];
    const void* e_lnb  = d_in[35];
    const void* e_fW1  = d_in[36];
    const void* e_fb1  = d_in[37];
    const void* e_fW2  = d_in[38];
    const void* e_fb2  = d_in[39];
    const void* e_flng = d_in[40];
    const void* e_flnb = d_in[41];

    // ---- workspace carve-up (units: floats) ----
    float* p = (float*)d_ws;
    size_t off = 0;
    auto AL = [&](size_t n){ float* r = p + off; off += n; return r; };
    int* flagp = (int*)AL(64);
    float* xA   = AL((size_t)kN*kND);
    float* xB   = AL((size_t)kN*kND);
    float* xM   = AL((size_t)kN*kND);
    ush*   xAb  = (ush*)AL((size_t)kN*kND/2);
    ush*   xBb  = (ush*)AL((size_t)kN*kND/2);
    ush*   xMb  = (ush*)AL((size_t)kN*kND/2);
    float* qkvb = AL((size_t)kN*kQW);
    ush*   kvloc= (ush*)AL((size_t)kN*128);      // kN*256 bf16 compact local K/V
    ush*   ob   = (ush*)AL((size_t)kN*kND/2);
    float* tN   = AL((size_t)kN*kND);
    ush*   nh   = (ush*)AL((size_t)kN*512);      // kN*1024 bf16
    ush*   lgA  = (ush*)AL((size_t)kEL*kED/2);   // bf16 edge residual chain
    ush*   lgB  = (ush*)AL((size_t)kEL*kED/2);
    ush*   lgM  = (ush*)AL((size_t)kEL*kED/2);
    ush*   eqb  = (ush*)AL((size_t)kEL*16);      // kEL*32 bf16
    ush*   ekb  = (ush*)AL((size_t)kEL*16);
    ush*   evb  = (ush*)AL((size_t)kEL*16);
    // CSR structures
    int* cntL  = (int*)AL(kN);
    int* rowL  = (int*)AL(kN + 64);
    int* curL  = (int*)AL(kN);
    int* eidL  = (int*)AL(kEL);
    int* cntG  = (int*)AL(kEL);
    int* rowG  = (int*)AL(kEL + 64);
    int* curG  = (int*)AL(kEL);
    int* eidG  = (int*)AL(kELG);
    int* bsum  = (int*)AL(256);
    // pre-transposed bf16 weights
    ush* wtQKVSD = (ush*)AL(212992);   // [L][832][256] bf16 (425984 ush)
    float* bQKV  = AL(2*kQW);
    ush* wtO  = (ush*)AL(65536);
    ush* wtF1 = (ush*)AL(262144);
    ush* wtF2 = (ush*)AL(262144);
    ush* wtEQKV = (ush*)AL(3072);
    ush* wtEO   = (ush*)AL(1024);
    ush* wtEF1  = (ush*)AL(4096);
    ush* wtEF2  = (ush*)AL(4096);
    if (ws_size < off * sizeof(float)) return;

    detect_k<<<1, 64, 0, stream>>>((const ush*)x_in, flagp);
    {
        long total = (long)kN*kND + (long)kEL*kED + 2*kQW + kN + kEL;
        int blocks = (int)((total + 255) / 256);
        setup_misc_k<<<blocks, 256, 0, stream>>>(x_in, rel, edge_feat, n_bq, n_bk, n_bv,
                                                 xA, xAb, lgA, bQKV, cntL, cntG, flagp);
    }
    trans_all_k<<<6368, 256, 0, stream>>>(n_Wq, n_Wk, n_Wv, n_Wo, n_fW1, n_fW2,
                                          e_Wsrc, e_Wdst, e_Wq, e_Wk, e_Wv, e_Wo,
                                          e_fW1, e_fW2, flagp,
                                          wtQKVSD, wtO, wtF1, wtF2,
                                          wtEQKV, wtEO, wtEF1, wtEF2);

    count2_k<<<(kEL+kELG)/256, 256, 0, stream>>>(g_dst, lg_dst, cntL, cntG);
    scan_blk2_k<<<132, 256, 0, stream>>>(cntL, cntG, rowL, rowG, bsum);
    scan_top2_k<<<1, 256, 0, stream>>>(bsum);
    scan_add2_k<<<(kN+kEL)/256, 256, 0, stream>>>(rowL, rowG, bsum, curL, curG);
    fill2_k<<<(kEL+kELG)/256, 256, 0, stream>>>(g_dst, lg_dst, curL, curG, eidL, eidG);

    float* xc = xA;  float* xn = xB;
    ush* xcb = xAb;  ush* xnb = xBb;
    ush* lgc = lgA;  ush* lgn = lgB;

    for (int i = 0; i < kL; ++i) {
        const size_t o256 = (size_t)i*kND;
        const size_t o1024= (size_t)i*1024;
        const size_t o32  = (size_t)i*kED;
        const size_t o128 = (size_t)i*128;

        // ===== node update (+ packed xs/xd in cols 768-831; kvloc side-output) =====
        mgemm((const float*)xcb, wtQKVSD + (size_t)i*212992, bQKV, (size_t)i*kQW, qkvb,
              flagp, kN, kQW, kND, 4|16|32|64, stream, kvloc);
        full_attn_k<<<512, 512, 0, stream>>>(qkvb, qkvb+256, qkvb+512, rel, full_feat,
                                             ob, flagp, kQW);
        loc_gather_k<<<kN, 256, 0, stream>>>(qkvb, kvloc, lgc, g_src,
                                             rowL, eidL, ob, kQW);
        mgemm((const float*)ob, wtO + (size_t)i*65536, n_bo, o256, tN, flagp,
              kN, kND, kND, 4|32, stream, nullptr);
        ln_k<<<kN, 64, 0, stream>>>(xc, tN, n_lng, n_lnb, o256, xM, xMb, flagp, kND);
        mgemm((const float*)xMb, wtF1 + (size_t)i*262144, n_fb1, o1024, (float*)nh, flagp,
              kN, 1024, kND, 4|2|8|32, stream, nullptr);
        mgemm((const float*)nh, wtF2 + (size_t)i*262144, n_fb2, o256, tN, flagp,
              kN, kND, 1024, 4|32, stream, nullptr);
        ln_k<<<kN, 64, 0, stream>>>(xM, tN, n_flng, n_flnb, o256, xn, xnb, flagp, kND);

        // ===== edge update (uses PRE-update xc, lgc) =====
        eqkv_mfma_k<<<kEL/128, 256, 0, stream>>>(lgc, qkvb + 768, g_src, g_dst,
                                                 wtEQKV, (size_t)i*1024, e_bq, o32,
                                                 eqb, ekb, evb, flagp);
        lgs_ewo_k<<<kEL/32, 256, 0, stream>>>(eqb, ekb, evb, lg_src, rowG, eidG,
                                              lgc, wtEO, (size_t)i*1024, e_bo, o32,
                                              e_lng, e_lnb, o32, lgM, flagp);
        effn_mfma_k<<<kEL/128, 256, 0, stream>>>(lgM, wtEF1, (size_t)i*4096, e_fb1, o128,
                                                 wtEF2, (size_t)i*4096, e_fb2, o32,
                                                 e_flng, e_flnb, o32, lgn, flagp);

        { float* t = xc; xc = xn; xn = t; }
        { ush* t = xcb; xcb = xnb; xnb = t; }
        { ush* t = lgc; lgc = lgn; lgn = t; }
    }

    out_k<<<(kN*kND + kEL*kED)/256, 256, 0, stream>>>(xc, lgc, d_out, flagp);
}

// Round 9
// 522.700 us; speedup vs baseline: 1.4767x; 1.0047x over previous
//
#include <hip/hip_runtime.h>
#include <hip/hip_bf16.h>

typedef __hip_bfloat16 bf16;
typedef unsigned short ush;

static constexpr int kN   = 4096;    // nodes
static constexpr int kND  = 256;     // hidden
static constexpr int kEL  = 131072;  // local edges
static constexpr int kED  = 32;      // edge dim
static constexpr int kELG = 262144;  // line-graph edges
static constexpr int kL   = 2;
static constexpr int kQW  = 832;     // packed qkv+sd GEMM width
static constexpr int kKV  = 576;     // kvaux row stride (bf16): K 0-255, V 256-511, SD 512-575
static constexpr float kScaleN = 0.17677669529663687f; // 1/sqrt(32)

using frag_ab = __attribute__((ext_vector_type(8))) short;   // 8 bf16 (4 VGPRs)
using frag_cd = __attribute__((ext_vector_type(4))) float;   // 4 fp32

__device__ __forceinline__ float ldf(const void* p, size_t i, int isbf){
    return isbf ? __bfloat162float(((const bf16*)p)[i]) : ((const float*)p)[i];
}
__device__ __forceinline__ ush f2b(float f){ bf16 h = __float2bfloat16(f); return *(ush*)&h; }
__device__ __forceinline__ float b2f(ush u){ return __uint_as_float(((unsigned)u)<<16); }
__device__ __forceinline__ ush ldb(const void* p, size_t i, int isbf){
    return isbf ? ((const ush*)p)[i] : f2b(((const float*)p)[i]);
}

// ---------------- dtype detection ----------------
__global__ void detect_k(const ush* __restrict__ xin, int* __restrict__ flag){
    if (threadIdx.x == 0 && blockIdx.x == 0) {
        int plausible = 0;
        for (int i = 0; i < 128; ++i) {
            ush u = xin[i];
            int e = (u >> 7) & 0xFF;
            if (e == 0 || (e >= 110 && e <= 140)) ++plausible;
        }
        *flag = (plausible >= 102) ? 1 : 0;
    }
}

// ---------------- fused setup: cast x (f32+bf16), init lg (bf16), pack bias, zero counters ----------------
__global__ void setup_misc_k(const void* __restrict__ xin, const void* __restrict__ rel,
                             const int* __restrict__ feat,
                             const void* __restrict__ bq, const void* __restrict__ bk,
                             const void* __restrict__ bv,
                             float* __restrict__ xA, ush* __restrict__ xAb,
                             ush* __restrict__ lgA,
                             float* __restrict__ bQKV,
                             int* __restrict__ cntL, int* __restrict__ cntG,
                             const int* __restrict__ flag){
    const int isbf = *flag;
    long g = (long)blockIdx.x*256 + threadIdx.x;
    if (g < (long)kN*kND) {
        float v = ldf(xin, g, isbf);
        xA[g] = v; xAb[g] = f2b(v);
        return;
    }
    g -= (long)kN*kND;
    if (g < (long)kEL*kED) { int e = (int)(g >> 5), d = (int)(g & 31);
        lgA[g] = ldb(rel, (size_t)feat[e]*kED + d, isbf); return; }
    g -= (long)kEL*kED;
    if (g < 2*kQW) {
        int layer = (int)(g / kQW), j = (int)(g - (long)layer*kQW);
        float v = 0.f;
        if (j < 768) { int w = j >> 8, jj = j & 255;
            const void* B = (w==0)?bq:((w==1)?bk:bv);
            v = ldf(B, (size_t)layer*256 + jj, isbf); }
        bQKV[g] = v; return;
    }
    g -= 2*kQW;
    if (g < kN) { cntL[g] = 0; return; }
    g -= kN;
    if (g < kEL) { cntG[g] = 0; return; }
}

// ---------------- ALL weight pre-transposes in one kernel ----------------
__global__ void trans_all_k(
    const void* __restrict__ nWq, const void* __restrict__ nWk, const void* __restrict__ nWv,
    const void* __restrict__ nWo, const void* __restrict__ nF1, const void* __restrict__ nF2,
    const void* __restrict__ eWs, const void* __restrict__ eWd,
    const void* __restrict__ eWq, const void* __restrict__ eWk, const void* __restrict__ eWv,
    const void* __restrict__ eWo, const void* __restrict__ eF1, const void* __restrict__ eF2,
    const int* __restrict__ flag,
    ush* __restrict__ wtQKVSD, ush* __restrict__ wtO, ush* __restrict__ wtF1,
    ush* __restrict__ wtF2, ush* __restrict__ wtEQKV, ush* __restrict__ wtEO,
    ush* __restrict__ wtEF1, ush* __restrict__ wtEF2)
{
    const int isbf = *flag;
    int g = blockIdx.x*256 + threadIdx.x;
    if (g < 393216){                                   // QKV -> wtQKVSD rows 0-767
        int w = g >> 17, gg = g & 131071;
        int layer = gg >> 16, idx = gg & 65535;
        int n = idx >> 8, k = idx & 255;
        const void* W = (w==0)?nWq:((w==1)?nWk:nWv);
        wtQKVSD[(size_t)layer*212992 + (size_t)(w*256+n)*256 + k] =
            ldb(W, (size_t)layer*65536 + (size_t)k*256 + n, isbf);
        return;
    }
    g -= 393216;
    if (g < 32768){                                    // src/dst -> wtQKVSD rows 768-831
        int w = g >> 14, gg = g & 16383;
        int layer = gg >> 13, idx = gg & 8191;
        int n = idx >> 8, k = idx & 255;
        const void* W = w ? eWd : eWs;
        wtQKVSD[(size_t)layer*212992 + (size_t)(768 + w*32 + n)*256 + k] =
            ldb(W, (size_t)layer*8192 + (size_t)k*32 + n, isbf);
        return;
    }
    g -= 32768;
    if (g < 131072){                                   // Wo [L][256][256]
        int layer = g >> 16, rem = g & 65535;
        int n = rem >> 8, k = rem & 255;
        wtO[g] = ldb(nWo, (size_t)layer*65536 + (size_t)k*256 + n, isbf);
        return;
    }
    g -= 131072;
    if (g < 524288){                                   // F1 [L][1024][256]
        int layer = g >> 18, rem = g & 262143;
        int n = rem >> 8, k = rem & 255;
        wtF1[g] = ldb(nF1, (size_t)layer*262144 + (size_t)k*1024 + n, isbf);
        return;
    }
    g -= 524288;
    if (g < 524288){                                   // F2 [L][256][1024]
        int layer = g >> 18, rem = g & 262143;
        int n = rem >> 10, k = rem & 1023;
        wtF2[g] = ldb(nF2, (size_t)layer*262144 + (size_t)k*256 + n, isbf);
        return;
    }
    g -= 524288;
    if (g < 6144){                                     // eQKV [3][L][32][32]
        int w = g >> 11, gg = g & 2047;
        int layer = gg >> 10, rem = gg & 1023;
        int n = rem >> 5, k = rem & 31;
        const void* W = (w==0)?eWq:((w==1)?eWk:eWv);
        wtEQKV[g] = ldb(W, (size_t)layer*1024 + (size_t)k*32 + n, isbf);
        return;
    }
    g -= 6144;
    if (g < 2048){                                     // eWo [L][32][32]
        int layer = g >> 10, rem = g & 1023;
        int n = rem >> 5, k = rem & 31;
        wtEO[g] = ldb(eWo, (size_t)layer*1024 + (size_t)k*32 + n, isbf);
        return;
    }
    g -= 2048;
    if (g < 8192){                                     // eF1 [L][128][32]
        int layer = g >> 12, rem = g & 4095;
        int n = rem >> 5, k = rem & 31;
        wtEF1[g] = ldb(eF1, (size_t)layer*4096 + (size_t)k*128 + n, isbf);
        return;
    }
    g -= 8192;
    if (g < 8192){                                     // eF2 [L][32][128]
        int layer = g >> 12, rem = g & 4095;
        int n = rem >> 7, k = rem & 127;
        wtEF2[g] = ldb(eF2, (size_t)layer*4096 + (size_t)k*32 + n, isbf);
        return;
    }
}

// ---------------- CSR build (both graphs fused) ----------------
__global__ void count2_k(const int* __restrict__ gd, const int* __restrict__ lgd,
                         int* __restrict__ cntL, int* __restrict__ cntG){
    int g = blockIdx.x*256 + threadIdx.x;
    if (g < kEL) atomicAdd(&cntL[gd[g]], 1);
    else if (g < kEL + kELG) atomicAdd(&cntG[lgd[g - kEL]], 1);
}
__global__ __launch_bounds__(256) void scan_blk2_k(
    const int* __restrict__ cntL, const int* __restrict__ cntG,
    int* __restrict__ rowL, int* __restrict__ rowG, int* __restrict__ bsum)
{
    __shared__ int s[256];
    const int t = threadIdx.x;
    const bool isL = blockIdx.x < 4;
    const int* cnt = isL ? cntL : cntG;
    int* out = isL ? rowL : rowG;
    const int blk = isL ? blockIdx.x : blockIdx.x - 4;
    const int n = isL ? kN : kEL;
    const int b0 = blk*1024;
    int v[4], pre[4], tsum = 0;
    #pragma unroll
    for (int j=0;j<4;++j){
        int idx = b0 + t*4 + j;
        v[j] = (idx < n) ? cnt[idx] : 0;
        pre[j] = tsum; tsum += v[j];
    }
    s[t] = tsum; __syncthreads();
    for (int off=1; off<256; off<<=1){
        int x = (t>=off) ? s[t-off] : 0;
        __syncthreads();
        s[t] += x;
        __syncthreads();
    }
    int texc = s[t] - tsum;
    #pragma unroll
    for (int j=0;j<4;++j){
        int idx = b0 + t*4 + j;
        if (idx < n) out[idx] = texc + pre[j];
    }
    if (t == 255) bsum[(isL ? 0 : 8) + blk] = s[255];
}
__global__ __launch_bounds__(256) void scan_top2_k(int* __restrict__ bsum){
    __shared__ int sL[256], sG[256];
    const int t = threadIdx.x;
    int vL = (t < 4)   ? bsum[t]     : 0;
    int vG = (t < 128) ? bsum[8 + t] : 0;
    sL[t] = vL; sG[t] = vG; __syncthreads();
    for (int off=1; off<256; off<<=1){
        int xL = (t>=off) ? sL[t-off] : 0;
        int xG = (t>=off) ? sG[t-off] : 0;
        __syncthreads();
        sL[t] += xL; sG[t] += xG;
        __syncthreads();
    }
    if (t < 4)   bsum[t]     = sL[t] - vL;
    if (t < 128) bsum[8 + t] = sG[t] - vG;
}
__global__ void scan_add2_k(int* __restrict__ rowL, int* __restrict__ rowG,
                            const int* __restrict__ bsum,
                            int* __restrict__ curL, int* __restrict__ curG){
    int g = blockIdx.x*256 + threadIdx.x;
    if (g < kN){ int v = rowL[g] + bsum[g >> 10]; rowL[g] = v; curL[g] = v; }
    else if (g < kN + kEL){ int gg = g - kN;
        int v = rowG[gg] + bsum[8 + (gg >> 10)]; rowG[gg] = v; curG[gg] = v; }
    if (g == 0){ rowL[kN] = kEL; rowG[kEL] = kELG; }
}
__global__ void fill2_k(const int* __restrict__ gd, const int* __restrict__ lgd,
                        int* __restrict__ curL, int* __restrict__ curG,
                        int* __restrict__ eidL, int* __restrict__ eidG){
    int g = blockIdx.x*256 + threadIdx.x;
    if (g < kEL){ int pos = atomicAdd(&curL[gd[g]], 1); eidL[pos] = g; }
    else if (g < kEL + kELG){ int gg = g - kEL;
        int pos = atomicAdd(&curG[lgd[gg]], 1); eidG[pos] = gg; }
}

// ---------------- MFMA GEMM: C[M,N] = A@WT^T + bias (opt relu); BK=64 ----------------
// WT: bf16 [N][K]. 64x64 tile, 4 waves. Requires K%64==0, N%64==0.
// flags: 2=RELU, 4=has-bias, 8=bf16 out, 16=bias packed fp32, 32=A is bf16,
//        64=QKV split output: col<256 -> fp32 C stride 256; col>=256 -> bf16 aux stride kKV
__global__ __launch_bounds__(256) void mgemm_k(
    const float* __restrict__ A, const ush* __restrict__ WT,
    const void* __restrict__ bias, size_t boff,
    float* __restrict__ C, const int* __restrict__ flag,
    int M, int N, int K, int flags, ush* __restrict__ aux)
{
    __shared__ __align__(16) ush As[64*72];
    __shared__ __align__(16) ush Ws[64*72];
    const int isbf = *flag;
    const int t = threadIdx.x;
    const int m0 = blockIdx.y*64, n0 = blockIdx.x*64;
    const int wave = t>>6, lane = t&63;
    const int quad = lane>>4, l15 = lane&15;
    const int r = t>>3, kq = (t&7)*8;      // rows r and r+32, 8 K-elems at kq
    const bool abf = flags & 32;

    frag_cd acc[4];
    #pragma unroll
    for (int tl=0; tl<4; ++tl)
        #pragma unroll
        for (int j=0;j<4;++j) acc[tl][j] = 0.f;

    const float* ap0 = A + (size_t)(m0+r)*K + kq;
    const float* ap1 = A + (size_t)(m0+r+32)*K + kq;
    const ush*   ab0 = (const ush*)A + (size_t)(m0+r)*K + kq;
    const ush*   ab1 = (const ush*)A + (size_t)(m0+r+32)*K + kq;
    const ush*   wp0 = WT + (size_t)(n0+r)*K + kq;
    const ush*   wp1 = WT + (size_t)(n0+r+32)*K + kq;

    float4 a00,a01,a10,a11; uint4 av0,av1, wv0,wv1;
    auto loadT = [&](int kk){
        if (abf) { av0 = *(const uint4*)(ab0+kk); av1 = *(const uint4*)(ab1+kk); }
        else { a00 = *(const float4*)(ap0+kk); a01 = *(const float4*)(ap0+kk+4);
               a10 = *(const float4*)(ap1+kk); a11 = *(const float4*)(ap1+kk+4); }
        wv0 = *(const uint4*)(wp0+kk); wv1 = *(const uint4*)(wp1+kk);
    };
    loadT(0);

    for (int kk = 0; kk < K; kk += 64) {
        if (abf) {
            *(uint4*)&As[r*72 + kq]        = av0;
            *(uint4*)&As[(r+32)*72 + kq]   = av1;
        } else {
            *(ushort4*)&As[r*72 + kq]       = make_ushort4(f2b(a00.x),f2b(a00.y),f2b(a00.z),f2b(a00.w));
            *(ushort4*)&As[r*72 + kq + 4]   = make_ushort4(f2b(a01.x),f2b(a01.y),f2b(a01.z),f2b(a01.w));
            *(ushort4*)&As[(r+32)*72 + kq]     = make_ushort4(f2b(a10.x),f2b(a10.y),f2b(a10.z),f2b(a10.w));
            *(ushort4*)&As[(r+32)*72 + kq + 4] = make_ushort4(f2b(a11.x),f2b(a11.y),f2b(a11.z),f2b(a11.w));
        }
        *(uint4*)&Ws[r*72 + kq]      = wv0;
        *(uint4*)&Ws[(r+32)*72 + kq] = wv1;
        __syncthreads();
        if (kk + 64 < K) loadT(kk + 64);
        frag_ab af0 = *(const frag_ab*)&As[(wave*16 + l15)*72 + quad*8];
        frag_ab af1 = *(const frag_ab*)&As[(wave*16 + l15)*72 + 32 + quad*8];
        #pragma unroll
        for (int tl = 0; tl < 4; ++tl) {
            frag_ab bf0 = *(const frag_ab*)&Ws[(tl*16 + l15)*72 + quad*8];
            acc[tl] = __builtin_amdgcn_mfma_f32_16x16x32_bf16(af0, bf0, acc[tl], 0, 0, 0);
            frag_ab bf1 = *(const frag_ab*)&Ws[(tl*16 + l15)*72 + 32 + quad*8];
            acc[tl] = __builtin_amdgcn_mfma_f32_16x16x32_bf16(af1, bf1, acc[tl], 0, 0, 0);
        }
        __syncthreads();
    }
    const bool do_relu = flags & 2;
    const bool has_b   = flags & 4;
    const bool obf     = flags & 8;
    #pragma unroll
    for (int tl = 0; tl < 4; ++tl) {
        int col = n0 + tl*16 + l15;
        float bv = 0.f;
        if (has_b) bv = (flags & 16) ? ((const float*)bias)[boff + col]
                                     : ldf(bias, boff + col, isbf);
        #pragma unroll
        for (int rg = 0; rg < 4; ++rg) {
            int row = m0 + wave*16 + quad*4 + rg;
            float v = acc[tl][rg] + bv;
            if (do_relu) v = fmaxf(v, 0.f);
            if (flags & 64) {
                if (col < 256) C[(size_t)row*256 + col] = v;
                else           aux[(size_t)row*kKV + (col - 256)] = f2b(v);
            } else if (obf) ((ush*)C)[(size_t)row*N + col] = f2b(v);
            else            C[(size_t)row*N + col] = v;
        }
    }
}

// ---------------- LayerNorm (node rows, D=256): out = LN(a + b), dual f32+bf16 ----------------
__global__ __launch_bounds__(64) void ln_k(
    const float* __restrict__ a, const float* __restrict__ b,
    const void* __restrict__ g, const void* __restrict__ be, size_t goff,
    float* __restrict__ out, ush* __restrict__ outb,
    const int* __restrict__ flag, int D)
{
    const int isbf = *flag;
    const int row = blockIdx.x;
    const int t = threadIdx.x;
    float v[4];
    int cnt = 0;
    float s = 0.f;
    for (int i = t; i < D; i += 64) {
        float x = a[(size_t)row*D + i];
        if (b) x += b[(size_t)row*D + i];
        v[cnt++] = x; s += x;
    }
    #pragma unroll
    for (int off = 32; off > 0; off >>= 1) s += __shfl_down(s, off);
    s = __shfl(s, 0);
    const float mean = s / D;
    float qq = 0.f;
    for (int c2 = 0; c2 < cnt; ++c2) { float d = v[c2]-mean; qq += d*d; }
    #pragma unroll
    for (int off = 32; off > 0; off >>= 1) qq += __shfl_down(qq, off);
    qq = __shfl(qq, 0);
    const float inv = rsqrtf(fmaxf(qq, 0.f) / D + 1e-5f);
    cnt = 0;
    for (int i = t; i < D; i += 64) {
        float r = (v[cnt++] - mean)*inv*ldf(g, goff + i, isbf) + ldf(be, goff + i, isbf);
        out[(size_t)row*D + i] = r;
        outb[(size_t)row*D + i] = f2b(r);
    }
}

// ---------------- MFMA eq/ek/ev (+gathered mixed), 128 rows/block, bf16 in/out ----------------
// kv: kvaux [4096][kKV] bf16; xs at cols 512-543, xd at 544-575
__global__ __launch_bounds__(256) void eqkv_mfma_k(
    const ush* __restrict__ lg, const ush* __restrict__ kv,
    const int* __restrict__ gsrc, const int* __restrict__ gdst,
    const ush* __restrict__ WQKV, size_t woff,
    const void* __restrict__ bq, size_t boff,
    ush* __restrict__ eq, ush* __restrict__ ek, ush* __restrict__ ev,
    const int* __restrict__ flag)
{
    __shared__ __align__(16) ush mixs[128*40];
    __shared__ __align__(16) ush wts[3][32*40];
    __shared__ float bqs[32];
    const int isbf = *flag;
    const int t = threadIdx.x;
    const int e0 = blockIdx.x * 128;
    #pragma unroll
    for (int i = t; i < 768; i += 256) {
        int m = i >> 8, r2 = i & 255;
        int n = r2 >> 3, k4 = (r2 & 7) * 4;
        *(ushort4*)&wts[m][n*40 + k4] =
            *(const ushort4*)&WQKV[(size_t)m*2048 + woff + (size_t)n*32 + k4];
    }
    if (t < 32) bqs[t] = ldf(bq, boff + t, isbf);
    {
        int r = t >> 1, c0 = (t & 1) * 16;
        int e = e0 + r;
        int s = gsrc[e], d2 = gdst[e];
        const ush* lp = lg + (size_t)e*32 + c0;
        const ush* sp = kv + (size_t)s*kKV + 512 + c0;
        const ush* dp = kv + (size_t)d2*kKV + 544 + c0;
        #pragma unroll
        for (int j = 0; j < 16; ++j)
            mixs[r*40 + c0 + j] = f2b(b2f(lp[j]) + b2f(sp[j]) + b2f(dp[j]));
    }
    __syncthreads();
    const int wave = t >> 6, l15 = t & 15, quad = (t >> 4) & 3;
    #pragma unroll
    for (int mi = 0; mi < 2; ++mi) {
        const int mt = wave*2 + mi;
        frag_ab af = *(const frag_ab*)&mixs[(mt*16 + l15)*40 + quad*8];
        #pragma unroll
        for (int w = 0; w < 3; ++w) {
            ush* outp = (w==0) ? eq : ((w==1) ? ek : ev);
            #pragma unroll
            for (int nt = 0; nt < 2; ++nt) {
                frag_ab bf = *(const frag_ab*)&wts[w][(nt*16 + l15)*40 + quad*8];
                frag_cd acc = {0.f, 0.f, 0.f, 0.f};
                acc = __builtin_amdgcn_mfma_f32_16x16x32_bf16(af, bf, acc, 0, 0, 0);
                const float bv = (w==0) ? bqs[nt*16 + l15] : 0.f;
                #pragma unroll
                for (int rg = 0; rg < 4; ++rg) {
                    int row = e0 + mt*16 + quad*4 + rg;
                    outp[(size_t)row*32 + nt*16 + l15] = f2b(acc[rg] + bv);
                }
            }
        }
    }
}

// ---------------- MFMA edge FFN: LN(A + relu(A@W1+b1)@W2 + b2); bf16 A / bf16 out ----------------
__global__ __launch_bounds__(256) void effn_mfma_k(
    const ush* __restrict__ A,
    const ush* __restrict__ W1T, size_t w1off, const void* __restrict__ b1, size_t b1off,
    const ush* __restrict__ W2T, size_t w2off, const void* __restrict__ b2, size_t b2off,
    const void* __restrict__ g, const void* __restrict__ be, size_t goff,
    ush* __restrict__ out, const int* __restrict__ flag)
{
    __shared__ __align__(16) ush w1t[128*40];
    __shared__ __align__(16) ush w2t[32*136];
    __shared__ __align__(16) ush hid[64*136];
    __shared__ float b1s[128], b2s[32];
    const int isbf = *flag;
    const int t = threadIdx.x;
    const int wave = t >> 6, l15 = t & 15, quad = (t >> 4) & 3;

    #pragma unroll
    for (int i = t; i < 1024; i += 256) {
        int n1 = i >> 3, k4 = (i & 7) * 4;
        *(ushort4*)&w1t[n1*40 + k4] = *(const ushort4*)&W1T[w1off + (size_t)n1*32 + k4];
        int n2 = i >> 5, kq2 = (i & 31) * 4;
        *(ushort4*)&w2t[n2*136 + kq2] = *(const ushort4*)&W2T[w2off + (size_t)n2*128 + kq2];
    }
    if (t < 128) b1s[t] = ldf(b1, b1off + t, isbf);
    if (t < 32)  b2s[t] = ldf(b2, b2off + t, isbf);
    __syncthreads();

    const float g0  = ldf(g,  goff + l15, isbf),      g1v = ldf(g,  goff + 16 + l15, isbf);
    const float be0 = ldf(be, goff + l15, isbf),      be1 = ldf(be, goff + 16 + l15, isbf);
    const float bb0 = b2s[l15], bb1 = b2s[16 + l15];

    for (int tt = 0; tt < 2; ++tt) {
        const int e0 = (blockIdx.x*2 + tt) * 64;
        {
            const int m = wave*16 + l15;
            frag_ab af = *(const frag_ab*)&A[(size_t)(e0+m)*32 + quad*8];
            #pragma unroll
            for (int nt = 0; nt < 8; ++nt) {
                frag_ab bf = *(const frag_ab*)&w1t[(nt*16 + l15)*40 + quad*8];
                frag_cd acc = {0.f, 0.f, 0.f, 0.f};
                acc = __builtin_amdgcn_mfma_f32_16x16x32_bf16(af, bf, acc, 0, 0, 0);
                float bv = b1s[nt*16 + l15];
                #pragma unroll
                for (int rg = 0; rg < 4; ++rg) {
                    int row = wave*16 + quad*4 + rg;
                    hid[row*136 + nt*16 + l15] = f2b(fmaxf(acc[rg] + bv, 0.f));
                }
            }
        }
        // hid rows are wave-private -> no barrier needed
        frag_cd acc2[2] = {{0.f,0.f,0.f,0.f},{0.f,0.f,0.f,0.f}};
        #pragma unroll
        for (int ks = 0; ks < 4; ++ks) {
            frag_ab af2 = *(const frag_ab*)&hid[(wave*16 + l15)*136 + ks*32 + quad*8];
            #pragma unroll
            for (int tl = 0; tl < 2; ++tl) {
                frag_ab bf2 = *(const frag_ab*)&w2t[(tl*16 + l15)*136 + ks*32 + quad*8];
                acc2[tl] = __builtin_amdgcn_mfma_f32_16x16x32_bf16(af2, bf2, acc2[tl], 0, 0, 0);
            }
        }
        #pragma unroll
        for (int rg = 0; rg < 4; ++rg) {
            const int row = e0 + wave*16 + quad*4 + rg;
            float v0 = acc2[0][rg] + bb0 + b2f(A[(size_t)row*32 + l15]);
            float v1 = acc2[1][rg] + bb1 + b2f(A[(size_t)row*32 + 16 + l15]);
            float s = v0 + v1;
            s += __shfl_xor(s,1); s += __shfl_xor(s,2); s += __shfl_xor(s,4); s += __shfl_xor(s,8);
            const float mean = s * (1.f/32.f);
            float q = (v0-mean)*(v0-mean) + (v1-mean)*(v1-mean);
            q += __shfl_xor(q,1); q += __shfl_xor(q,2); q += __shfl_xor(q,4); q += __shfl_xor(q,8);
            const float inv = rsqrtf(q * (1.f/32.f) + 1e-5f);
            out[(size_t)row*32 + l15]      = f2b((v0-mean)*inv*g0  + be0);
            out[(size_t)row*32 + 16 + l15] = f2b((v1-mean)*inv*g1v + be1);
        }
    }
}

// ---------------- full-graph attention: (b,h,quarter) blocks, 512 grid ----------------
// q: fp32 [4096][256]; kv: bf16 [4096][kKV] (K 0-255, V 256-511)
__global__ __launch_bounds__(512) void full_attn_k(
    const float* __restrict__ q, const ush* __restrict__ kv,
    const void* __restrict__ rel, const int* __restrict__ feat, ush* __restrict__ o,
    const int* __restrict__ flag)
{
    __shared__ __align__(8) ush ks[128][36];
    __shared__ __align__(8) ush vs[128][36];
    __shared__ __align__(8) ush rs[128][36];
    __shared__ float pb[8][32][34];            // per-wave partials: m, l, acc[32]
    const int isbf = *flag;
    const int bid = blockIdx.x;
    const int b = bid >> 4, h = (bid >> 2) & 3, qtr = bid & 3;
    const int t = threadIdx.x;
    for (int i = t; i < 4096; i += 512) {
        int r = i >> 5, d = i & 31;
        rs[r][d] = ldb(rel, i, isbf);
        const ush* kvrow = kv + (size_t)(b*128 + r)*kKV + h*32 + d;
        ks[r][d] = kvrow[0];
        vs[r][d] = kvrow[256];
    }
    __syncthreads();
    const int wave = t >> 6, lane = t & 63;
    const int dstL = lane >> 1, part = lane & 1;   // 2 lanes per dst
    const int dst = qtr*32 + dstL;
    const int dbase = part*16;                     // this lane's 16 dims
    float qr[16];
    { size_t base = ((size_t)(b*128 + dst))*256 + h*32 + dbase;
      #pragma unroll
      for (int d=0; d<16; ++d) qr[d] = q[base + d]; }
    const int* fp = feat + (size_t)b*16384 + dst;
    const int s0 = wave*16;
    float m = -1e30f, l = 0.f;
    float acc[16];
    #pragma unroll
    for (int d=0; d<16; ++d) acc[d] = 0.f;
    int f = fp[s0*128];
    for (int sI = 0; sI < 16; ++sI) {
        const int s = s0 + sI;
        int fn = (sI+1 < 16) ? fp[(s+1)*128] : 0;
        float er[16];
        float scp = 0.f;
        #pragma unroll
        for (int j2 = 0; j2 < 4; ++j2) {
            ushort4 eu = *(const ushort4*)&rs[f][dbase + j2*4];
            ushort4 ku = *(const ushort4*)&ks[s][dbase + j2*4];
            float e0 = b2f(eu.x), e1 = b2f(eu.y), e2 = b2f(eu.z), e3 = b2f(eu.w);
            er[j2*4+0]=e0; er[j2*4+1]=e1; er[j2*4+2]=e2; er[j2*4+3]=e3;
            scp += (b2f(ku.x)+e0)*qr[j2*4+0] + (b2f(ku.y)+e1)*qr[j2*4+1]
                 + (b2f(ku.z)+e2)*qr[j2*4+2] + (b2f(ku.w)+e3)*qr[j2*4+3];
        }
        const float sc = (scp + __shfl_xor(scp, 1)) * kScaleN;
        float mn = fmaxf(m, sc);
        float c0 = __expf(m - mn);
        float pp = __expf(sc - mn);
        l = l*c0 + pp;
        #pragma unroll
        for (int j2 = 0; j2 < 4; ++j2) {
            ushort4 vu = *(const ushort4*)&vs[s][dbase + j2*4];
            acc[j2*4+0] = acc[j2*4+0]*c0 + pp*(b2f(vu.x)+er[j2*4+0]);
            acc[j2*4+1] = acc[j2*4+1]*c0 + pp*(b2f(vu.y)+er[j2*4+1]);
            acc[j2*4+2] = acc[j2*4+2]*c0 + pp*(b2f(vu.z)+er[j2*4+2]);
            acc[j2*4+3] = acc[j2*4+3]*c0 + pp*(b2f(vu.w)+er[j2*4+3]);
        }
        m = mn; f = fn;
    }
    if (part == 0) { pb[wave][dstL][0] = m; pb[wave][dstL][1] = l; }
    #pragma unroll
    for (int d=0; d<16; ++d) pb[wave][dstL][2 + dbase + d] = acc[d];
    __syncthreads();
    // merge: thread (dstL2, grp) handles dims [grp*2, grp*2+2) of dst=qtr*32+dstL2
    {
        const int dstL2 = t & 31, grp = t >> 5;   // grp in [0,16)
        float mw[8], lw[8];
        #pragma unroll
        for (int w=0; w<8; ++w){ mw[w]=pb[w][dstL2][0]; lw[w]=pb[w][dstL2][1]; }
        float M = mw[0];
        #pragma unroll
        for (int w=1; w<8; ++w) M = fmaxf(M, mw[w]);
        float sw[8];
        float L = 0.f;
        #pragma unroll
        for (int w=0; w<8; ++w){ sw[w] = __expf(mw[w]-M); L += lw[w]*sw[w]; }
        const float inv = 1.f / fmaxf(L, 1e-30f);
        size_t base = ((size_t)(b*128 + qtr*32 + dstL2))*kND + h*32 + grp*2;
        #pragma unroll
        for (int d=0; d<2; ++d) {
            float a = 0.f;
            #pragma unroll
            for (int w=0; w<8; ++w) a += pb[w][dstL2][2+grp*2+d]*sw[w];
            o[base + d] = f2b(a*inv);
        }
    }
}

// ---------------- local-graph GATHER attention (heads 4..7), bf16 kvaux ----------------
// kv: [4096][kKV] bf16: local K at 128+h*32, local V at 384+h*32
__global__ __launch_bounds__(256) void loc_gather_k(
    const float* __restrict__ q, const ush* __restrict__ kv,
    const ush* __restrict__ lg, const int* __restrict__ gsrc,
    const int* __restrict__ rowp, const int* __restrict__ eidl,
    ush* __restrict__ o)
{
    const int n = blockIdx.x;
    const int h = threadIdx.x >> 6;
    const int lane = threadIdx.x & 63;
    const int g = lane >> 4;
    const int d0 = (lane & 15) * 2;
    const size_t hoff = (size_t)(4 + h) * 32 + d0;
    const float2 q2 = *(const float2*)&q[(size_t)n*256 + hoff];
    const int beg = rowp[n], end = rowp[n+1];
    const int deg = end - beg;
    float m = -1e30f, l = 0.f, ax = 0.f, ay = 0.f;
    if (deg > 0) {
        const int nIter = (deg + 3) >> 2;
        int idx = beg + g;
        int ce = eidl[min(idx, end-1)];
        int cs = gsrc[ce];
        for (int it = 0; it < nIter; ++it) {
            const bool valid = idx < end;
            const int e = ce, s = cs;
            idx += 4;
            if (it + 1 < nIter) { ce = eidl[min(idx, end-1)]; cs = gsrc[ce]; }
            const ushort2 ku = *(const ushort2*)&kv[(size_t)s*kKV + 128 + h*32 + d0];
            const ushort2 lvu = *(const ushort2*)&lg[(size_t)e*32 + d0];
            const ushort2 vu = *(const ushort2*)&kv[(size_t)s*kKV + 384 + h*32 + d0];
            const float lvx = b2f(lvu.x), lvy = b2f(lvu.y);
            float part = (b2f(ku.x)+lvx)*q2.x + (b2f(ku.y)+lvy)*q2.y;
            part += __shfl_xor(part, 1);
            part += __shfl_xor(part, 2);
            part += __shfl_xor(part, 4);
            part += __shfl_xor(part, 8);
            const float sc = part * kScaleN;
            const float mn = valid ? fmaxf(m, sc) : m;
            const float c  = __expf(m - mn);
            const float pp = valid ? __expf(sc - mn) : 0.f;
            l  = l*c  + pp;
            ax = ax*c + pp*(b2f(vu.x)+lvx);
            ay = ay*c + pp*(b2f(vu.y)+lvy);
            m  = mn;
        }
        #pragma unroll
        for (int off = 16; off <= 32; off <<= 1) {
            const float mo = __shfl_xor(m, off);
            const float lo = __shfl_xor(l, off);
            const float xo = __shfl_xor(ax, off);
            const float yo = __shfl_xor(ay, off);
            const float M  = fmaxf(m, mo);
            const float c1 = __expf(m - M);
            const float c2 = __expf(mo - M);
            l  = l*c1  + lo*c2;
            ax = ax*c1 + xo*c2;
            ay = ay*c1 + yo*c2;
            m  = M;
        }
    }
    if (g == 0) {
        const float inv = 1.f / fmaxf(l, 1e-30f);
        *(ushort2*)&o[(size_t)n*kND + hoff] = make_ushort2(f2b(ax*inv), f2b(ay*inv));
    }
}

// ---------------- fused line-graph attention + Wo GEMM + LN (bf16 in/out) ----------------
__global__ __launch_bounds__(256) void lgs_ewo_k(
    const ush* __restrict__ eq, const ush* __restrict__ ek, const ush* __restrict__ ev,
    const int* __restrict__ lsrc, const int* __restrict__ rowp, const int* __restrict__ eidl,
    const ush* __restrict__ res,
    const ush* __restrict__ WO, size_t wooff, const void* __restrict__ bo, size_t booff,
    const void* __restrict__ g1, const void* __restrict__ be1, size_t g1off,
    ush* __restrict__ out, const int* __restrict__ flag)
{
    __shared__ __align__(16) ush ows[32*40];
    __shared__ __align__(16) ush wos[32*40];
    __shared__ float cs[32][36];
    __shared__ float bos[32], gs[32], bs[32];
    const int isbf = *flag;
    const int t = threadIdx.x;
    const int base = blockIdx.x * 32;
    {
        int n = t >> 3, k4 = (t & 7) * 4;
        *(ushort4*)&wos[n*40 + k4] = *(const ushort4*)&WO[wooff + (size_t)n*32 + k4];
    }
    if (t < 32) {
        bos[t] = ldf(bo, booff + t, isbf);
        gs[t]  = ldf(g1, g1off + t, isbf);
        bs[t]  = ldf(be1, g1off + t, isbf);
    }
    // ---- phase 1: gather attention, thread = (dst-edge, head) ----
    {
        const int d2 = base + (t >> 3), h = t & 7;
        const ushort4 qu = *(const ushort4*)&eq[(size_t)d2*32 + h*4];
        const float q0 = b2f(qu.x), q1 = b2f(qu.y), q2 = b2f(qu.z), q3 = b2f(qu.w);
        const int beg = rowp[d2], end = rowp[d2+1];
        float m = -1e30f, l = 0.f;
        float4 acc = make_float4(0.f,0.f,0.f,0.f);
        int i = beg;
        int s = 0;
        if (i < end) { s = lsrc[eidl[i]]; }
        while (i < end) {
            const int sc_s = s;
            ++i;
            if (i < end) { s = lsrc[eidl[i]]; }      // prefetch next src
            const ushort4 ku = *(const ushort4*)&ek[(size_t)sc_s*32 + h*4];
            const ushort4 vu = *(const ushort4*)&ev[(size_t)sc_s*32 + h*4];
            float sc = (b2f(ku.x)*q0 + b2f(ku.y)*q1 + b2f(ku.z)*q2 + b2f(ku.w)*q3) * 0.5f;
            float mn = fmaxf(m, sc);
            float c = __expf(m - mn);
            float pp = __expf(sc - mn);
            l = l*c + pp;
            acc.x = acc.x*c + pp*b2f(vu.x);
            acc.y = acc.y*c + pp*b2f(vu.y);
            acc.z = acc.z*c + pp*b2f(vu.z);
            acc.w = acc.w*c + pp*b2f(vu.w);
            m = mn;
        }
        const float inv = 1.f / fmaxf(l, 1e-30f);
        const int r = t >> 3, c0 = h*4;
        ows[r*40 + c0 + 0] = f2b(acc.x*inv);
        ows[r*40 + c0 + 1] = f2b(acc.y*inv);
        ows[r*40 + c0 + 2] = f2b(acc.z*inv);
        ows[r*40 + c0 + 3] = f2b(acc.w*inv);
    }
    __syncthreads();
    // ---- phase 2: 32x32 GEMM ----
    {
        const int wave = t >> 6, l15 = t & 15, quad = (t >> 4) & 3;
        const int mt = wave & 1, nt = wave >> 1;
        frag_ab af = *(const frag_ab*)&ows[(mt*16 + l15)*40 + quad*8];
        frag_ab bf = *(const frag_ab*)&wos[(nt*16 + l15)*40 + quad*8];
        frag_cd acc = {0.f, 0.f, 0.f, 0.f};
        acc = __builtin_amdgcn_mfma_f32_16x16x32_bf16(af, bf, acc, 0, 0, 0);
        #pragma unroll
        for (int rg = 0; rg < 4; ++rg) {
            const int row = mt*16 + quad*4 + rg;
            const int col = nt*16 + l15;
            cs[row][col] = acc[rg] + bos[col] + b2f(res[(size_t)(base+row)*32 + col]);
        }
    }
    __syncthreads();
    // ---- phase 3: LN per row ----
    {
        const int row = t >> 3, c0 = (t & 7) * 4;
        const float v0 = cs[row][c0], v1 = cs[row][c0+1];
        const float v2 = cs[row][c0+2], v3 = cs[row][c0+3];
        float s = v0+v1+v2+v3;
        s += __shfl_xor(s,1); s += __shfl_xor(s,2); s += __shfl_xor(s,4);
        const float mean = s * (1.f/32.f);
        float qq = (v0-mean)*(v0-mean)+(v1-mean)*(v1-mean)
                 + (v2-mean)*(v2-mean)+(v3-mean)*(v3-mean);
        qq += __shfl_xor(qq,1); qq += __shfl_xor(qq,2); qq += __shfl_xor(qq,4);
        const float inv = rsqrtf(qq * (1.f/32.f) + 1e-5f);
        out[(size_t)(base+row)*32 + c0 + 0] = f2b((v0-mean)*inv*gs[c0+0] + bs[c0+0]);
        out[(size_t)(base+row)*32 + c0 + 1] = f2b((v1-mean)*inv*gs[c0+1] + bs[c0+1]);
        out[(size_t)(base+row)*32 + c0 + 2] = f2b((v2-mean)*inv*gs[c0+2] + bs[c0+2]);
        out[(size_t)(base+row)*32 + c0 + 3] = f2b((v3-mean)*inv*gs[c0+3] + bs[c0+3]);
    }
}

// ---------------- output ----------------
__global__ void out_k(const float* __restrict__ xf, const ush* __restrict__ lgf,
                      void* __restrict__ out, const int* __restrict__ flag){
    const int isbf = *flag;
    int g = blockIdx.x*256 + threadIdx.x;
    if (g < kN*kND) {
        float v = xf[g];
        if (isbf) ((ush*)out)[g] = f2b(v);
        else      ((float*)out)[g] = v;
    } else {
        ush u = lgf[g - kN*kND];
        if (isbf) ((ush*)out)[g] = u;
        else      ((float*)out)[g] = b2f(u);
    }
}

// ---------------- host helper ----------------
static inline void mgemm(const float* A, const ush* WT, const void* bias, size_t boff,
                         float* C, const int* flag, int M, int N, int K, int flags,
                         hipStream_t s, ush* aux){
    dim3 grid((N+63)/64, M/64);
    mgemm_k<<<grid, 256, 0, s>>>(A, WT, bias, boff, C, flag, M, N, K, flags, aux);
}

extern "C" void kernel_launch(void* const* d_in, const int* in_sizes, int n_in,
                              void* d_out, int out_size, void* d_ws, size_t ws_size,
                              hipStream_t stream) {
    const void* x_in      = d_in[0];
    const void* rel       = d_in[1];
    const int* g_src      = (const int*)d_in[4];
    const int* g_dst      = (const int*)d_in[5];
    const int* lg_src     = (const int*)d_in[6];
    const int* lg_dst     = (const int*)d_in[7];
    const int* edge_feat  = (const int*)d_in[8];
    const int* full_feat  = (const int*)d_in[9];
    const void* n_Wq   = d_in[10];
    const void* n_bq   = d_in[11];
    const void* n_Wk   = d_in[12];
    const void* n_bk   = d_in[13];
    const void* n_Wv   = d_in[14];
    const void* n_bv   = d_in[15];
    const void* n_Wo   = d_in[16];
    const void* n_bo   = d_in[17];
    const void* n_lng  = d_in[18];
    const void* n_lnb  = d_in[19];
    const void* n_fW1  = d_in[20];
    const void* n_fb1  = d_in[21];
    const void* n_fW2  = d_in[22];
    const void* n_fb2  = d_in[23];
    const void* n_flng = d_in[24];
    const void* n_flnb = d_in[25];
    const void* e_Wsrc = d_in[26];
    const void* e_Wdst = d_in[27];
    const void* e_Wq   = d_in[28];
    const void* e_bq   = d_in[29];
    const void* e_Wk   = d_in[30];
    const void* e_Wv   = d_in[31];
    const void* e_Wo   = d_in[32];
    const void* e_bo   = d_in[33];
    const void* e_lng  = d_in[34];
    const void* e_lnb  = d_in[35];
    const void* e_fW1  = d_in[36];
    const void* e_fb1  = d_in[37];
    const void* e_fW2  = d_in[38];
    const void* e_fb2  = d_in[39];
    const void* e_flng = d_in[40];
    const void* e_flnb = d_in[41];

    // ---- workspace carve-up (units: floats) ----
    float* p = (float*)d_ws;
    size_t off = 0;
    auto AL = [&](size_t n){ float* r = p + off; off += n; return r; };
    int* flagp = (int*)AL(64);
    float* xA   = AL((size_t)kN*kND);
    float* xB   = AL((size_t)kN*kND);
    float* xM   = AL((size_t)kN*kND);
    ush*   xAb  = (ush*)AL((size_t)kN*kND/2);
    ush*   xBb  = (ush*)AL((size_t)kN*kND/2);
    ush*   xMb  = (ush*)AL((size_t)kN*kND/2);
    float* qkvb = AL((size_t)kN*kND);            // fp32 Q only, [4096][256]
    ush*   kvaux= (ush*)AL((size_t)kN*kKV/2);    // bf16 [4096][576]: K,V,SD
    ush*   ob   = (ush*)AL((size_t)kN*kND/2);
    float* tN   = AL((size_t)kN*kND);
    ush*   nh   = (ush*)AL((size_t)kN*512);      // kN*1024 bf16
    ush*   lgA  = (ush*)AL((size_t)kEL*kED/2);   // bf16 edge residual chain
    ush*   lgB  = (ush*)AL((size_t)kEL*kED/2);
    ush*   lgM  = (ush*)AL((size_t)kEL*kED/2);
    ush*   eqb  = (ush*)AL((size_t)kEL*16);      // kEL*32 bf16
    ush*   ekb  = (ush*)AL((size_t)kEL*16);
    ush*   evb  = (ush*)AL((size_t)kEL*16);
    // CSR structures
    int* cntL  = (int*)AL(kN);
    int* rowL  = (int*)AL(kN + 64);
    int* curL  = (int*)AL(kN);
    int* eidL  = (int*)AL(kEL);
    int* cntG  = (int*)AL(kEL);
    int* rowG  = (int*)AL(kEL + 64);
    int* curG  = (int*)AL(kEL);
    int* eidG  = (int*)AL(kELG);
    int* bsum  = (int*)AL(256);
    // pre-transposed bf16 weights
    ush* wtQKVSD = (ush*)AL(212992);   // [L][832][256] bf16 (425984 ush)
    float* bQKV  = AL(2*kQW);
    ush* wtO  = (ush*)AL(65536);
    ush* wtF1 = (ush*)AL(262144);
    ush* wtF2 = (ush*)AL(262144);
    ush* wtEQKV = (ush*)AL(3072);
    ush* wtEO   = (ush*)AL(1024);
    ush* wtEF1  = (ush*)AL(4096);
    ush* wtEF2  = (ush*)AL(4096);
    if (ws_size < off * sizeof(float)) return;

    detect_k<<<1, 64, 0, stream>>>((const ush*)x_in, flagp);
    {
        long total = (long)kN*kND + (long)kEL*kED + 2*kQW + kN + kEL;
        int blocks = (int)((total + 255) / 256);
        setup_misc_k<<<blocks, 256, 0, stream>>>(x_in, rel, edge_feat, n_bq, n_bk, n_bv,
                                                 xA, xAb, lgA, bQKV, cntL, cntG, flagp);
    }
    trans_all_k<<<6368, 256, 0, stream>>>(n_Wq, n_Wk, n_Wv, n_Wo, n_fW1, n_fW2,
                                          e_Wsrc, e_Wdst, e_Wq, e_Wk, e_Wv, e_Wo,
                                          e_fW1, e_fW2, flagp,
                                          wtQKVSD, wtO, wtF1, wtF2,
                                          wtEQKV, wtEO, wtEF1, wtEF2);

    count2_k<<<(kEL+kELG)/256, 256, 0, stream>>>(g_dst, lg_dst, cntL, cntG);
    scan_blk2_k<<<132, 256, 0, stream>>>(cntL, cntG, rowL, rowG, bsum);
    scan_top2_k<<<1, 256, 0, stream>>>(bsum);
    scan_add2_k<<<(kN+kEL)/256, 256, 0, stream>>>(rowL, rowG, bsum, curL, curG);
    fill2_k<<<(kEL+kELG)/256, 256, 0, stream>>>(g_dst, lg_dst, curL, curG, eidL, eidG);

    float* xc = xA;  float* xn = xB;
    ush* xcb = xAb;  ush* xnb = xBb;
    ush* lgc = lgA;  ush* lgn = lgB;

    for (int i = 0; i < kL; ++i) {
        const size_t o256 = (size_t)i*kND;
        const size_t o1024= (size_t)i*1024;
        const size_t o32  = (size_t)i*kED;
        const size_t o128 = (size_t)i*128;

        // ===== node update (fp32 Q + bf16 K/V/SD side-output) =====
        mgemm((const float*)xcb, wtQKVSD + (size_t)i*212992, bQKV, (size_t)i*kQW, qkvb,
              flagp, kN, kQW, kND, 4|16|32|64, stream, kvaux);
        full_attn_k<<<512, 512, 0, stream>>>(qkvb, kvaux, rel, full_feat, ob, flagp);
        loc_gather_k<<<kN, 256, 0, stream>>>(qkvb, kvaux, lgc, g_src, rowL, eidL, ob);
        mgemm((const float*)ob, wtO + (size_t)i*65536, n_bo, o256, tN, flagp,
              kN, kND, kND, 4|32, stream, nullptr);
        ln_k<<<kN, 64, 0, stream>>>(xc, tN, n_lng, n_lnb, o256, xM, xMb, flagp, kND);
        mgemm((const float*)xMb, wtF1 + (size_t)i*262144, n_fb1, o1024, (float*)nh, flagp,
              kN, 1024, kND, 4|2|8|32, stream, nullptr);
        mgemm((const float*)nh, wtF2 + (size_t)i*262144, n_fb2, o256, tN, flagp,
              kN, kND, 1024, 4|32, stream, nullptr);
        ln_k<<<kN, 64, 0, stream>>>(xM, tN, n_flng, n_flnb, o256, xn, xnb, flagp, kND);

        // ===== edge update (uses PRE-update xc, lgc) =====
        eqkv_mfma_k<<<kEL/128, 256, 0, stream>>>(lgc, kvaux, g_src, g_dst,
                                                 wtEQKV, (size_t)i*1024, e_bq, o32,
                                                 eqb, ekb, evb, flagp);
        lgs_ewo_k<<<kEL/32, 256, 0, stream>>>(eqb, ekb, evb, lg_src, rowG, eidG,
                                              lgc, wtEO, (size_t)i*1024, e_bo, o32,
                                              e_lng, e_lnb, o32, lgM, flagp);
        effn_mfma_k<<<kEL/128, 256, 0, stream>>>(lgM, wtEF1, (size_t)i*4096, e_fb1, o128,
                                                 wtEF2, (size_t)i*4096, e_fb2, o32,
                                                 e_flng, e_flnb, o32, lgn, flagp);

        { float* t = xc; xc = xn; xn = t; }
        { ush* t = xcb; xcb = xnb; xnb = t; }
        { ush* t = lgc; lgc = lgn; lgn = t; }
    }

    out_k<<<(kN*kND + kEL*kED)/256, 256, 0, stream>>>(xc, lgc, d_out, flagp);
}